// Round 1
// baseline (1633.910 us; speedup 1.0000x reference)
//
#include <hip/hip_runtime.h>
#include <hip/hip_bf16.h>

using bf16 = __hip_bfloat16;
using bf16x8 = __attribute__((ext_vector_type(8))) short;  // 8 bf16 (4 VGPRs)
using f32x4 = __attribute__((ext_vector_type(4))) float;

#define B_ 2
#define T_ 2048
#define C_ 1024
#define BT_ (B_*T_)
#define H_ 16
#define N_ 64

__device__ __forceinline__ float allred64(float v) {
#pragma unroll
  for (int m = 1; m < 64; m <<= 1) v += __shfl_xor(v, m, 64);
  return v;
}

__device__ __forceinline__ bf16 tobf(float f) { return __float2bfloat16(f); }

__device__ __forceinline__ f32x4 mfma16x16x32(bf16x8 a, bf16x8 b, f32x4 c) {
  return __builtin_amdgcn_mfma_f32_16x16x32_bf16(a, b, c, 0, 0, 0);
}

// ---------------- weight transpose + bf16 cast (19 jobs, one launch) -------
struct PrepArgs {
  const float* src[19];
  bf16* dst[19];
};
__constant__ int kTR[19] = {1024,1024,1024,1024, 1024, 32,32,32,32,32,32,
                            1024,64, 1024,64, 1024,64, 1024,128};
__constant__ int kTC[19] = {1024,1024,1024,1024, 192, 1024,1024,1024,1024,1024,1024,
                            64,1024, 64,1024, 64,1024, 128,1024};

__global__ __launch_bounds__(256) void prep_weights(PrepArgs pa) {
  const int job = blockIdx.y;
  const int R = kTR[job], Cc = kTC[job];
  const int ntx = Cc >> 5, nty = R >> 5;
  const int tile = blockIdx.x;
  if (tile >= ntx * nty) return;
  const int tx = tile % ntx, ty = tile / ntx;
  const float* __restrict__ src = pa.src[job];
  bf16* __restrict__ dst = pa.dst[job];
  __shared__ float tl[32][33];
  const int lx = threadIdx.x & 31, ly = threadIdx.x >> 5;  // 32 x 8
#pragma unroll
  for (int q = 0; q < 4; ++q)
    tl[ly + 8*q][lx] = src[(size_t)(ty*32 + ly + 8*q) * Cc + tx*32 + lx];
  __syncthreads();
#pragma unroll
  for (int q = 0; q < 4; ++q)
    dst[(size_t)(tx*32 + ly + 8*q) * R + ty*32 + lx] = tobf(tl[lx][ly + 8*q]);
}

// ---------------- GEMM: C[M,N] = A[M,K](bf16) * Bt[N,K](bf16)^T ------------
// tile 64x64, BK=32, 4 waves; EPI: 0 = f32 raw, 1 = bf16 tanh, 2 = bf16 raw
template<int EPI>
__global__ __launch_bounds__(256) void gemm_bt(
    const bf16* __restrict__ A, int lda,
    const bf16* __restrict__ Bt, int ldb,
    void* __restrict__ Cout, int ldc, int K)
{
  __shared__ short As[64][40];   // +8 pad: rows stride 80B -> banks spread
  __shared__ short Bs[64][40];
  const int bm0 = blockIdx.x * 64;
  const int bn0 = blockIdx.y * 64;
  const int tid = threadIdx.x;
  const int wave = tid >> 6, lane = tid & 63;
  const int lm = lane & 15, kg = lane >> 4;       // frag row / k-group
  const int srow = tid >> 2, scol = (tid & 3) * 8; // staging: 64 rows x 32 cols
  f32x4 acc[4] = {};
  const size_t abase = (size_t)(bm0 + srow) * lda + scol;
  const size_t bbase = (size_t)(bn0 + srow) * ldb + scol;
  for (int k0 = 0; k0 < K; k0 += 32) {
    *(uint4*)&As[srow][scol] = *(const uint4*)(A + abase + k0);
    *(uint4*)&Bs[srow][scol] = *(const uint4*)(Bt + bbase + k0);
    __syncthreads();
    // A frag: lane holds A[m=lm][k=kg*8..+7]; B frag: Bt row n=f*16+lm same k
    bf16x8 af = *(const bf16x8*)&As[wave*16 + lm][kg*8];
#pragma unroll
    for (int f = 0; f < 4; ++f) {
      bf16x8 bfr = *(const bf16x8*)&Bs[f*16 + lm][kg*8];
      acc[f] = mfma16x16x32(af, bfr, acc[f]);
    }
    __syncthreads();
  }
  // D mapping (m89/m91): col = lane&15, row = (lane>>4)*4 + reg
  const int row0 = bm0 + wave*16 + kg*4;
  const int col0 = bn0 + lm;
#pragma unroll
  for (int f = 0; f < 4; ++f) {
#pragma unroll
    for (int q = 0; q < 4; ++q) {
      float val = acc[f][q];
      size_t o = (size_t)(row0 + q) * ldc + col0 + f*16;
      if (EPI == 0)      ((float*)Cout)[o] = val;
      else if (EPI == 1) ((bf16*)Cout)[o] = tobf(tanhf(val));
      else               ((bf16*)Cout)[o] = tobf(val);
    }
  }
}

// ---------------- elementwise ----------------------------------------------
__global__ __launch_bounds__(256) void xx_xin_k(
    const float* __restrict__ x, const float* __restrict__ maa_x,
    float* __restrict__ xx, bf16* __restrict__ xinb)
{
  size_t idx = (size_t)blockIdx.x * 256 + threadIdx.x;
  int c = idx & (C_ - 1);
  int t = (int)((idx >> 10) & (T_ - 1));
  float xv = x[idx];
  float xp = t ? x[idx - C_] : 0.f;
  float xxv = xp - xv;
  xx[idx] = xxv;
  xinb[idx] = tobf(xv + xxv * maa_x[c]);
}

__global__ __launch_bounds__(256) void combine_branch(
    const float* __restrict__ x, const float* __restrict__ xx,
    const float* __restrict__ maa, const float* __restrict__ m,
    bf16* __restrict__ xsb)
{
  size_t idx = (size_t)blockIdx.x * 256 + threadIdx.x;
  int c = idx & (C_ - 1);
  xsb[idx] = tobf(x[idx] + xx[idx] * (maa[c] + m[idx]));
}

__global__ __launch_bounds__(256) void w_finalize(
    const float* __restrict__ wraw, const float* __restrict__ td,
    float* __restrict__ wd, float* __restrict__ k)
{
  size_t idx = (size_t)blockIdx.x * 256 + threadIdx.x;
  int c = idx & (C_ - 1);
  float wr = wraw[idx] + td[c];
  // w = -softplus(-wr) - 0.5, stable
  float sp = fmaxf(-wr, 0.f) + log1pf(expf(-fabsf(wr)));
  float w = -sp - 0.5f;
  wd[idx] = expf(-expf(w));
  k[idx] *= expf(fminf(0.5f * w, 0.f));
}

__global__ __launch_bounds__(256) void a_finalize(
    const float* __restrict__ araw, const float* __restrict__ aaaaa,
    float* __restrict__ aamt)
{
  size_t idx = (size_t)blockIdx.x * 256 + threadIdx.x;
  int c = idx & (C_ - 1);
  float z = aaaaa[c] + araw[idx];
  aamt[idx] = 2.f / (1.f + expf(-z));
}

// kk = (k + kkadd) / max(||k+kkadd||_2 over C, 1e-12)  (one block per row)
__global__ __launch_bounds__(256) void kk_normalize(
    const float* __restrict__ kraw, const float* __restrict__ kkadd,
    float* __restrict__ kkout)
{
  const int bt = blockIdx.x;
  const int tid = threadIdx.x;
  const size_t o = (size_t)bt * C_;
  float vals[4]; float ss = 0.f;
#pragma unroll
  for (int q = 0; q < 4; ++q) {
    float u = kraw[o + tid + q*256] + kkadd[o + tid + q*256];
    vals[q] = u; ss += u * u;
  }
  ss = allred64(ss);
  __shared__ float red[4];
  const int wave = tid >> 6, lane = tid & 63;
  if (lane == 0) red[wave] = ss;
  __syncthreads();
  float tot = red[0] + red[1] + red[2] + red[3];
  float inv = 1.f / fmaxf(sqrtf(tot), 1e-12f);
#pragma unroll
  for (int q = 0; q < 4; ++q) kkout[o + tid + q*256] = vals[q] * inv;
}

// ---------------- RWKV-7 scan: wave per (b,h,row i), lane = column j -------
__global__ __launch_bounds__(256) void rwkv_scan(
    const float* __restrict__ rr, const float* __restrict__ wd,
    const float* __restrict__ kk_s, const float* __restrict__ kkv,
    const float* __restrict__ aam, const float* __restrict__ vv,
    float* __restrict__ y)
{
  const int blk = blockIdx.x;        // 512 blocks = 32 heads * 16 rowgroups
  const int bh = blk >> 4;
  const int b = bh >> 4, h = bh & 15;
  const int wave = threadIdx.x >> 6, lane = threadIdx.x & 63;
  const int i = (blk & 15) * 4 + wave;
  const size_t head0 = (size_t)b * T_ * C_ + h * N_;
  const float* pr = rr   + head0 + lane;
  const float* pw = wd   + head0 + lane;
  const float* pk = kk_s + head0 + lane;
  const float* pq = kkv  + head0 + lane;
  const float* pa = aam  + head0 + lane;
  const float* pv = vv   + head0 + i;
  float* py = y + head0 + i;
  float S = 0.f;
  float rj = *pr, wdj = *pw, kj = *pk, kkj = *pq, aj = *pa, vi = *pv;
  for (int t = 0; t < T_; ++t) {
    const int adv = (t + 1 < T_) ? C_ : 0;      // prefetch next step
    pr += adv; pw += adv; pk += adv; pq += adv; pa += adv; pv += adv;
    float nr = *pr, nw = *pw, nk = *pk, nq = *pq, na = *pa, nv = *pv;
    float bj = kkj * aj;                        // b_t = kk * a_amt
    float sa = allred64(S * (-kkj));            // a_t = -kk
    S = S * wdj + sa * bj + vi * kj;
    float yp = allred64(S * rj);
    if (lane == 0) py[(size_t)t * C_] = yp;
    rj = nr; wdj = nw; kj = nk; kkj = nq; aj = na; vi = nv;
  }
}

// ---------------- groupnorm + bonus + gate ---------------------------------
__global__ __launch_bounds__(256) void gn_bonus_gate(
    const float* __restrict__ y, const float* __restrict__ rr,
    const float* __restrict__ kk_s, const float* __restrict__ vv,
    const float* __restrict__ gg, const float* __restrict__ faaaa,
    const float* __restrict__ lnw, const float* __restrict__ lnb,
    bf16* __restrict__ zb)
{
  const int bt = blockIdx.x;
  const int wave = threadIdx.x >> 6, lane = threadIdx.x & 63;
  const float inv64 = 1.f / 64.f;
  for (int h = wave; h < H_; h += 4) {
    const int c = h * 64 + lane;
    const size_t o = (size_t)bt * C_ + c;
    float yv = y[o];
    float mean = allred64(yv) * inv64;
    float d = yv - mean;
    float var = allred64(d * d) * inv64;
    float xn = d * rsqrtf(var + 6.4e-4f);       // eps = 1e-5 * 64
    float gn = xn * lnw[c] + lnb[c];
    float rk = allred64(rr[o] * kk_s[o] * faaaa[c]);
    float z = (gn + rk * vv[o]) * gg[o];
    zb[o] = tobf(z);
  }
}

// ---------------- driver ----------------------------------------------------
extern "C" void kernel_launch(void* const* d_in, const int* in_sizes, int n_in,
                              void* d_out, int out_size, void* d_ws, size_t ws_size,
                              hipStream_t stream)
{
  const float* x     = (const float*)d_in[0];
  const float* maa_x = (const float*)d_in[1];
  const float* maa_r = (const float*)d_in[2];
  const float* maa_w = (const float*)d_in[3];
  const float* maa_k = (const float*)d_in[4];
  const float* maa_v = (const float*)d_in[5];
  const float* maa_a = (const float*)d_in[6];
  const float* maa_g = (const float*)d_in[7];
  const float* tdec  = (const float*)d_in[8];
  const float* faaaa = (const float*)d_in[9];
  const float* aaaaa = (const float*)d_in[10];
  const float* maa_w1= (const float*)d_in[11];
  const float* maa_w2= (const float*)d_in[12];
  const float* dec_w1= (const float*)d_in[13];
  const float* dec_w2= (const float*)d_in[14];
  const float* aaa_w1= (const float*)d_in[15];
  const float* aaa_w2= (const float*)d_in[16];
  const float* kkk_w1= (const float*)d_in[17];
  const float* kkk_w2= (const float*)d_in[18];
  const float* gate_w1=(const float*)d_in[19];
  const float* gate_w2=(const float*)d_in[20];
  const float* W_r   = (const float*)d_in[21];
  const float* W_k   = (const float*)d_in[22];
  const float* W_v   = (const float*)d_in[23];
  const float* W_o   = (const float*)d_in[24];
  const float* lnw   = (const float*)d_in[25];
  const float* lnb   = (const float*)d_in[26];

  char* ws = (char*)d_ws;
  size_t cur = 0;
  auto alloc = [&](size_t bytes) -> void* {
    void* p = ws + cur; cur += (bytes + 255) & ~(size_t)255; return p;
  };
  const size_t FBT = (size_t)BT_ * C_ * sizeof(float);
  float* xx   = (float*)alloc(FBT);
  float* wdb  = (float*)alloc(FBT);
  float* rb   = (float*)alloc(FBT);
  float* kb   = (float*)alloc(FBT);
  float* vb   = (float*)alloc(FBT);
  float* kkb  = (float*)alloc(FBT);
  float* aamt = (float*)alloc(FBT);
  float* gb   = (float*)alloc(FBT);
  float* mtmp = (float*)alloc(FBT);
  bf16* xinb = (bf16*)alloc((size_t)BT_*C_*2);
  bf16* mixb = (bf16*)alloc((size_t)BT_*192*2);
  bf16* xbr[6];
  for (int s = 0; s < 6; ++s) xbr[s] = (bf16*)alloc((size_t)BT_*C_*2);
  bf16* h64b = (bf16*)alloc((size_t)BT_*64*2);
  bf16* h128b= (bf16*)alloc((size_t)BT_*128*2);
  bf16* zb   = (bf16*)alloc((size_t)BT_*C_*2);
  bf16* WtR  = (bf16*)alloc((size_t)C_*C_*2);
  bf16* WtK  = (bf16*)alloc((size_t)C_*C_*2);
  bf16* WtV  = (bf16*)alloc((size_t)C_*C_*2);
  bf16* WtO  = (bf16*)alloc((size_t)C_*C_*2);
  bf16* w1t  = (bf16*)alloc((size_t)192*C_*2);
  bf16* w2t  = (bf16*)alloc((size_t)6*C_*32*2);
  bf16* d1t  = (bf16*)alloc((size_t)64*C_*2);
  bf16* d2t  = (bf16*)alloc((size_t)C_*64*2);
  bf16* a1t  = (bf16*)alloc((size_t)64*C_*2);
  bf16* a2t  = (bf16*)alloc((size_t)C_*64*2);
  bf16* k1t  = (bf16*)alloc((size_t)64*C_*2);
  bf16* k2t  = (bf16*)alloc((size_t)C_*64*2);
  bf16* g1t  = (bf16*)alloc((size_t)128*C_*2);
  bf16* g2t  = (bf16*)alloc((size_t)C_*128*2);
  (void)ws_size; (void)in_sizes; (void)n_in; (void)out_size; // ~235 MB used

  PrepArgs pa;
  pa.src[0] = W_r;  pa.dst[0] = WtR;
  pa.src[1] = W_k;  pa.dst[1] = WtK;
  pa.src[2] = W_v;  pa.dst[2] = WtV;
  pa.src[3] = W_o;  pa.dst[3] = WtO;
  pa.src[4] = maa_w1; pa.dst[4] = w1t;
  for (int s = 0; s < 6; ++s) { pa.src[5+s] = maa_w2 + (size_t)s*32*C_; pa.dst[5+s] = w2t + (size_t)s*C_*32; }
  pa.src[11] = dec_w1; pa.dst[11] = d1t;
  pa.src[12] = dec_w2; pa.dst[12] = d2t;
  pa.src[13] = aaa_w1; pa.dst[13] = a1t;
  pa.src[14] = aaa_w2; pa.dst[14] = a2t;
  pa.src[15] = kkk_w1; pa.dst[15] = k1t;
  pa.src[16] = kkk_w2; pa.dst[16] = k2t;
  pa.src[17] = gate_w1; pa.dst[17] = g1t;
  pa.src[18] = gate_w2; pa.dst[18] = g2t;
  prep_weights<<<dim3(1024, 19), 256, 0, stream>>>(pa);

  const int EW_GRID = (BT_ * C_) / 256;  // 16384
  xx_xin_k<<<EW_GRID, 256, 0, stream>>>(x, maa_x, xx, xinb);

  // mix = tanh(xin @ w1) : M=4096 N=192 K=1024
  gemm_bt<1><<<dim3(64, 3), 256, 0, stream>>>(xinb, C_, w1t, C_, mixb, 192, C_);

  const float* maas[6] = {maa_r, maa_w, maa_k, maa_v, maa_a, maa_g};
  for (int s = 0; s < 6; ++s) {
    // m_s = mix[:, s*32:+32] @ w2[s] : K=32, N=1024
    gemm_bt<0><<<dim3(64, 16), 256, 0, stream>>>(mixb + s*32, 192, w2t + (size_t)s*C_*32, 32, mtmp, C_, 32);
    combine_branch<<<EW_GRID, 256, 0, stream>>>(x, xx, maas[s], mtmp, xbr[s]);
  }

  // r, k, v
  gemm_bt<0><<<dim3(64, 16), 256, 0, stream>>>(xbr[0], C_, WtR, C_, rb, C_, C_);
  gemm_bt<0><<<dim3(64, 16), 256, 0, stream>>>(xbr[2], C_, WtK, C_, kb, C_, C_);
  gemm_bt<0><<<dim3(64, 16), 256, 0, stream>>>(xbr[3], C_, WtV, C_, vb, C_, C_);

  // kk path (uses UNscaled k)
  gemm_bt<1><<<dim3(64, 1), 256, 0, stream>>>(xbr[2], C_, k1t, C_, h64b, 64, C_);
  gemm_bt<0><<<dim3(64, 16), 256, 0, stream>>>(h64b, 64, k2t, 64, mtmp, C_, 64);
  kk_normalize<<<BT_, 256, 0, stream>>>(kb, mtmp, kkb);

  // w path (then scales k in place)
  gemm_bt<1><<<dim3(64, 1), 256, 0, stream>>>(xbr[1], C_, d1t, C_, h64b, 64, C_);
  gemm_bt<0><<<dim3(64, 16), 256, 0, stream>>>(h64b, 64, d2t, 64, mtmp, C_, 64);
  w_finalize<<<EW_GRID, 256, 0, stream>>>(mtmp, tdec, wdb, kb);

  // a path (NO tanh on inner projection)
  gemm_bt<2><<<dim3(64, 1), 256, 0, stream>>>(xbr[4], C_, a1t, C_, h64b, 64, C_);
  gemm_bt<0><<<dim3(64, 16), 256, 0, stream>>>(h64b, 64, a2t, 64, mtmp, C_, 64);
  a_finalize<<<EW_GRID, 256, 0, stream>>>(mtmp, aaaaa, aamt);

  // g path
  gemm_bt<1><<<dim3(64, 2), 256, 0, stream>>>(xbr[5], C_, g1t, C_, h128b, 128, C_);
  gemm_bt<0><<<dim3(64, 16), 256, 0, stream>>>(h128b, 128, g2t, 128, gb, C_, 128);

  // scan -> y staged in d_out (fully overwritten by final GEMM afterwards)
  rwkv_scan<<<512, 256, 0, stream>>>(rb, wdb, kb, kkb, aamt, vb, (float*)d_out);

  gn_bonus_gate<<<BT_, 256, 0, stream>>>((const float*)d_out, rb, kb, vb, gb,
                                         faaaa, lnw, lnb, zb);

  // out = z @ W_o
  gemm_bt<0><<<dim3(64, 16), 256, 0, stream>>>(zb, C_, WtO, C_, d_out, C_, C_);
}

// Round 2
// 1075.090 us; speedup vs baseline: 1.5198x; 1.5198x over previous
//
#include <hip/hip_runtime.h>
#include <hip/hip_bf16.h>

using bf16 = __hip_bfloat16;
using bf16x8 = __attribute__((ext_vector_type(8))) short;  // 8 bf16 (4 VGPRs)
using f32x4 = __attribute__((ext_vector_type(4))) float;

#define B_ 2
#define T_ 2048
#define C_ 1024
#define BT_ (B_*T_)
#define H_ 16
#define N_ 64

__device__ __forceinline__ float allred64(float v) {
#pragma unroll
  for (int m = 1; m < 64; m <<= 1) v += __shfl_xor(v, m, 64);
  return v;
}

__device__ __forceinline__ bf16 tobf(float f) { return __float2bfloat16(f); }

__device__ __forceinline__ f32x4 mfma16x16x32(bf16x8 a, bf16x8 b, f32x4 c) {
  return __builtin_amdgcn_mfma_f32_16x16x32_bf16(a, b, c, 0, 0, 0);
}

// ---- DPP wave64 sum: canonical row_shr accumulate + row_bcast; sum -> lane 63
template<int CTRL>
__device__ __forceinline__ float dppadd(float v) {
  int t = __builtin_amdgcn_update_dpp(0, __builtin_bit_cast(int, v),
                                      CTRL, 0xf, 0xf, true);
  return v + __builtin_bit_cast(float, t);
}
__device__ __forceinline__ float rd63(float v) {
  return __builtin_bit_cast(float,
      __builtin_amdgcn_readlane(__builtin_bit_cast(int, v), 63));
}
// 4 independent chains, stage-interleaved for ILP
__device__ __forceinline__ void wred4(float& a, float& b, float& c, float& d) {
  a = dppadd<0x111>(a); b = dppadd<0x111>(b); c = dppadd<0x111>(c); d = dppadd<0x111>(d);
  a = dppadd<0x112>(a); b = dppadd<0x112>(b); c = dppadd<0x112>(c); d = dppadd<0x112>(d);
  a = dppadd<0x114>(a); b = dppadd<0x114>(b); c = dppadd<0x114>(c); d = dppadd<0x114>(d);
  a = dppadd<0x118>(a); b = dppadd<0x118>(b); c = dppadd<0x118>(c); d = dppadd<0x118>(d);
  a = dppadd<0x142>(a); b = dppadd<0x142>(b); c = dppadd<0x142>(c); d = dppadd<0x142>(d);
  a = dppadd<0x143>(a); b = dppadd<0x143>(b); c = dppadd<0x143>(c); d = dppadd<0x143>(d);
}

// ---------------- weight transpose + bf16 cast (19 jobs, one launch) -------
struct PrepArgs {
  const float* src[19];
  bf16* dst[19];
};
__constant__ int kTR[19] = {1024,1024,1024,1024, 1024, 32,32,32,32,32,32,
                            1024,64, 1024,64, 1024,64, 1024,128};
__constant__ int kTC[19] = {1024,1024,1024,1024, 192, 1024,1024,1024,1024,1024,1024,
                            64,1024, 64,1024, 64,1024, 128,1024};

__global__ __launch_bounds__(256) void prep_weights(PrepArgs pa) {
  const int job = blockIdx.y;
  const int R = kTR[job], Cc = kTC[job];
  const int ntx = Cc >> 5, nty = R >> 5;
  const int tile = blockIdx.x;
  if (tile >= ntx * nty) return;
  const int tx = tile % ntx, ty = tile / ntx;
  const float* __restrict__ src = pa.src[job];
  bf16* __restrict__ dst = pa.dst[job];
  __shared__ float tl[32][33];
  const int lx = threadIdx.x & 31, ly = threadIdx.x >> 5;  // 32 x 8
#pragma unroll
  for (int q = 0; q < 4; ++q)
    tl[ly + 8*q][lx] = src[(size_t)(ty*32 + ly + 8*q) * Cc + tx*32 + lx];
  __syncthreads();
#pragma unroll
  for (int q = 0; q < 4; ++q)
    dst[(size_t)(tx*32 + ly + 8*q) * R + ty*32 + lx] = tobf(tl[lx][ly + 8*q]);
}

// ---------------- GEMM: C[M,N] = A[M,K](bf16) * Bt[N,K](bf16)^T ------------
// tile 64x64, BK=32, 4 waves; EPI: 0 = f32 raw, 1 = bf16 tanh, 2 = bf16 raw
template<int EPI>
__global__ __launch_bounds__(256) void gemm_bt(
    const bf16* __restrict__ A, int lda,
    const bf16* __restrict__ Bt, int ldb,
    void* __restrict__ Cout, int ldc, int K)
{
  __shared__ short As[64][40];   // +8 pad: rows stride 80B -> banks spread
  __shared__ short Bs[64][40];
  const int bm0 = blockIdx.x * 64;
  const int bn0 = blockIdx.y * 64;
  const int tid = threadIdx.x;
  const int wave = tid >> 6, lane = tid & 63;
  const int lm = lane & 15, kg = lane >> 4;       // frag row / k-group
  const int srow = tid >> 2, scol = (tid & 3) * 8; // staging: 64 rows x 32 cols
  f32x4 acc[4] = {};
  const size_t abase = (size_t)(bm0 + srow) * lda + scol;
  const size_t bbase = (size_t)(bn0 + srow) * ldb + scol;
  for (int k0 = 0; k0 < K; k0 += 32) {
    *(uint4*)&As[srow][scol] = *(const uint4*)(A + abase + k0);
    *(uint4*)&Bs[srow][scol] = *(const uint4*)(Bt + bbase + k0);
    __syncthreads();
    bf16x8 af = *(const bf16x8*)&As[wave*16 + lm][kg*8];
#pragma unroll
    for (int f = 0; f < 4; ++f) {
      bf16x8 bfr = *(const bf16x8*)&Bs[f*16 + lm][kg*8];
      acc[f] = mfma16x16x32(af, bfr, acc[f]);
    }
    __syncthreads();
  }
  // D mapping (m89/m91): col = lane&15, row = (lane>>4)*4 + reg
  const int row0 = bm0 + wave*16 + kg*4;
  const int col0 = bn0 + lm;
#pragma unroll
  for (int f = 0; f < 4; ++f) {
#pragma unroll
    for (int q = 0; q < 4; ++q) {
      float val = acc[f][q];
      size_t o = (size_t)(row0 + q) * ldc + col0 + f*16;
      if (EPI == 0)      ((float*)Cout)[o] = val;
      else if (EPI == 1) ((bf16*)Cout)[o] = tobf(tanhf(val));
      else               ((bf16*)Cout)[o] = tobf(val);
    }
  }
}

// ---------------- elementwise ----------------------------------------------
__global__ __launch_bounds__(256) void xx_xin_k(
    const float* __restrict__ x, const float* __restrict__ maa_x,
    float* __restrict__ xx, bf16* __restrict__ xinb)
{
  size_t idx = (size_t)blockIdx.x * 256 + threadIdx.x;
  int c = idx & (C_ - 1);
  int t = (int)((idx >> 10) & (T_ - 1));
  float xv = x[idx];
  float xp = t ? x[idx - C_] : 0.f;
  float xxv = xp - xv;
  xx[idx] = xxv;
  xinb[idx] = tobf(xv + xxv * maa_x[c]);
}

__global__ __launch_bounds__(256) void combine_branch(
    const float* __restrict__ x, const float* __restrict__ xx,
    const float* __restrict__ maa, const float* __restrict__ m,
    bf16* __restrict__ xsb)
{
  size_t idx = (size_t)blockIdx.x * 256 + threadIdx.x;
  int c = idx & (C_ - 1);
  xsb[idx] = tobf(x[idx] + xx[idx] * (maa[c] + m[idx]));
}

__global__ __launch_bounds__(256) void w_finalize(
    const float* __restrict__ wraw, const float* __restrict__ td,
    float* __restrict__ wd, float* __restrict__ k)
{
  size_t idx = (size_t)blockIdx.x * 256 + threadIdx.x;
  int c = idx & (C_ - 1);
  float wr = wraw[idx] + td[c];
  float sp = fmaxf(-wr, 0.f) + log1pf(expf(-fabsf(wr)));
  float w = -sp - 0.5f;
  wd[idx] = expf(-expf(w));
  k[idx] *= expf(fminf(0.5f * w, 0.f));
}

__global__ __launch_bounds__(256) void a_finalize(
    const float* __restrict__ araw, const float* __restrict__ aaaaa,
    float* __restrict__ aamt)
{
  size_t idx = (size_t)blockIdx.x * 256 + threadIdx.x;
  int c = idx & (C_ - 1);
  float z = aaaaa[c] + araw[idx];
  aamt[idx] = 2.f / (1.f + expf(-z));
}

__global__ __launch_bounds__(256) void kk_normalize(
    const float* __restrict__ kraw, const float* __restrict__ kkadd,
    float* __restrict__ kkout)
{
  const int bt = blockIdx.x;
  const int tid = threadIdx.x;
  const size_t o = (size_t)bt * C_;
  float vals[4]; float ss = 0.f;
#pragma unroll
  for (int q = 0; q < 4; ++q) {
    float u = kraw[o + tid + q*256] + kkadd[o + tid + q*256];
    vals[q] = u; ss += u * u;
  }
  ss = allred64(ss);
  __shared__ float red[4];
  const int wave = tid >> 6, lane = tid & 63;
  if (lane == 0) red[wave] = ss;
  __syncthreads();
  float tot = red[0] + red[1] + red[2] + red[3];
  float inv = 1.f / fmaxf(sqrtf(tot), 1e-12f);
#pragma unroll
  for (int q = 0; q < 4; ++q) kkout[o + tid + q*256] = vals[q] * inv;
}

// ---------------- RWKV-7 scan: wave per (b,h,row i), lane = column j -------
// y_t = S_old (w.*r) + sa*(b.r) + v*(k.r): all 4 reductions read S_old ->
// 4 independent DPP chains; prefetch distance 2 hides L2/HBM latency.
struct St { float r, w, k, q, a, v; };

__device__ __forceinline__ St ldstep(
    const float* pr, const float* pw, const float* pk,
    const float* pq, const float* pa, const float* pv, int t) {
  size_t o = (size_t)t * C_;
  St s;
  s.r = pr[o]; s.w = pw[o]; s.k = pk[o];
  s.q = pq[o]; s.a = pa[o]; s.v = pv[o];
  return s;
}

__global__ __launch_bounds__(256) void rwkv_scan(
    const float* __restrict__ rr, const float* __restrict__ wd,
    const float* __restrict__ kk_s, const float* __restrict__ kkv,
    const float* __restrict__ aam, const float* __restrict__ vv,
    float* __restrict__ y)
{
  const int blk = blockIdx.x;        // 512 blocks = 32 heads * 16 rowgroups
  const int bh = blk >> 4;
  const int b = bh >> 4, h = bh & 15;
  const int wave = threadIdx.x >> 6, lane = threadIdx.x & 63;
  const int i = (blk & 15) * 4 + wave;
  const size_t head0 = (size_t)b * T_ * C_ + h * N_;
  const float* pr = rr   + head0 + lane;
  const float* pw = wd   + head0 + lane;
  const float* pk = kk_s + head0 + lane;
  const float* pq = kkv  + head0 + lane;
  const float* pa = aam  + head0 + lane;
  const float* pv = vv   + head0 + i;
  float* py = y + head0 + i;
  float S = 0.f;
  // NOTE: tail loads read up to ~12KB past this (b,h) segment into the next
  // workspace buffer (values unused) -- all scan inputs sit mid-workspace.
  St s0 = ldstep(pr, pw, pk, pq, pa, pv, 0);
  St s1 = ldstep(pr, pw, pk, pq, pa, pv, 1);
  for (int t = 0; t < T_; t += 2) {
    St s2 = ldstep(pr, pw, pk, pq, pa, pv, t + 2);
    {
      float bj = s0.q * s0.a;               // b_t[j] = kk*a_amt
      float p0 = S * (-s0.q);               // -> sa
      float p1 = S * (s0.w * s0.r);         // -> yS
      float p2 = bj * s0.r;                 // -> b.r
      float p3 = s0.k * s0.r;               // -> k.r
      wred4(p0, p1, p2, p3);
      float sa = rd63(p0), yS = rd63(p1), br = rd63(p2), kr = rd63(p3);
      S = S * s0.w + sa * bj + s0.v * s0.k;
      if (lane == 0) py[(size_t)t * C_] = yS + sa * br + s0.v * kr;
    }
    St s3 = ldstep(pr, pw, pk, pq, pa, pv, t + 3);
    {
      float bj = s1.q * s1.a;
      float p0 = S * (-s1.q);
      float p1 = S * (s1.w * s1.r);
      float p2 = bj * s1.r;
      float p3 = s1.k * s1.r;
      wred4(p0, p1, p2, p3);
      float sa = rd63(p0), yS = rd63(p1), br = rd63(p2), kr = rd63(p3);
      S = S * s1.w + sa * bj + s1.v * s1.k;
      if (lane == 0) py[(size_t)(t + 1) * C_] = yS + sa * br + s1.v * kr;
    }
    s0 = s2; s1 = s3;
  }
}

// ---------------- groupnorm + bonus + gate ---------------------------------
__global__ __launch_bounds__(256) void gn_bonus_gate(
    const float* __restrict__ y, const float* __restrict__ rr,
    const float* __restrict__ kk_s, const float* __restrict__ vv,
    const float* __restrict__ gg, const float* __restrict__ faaaa,
    const float* __restrict__ lnw, const float* __restrict__ lnb,
    bf16* __restrict__ zb)
{
  const int bt = blockIdx.x;
  const int wave = threadIdx.x >> 6, lane = threadIdx.x & 63;
  const float inv64 = 1.f / 64.f;
  for (int h = wave; h < H_; h += 4) {
    const int c = h * 64 + lane;
    const size_t o = (size_t)bt * C_ + c;
    float yv = y[o];
    float mean = allred64(yv) * inv64;
    float d = yv - mean;
    float var = allred64(d * d) * inv64;
    float xn = d * rsqrtf(var + 6.4e-4f);       // eps = 1e-5 * 64
    float gn = xn * lnw[c] + lnb[c];
    float rk = allred64(rr[o] * kk_s[o] * faaaa[c]);
    float z = (gn + rk * vv[o]) * gg[o];
    zb[o] = tobf(z);
  }
}

// ---------------- driver ----------------------------------------------------
extern "C" void kernel_launch(void* const* d_in, const int* in_sizes, int n_in,
                              void* d_out, int out_size, void* d_ws, size_t ws_size,
                              hipStream_t stream)
{
  const float* x     = (const float*)d_in[0];
  const float* maa_x = (const float*)d_in[1];
  const float* maa_r = (const float*)d_in[2];
  const float* maa_w = (const float*)d_in[3];
  const float* maa_k = (const float*)d_in[4];
  const float* maa_v = (const float*)d_in[5];
  const float* maa_a = (const float*)d_in[6];
  const float* maa_g = (const float*)d_in[7];
  const float* tdec  = (const float*)d_in[8];
  const float* faaaa = (const float*)d_in[9];
  const float* aaaaa = (const float*)d_in[10];
  const float* maa_w1= (const float*)d_in[11];
  const float* maa_w2= (const float*)d_in[12];
  const float* dec_w1= (const float*)d_in[13];
  const float* dec_w2= (const float*)d_in[14];
  const float* aaa_w1= (const float*)d_in[15];
  const float* aaa_w2= (const float*)d_in[16];
  const float* kkk_w1= (const float*)d_in[17];
  const float* kkk_w2= (const float*)d_in[18];
  const float* gate_w1=(const float*)d_in[19];
  const float* gate_w2=(const float*)d_in[20];
  const float* W_r   = (const float*)d_in[21];
  const float* W_k   = (const float*)d_in[22];
  const float* W_v   = (const float*)d_in[23];
  const float* W_o   = (const float*)d_in[24];
  const float* lnw   = (const float*)d_in[25];
  const float* lnb   = (const float*)d_in[26];

  char* ws = (char*)d_ws;
  size_t cur = 0;
  auto alloc = [&](size_t bytes) -> void* {
    void* p = ws + cur; cur += (bytes + 255) & ~(size_t)255; return p;
  };
  const size_t FBT = (size_t)BT_ * C_ * sizeof(float);
  float* xx   = (float*)alloc(FBT);
  float* wdb  = (float*)alloc(FBT);
  float* rb   = (float*)alloc(FBT);
  float* kb   = (float*)alloc(FBT);
  float* vb   = (float*)alloc(FBT);
  float* kkb  = (float*)alloc(FBT);
  float* aamt = (float*)alloc(FBT);
  float* gb   = (float*)alloc(FBT);
  float* mtmp = (float*)alloc(FBT);
  bf16* xinb = (bf16*)alloc((size_t)BT_*C_*2);
  bf16* mixb = (bf16*)alloc((size_t)BT_*192*2);
  bf16* xbr[6];
  for (int s = 0; s < 6; ++s) xbr[s] = (bf16*)alloc((size_t)BT_*C_*2);
  bf16* h64b = (bf16*)alloc((size_t)BT_*64*2);
  bf16* h128b= (bf16*)alloc((size_t)BT_*128*2);
  bf16* zb   = (bf16*)alloc((size_t)BT_*C_*2);
  bf16* WtR  = (bf16*)alloc((size_t)C_*C_*2);
  bf16* WtK  = (bf16*)alloc((size_t)C_*C_*2);
  bf16* WtV  = (bf16*)alloc((size_t)C_*C_*2);
  bf16* WtO  = (bf16*)alloc((size_t)C_*C_*2);
  bf16* w1t  = (bf16*)alloc((size_t)192*C_*2);
  bf16* w2t  = (bf16*)alloc((size_t)6*C_*32*2);
  bf16* d1t  = (bf16*)alloc((size_t)64*C_*2);
  bf16* d2t  = (bf16*)alloc((size_t)C_*64*2);
  bf16* a1t  = (bf16*)alloc((size_t)64*C_*2);
  bf16* a2t  = (bf16*)alloc((size_t)C_*64*2);
  bf16* k1t  = (bf16*)alloc((size_t)64*C_*2);
  bf16* k2t  = (bf16*)alloc((size_t)C_*64*2);
  bf16* g1t  = (bf16*)alloc((size_t)128*C_*2);
  bf16* g2t  = (bf16*)alloc((size_t)C_*128*2);
  (void)ws_size; (void)in_sizes; (void)n_in; (void)out_size; // ~235 MB used

  PrepArgs pa;
  pa.src[0] = W_r;  pa.dst[0] = WtR;
  pa.src[1] = W_k;  pa.dst[1] = WtK;
  pa.src[2] = W_v;  pa.dst[2] = WtV;
  pa.src[3] = W_o;  pa.dst[3] = WtO;
  pa.src[4] = maa_w1; pa.dst[4] = w1t;
  for (int s = 0; s < 6; ++s) { pa.src[5+s] = maa_w2 + (size_t)s*32*C_; pa.dst[5+s] = w2t + (size_t)s*C_*32; }
  pa.src[11] = dec_w1; pa.dst[11] = d1t;
  pa.src[12] = dec_w2; pa.dst[12] = d2t;
  pa.src[13] = aaa_w1; pa.dst[13] = a1t;
  pa.src[14] = aaa_w2; pa.dst[14] = a2t;
  pa.src[15] = kkk_w1; pa.dst[15] = k1t;
  pa.src[16] = kkk_w2; pa.dst[16] = k2t;
  pa.src[17] = gate_w1; pa.dst[17] = g1t;
  pa.src[18] = gate_w2; pa.dst[18] = g2t;
  prep_weights<<<dim3(1024, 19), 256, 0, stream>>>(pa);

  const int EW_GRID = (BT_ * C_) / 256;  // 16384
  xx_xin_k<<<EW_GRID, 256, 0, stream>>>(x, maa_x, xx, xinb);

  // mix = tanh(xin @ w1) : M=4096 N=192 K=1024
  gemm_bt<1><<<dim3(64, 3), 256, 0, stream>>>(xinb, C_, w1t, C_, mixb, 192, C_);

  const float* maas[6] = {maa_r, maa_w, maa_k, maa_v, maa_a, maa_g};
  for (int s = 0; s < 6; ++s) {
    gemm_bt<0><<<dim3(64, 16), 256, 0, stream>>>(mixb + s*32, 192, w2t + (size_t)s*C_*32, 32, mtmp, C_, 32);
    combine_branch<<<EW_GRID, 256, 0, stream>>>(x, xx, maas[s], mtmp, xbr[s]);
  }

  // r, k, v
  gemm_bt<0><<<dim3(64, 16), 256, 0, stream>>>(xbr[0], C_, WtR, C_, rb, C_, C_);
  gemm_bt<0><<<dim3(64, 16), 256, 0, stream>>>(xbr[2], C_, WtK, C_, kb, C_, C_);
  gemm_bt<0><<<dim3(64, 16), 256, 0, stream>>>(xbr[3], C_, WtV, C_, vb, C_, C_);

  // kk path (uses UNscaled k)
  gemm_bt<1><<<dim3(64, 1), 256, 0, stream>>>(xbr[2], C_, k1t, C_, h64b, 64, C_);
  gemm_bt<0><<<dim3(64, 16), 256, 0, stream>>>(h64b, 64, k2t, 64, mtmp, C_, 64);
  kk_normalize<<<BT_, 256, 0, stream>>>(kb, mtmp, kkb);

  // w path (then scales k in place)
  gemm_bt<1><<<dim3(64, 1), 256, 0, stream>>>(xbr[1], C_, d1t, C_, h64b, 64, C_);
  gemm_bt<0><<<dim3(64, 16), 256, 0, stream>>>(h64b, 64, d2t, 64, mtmp, C_, 64);
  w_finalize<<<EW_GRID, 256, 0, stream>>>(mtmp, tdec, wdb, kb);

  // a path (NO tanh on inner projection)
  gemm_bt<2><<<dim3(64, 1), 256, 0, stream>>>(xbr[4], C_, a1t, C_, h64b, 64, C_);
  gemm_bt<0><<<dim3(64, 16), 256, 0, stream>>>(h64b, 64, a2t, 64, mtmp, C_, 64);
  a_finalize<<<EW_GRID, 256, 0, stream>>>(mtmp, aaaaa, aamt);

  // g path
  gemm_bt<1><<<dim3(64, 2), 256, 0, stream>>>(xbr[5], C_, g1t, C_, h128b, 128, C_);
  gemm_bt<0><<<dim3(64, 16), 256, 0, stream>>>(h128b, 128, g2t, 128, gb, C_, 128);

  // scan -> y staged in d_out (fully overwritten by final GEMM afterwards)
  rwkv_scan<<<512, 256, 0, stream>>>(rb, wdb, kb, kkb, aamt, vb, (float*)d_out);

  gn_bonus_gate<<<BT_, 256, 0, stream>>>((const float*)d_out, rb, kb, vb, gb,
                                         faaaa, lnw, lnb, zb);

  // out = z @ W_o
  gemm_bt<0><<<dim3(64, 16), 256, 0, stream>>>(zb, C_, WtO, C_, d_out, C_, C_);
}

// Round 4
// 764.685 us; speedup vs baseline: 2.1367x; 1.4059x over previous
//
#include <hip/hip_runtime.h>
#include <hip/hip_bf16.h>

using bf16 = __hip_bfloat16;
using bf16x8 = __attribute__((ext_vector_type(8))) short;  // 8 bf16 (4 VGPRs)
using f32x4 = __attribute__((ext_vector_type(4))) float;

#define B_ 2
#define T_ 2048
#define C_ 1024
#define BT_ (B_*T_)
#define H_ 16
#define N_ 64
#define LCH 32            // scan chunk length
#define NCH (T_/LCH)      // 64 chunks per head
#define CHD (B_*H_*NCH)   // 2048 chunk-heads

__device__ __forceinline__ float allred64(float v) {
#pragma unroll
  for (int m = 1; m < 64; m <<= 1) v += __shfl_xor(v, m, 64);
  return v;
}

__device__ __forceinline__ bf16 tobf(float f) { return __float2bfloat16(f); }
__device__ __forceinline__ float bf2f(unsigned short u) {
  unsigned int x = ((unsigned int)u) << 16;
  return __builtin_bit_cast(float, x);
}

__device__ __forceinline__ f32x4 mfma16x16x32(bf16x8 a, bf16x8 b, f32x4 c) {
  return __builtin_amdgcn_mfma_f32_16x16x32_bf16(a, b, c, 0, 0, 0);
}

// ---------------- ws_size diagnostic ----------------------------------------
__global__ void ws_diag(float a, float b, float* out) { out[0] = a; out[1] = b; }

// ---------------- weight transpose + bf16 cast (19 jobs, one launch) -------
struct PrepArgs {
  const float* src[19];
  bf16* dst[19];
};
__constant__ int kTR[19] = {1024,1024,1024,1024, 1024, 32,32,32,32,32,32,
                            1024,64, 1024,64, 1024,64, 1024,128};
__constant__ int kTC[19] = {1024,1024,1024,1024, 192, 1024,1024,1024,1024,1024,1024,
                            64,1024, 64,1024, 64,1024, 128,1024};

__global__ __launch_bounds__(256) void prep_weights(PrepArgs pa) {
  const int job = blockIdx.y;
  const int R = kTR[job], Cc = kTC[job];
  const int ntx = Cc >> 5, nty = R >> 5;
  const int tile = blockIdx.x;
  if (tile >= ntx * nty) return;
  const int tx = tile % ntx, ty = tile / ntx;
  const float* __restrict__ src = pa.src[job];
  bf16* __restrict__ dst = pa.dst[job];
  __shared__ float tl[32][33];
  const int lx = threadIdx.x & 31, ly = threadIdx.x >> 5;  // 32 x 8
#pragma unroll
  for (int q = 0; q < 4; ++q)
    tl[ly + 8*q][lx] = src[(size_t)(ty*32 + ly + 8*q) * Cc + tx*32 + lx];
  __syncthreads();
#pragma unroll
  for (int q = 0; q < 4; ++q)
    dst[(size_t)(tx*32 + ly + 8*q) * R + ty*32 + lx] = tobf(tl[lx][ly + 8*q]);
}

// ---------------- GEMM: C[M,N] = A[M,K](bf16) * Bt[N,K](bf16)^T ------------
template<int EPI>
__global__ __launch_bounds__(256) void gemm_bt(
    const bf16* __restrict__ A, int lda,
    const bf16* __restrict__ Bt, int ldb,
    void* __restrict__ Cout, int ldc, int K)
{
  __shared__ short As[64][40];
  __shared__ short Bs[64][40];
  const int bm0 = blockIdx.x * 64;
  const int bn0 = blockIdx.y * 64;
  const int tid = threadIdx.x;
  const int wave = tid >> 6, lane = tid & 63;
  const int lm = lane & 15, kg = lane >> 4;
  const int srow = tid >> 2, scol = (tid & 3) * 8;
  f32x4 acc[4] = {};
  const size_t abase = (size_t)(bm0 + srow) * lda + scol;
  const size_t bbase = (size_t)(bn0 + srow) * ldb + scol;
  for (int k0 = 0; k0 < K; k0 += 32) {
    *(uint4*)&As[srow][scol] = *(const uint4*)(A + abase + k0);
    *(uint4*)&Bs[srow][scol] = *(const uint4*)(Bt + bbase + k0);
    __syncthreads();
    bf16x8 af = *(const bf16x8*)&As[wave*16 + lm][kg*8];
#pragma unroll
    for (int f = 0; f < 4; ++f) {
      bf16x8 bfr = *(const bf16x8*)&Bs[f*16 + lm][kg*8];
      acc[f] = mfma16x16x32(af, bfr, acc[f]);
    }
    __syncthreads();
  }
  const int row0 = bm0 + wave*16 + kg*4;
  const int col0 = bn0 + lm;
#pragma unroll
  for (int f = 0; f < 4; ++f) {
#pragma unroll
    for (int q = 0; q < 4; ++q) {
      float val = acc[f][q];
      size_t o = (size_t)(row0 + q) * ldc + col0 + f*16;
      if (EPI == 0)      ((float*)Cout)[o] = val;
      else if (EPI == 1) ((bf16*)Cout)[o] = tobf(tanhf(val));
      else               ((bf16*)Cout)[o] = tobf(val);
    }
  }
}

// ---------------- elementwise ----------------------------------------------
__global__ __launch_bounds__(256) void xx_xin_k(
    const float* __restrict__ x, const float* __restrict__ maa_x,
    float* __restrict__ xx, bf16* __restrict__ xinb)
{
  size_t idx = (size_t)blockIdx.x * 256 + threadIdx.x;
  int c = idx & (C_ - 1);
  int t = (int)((idx >> 10) & (T_ - 1));
  float xv = x[idx];
  float xp = t ? x[idx - C_] : 0.f;
  float xxv = xp - xv;
  xx[idx] = xxv;
  xinb[idx] = tobf(xv + xxv * maa_x[c]);
}

__global__ __launch_bounds__(256) void combine_branch(
    const float* __restrict__ x, const float* __restrict__ xx,
    const float* __restrict__ maa, const float* __restrict__ m,
    bf16* __restrict__ xsb)
{
  size_t idx = (size_t)blockIdx.x * 256 + threadIdx.x;
  int c = idx & (C_ - 1);
  xsb[idx] = tobf(x[idx] + xx[idx] * (maa[c] + m[idx]));
}

// outputs log-decay lw = -exp(w) (used by chunked scan) and scales k in place
__global__ __launch_bounds__(256) void w_finalize(
    const float* __restrict__ wraw, const float* __restrict__ td,
    float* __restrict__ lw_out, float* __restrict__ k)
{
  size_t idx = (size_t)blockIdx.x * 256 + threadIdx.x;
  int c = idx & (C_ - 1);
  float wr = wraw[idx] + td[c];
  float sp = fmaxf(-wr, 0.f) + log1pf(expf(-fabsf(wr)));
  float w = -sp - 0.5f;
  lw_out[idx] = -expf(w);
  k[idx] *= expf(fminf(0.5f * w, 0.f));
}

__global__ __launch_bounds__(256) void a_finalize(
    const float* __restrict__ araw, const float* __restrict__ aaaaa,
    float* __restrict__ aamt)
{
  size_t idx = (size_t)blockIdx.x * 256 + threadIdx.x;
  int c = idx & (C_ - 1);
  float z = aaaaa[c] + araw[idx];
  aamt[idx] = 2.f / (1.f + expf(-z));
}

__global__ __launch_bounds__(256) void kk_normalize(
    const float* __restrict__ kraw, const float* __restrict__ kkadd,
    float* __restrict__ kkout)
{
  const int bt = blockIdx.x;
  const int tid = threadIdx.x;
  const size_t o = (size_t)bt * C_;
  float vals[4]; float ss = 0.f;
#pragma unroll
  for (int q = 0; q < 4; ++q) {
    float u = kraw[o + tid + q*256] + kkadd[o + tid + q*256];
    vals[q] = u; ss += u * u;
  }
  ss = allred64(ss);
  __shared__ float red[4];
  const int wave = tid >> 6, lane = tid & 63;
  if (lane == 0) red[wave] = ss;
  __syncthreads();
  float tot = red[0] + red[1] + red[2] + red[3];
  float inv = 1.f / fmaxf(sqrtf(tot), 1e-12f);
#pragma unroll
  for (int q = 0; q < 4; ++q) kkout[o + tid + q*256] = vals[q] * inv;
}

// ============ Chunked RWKV-7 scan (fp32 core, bf16 transfer ops) ============
// Derivation (verified): with lc_s = cumsum(log w), a_chk=a.*e^{lc_{s-1}},
// bt=b.*e^{-lc}, kt=k.*e^{-lc}, rt=r.*e^{lc}:
//   SA = (I-trilA)^{-1}(Achk S0^T + trilC V) = W S0^T + SA_loc
//   y[s] = rt_s S0^T + sum_{u<=s} ABy[s][u] SA_u + CKy[s][u] V_u
//   S_L = S0 diag(dL) + S0 G + U,  G=(W^T Bt).*dL_j, U=(SA_loc^T Bt+V^T Kt).*dL_j

__global__ __launch_bounds__(256) void rwkv_chunk_pre(
    const float* __restrict__ rr, const float* __restrict__ lw,
    const float* __restrict__ kk_s, const float* __restrict__ kkv,
    const float* __restrict__ aam, const float* __restrict__ vv,
    float* __restrict__ wbuf, float* __restrict__ sabuf,
    float* __restrict__ abybuf, float* __restrict__ ckybuf,
    bf16* __restrict__ ubufb, bf16* __restrict__ gbufb,
    float* __restrict__ dlbuf)
{
  __shared__ float aC[LCH][65], bTl[LCH][65], kTl[LCH][65], rC[LCH][65], vL[LCH][65];
  __shared__ float Am[LCH][33], Cm[LCH][33];
  __shared__ float X[LCH][129];     // cols 0..63 = W, 64..127 = SA_loc
  __shared__ float wtot[4][64];
  __shared__ float lcl[64];

  const int ch = blockIdx.x;
  const int c  = ch & (NCH - 1);
  const int bh = ch >> 6;                 // NCH = 64
  const int b  = bh >> 4, h = bh & 15;
  const int tid = threadIdx.x, wv = tid >> 6, ln = tid & 63;
  const size_t base = ((size_t)(b*T_ + c*LCH) * C_) + h*N_ + ln;

  // --- cumulative log-decay (8 rows per wave, contiguous) ---
  float lwr[8], lcE[8];
  {
    float run = 0.f;
#pragma unroll
    for (int q = 0; q < 8; ++q) {
      lwr[q] = lw[base + (size_t)(wv*8 + q) * C_];
      lcE[q] = run; run += lwr[q];
    }
    wtot[wv][ln] = run;
  }
  __syncthreads();
  {
    float pre = 0.f;
    for (int w2 = 0; w2 < wv; ++w2) pre += wtot[w2][ln];
    if (wv == 0) lcl[ln] = wtot[0][ln] + wtot[1][ln] + wtot[2][ln] + wtot[3][ln];
#pragma unroll
    for (int q = 0; q < 8; ++q) lcE[q] += pre;
  }
  // --- load + scale into LDS ---
#pragma unroll
  for (int q = 0; q < 8; ++q) {
    const int s = wv*8 + q;
    const size_t off = base + (size_t)s * C_;
    float kkx = kkv[off], aax = aam[off], kx = kk_s[off], rx = rr[off], vx = vv[off];
    float lcI = lcE[q] + lwr[q];
    float eE  = __expf(lcE[q]);
    float eIm = __expf(-lcI);
    float eI  = __expf(lcI);
    aC[s][ln]  = -kkx * eE;
    bTl[s][ln] = kkx * aax * eIm;
    kTl[s][ln] = kx * eIm;
    rC[s][ln]  = rx * eI;
    vL[s][ln]  = vx;
  }
  __syncthreads();

  // --- 4 small matrices (32x32 dots over j=64) ---
  {
    const int s = tid >> 3, u0 = (tid & 7) * 4;
    float accA[4] = {}, accC[4] = {}, accB[4] = {}, accK[4] = {};
    for (int j = 0; j < 64; ++j) {
      float av = aC[s][j], rv2 = rC[s][j];
#pragma unroll
      for (int e = 0; e < 4; ++e) {
        float bb = bTl[u0+e][j], kk2 = kTl[u0+e][j];
        accA[e] += av * bb;  accC[e] += av * kk2;
        accB[e] += rv2 * bb; accK[e] += rv2 * kk2;
      }
    }
#pragma unroll
    for (int e = 0; e < 4; ++e) {
      Am[s][u0+e] = accA[e]; Cm[s][u0+e] = accC[e];
      abybuf[(size_t)ch*LCH*LCH + s*LCH + u0+e] = accB[e];
      ckybuf[(size_t)ch*LCH*LCH + s*LCH + u0+e] = accK[e];
    }
  }
  __syncthreads();

  // --- X init: cols 0..63 = Achk (RHS for W), 64..127 = trilC @ V ---
  {
    const int s = tid >> 3, i0 = (tid & 7) * 8;
    float acc[8] = {};
    for (int u = 0; u < s; ++u) {
      float cs = Cm[s][u];
#pragma unroll
      for (int ii = 0; ii < 8; ++ii) acc[ii] += cs * vL[u][i0+ii];
    }
#pragma unroll
    for (int ii = 0; ii < 8; ++ii) {
      X[s][64 + i0 + ii] = acc[ii];
      X[s][i0 + ii] = aC[s][i0 + ii];
    }
  }
  __syncthreads();

  // --- forward substitution: X[s] += sum_{u<s} A[s][u] X[u] ---
  for (int s = 1; s < LCH; ++s) {
    if (tid < 128) {
      float acc = 0.f;
      for (int u = 0; u < s; ++u) acc += Am[s][u] * X[u][tid];
      X[s][tid] += acc;
    }
    __syncthreads();
  }

  // --- store W, SA_loc, dL ---
#pragma unroll
  for (int q = 0; q < 8; ++q) {
    int idx = q*256 + tid; int s = idx >> 6, j = idx & 63;
    wbuf[(size_t)ch*2048 + idx]  = X[s][j];
    sabuf[(size_t)ch*2048 + idx] = X[s][64 + j];
  }
  if (tid < 64) dlbuf[(size_t)ch*64 + tid] = __expf(lcl[tid]);

  // --- U (64x64) and G (64x64), stored bf16 ---
  {
    const int i = tid >> 2, j0 = (tid & 3) * 16;
    float dlj[16];
#pragma unroll
    for (int jj = 0; jj < 16; ++jj) dlj[jj] = __expf(lcl[j0 + jj]);
    float aU[16] = {}, aG[16] = {};
    for (int u = 0; u < LCH; ++u) {
      float su = X[u][64 + i], vu = vL[u][i], wm = X[u][i];
#pragma unroll
      for (int jj = 0; jj < 16; ++jj) {
        float bb = bTl[u][j0+jj];
        aU[jj] += su * bb + vu * kTl[u][j0+jj];
        aG[jj] += wm * bb;
      }
    }
#pragma unroll
    for (int jj = 0; jj < 16; ++jj) {
      ubufb[(size_t)ch*4096 + i*64 + j0 + jj] = tobf(aU[jj] * dlj[jj]);
      gbufb[(size_t)ch*4096 + i*64 + j0 + jj] = tobf(aG[jj] * dlj[jj]);
    }
  }
}

// Phase B: serial over chunks; 256 WGs = 32 heads x 8 rowgroups (8 rows each).
__global__ __launch_bounds__(256) void rwkv_chunk_state(
    const unsigned short* __restrict__ ubufb,
    const unsigned short* __restrict__ gbufb,
    const float* __restrict__ dlbuf, float* __restrict__ s0buf)
{
  __shared__ float Sl[8][65];
  __shared__ float Gl[64][68];
  __shared__ float Ul[8][65];
  __shared__ float dll[64];
  const int bh = blockIdx.x >> 3, rg = blockIdx.x & 7;
  const int i0 = rg * 8;
  const int tid = threadIdx.x;
#pragma unroll
  for (int q = 0; q < 2; ++q) { int idx = q*256 + tid; Sl[idx>>6][idx&63] = 0.f; }
  __syncthreads();

  uint4 gpre0, gpre1; unsigned int upre = 0; float dpre = 0.f;
  auto prefetch = [&](int c) {
    const size_t chb = (size_t)(bh*NCH + c);
    const unsigned short* gp = gbufb + chb*4096 + (size_t)tid*16;
    gpre0 = *(const uint4*)gp;
    gpre1 = *(const uint4*)(gp + 8);
    upre  = *(const unsigned int*)(ubufb + chb*4096 +
              (size_t)(i0 + (tid>>5))*64 + ((tid*2)&63));
    if (tid < 64) dpre = dlbuf[chb*64 + tid];
  };
  prefetch(0);

  for (int cc = 0; cc < NCH; ++cc) {
    const size_t ch = (size_t)bh*NCH + cc;
    // store S0 (state at chunk start)
#pragma unroll
    for (int q = 0; q < 2; ++q) {
      int idx = q*256 + tid; int il = idx >> 6, j = idx & 63;
      s0buf[(ch*64 + (i0 + il))*64 + j] = Sl[il][j];
    }
    // commit prefetched G/U/dl to LDS (bf16 -> f32)
    {
      const unsigned int* gw0 = (const unsigned int*)&gpre0;
      const unsigned int* gw1 = (const unsigned int*)&gpre1;
#pragma unroll
      for (int e = 0; e < 4; ++e) {
        int f0 = tid*16 + e*2;
        Gl[f0>>6][f0&63]       = bf2f((unsigned short)(gw0[e] & 0xffff));
        Gl[f0>>6][(f0&63)+1]   = bf2f((unsigned short)(gw0[e] >> 16));
        int f1 = tid*16 + 8 + e*2;
        Gl[f1>>6][f1&63]       = bf2f((unsigned short)(gw1[e] & 0xffff));
        Gl[f1>>6][(f1&63)+1]   = bf2f((unsigned short)(gw1[e] >> 16));
      }
      int fl = tid*2;
      Ul[fl>>6][fl&63]       = bf2f((unsigned short)(upre & 0xffff));
      Ul[fl>>6][(fl&63)+1]   = bf2f((unsigned short)(upre >> 16));
      if (tid < 64) dll[tid] = dpre;
    }
    __syncthreads();
    if (cc + 1 < NCH) prefetch(cc + 1);
    const int il = tid >> 5, j1 = tid & 31, j2 = j1 + 32;
    float a1 = Ul[il][j1] + Sl[il][j1] * dll[j1];
    float a2 = Ul[il][j2] + Sl[il][j2] * dll[j2];
    for (int m = 0; m < 64; ++m) {
      float sv = Sl[il][m];
      a1 += sv * Gl[m][j1];
      a2 += sv * Gl[m][j2];
    }
    __syncthreads();
    Sl[il][j1] = a1; Sl[il][j2] = a2;
    __syncthreads();
  }
}

// Phase C: per chunk-head, compute SA then y. Recomputes rt from rr, lw.
__global__ __launch_bounds__(256) void rwkv_chunk_out(
    const float* __restrict__ rr, const float* __restrict__ lw,
    const float* __restrict__ vv, const float* __restrict__ s0buf,
    const float* __restrict__ wbuf, const float* __restrict__ sabuf,
    const float* __restrict__ abybuf, const float* __restrict__ ckybuf,
    float* __restrict__ y)
{
  __shared__ float S0l[64][65];
  __shared__ float Wl[LCH][65], SAll[LCH][65], Rl[LCH][65], Vl[LCH][65], SAo[LCH][65];
  __shared__ float ABl[LCH][33], CKl[LCH][33];
  __shared__ float wtot[4][64];
  const int ch = blockIdx.x;
  const int c = ch & (NCH - 1), bh = ch >> 6, b = bh >> 4, h = bh & 15;
  const int tid = threadIdx.x, wv = tid >> 6, ln = tid & 63;
  const size_t base = ((size_t)(b*T_ + c*LCH) * C_) + h*N_ + ln;

  // recompute cumulative log-decay -> rt
  float lwr[8], lcE[8];
  {
    float run = 0.f;
#pragma unroll
    for (int q = 0; q < 8; ++q) {
      lwr[q] = lw[base + (size_t)(wv*8 + q) * C_];
      lcE[q] = run; run += lwr[q];
    }
    wtot[wv][ln] = run;
  }
  __syncthreads();
  {
    float pre = 0.f;
    for (int w2 = 0; w2 < wv; ++w2) pre += wtot[w2][ln];
#pragma unroll
    for (int q = 0; q < 8; ++q) lcE[q] += pre;
  }
#pragma unroll
  for (int q = 0; q < 8; ++q) {
    const int s = wv*8 + q;
    const size_t off = base + (size_t)s * C_;
    Rl[s][ln] = rr[off] * __expf(lcE[q] + lwr[q]);
    Vl[s][ln] = vv[off];
  }
#pragma unroll
  for (int q = 0; q < 16; ++q) {
    int idx = q*256 + tid;
    S0l[idx>>6][idx&63] = s0buf[(size_t)ch*4096 + idx];
  }
#pragma unroll
  for (int q = 0; q < 8; ++q) {
    int idx = q*256 + tid; int s = idx >> 6, j = idx & 63;
    Wl[s][j]   = wbuf[(size_t)ch*2048 + idx];
    SAll[s][j] = sabuf[(size_t)ch*2048 + idx];
  }
#pragma unroll
  for (int q = 0; q < 4; ++q) {
    int idx = q*256 + tid; int s = idx >> 5, u = idx & 31;
    ABl[s][u] = abybuf[(size_t)ch*1024 + idx];
    CKl[s][u] = ckybuf[(size_t)ch*1024 + idx];
  }
  __syncthreads();

  const int s = tid >> 3, i0 = (tid & 7) * 8;
  {
    float acc[8] = {};
    for (int j = 0; j < 64; ++j) {
      float wvv = Wl[s][j];
#pragma unroll
      for (int ii = 0; ii < 8; ++ii) acc[ii] += wvv * S0l[i0+ii][j];
    }
#pragma unroll
    for (int ii = 0; ii < 8; ++ii) SAo[s][i0+ii] = acc[ii] + SAll[s][i0+ii];
  }
  __syncthreads();
  {
    float yacc[8] = {};
    for (int j = 0; j < 64; ++j) {
      float rvv = Rl[s][j];
#pragma unroll
      for (int ii = 0; ii < 8; ++ii) yacc[ii] += rvv * S0l[i0+ii][j];
    }
    for (int u = 0; u <= s; ++u) {
      float ab = ABl[s][u], ck = CKl[s][u];
#pragma unroll
      for (int ii = 0; ii < 8; ++ii)
        yacc[ii] += ab * SAo[u][i0+ii] + ck * Vl[u][i0+ii];
    }
    size_t yb = ((size_t)(b*T_ + c*LCH + s)) * C_ + h*N_ + i0;
#pragma unroll
    for (int ii = 0; ii < 8; ++ii) y[yb + ii] = yacc[ii];
  }
}

// ---------------- groupnorm + bonus + gate ---------------------------------
__global__ __launch_bounds__(256) void gn_bonus_gate(
    const float* __restrict__ y, const float* __restrict__ rr,
    const float* __restrict__ kk_s, const float* __restrict__ vv,
    const bf16* __restrict__ gg, const float* __restrict__ faaaa,
    const float* __restrict__ lnw, const float* __restrict__ lnb,
    bf16* __restrict__ zb)
{
  const int bt = blockIdx.x;
  const int wave = threadIdx.x >> 6, lane = threadIdx.x & 63;
  const float inv64 = 1.f / 64.f;
  for (int h = wave; h < H_; h += 4) {
    const int c = h * 64 + lane;
    const size_t o = (size_t)bt * C_ + c;
    float yv = y[o];
    float mean = allred64(yv) * inv64;
    float d = yv - mean;
    float var = allred64(d * d) * inv64;
    float xn = d * rsqrtf(var + 6.4e-4f);
    float gn = xn * lnw[c] + lnb[c];
    float rk = allred64(rr[o] * kk_s[o] * faaaa[c]);
    float z = (gn + rk * vv[o]) * __bfloat162float(gg[o]);
    zb[o] = tobf(z);
  }
}

// ---------------- driver ----------------------------------------------------
extern "C" void kernel_launch(void* const* d_in, const int* in_sizes, int n_in,
                              void* d_out, int out_size, void* d_ws, size_t ws_size,
                              hipStream_t stream)
{
  const float* x     = (const float*)d_in[0];
  const float* maa_x = (const float*)d_in[1];
  const float* maa_r = (const float*)d_in[2];
  const float* maa_w = (const float*)d_in[3];
  const float* maa_k = (const float*)d_in[4];
  const float* maa_v = (const float*)d_in[5];
  const float* maa_a = (const float*)d_in[6];
  const float* maa_g = (const float*)d_in[7];
  const float* tdec  = (const float*)d_in[8];
  const float* faaaa = (const float*)d_in[9];
  const float* aaaaa = (const float*)d_in[10];
  const float* maa_w1= (const float*)d_in[11];
  const float* maa_w2= (const float*)d_in[12];
  const float* dec_w1= (const float*)d_in[13];
  const float* dec_w2= (const float*)d_in[14];
  const float* aaa_w1= (const float*)d_in[15];
  const float* aaa_w2= (const float*)d_in[16];
  const float* kkk_w1= (const float*)d_in[17];
  const float* kkk_w2= (const float*)d_in[18];
  const float* gate_w1=(const float*)d_in[19];
  const float* gate_w2=(const float*)d_in[20];
  const float* W_r   = (const float*)d_in[21];
  const float* W_k   = (const float*)d_in[22];
  const float* W_v   = (const float*)d_in[23];
  const float* W_o   = (const float*)d_in[24];
  const float* lnw   = (const float*)d_in[25];
  const float* lnb   = (const float*)d_in[26];

  char* ws = (char*)d_ws;
  size_t cur = 0;
  auto alloc = [&](size_t bytes) -> void* {
    void* p = ws + cur; cur += (bytes + 255) & ~(size_t)255; return p;
  };
  const size_t FBT = (size_t)BT_ * C_ * sizeof(float);

  // ---- persistent ----
  float* rb   = (float*)alloc(FBT);
  float* kb   = (float*)alloc(FBT);
  float* vb   = (float*)alloc(FBT);
  bf16*  gbb  = (bf16*)alloc((size_t)BT_*C_*2);
  bf16* WtR  = (bf16*)alloc((size_t)C_*C_*2);
  bf16* WtK  = (bf16*)alloc((size_t)C_*C_*2);
  bf16* WtV  = (bf16*)alloc((size_t)C_*C_*2);
  bf16* WtO  = (bf16*)alloc((size_t)C_*C_*2);
  bf16* w1t  = (bf16*)alloc((size_t)192*C_*2);
  bf16* w2t  = (bf16*)alloc((size_t)6*C_*32*2);
  bf16* d1t  = (bf16*)alloc((size_t)64*C_*2);
  bf16* d2t  = (bf16*)alloc((size_t)C_*64*2);
  bf16* a1t  = (bf16*)alloc((size_t)64*C_*2);
  bf16* a2t  = (bf16*)alloc((size_t)C_*64*2);
  bf16* k1t  = (bf16*)alloc((size_t)64*C_*2);
  bf16* k2t  = (bf16*)alloc((size_t)C_*64*2);
  bf16* g1t  = (bf16*)alloc((size_t)128*C_*2);
  bf16* g2t  = (bf16*)alloc((size_t)C_*128*2);
  float* lwb  = (float*)alloc(FBT);                 // alive through chunk_out
  // kkb+aamt: dead after chunk_pre; s0buf (32MB) overlays both
  float* kkb  = (float*)alloc(FBT);
  float* aamt = (float*)alloc(FBT);
  float* s0buf = kkb;

  // ---- union region: pre-scan temporaries overlaid by scan-phase buffers ----
  const size_t ubase = cur;
  float* xx   = (float*)alloc(FBT);
  float* mtmp = (float*)alloc(FBT);
  bf16* xinb = (bf16*)alloc((size_t)BT_*C_*2);
  bf16* mixb = (bf16*)alloc((size_t)BT_*192*2);
  bf16* xbr[6];
  for (int s = 0; s < 6; ++s) xbr[s] = (bf16*)alloc((size_t)BT_*C_*2);
  bf16* h64b = (bf16*)alloc((size_t)BT_*64*2);
  bf16* h128b= (bf16*)alloc((size_t)BT_*128*2);
  const size_t tmp_end = cur;
  cur = ubase;  // overlay
  float* wbuf   = (float*)alloc((size_t)CHD*2048*4);
  float* sabuf  = (float*)alloc((size_t)CHD*2048*4);
  float* abybuf = (float*)alloc((size_t)CHD*1024*4);
  float* ckybuf = (float*)alloc((size_t)CHD*1024*4);
  bf16*  ubufb  = (bf16*)alloc((size_t)CHD*4096*2);
  bf16*  gbufb  = (bf16*)alloc((size_t)CHD*4096*2);
  float* dlbuf  = (float*)alloc((size_t)CHD*64*4);
  bf16*  zb     = (bf16*)ubufb;   // alias: ubufb dead after chunk_state
  if (tmp_end > cur) cur = tmp_end;
  const size_t need = cur;        // ~215.0 MB (< 231.7 MB proven in R1/R2)
  (void)in_sizes; (void)n_in; (void)out_size;

  if (ws_size < need) {  // diagnostic: encode ws_size/need in output, fail clean
    ws_diag<<<1, 1, 0, stream>>>((float)ws_size, (float)need, (float*)d_out);
    return;
  }

  PrepArgs pa;
  pa.src[0] = W_r;  pa.dst[0] = WtR;
  pa.src[1] = W_k;  pa.dst[1] = WtK;
  pa.src[2] = W_v;  pa.dst[2] = WtV;
  pa.src[3] = W_o;  pa.dst[3] = WtO;
  pa.src[4] = maa_w1; pa.dst[4] = w1t;
  for (int s = 0; s < 6; ++s) { pa.src[5+s] = maa_w2 + (size_t)s*32*C_; pa.dst[5+s] = w2t + (size_t)s*C_*32; }
  pa.src[11] = dec_w1; pa.dst[11] = d1t;
  pa.src[12] = dec_w2; pa.dst[12] = d2t;
  pa.src[13] = aaa_w1; pa.dst[13] = a1t;
  pa.src[14] = aaa_w2; pa.dst[14] = a2t;
  pa.src[15] = kkk_w1; pa.dst[15] = k1t;
  pa.src[16] = kkk_w2; pa.dst[16] = k2t;
  pa.src[17] = gate_w1; pa.dst[17] = g1t;
  pa.src[18] = gate_w2; pa.dst[18] = g2t;
  prep_weights<<<dim3(1024, 19), 256, 0, stream>>>(pa);

  const int EW_GRID = (BT_ * C_) / 256;  // 16384
  xx_xin_k<<<EW_GRID, 256, 0, stream>>>(x, maa_x, xx, xinb);

  gemm_bt<1><<<dim3(64, 3), 256, 0, stream>>>(xinb, C_, w1t, C_, mixb, 192, C_);

  const float* maas[6] = {maa_r, maa_w, maa_k, maa_v, maa_a, maa_g};
  for (int s = 0; s < 6; ++s) {
    gemm_bt<0><<<dim3(64, 16), 256, 0, stream>>>(mixb + s*32, 192, w2t + (size_t)s*C_*32, 32, mtmp, C_, 32);
    combine_branch<<<EW_GRID, 256, 0, stream>>>(x, xx, maas[s], mtmp, xbr[s]);
  }

  gemm_bt<0><<<dim3(64, 16), 256, 0, stream>>>(xbr[0], C_, WtR, C_, rb, C_, C_);
  gemm_bt<0><<<dim3(64, 16), 256, 0, stream>>>(xbr[2], C_, WtK, C_, kb, C_, C_);
  gemm_bt<0><<<dim3(64, 16), 256, 0, stream>>>(xbr[3], C_, WtV, C_, vb, C_, C_);

  // kk path (uses UNscaled k)
  gemm_bt<1><<<dim3(64, 1), 256, 0, stream>>>(xbr[2], C_, k1t, C_, h64b, 64, C_);
  gemm_bt<0><<<dim3(64, 16), 256, 0, stream>>>(h64b, 64, k2t, 64, mtmp, C_, 64);
  kk_normalize<<<BT_, 256, 0, stream>>>(kb, mtmp, kkb);

  // w path (then scales k in place)
  gemm_bt<1><<<dim3(64, 1), 256, 0, stream>>>(xbr[1], C_, d1t, C_, h64b, 64, C_);
  gemm_bt<0><<<dim3(64, 16), 256, 0, stream>>>(h64b, 64, d2t, 64, mtmp, C_, 64);
  w_finalize<<<EW_GRID, 256, 0, stream>>>(mtmp, tdec, lwb, kb);

  // a path (NO tanh on inner projection)
  gemm_bt<2><<<dim3(64, 1), 256, 0, stream>>>(xbr[4], C_, a1t, C_, h64b, 64, C_);
  gemm_bt<0><<<dim3(64, 16), 256, 0, stream>>>(h64b, 64, a2t, 64, mtmp, C_, 64);
  a_finalize<<<EW_GRID, 256, 0, stream>>>(mtmp, aaaaa, aamt);

  // g path -> bf16 gate buffer
  gemm_bt<1><<<dim3(64, 2), 256, 0, stream>>>(xbr[5], C_, g1t, C_, h128b, 128, C_);
  gemm_bt<2><<<dim3(64, 16), 256, 0, stream>>>(h128b, 128, g2t, 128, gbb, C_, 128);

  // ---- chunked scan ----
  rwkv_chunk_pre<<<CHD, 256, 0, stream>>>(rb, lwb, kb, kkb, aamt, vb,
      wbuf, sabuf, abybuf, ckybuf, ubufb, gbufb, dlbuf);
  rwkv_chunk_state<<<256, 256, 0, stream>>>((const unsigned short*)ubufb,
      (const unsigned short*)gbufb, dlbuf, s0buf);
  rwkv_chunk_out<<<CHD, 256, 0, stream>>>(rb, lwb, vb, s0buf, wbuf, sabuf,
      abybuf, ckybuf, (float*)d_out);

  gn_bonus_gate<<<BT_, 256, 0, stream>>>((const float*)d_out, rb, kb, vb, gbb,
                                         faaaa, lnw, lnb, zb);

  gemm_bt<0><<<dim3(64, 16), 256, 0, stream>>>(zb, C_, WtO, C_, d_out, C_, C_);
}

// Round 5
// 603.755 us; speedup vs baseline: 2.7062x; 1.2665x over previous
//
#include <hip/hip_runtime.h>
#include <hip/hip_bf16.h>

using bf16 = __hip_bfloat16;
using bf16x8 = __attribute__((ext_vector_type(8))) short;  // 8 bf16 (4 VGPRs)
using f32x4 = __attribute__((ext_vector_type(4))) float;

#define B_ 2
#define T_ 2048
#define C_ 1024
#define BT_ (B_*T_)
#define H_ 16
#define N_ 64
#define LCH 32            // scan chunk length
#define NCH (T_/LCH)      // 64 chunks per head
#define CHD (B_*H_*NCH)   // 2048 chunk-heads

__device__ __forceinline__ float allred64(float v) {
#pragma unroll
  for (int m = 1; m < 64; m <<= 1) v += __shfl_xor(v, m, 64);
  return v;
}

__device__ __forceinline__ bf16 tobf(float f) { return __float2bfloat16(f); }
__device__ __forceinline__ float bf2f(unsigned short u) {
  unsigned int x = ((unsigned int)u) << 16;
  return __builtin_bit_cast(float, x);
}
__device__ __forceinline__ float rdlane(float v, int m) {
  return __builtin_bit_cast(float,
      __builtin_amdgcn_readlane(__builtin_bit_cast(int, v), m));
}

__device__ __forceinline__ f32x4 mfma16x16x32(bf16x8 a, bf16x8 b, f32x4 c) {
  return __builtin_amdgcn_mfma_f32_16x16x32_bf16(a, b, c, 0, 0, 0);
}

// ---------------- ws_size diagnostic ----------------------------------------
__global__ void ws_diag(float a, float b, float* out) { out[0] = a; out[1] = b; }

// ---------------- weight transpose + bf16 cast (19 jobs, one launch) -------
struct PrepArgs {
  const float* src[19];
  bf16* dst[19];
};
__constant__ int kTR[19] = {1024,1024,1024,1024, 1024, 32,32,32,32,32,32,
                            1024,64, 1024,64, 1024,64, 1024,128};
__constant__ int kTC[19] = {1024,1024,1024,1024, 192, 1024,1024,1024,1024,1024,1024,
                            64,1024, 64,1024, 64,1024, 128,1024};

__global__ __launch_bounds__(256) void prep_weights(PrepArgs pa) {
  const int job = blockIdx.y;
  const int R = kTR[job], Cc = kTC[job];
  const int ntx = Cc >> 5, nty = R >> 5;
  const int tile = blockIdx.x;
  if (tile >= ntx * nty) return;
  const int tx = tile % ntx, ty = tile / ntx;
  const float* __restrict__ src = pa.src[job];
  bf16* __restrict__ dst = pa.dst[job];
  __shared__ float tl[32][33];
  const int lx = threadIdx.x & 31, ly = threadIdx.x >> 5;  // 32 x 8
#pragma unroll
  for (int q = 0; q < 4; ++q)
    tl[ly + 8*q][lx] = src[(size_t)(ty*32 + ly + 8*q) * Cc + tx*32 + lx];
  __syncthreads();
#pragma unroll
  for (int q = 0; q < 4; ++q)
    dst[(size_t)(tx*32 + ly + 8*q) * R + ty*32 + lx] = tobf(tl[lx][ly + 8*q]);
}

// ---------------- GEMM: C[M,N] = A[M,K](bf16) * Bt[N,K](bf16)^T ------------
template<int EPI>
__global__ __launch_bounds__(256) void gemm_bt(
    const bf16* __restrict__ A, int lda,
    const bf16* __restrict__ Bt, int ldb,
    void* __restrict__ Cout, int ldc, int K)
{
  __shared__ short As[64][40];
  __shared__ short Bs[64][40];
  const int bm0 = blockIdx.x * 64;
  const int bn0 = blockIdx.y * 64;
  const int tid = threadIdx.x;
  const int wave = tid >> 6, lane = tid & 63;
  const int lm = lane & 15, kg = lane >> 4;
  const int srow = tid >> 2, scol = (tid & 3) * 8;
  f32x4 acc[4] = {};
  const size_t abase = (size_t)(bm0 + srow) * lda + scol;
  const size_t bbase = (size_t)(bn0 + srow) * ldb + scol;
  for (int k0 = 0; k0 < K; k0 += 32) {
    *(uint4*)&As[srow][scol] = *(const uint4*)(A + abase + k0);
    *(uint4*)&Bs[srow][scol] = *(const uint4*)(Bt + bbase + k0);
    __syncthreads();
    bf16x8 af = *(const bf16x8*)&As[wave*16 + lm][kg*8];
#pragma unroll
    for (int f = 0; f < 4; ++f) {
      bf16x8 bfr = *(const bf16x8*)&Bs[f*16 + lm][kg*8];
      acc[f] = mfma16x16x32(af, bfr, acc[f]);
    }
    __syncthreads();
  }
  const int row0 = bm0 + wave*16 + kg*4;
  const int col0 = bn0 + lm;
#pragma unroll
  for (int f = 0; f < 4; ++f) {
#pragma unroll
    for (int q = 0; q < 4; ++q) {
      float val = acc[f][q];
      size_t o = (size_t)(row0 + q) * ldc + col0 + f*16;
      if (EPI == 0)      ((float*)Cout)[o] = val;
      else if (EPI == 1) ((bf16*)Cout)[o] = tobf(tanhf(val));
      else               ((bf16*)Cout)[o] = tobf(val);
    }
  }
}

// --------- fused 6-branch low-rank projection + combine ---------------------
// m_s = mix[:, 32s:32s+32] @ w2[s]; xbr_s = x + (x_prev - x)*(maa_s + m_s)
struct Mix6Args { const float* maa[6]; bf16* out[6]; };

__global__ __launch_bounds__(256) void mix_combine(
    const bf16* __restrict__ mixb, const bf16* __restrict__ w2t,
    const float* __restrict__ x, Mix6Args ma)
{
  __shared__ short As[64][40];
  __shared__ short Bs[64][40];
  const int s6 = blockIdx.z;
  const bf16* __restrict__ A  = mixb + s6*32;            // lda = 192
  const bf16* __restrict__ Bt = w2t + (size_t)s6*C_*32;  // ldb = 32
  const float* __restrict__ maa = ma.maa[s6];
  bf16* __restrict__ out = ma.out[s6];
  const int bm0 = blockIdx.x * 64, bn0 = blockIdx.y * 64;
  const int tid = threadIdx.x, wave = tid >> 6, lane = tid & 63;
  const int lm = lane & 15, kg = lane >> 4;
  const int srow = tid >> 2, scol = (tid & 3) * 8;
  *(uint4*)&As[srow][scol] = *(const uint4*)(A + (size_t)(bm0 + srow)*192 + scol);
  *(uint4*)&Bs[srow][scol] = *(const uint4*)(Bt + (size_t)(bn0 + srow)*32 + scol);
  __syncthreads();
  bf16x8 af = *(const bf16x8*)&As[wave*16 + lm][kg*8];
  f32x4 acc[4] = {};
#pragma unroll
  for (int f = 0; f < 4; ++f) {
    bf16x8 bfr = *(const bf16x8*)&Bs[f*16 + lm][kg*8];
    acc[f] = mfma16x16x32(af, bfr, acc[f]);
  }
  const int row0 = bm0 + wave*16 + kg*4;
  const int col0 = bn0 + lm;
#pragma unroll
  for (int f = 0; f < 4; ++f) {
#pragma unroll
    for (int q = 0; q < 4; ++q) {
      const int row = row0 + q, col = col0 + f*16;
      const size_t o = (size_t)row * C_ + col;
      float xv = x[o];
      float xp = (row & (T_ - 1)) ? x[o - C_] : 0.f;
      out[o] = tobf(xv + (xp - xv) * (maa[col] + acc[f][q]));
    }
  }
}

// ---------------- elementwise ----------------------------------------------
__global__ __launch_bounds__(256) void xin_k(
    const float* __restrict__ x, const float* __restrict__ maa_x,
    bf16* __restrict__ xinb)
{
  size_t idx = (size_t)blockIdx.x * 256 + threadIdx.x;
  int c = idx & (C_ - 1);
  int t = (int)((idx >> 10) & (T_ - 1));
  float xv = x[idx];
  float xp = t ? x[idx - C_] : 0.f;
  xinb[idx] = tobf(xv + (xp - xv) * maa_x[c]);
}

// outputs log-decay lw = -exp(w) (used by chunked scan) and scales k in place
__global__ __launch_bounds__(256) void w_finalize(
    const float* __restrict__ wraw, const float* __restrict__ td,
    float* __restrict__ lw_out, float* __restrict__ k)
{
  size_t idx = (size_t)blockIdx.x * 256 + threadIdx.x;
  int c = idx & (C_ - 1);
  float wr = wraw[idx] + td[c];
  float sp = fmaxf(-wr, 0.f) + log1pf(expf(-fabsf(wr)));
  float w = -sp - 0.5f;
  lw_out[idx] = -expf(w);
  k[idx] *= expf(fminf(0.5f * w, 0.f));
}

__global__ __launch_bounds__(256) void a_finalize(
    const float* __restrict__ araw, const float* __restrict__ aaaaa,
    float* __restrict__ aamt)
{
  size_t idx = (size_t)blockIdx.x * 256 + threadIdx.x;
  int c = idx & (C_ - 1);
  float z = aaaaa[c] + araw[idx];
  aamt[idx] = 2.f / (1.f + expf(-z));
}

__global__ __launch_bounds__(256) void kk_normalize(
    const float* __restrict__ kraw, const float* __restrict__ kkadd,
    float* __restrict__ kkout)
{
  const int bt = blockIdx.x;
  const int tid = threadIdx.x;
  const size_t o = (size_t)bt * C_;
  float vals[4]; float ss = 0.f;
#pragma unroll
  for (int q = 0; q < 4; ++q) {
    float u = kraw[o + tid + q*256] + kkadd[o + tid + q*256];
    vals[q] = u; ss += u * u;
  }
  ss = allred64(ss);
  __shared__ float red[4];
  const int wave = tid >> 6, lane = tid & 63;
  if (lane == 0) red[wave] = ss;
  __syncthreads();
  float tot = red[0] + red[1] + red[2] + red[3];
  float inv = 1.f / fmaxf(sqrtf(tot), 1e-12f);
#pragma unroll
  for (int q = 0; q < 4; ++q) kkout[o + tid + q*256] = vals[q] * inv;
}

// ============ Chunked RWKV-7 scan (fp32 core, bf16 transfer ops) ============
// Derivation (verified): with lc_s = cumsum(log w), a_chk=a.*e^{lc_{s-1}},
// bt=b.*e^{-lc}, kt=k.*e^{-lc}, rt=r.*e^{lc}:
//   SA = (I-trilA)^{-1}(Achk S0^T + trilC V) = W S0^T + SA_loc
//   y[s] = rt_s S0^T + sum_{u<=s} ABy[s][u] SA_u + CKy[s][u] V_u
//   S_L = S0 diag(dL) + S0 G + U,  G=(W^T Bt).*dL_j, U=(SA_loc^T Bt+V^T Kt).*dL_j

__global__ __launch_bounds__(256) void rwkv_chunk_pre(
    const float* __restrict__ rr, const float* __restrict__ lw,
    const float* __restrict__ kk_s, const float* __restrict__ kkv,
    const float* __restrict__ aam, const float* __restrict__ vv,
    float* __restrict__ wbuf, float* __restrict__ sabuf,
    float* __restrict__ abybuf, float* __restrict__ ckybuf,
    bf16* __restrict__ ubufb, bf16* __restrict__ gbufb,
    float* __restrict__ dlbuf)
{
  __shared__ float aC[LCH][65], bTl[LCH][65], kTl[LCH][65], rC[LCH][65], vL[LCH][65];
  __shared__ float Am[LCH][33], Cm[LCH][33];
  __shared__ float X[LCH][129];     // cols 0..63 = W, 64..127 = SA_loc
  __shared__ float wtot[4][64];
  __shared__ float lcl[64];

  const int ch = blockIdx.x;
  const int c  = ch & (NCH - 1);
  const int bh = ch >> 6;                 // NCH = 64
  const int b  = bh >> 4, h = bh & 15;
  const int tid = threadIdx.x, wv = tid >> 6, ln = tid & 63;
  const size_t base = ((size_t)(b*T_ + c*LCH) * C_) + h*N_ + ln;

  // --- cumulative log-decay (8 rows per wave, contiguous) ---
  float lwr[8], lcE[8];
  {
    float run = 0.f;
#pragma unroll
    for (int q = 0; q < 8; ++q) {
      lwr[q] = lw[base + (size_t)(wv*8 + q) * C_];
      lcE[q] = run; run += lwr[q];
    }
    wtot[wv][ln] = run;
  }
  __syncthreads();
  {
    float pre = 0.f;
    for (int w2 = 0; w2 < wv; ++w2) pre += wtot[w2][ln];
    if (wv == 0) lcl[ln] = wtot[0][ln] + wtot[1][ln] + wtot[2][ln] + wtot[3][ln];
#pragma unroll
    for (int q = 0; q < 8; ++q) lcE[q] += pre;
  }
  // --- load + scale into LDS ---
#pragma unroll
  for (int q = 0; q < 8; ++q) {
    const int s = wv*8 + q;
    const size_t off = base + (size_t)s * C_;
    float kkx = kkv[off], aax = aam[off], kx = kk_s[off], rx = rr[off], vx = vv[off];
    float lcI = lcE[q] + lwr[q];
    float eE  = __expf(lcE[q]);
    float eIm = __expf(-lcI);
    float eI  = __expf(lcI);
    aC[s][ln]  = -kkx * eE;
    bTl[s][ln] = kkx * aax * eIm;
    kTl[s][ln] = kx * eIm;
    rC[s][ln]  = rx * eI;
    vL[s][ln]  = vx;
  }
  __syncthreads();

  // --- 4 small matrices (32x32 dots over j=64) ---
  {
    const int s = tid >> 3, u0 = (tid & 7) * 4;
    float accA[4] = {}, accC[4] = {}, accB[4] = {}, accK[4] = {};
    for (int j = 0; j < 64; ++j) {
      float av = aC[s][j], rv2 = rC[s][j];
#pragma unroll
      for (int e = 0; e < 4; ++e) {
        float bb = bTl[u0+e][j], kk2 = kTl[u0+e][j];
        accA[e] += av * bb;  accC[e] += av * kk2;
        accB[e] += rv2 * bb; accK[e] += rv2 * kk2;
      }
    }
#pragma unroll
    for (int e = 0; e < 4; ++e) {
      Am[s][u0+e] = accA[e]; Cm[s][u0+e] = accC[e];
      abybuf[(size_t)ch*LCH*LCH + s*LCH + u0+e] = accB[e];
      ckybuf[(size_t)ch*LCH*LCH + s*LCH + u0+e] = accK[e];
    }
  }
  __syncthreads();

  // --- X init: cols 0..63 = Achk (RHS for W), 64..127 = trilC @ V ---
  {
    const int s = tid >> 3, i0 = (tid & 7) * 8;
    float acc[8] = {};
    for (int u = 0; u < s; ++u) {
      float cs = Cm[s][u];
#pragma unroll
      for (int ii = 0; ii < 8; ++ii) acc[ii] += cs * vL[u][i0+ii];
    }
#pragma unroll
    for (int ii = 0; ii < 8; ++ii) {
      X[s][64 + i0 + ii] = acc[ii];
      X[s][i0 + ii] = aC[s][i0 + ii];
    }
  }
  __syncthreads();

  // --- forward substitution: X[s] += sum_{u<s} A[s][u] X[u] ---
  for (int s = 1; s < LCH; ++s) {
    if (tid < 128) {
      float acc = 0.f;
      for (int u = 0; u < s; ++u) acc += Am[s][u] * X[u][tid];
      X[s][tid] += acc;
    }
    __syncthreads();
  }

  // --- store W, SA_loc, dL ---
#pragma unroll
  for (int q = 0; q < 8; ++q) {
    int idx = q*256 + tid; int s = idx >> 6, j = idx & 63;
    wbuf[(size_t)ch*2048 + idx]  = X[s][j];
    sabuf[(size_t)ch*2048 + idx] = X[s][64 + j];
  }
  if (tid < 64) dlbuf[(size_t)ch*64 + tid] = __expf(lcl[tid]);

  // --- U (64x64) and G (64x64), stored bf16 ---
  {
    const int i = tid >> 2, j0 = (tid & 3) * 16;
    float dlj[16];
#pragma unroll
    for (int jj = 0; jj < 16; ++jj) dlj[jj] = __expf(lcl[j0 + jj]);
    float aU[16] = {}, aG[16] = {};
    for (int u = 0; u < LCH; ++u) {
      float su = X[u][64 + i], vu = vL[u][i], wm = X[u][i];
#pragma unroll
      for (int jj = 0; jj < 16; ++jj) {
        float bb = bTl[u][j0+jj];
        aU[jj] += su * bb + vu * kTl[u][j0+jj];
        aG[jj] += wm * bb;
      }
    }
#pragma unroll
    for (int jj = 0; jj < 16; ++jj) {
      ubufb[(size_t)ch*4096 + i*64 + j0 + jj] = tobf(aU[jj] * dlj[jj]);
      gbufb[(size_t)ch*4096 + i*64 + j0 + jj] = tobf(aG[jj] * dlj[jj]);
    }
  }
}

// Phase B: serial over chunks; 256 blocks = 32 heads x 8 rowgroups.
// Wave w owns rows i0=rg*8+2w, i0+1 with S in registers (lane = column j).
// S[i][m] broadcast via v_readlane; G staged f32 in double-buffered LDS.
__global__ __launch_bounds__(256) void rwkv_chunk_state(
    const unsigned short* __restrict__ ubufb,
    const unsigned short* __restrict__ gbufb,
    const float* __restrict__ dlbuf, float* __restrict__ s0buf)
{
  __shared__ float Gf[2][64][68];   // stride 68: 2-way bank alias only (free)
  const int bh = blockIdx.x >> 3, rg = blockIdx.x & 7;
  const int tid = threadIdx.x, wv = tid >> 6, ln = tid & 63;
  const int i0 = rg*8 + wv*2, i1 = i0 + 1;
  const int grow = tid >> 2, gcol = (tid & 3) * 16;  // coop G: 16 elems/thread
  float S0r = 0.f, S1r = 0.f;

  uint4 gp0, gp1; float u0p = 0.f, u1p = 0.f, dp = 0.f;
  auto prefetch = [&](int c) {
    const size_t chb = (size_t)(bh*NCH + c);
    const unsigned short* gp = gbufb + chb*4096 + (size_t)tid*16;
    gp0 = *(const uint4*)gp;
    gp1 = *(const uint4*)(gp + 8);
    u0p = bf2f(ubufb[chb*4096 + i0*64 + ln]);
    u1p = bf2f(ubufb[chb*4096 + i1*64 + ln]);
    dp  = dlbuf[chb*64 + ln];
  };
  prefetch(0);

  for (int cc = 0; cc < NCH; ++cc) {
    const size_t ch = (size_t)bh*NCH + cc;
    const int n = cc & 1;
    // commit prefetched G(cc) -> LDS[n] as f32 (float2 stores)
    {
      const unsigned int* w0 = (const unsigned int*)&gp0;
      const unsigned int* w1 = (const unsigned int*)&gp1;
#pragma unroll
      for (int e = 0; e < 4; ++e) {
        *(float2*)&Gf[n][grow][gcol + e*2] =
            make_float2(bf2f((unsigned short)(w0[e] & 0xffff)),
                        bf2f((unsigned short)(w0[e] >> 16)));
        *(float2*)&Gf[n][grow][gcol + 8 + e*2] =
            make_float2(bf2f((unsigned short)(w1[e] & 0xffff)),
                        bf2f((unsigned short)(w1[e] >> 16)));
      }
    }
    const float ucur0 = u0p, ucur1 = u1p, dcur = dp;
    // store S0 (state at chunk start)
    s0buf[(ch*64 + i0)*64 + ln] = S0r;
    s0buf[(ch*64 + i1)*64 + ln] = S1r;
    __syncthreads();
    if (cc + 1 < NCH) prefetch(cc + 1);
    float a0 = ucur0 + S0r * dcur;
    float a1 = ucur1 + S1r * dcur;
#pragma unroll
    for (int m = 0; m < 64; ++m) {
      float g = Gf[n][m][ln];
      a0 += rdlane(S0r, m) * g;
      a1 += rdlane(S1r, m) * g;
    }
    S0r = a0; S1r = a1;
  }
}

// Phase C: per chunk-head, compute SA then y. Recomputes rt from rr, lw.
__global__ __launch_bounds__(256) void rwkv_chunk_out(
    const float* __restrict__ rr, const float* __restrict__ lw,
    const float* __restrict__ vv, const float* __restrict__ s0buf,
    const float* __restrict__ wbuf, const float* __restrict__ sabuf,
    const float* __restrict__ abybuf, const float* __restrict__ ckybuf,
    float* __restrict__ y)
{
  __shared__ float S0l[64][65];
  __shared__ float Wl[LCH][65], SAll[LCH][65], Rl[LCH][65], Vl[LCH][65], SAo[LCH][65];
  __shared__ float ABl[LCH][33], CKl[LCH][33];
  __shared__ float wtot[4][64];
  const int ch = blockIdx.x;
  const int c = ch & (NCH - 1), bh = ch >> 6, b = bh >> 4, h = bh & 15;
  const int tid = threadIdx.x, wv = tid >> 6, ln = tid & 63;
  const size_t base = ((size_t)(b*T_ + c*LCH) * C_) + h*N_ + ln;

  // recompute cumulative log-decay -> rt
  float lwr[8], lcE[8];
  {
    float run = 0.f;
#pragma unroll
    for (int q = 0; q < 8; ++q) {
      lwr[q] = lw[base + (size_t)(wv*8 + q) * C_];
      lcE[q] = run; run += lwr[q];
    }
    wtot[wv][ln] = run;
  }
  __syncthreads();
  {
    float pre = 0.f;
    for (int w2 = 0; w2 < wv; ++w2) pre += wtot[w2][ln];
#pragma unroll
    for (int q = 0; q < 8; ++q) lcE[q] += pre;
  }
#pragma unroll
  for (int q = 0; q < 8; ++q) {
    const int s = wv*8 + q;
    const size_t off = base + (size_t)s * C_;
    Rl[s][ln] = rr[off] * __expf(lcE[q] + lwr[q]);
    Vl[s][ln] = vv[off];
  }
#pragma unroll
  for (int q = 0; q < 16; ++q) {
    int idx = q*256 + tid;
    S0l[idx>>6][idx&63] = s0buf[(size_t)ch*4096 + idx];
  }
#pragma unroll
  for (int q = 0; q < 8; ++q) {
    int idx = q*256 + tid; int s = idx >> 6, j = idx & 63;
    Wl[s][j]   = wbuf[(size_t)ch*2048 + idx];
    SAll[s][j] = sabuf[(size_t)ch*2048 + idx];
  }
#pragma unroll
  for (int q = 0; q < 4; ++q) {
    int idx = q*256 + tid; int s = idx >> 5, u = idx & 31;
    ABl[s][u] = abybuf[(size_t)ch*1024 + idx];
    CKl[s][u] = ckybuf[(size_t)ch*1024 + idx];
  }
  __syncthreads();

  const int s = tid >> 3, i0 = (tid & 7) * 8;
  {
    float acc[8] = {};
    for (int j = 0; j < 64; ++j) {
      float wvv = Wl[s][j];
#pragma unroll
      for (int ii = 0; ii < 8; ++ii) acc[ii] += wvv * S0l[i0+ii][j];
    }
#pragma unroll
    for (int ii = 0; ii < 8; ++ii) SAo[s][i0+ii] = acc[ii] + SAll[s][i0+ii];
  }
  __syncthreads();
  {
    float yacc[8] = {};
    for (int j = 0; j < 64; ++j) {
      float rvv = Rl[s][j];
#pragma unroll
      for (int ii = 0; ii < 8; ++ii) yacc[ii] += rvv * S0l[i0+ii][j];
    }
    for (int u = 0; u <= s; ++u) {
      float ab = ABl[s][u], ck = CKl[s][u];
#pragma unroll
      for (int ii = 0; ii < 8; ++ii)
        yacc[ii] += ab * SAo[u][i0+ii] + ck * Vl[u][i0+ii];
    }
    size_t yb = ((size_t)(b*T_ + c*LCH + s)) * C_ + h*N_ + i0;
#pragma unroll
    for (int ii = 0; ii < 8; ++ii) y[yb + ii] = yacc[ii];
  }
}

// ---------------- groupnorm + bonus + gate ---------------------------------
__global__ __launch_bounds__(256) void gn_bonus_gate(
    const float* __restrict__ y, const float* __restrict__ rr,
    const float* __restrict__ kk_s, const float* __restrict__ vv,
    const bf16* __restrict__ gg, const float* __restrict__ faaaa,
    const float* __restrict__ lnw, const float* __restrict__ lnb,
    bf16* __restrict__ zb)
{
  const int bt = blockIdx.x;
  const int wave = threadIdx.x >> 6, lane = threadIdx.x & 63;
  const float inv64 = 1.f / 64.f;
  for (int h = wave; h < H_; h += 4) {
    const int c = h * 64 + lane;
    const size_t o = (size_t)bt * C_ + c;
    float yv = y[o];
    float mean = allred64(yv) * inv64;
    float d = yv - mean;
    float var = allred64(d * d) * inv64;
    float xn = d * rsqrtf(var + 6.4e-4f);
    float gn = xn * lnw[c] + lnb[c];
    float rk = allred64(rr[o] * kk_s[o] * faaaa[c]);
    float z = (gn + rk * vv[o]) * __bfloat162float(gg[o]);
    zb[o] = tobf(z);
  }
}

// ---------------- driver ----------------------------------------------------
extern "C" void kernel_launch(void* const* d_in, const int* in_sizes, int n_in,
                              void* d_out, int out_size, void* d_ws, size_t ws_size,
                              hipStream_t stream)
{
  const float* x     = (const float*)d_in[0];
  const float* maa_x = (const float*)d_in[1];
  const float* maa_r = (const float*)d_in[2];
  const float* maa_w = (const float*)d_in[3];
  const float* maa_k = (const float*)d_in[4];
  const float* maa_v = (const float*)d_in[5];
  const float* maa_a = (const float*)d_in[6];
  const float* maa_g = (const float*)d_in[7];
  const float* tdec  = (const float*)d_in[8];
  const float* faaaa = (const float*)d_in[9];
  const float* aaaaa = (const float*)d_in[10];
  const float* maa_w1= (const float*)d_in[11];
  const float* maa_w2= (const float*)d_in[12];
  const float* dec_w1= (const float*)d_in[13];
  const float* dec_w2= (const float*)d_in[14];
  const float* aaa_w1= (const float*)d_in[15];
  const float* aaa_w2= (const float*)d_in[16];
  const float* kkk_w1= (const float*)d_in[17];
  const float* kkk_w2= (const float*)d_in[18];
  const float* gate_w1=(const float*)d_in[19];
  const float* gate_w2=(const float*)d_in[20];
  const float* W_r   = (const float*)d_in[21];
  const float* W_k   = (const float*)d_in[22];
  const float* W_v   = (const float*)d_in[23];
  const float* W_o   = (const float*)d_in[24];
  const float* lnw   = (const float*)d_in[25];
  const float* lnb   = (const float*)d_in[26];

  char* ws = (char*)d_ws;
  size_t cur = 0;
  auto alloc = [&](size_t bytes) -> void* {
    void* p = ws + cur; cur += (bytes + 255) & ~(size_t)255; return p;
  };
  const size_t FBT = (size_t)BT_ * C_ * sizeof(float);

  // ---- persistent ----
  float* rb   = (float*)alloc(FBT);
  float* kb   = (float*)alloc(FBT);
  float* vb   = (float*)alloc(FBT);
  bf16*  gbb  = (bf16*)alloc((size_t)BT_*C_*2);
  bf16* WtR  = (bf16*)alloc((size_t)C_*C_*2);
  bf16* WtK  = (bf16*)alloc((size_t)C_*C_*2);
  bf16* WtV  = (bf16*)alloc((size_t)C_*C_*2);
  bf16* WtO  = (bf16*)alloc((size_t)C_*C_*2);
  bf16* w1t  = (bf16*)alloc((size_t)192*C_*2);
  bf16* w2t  = (bf16*)alloc((size_t)6*C_*32*2);
  bf16* d1t  = (bf16*)alloc((size_t)64*C_*2);
  bf16* d2t  = (bf16*)alloc((size_t)C_*64*2);
  bf16* a1t  = (bf16*)alloc((size_t)64*C_*2);
  bf16* a2t  = (bf16*)alloc((size_t)C_*64*2);
  bf16* k1t  = (bf16*)alloc((size_t)64*C_*2);
  bf16* k2t  = (bf16*)alloc((size_t)C_*64*2);
  bf16* g1t  = (bf16*)alloc((size_t)128*C_*2);
  bf16* g2t  = (bf16*)alloc((size_t)C_*128*2);
  float* lwb  = (float*)alloc(FBT);                 // alive through chunk_out
  // kkb+aamt: dead after chunk_pre; s0buf (32MB) overlays both
  float* kkb  = (float*)alloc(FBT);
  float* aamt = (float*)alloc(FBT);
  float* s0buf = kkb;

  // ---- union region: pre-scan temporaries overlaid by scan-phase buffers ----
  const size_t ubase = cur;
  float* mtmp = (float*)alloc(FBT);
  bf16* xinb = (bf16*)alloc((size_t)BT_*C_*2);
  bf16* mixb = (bf16*)alloc((size_t)BT_*192*2);
  bf16* xbr[6];
  for (int s = 0; s < 6; ++s) xbr[s] = (bf16*)alloc((size_t)BT_*C_*2);
  bf16* h64b = (bf16*)alloc((size_t)BT_*64*2);
  bf16* h128b= (bf16*)alloc((size_t)BT_*128*2);
  const size_t tmp_end = cur;
  cur = ubase;  // overlay
  float* wbuf   = (float*)alloc((size_t)CHD*2048*4);
  float* sabuf  = (float*)alloc((size_t)CHD*2048*4);
  float* abybuf = (float*)alloc((size_t)CHD*1024*4);
  float* ckybuf = (float*)alloc((size_t)CHD*1024*4);
  bf16*  ubufb  = (bf16*)alloc((size_t)CHD*4096*2);
  bf16*  gbufb  = (bf16*)alloc((size_t)CHD*4096*2);
  float* dlbuf  = (float*)alloc((size_t)CHD*64*4);
  bf16*  zb     = (bf16*)ubufb;   // alias: ubufb dead after chunk_state
  if (tmp_end > cur) cur = tmp_end;
  const size_t need = cur;        // ~199 MB (< 231.7 MB proven in R1/R2)
  (void)in_sizes; (void)n_in; (void)out_size;

  if (ws_size < need) {  // diagnostic: encode ws_size/need in output, fail clean
    ws_diag<<<1, 1, 0, stream>>>((float)ws_size, (float)need, (float*)d_out);
    return;
  }

  PrepArgs pa;
  pa.src[0] = W_r;  pa.dst[0] = WtR;
  pa.src[1] = W_k;  pa.dst[1] = WtK;
  pa.src[2] = W_v;  pa.dst[2] = WtV;
  pa.src[3] = W_o;  pa.dst[3] = WtO;
  pa.src[4] = maa_w1; pa.dst[4] = w1t;
  for (int s = 0; s < 6; ++s) { pa.src[5+s] = maa_w2 + (size_t)s*32*C_; pa.dst[5+s] = w2t + (size_t)s*C_*32; }
  pa.src[11] = dec_w1; pa.dst[11] = d1t;
  pa.src[12] = dec_w2; pa.dst[12] = d2t;
  pa.src[13] = aaa_w1; pa.dst[13] = a1t;
  pa.src[14] = aaa_w2; pa.dst[14] = a2t;
  pa.src[15] = kkk_w1; pa.dst[15] = k1t;
  pa.src[16] = kkk_w2; pa.dst[16] = k2t;
  pa.src[17] = gate_w1; pa.dst[17] = g1t;
  pa.src[18] = gate_w2; pa.dst[18] = g2t;
  prep_weights<<<dim3(1024, 19), 256, 0, stream>>>(pa);

  const int EW_GRID = (BT_ * C_) / 256;  // 16384
  xin_k<<<EW_GRID, 256, 0, stream>>>(x, maa_x, xinb);

  // mix = tanh(xin @ w1) : M=4096 N=192 K=1024
  gemm_bt<1><<<dim3(64, 3), 256, 0, stream>>>(xinb, C_, w1t, C_, mixb, 192, C_);

  // fused: 6 low-rank projections + branch combines in one launch
  Mix6Args ma;
  ma.maa[0] = maa_r; ma.maa[1] = maa_w; ma.maa[2] = maa_k;
  ma.maa[3] = maa_v; ma.maa[4] = maa_a; ma.maa[5] = maa_g;
  for (int s = 0; s < 6; ++s) ma.out[s] = xbr[s];
  mix_combine<<<dim3(64, 16, 6), 256, 0, stream>>>(mixb, w2t, x, ma);

  gemm_bt<0><<<dim3(64, 16), 256, 0, stream>>>(xbr[0], C_, WtR, C_, rb, C_, C_);
  gemm_bt<0><<<dim3(64, 16), 256, 0, stream>>>(xbr[2], C_, WtK, C_, kb, C_, C_);
  gemm_bt<0><<<dim3(64, 16), 256, 0, stream>>>(xbr[3], C_, WtV, C_, vb, C_, C_);

  // kk path (uses UNscaled k)
  gemm_bt<1><<<dim3(64, 1), 256, 0, stream>>>(xbr[2], C_, k1t, C_, h64b, 64, C_);
  gemm_bt<0><<<dim3(64, 16), 256, 0, stream>>>(h64b, 64, k2t, 64, mtmp, C_, 64);
  kk_normalize<<<BT_, 256, 0, stream>>>(kb, mtmp, kkb);

  // w path (then scales k in place)
  gemm_bt<1><<<dim3(64, 1), 256, 0, stream>>>(xbr[1], C_, d1t, C_, h64b, 64, C_);
  gemm_bt<0><<<dim3(64, 16), 256, 0, stream>>>(h64b, 64, d2t, 64, mtmp, C_, 64);
  w_finalize<<<EW_GRID, 256, 0, stream>>>(mtmp, tdec, lwb, kb);

  // a path (NO tanh on inner projection)
  gemm_bt<2><<<dim3(64, 1), 256, 0, stream>>>(xbr[4], C_, a1t, C_, h64b, 64, C_);
  gemm_bt<0><<<dim3(64, 16), 256, 0, stream>>>(h64b, 64, a2t, 64, mtmp, C_, 64);
  a_finalize<<<EW_GRID, 256, 0, stream>>>(mtmp, aaaaa, aamt);

  // g path -> bf16 gate buffer
  gemm_bt<1><<<dim3(64, 2), 256, 0, stream>>>(xbr[5], C_, g1t, C_, h128b, 128, C_);
  gemm_bt<2><<<dim3(64, 16), 256, 0, stream>>>(h128b, 128, g2t, 128, gbb, C_, 128);

  // ---- chunked scan ----
  rwkv_chunk_pre<<<CHD, 256, 0, stream>>>(rb, lwb, kb, kkb, aamt, vb,
      wbuf, sabuf, abybuf, ckybuf, ubufb, gbufb, dlbuf);
  rwkv_chunk_state<<<256, 256, 0, stream>>>((const unsigned short*)ubufb,
      (const unsigned short*)gbufb, dlbuf, s0buf);
  rwkv_chunk_out<<<CHD, 256, 0, stream>>>(rb, lwb, vb, s0buf, wbuf, sabuf,
      abybuf, ckybuf, (float*)d_out);

  gn_bonus_gate<<<BT_, 256, 0, stream>>>((const float*)d_out, rb, kb, vb, gbb,
                                         faaaa, lnw, lnb, zb);

  gemm_bt<0><<<dim3(64, 16), 256, 0, stream>>>(zb, C_, WtO, C_, d_out, C_, C_);
}

// Round 6
// 550.655 us; speedup vs baseline: 2.9672x; 1.0964x over previous
//
#include <hip/hip_runtime.h>
#include <hip/hip_bf16.h>

using bf16 = __hip_bfloat16;
using bf16x8 = __attribute__((ext_vector_type(8))) short;  // 8 bf16 (4 VGPRs)
using f32x4 = __attribute__((ext_vector_type(4))) float;

#define B_ 2
#define T_ 2048
#define C_ 1024
#define BT_ (B_*T_)
#define H_ 16
#define N_ 64
#define LCH 32            // scan chunk length
#define NCH (T_/LCH)      // 64 chunks per head
#define CHD (B_*H_*NCH)   // 2048 chunk-heads

__device__ __forceinline__ float allred64(float v) {
#pragma unroll
  for (int m = 1; m < 64; m <<= 1) v += __shfl_xor(v, m, 64);
  return v;
}

__device__ __forceinline__ bf16 tobf(float f) { return __float2bfloat16(f); }
__device__ __forceinline__ float bf2f(unsigned short u) {
  unsigned int x = ((unsigned int)u) << 16;
  return __builtin_bit_cast(float, x);
}
__device__ __forceinline__ float rdlane(float v, int m) {
  return __builtin_bit_cast(float,
      __builtin_amdgcn_readlane(__builtin_bit_cast(int, v), m));
}

__device__ __forceinline__ f32x4 mfma16x16x32(bf16x8 a, bf16x8 b, f32x4 c) {
  return __builtin_amdgcn_mfma_f32_16x16x32_bf16(a, b, c, 0, 0, 0);
}

// async global->LDS, 16B per lane (dest = wave-uniform base + lane*16)
typedef const __attribute__((address_space(1))) unsigned int* gas_ptr;
typedef __attribute__((address_space(3))) unsigned int* las_ptr;
__device__ __forceinline__ void gload16(const void* g, void* l) {
  __builtin_amdgcn_global_load_lds((gas_ptr)g, (las_ptr)l, 16, 0, 0);
}

// ---------------- ws_size diagnostic ----------------------------------------
__global__ void ws_diag(float a, float b, float* out) { out[0] = a; out[1] = b; }

// ---------------- weight transpose + bf16 cast (19 jobs, one launch) -------
struct PrepArgs {
  const float* src[19];
  bf16* dst[19];
};
__constant__ int kTR[19] = {1024,1024,1024,1024, 1024, 32,32,32,32,32,32,
                            1024,64, 1024,64, 1024,64, 1024,128};
__constant__ int kTC[19] = {1024,1024,1024,1024, 192, 1024,1024,1024,1024,1024,1024,
                            64,1024, 64,1024, 64,1024, 128,1024};

__global__ __launch_bounds__(256) void prep_weights(PrepArgs pa) {
  const int job = blockIdx.y;
  const int R = kTR[job], Cc = kTC[job];
  const int ntx = Cc >> 5, nty = R >> 5;
  const int tile = blockIdx.x;
  if (tile >= ntx * nty) return;
  const int tx = tile % ntx, ty = tile / ntx;
  const float* __restrict__ src = pa.src[job];
  bf16* __restrict__ dst = pa.dst[job];
  __shared__ float tl[32][33];
  const int lx = threadIdx.x & 31, ly = threadIdx.x >> 5;  // 32 x 8
#pragma unroll
  for (int q = 0; q < 4; ++q)
    tl[ly + 8*q][lx] = src[(size_t)(ty*32 + ly + 8*q) * Cc + tx*32 + lx];
  __syncthreads();
#pragma unroll
  for (int q = 0; q < 4; ++q)
    dst[(size_t)(tx*32 + ly + 8*q) * R + ty*32 + lx] = tobf(tl[lx][ly + 8*q]);
}

// ------- GEMM 64-tile (used for N not divisible by 128) ---------------------
template<int EPI>
__global__ __launch_bounds__(256) void gemm_bt(
    const bf16* __restrict__ A, int lda,
    const bf16* __restrict__ Bt, int ldb,
    void* __restrict__ Cout, int ldc, int K)
{
  __shared__ short As[64][40];
  __shared__ short Bs[64][40];
  const int bm0 = blockIdx.x * 64;
  const int bn0 = blockIdx.y * 64;
  const int tid = threadIdx.x;
  const int wave = tid >> 6, lane = tid & 63;
  const int lm = lane & 15, kg = lane >> 4;
  const int srow = tid >> 2, scol = (tid & 3) * 8;
  f32x4 acc[4] = {};
  const size_t abase = (size_t)(bm0 + srow) * lda + scol;
  const size_t bbase = (size_t)(bn0 + srow) * ldb + scol;
  for (int k0 = 0; k0 < K; k0 += 32) {
    *(uint4*)&As[srow][scol] = *(const uint4*)(A + abase + k0);
    *(uint4*)&Bs[srow][scol] = *(const uint4*)(Bt + bbase + k0);
    __syncthreads();
    bf16x8 af = *(const bf16x8*)&As[wave*16 + lm][kg*8];
#pragma unroll
    for (int f = 0; f < 4; ++f) {
      bf16x8 bfr = *(const bf16x8*)&Bs[f*16 + lm][kg*8];
      acc[f] = mfma16x16x32(af, bfr, acc[f]);
    }
    __syncthreads();
  }
  const int row0 = bm0 + wave*16 + kg*4;
  const int col0 = bn0 + lm;
#pragma unroll
  for (int f = 0; f < 4; ++f) {
#pragma unroll
    for (int q = 0; q < 4; ++q) {
      float val = acc[f][q];
      size_t o = (size_t)(row0 + q) * ldc + col0 + f*16;
      if (EPI == 0)      ((float*)Cout)[o] = val;
      else if (EPI == 1) ((bf16*)Cout)[o] = tobf(tanhf(val));
      else               ((bf16*)Cout)[o] = tobf(val);
    }
  }
}

// ------- GEMM 128-tile, m97 structure (global_load_lds staging) -------------
// C[M,N] = A[M,K](bf16) * Bt[N,K](bf16)^T. M%128==0, N%128==0, K%32==0.
template<int EPI>
__global__ __launch_bounds__(256) void gemm128(
    const bf16* __restrict__ A, int lda,
    const bf16* __restrict__ Bt, int ldb,
    void* __restrict__ Cout, int ldc, int K)
{
  __shared__ bf16 As[128][32];     // linear (required by global_load_lds)
  __shared__ bf16 Bs[128][32];
  const int bm0 = blockIdx.x * 128, bn0 = blockIdx.y * 128;
  const int tid = threadIdx.x, wv = tid >> 6, ln = tid & 63;
  const int wr = wv >> 1, wc = wv & 1;
  const int lm = ln & 15, kg = ln >> 4;
  const int srow = ln >> 2, scol = (ln & 3) * 8;  // lane's 16B within 16 rows
  f32x4 acc[4][4] = {};
  for (int k0 = 0; k0 < K; k0 += 32) {
#pragma unroll
    for (int i = 0; i < 2; ++i) {
      const int r0 = wv*32 + i*16;
      gload16(A  + (size_t)(bm0 + r0 + srow) * lda + k0 + scol, &As[r0][0]);
      gload16(Bt + (size_t)(bn0 + r0 + srow) * ldb + k0 + scol, &Bs[r0][0]);
    }
    asm volatile("s_waitcnt vmcnt(0)" ::: "memory");
    __syncthreads();
    bf16x8 af[4], bfr[4];
#pragma unroll
    for (int m = 0; m < 4; ++m) af[m] = *(const bf16x8*)&As[wr*64 + m*16 + lm][kg*8];
#pragma unroll
    for (int n = 0; n < 4; ++n) bfr[n] = *(const bf16x8*)&Bs[wc*64 + n*16 + lm][kg*8];
#pragma unroll
    for (int m = 0; m < 4; ++m)
#pragma unroll
      for (int n = 0; n < 4; ++n)
        acc[m][n] = mfma16x16x32(af[m], bfr[n], acc[m][n]);
    __syncthreads();
  }
#pragma unroll
  for (int m = 0; m < 4; ++m) {
    const int row0 = bm0 + wr*64 + m*16 + kg*4;
#pragma unroll
    for (int n = 0; n < 4; ++n) {
      const int col = bn0 + wc*64 + n*16 + lm;
#pragma unroll
      for (int q = 0; q < 4; ++q) {
        float val = acc[m][n][q];
        size_t o = (size_t)(row0 + q) * ldc + col;
        if (EPI == 0) ((float*)Cout)[o] = val;
        else          ((bf16*)Cout)[o] = tobf(val);
      }
    }
  }
}

// --------- fused 6-branch low-rank projection + combine ---------------------
struct Mix6Args { const float* maa[6]; bf16* out[6]; };

__global__ __launch_bounds__(256) void mix_combine(
    const bf16* __restrict__ mixb, const bf16* __restrict__ w2t,
    const float* __restrict__ x, Mix6Args ma)
{
  __shared__ short As[64][40];
  __shared__ short Bs[64][40];
  const int s6 = blockIdx.z;
  const bf16* __restrict__ A  = mixb + s6*32;            // lda = 192
  const bf16* __restrict__ Bt = w2t + (size_t)s6*C_*32;  // ldb = 32
  const float* __restrict__ maa = ma.maa[s6];
  bf16* __restrict__ out = ma.out[s6];
  const int bm0 = blockIdx.x * 64, bn0 = blockIdx.y * 64;
  const int tid = threadIdx.x, wave = tid >> 6, lane = tid & 63;
  const int lm = lane & 15, kg = lane >> 4;
  const int srow = tid >> 2, scol = (tid & 3) * 8;
  *(uint4*)&As[srow][scol] = *(const uint4*)(A + (size_t)(bm0 + srow)*192 + scol);
  *(uint4*)&Bs[srow][scol] = *(const uint4*)(Bt + (size_t)(bn0 + srow)*32 + scol);
  __syncthreads();
  bf16x8 af = *(const bf16x8*)&As[wave*16 + lm][kg*8];
  f32x4 acc[4] = {};
#pragma unroll
  for (int f = 0; f < 4; ++f) {
    bf16x8 bfr = *(const bf16x8*)&Bs[f*16 + lm][kg*8];
    acc[f] = mfma16x16x32(af, bfr, acc[f]);
  }
  const int row0 = bm0 + wave*16 + kg*4;
  const int col0 = bn0 + lm;
#pragma unroll
  for (int f = 0; f < 4; ++f) {
#pragma unroll
    for (int q = 0; q < 4; ++q) {
      const int row = row0 + q, col = col0 + f*16;
      const size_t o = (size_t)row * C_ + col;
      float xv = x[o];
      float xp = (row & (T_ - 1)) ? x[o - C_] : 0.f;
      out[o] = tobf(xv + (xp - xv) * (maa[col] + acc[f][q]));
    }
  }
}

// ---------------- elementwise ----------------------------------------------
__global__ __launch_bounds__(256) void xin_k(
    const float* __restrict__ x, const float* __restrict__ maa_x,
    bf16* __restrict__ xinb)
{
  size_t idx = (size_t)blockIdx.x * 256 + threadIdx.x;
  int c = idx & (C_ - 1);
  int t = (int)((idx >> 10) & (T_ - 1));
  float xv = x[idx];
  float xp = t ? x[idx - C_] : 0.f;
  xinb[idx] = tobf(xv + (xp - xv) * maa_x[c]);
}

__global__ __launch_bounds__(256) void w_finalize(
    const float* __restrict__ wraw, const float* __restrict__ td,
    float* __restrict__ lw_out, float* __restrict__ k)
{
  size_t idx = (size_t)blockIdx.x * 256 + threadIdx.x;
  int c = idx & (C_ - 1);
  float wr = wraw[idx] + td[c];
  float sp = fmaxf(-wr, 0.f) + log1pf(expf(-fabsf(wr)));
  float w = -sp - 0.5f;
  lw_out[idx] = -expf(w);
  k[idx] *= expf(fminf(0.5f * w, 0.f));
}

__global__ __launch_bounds__(256) void a_finalize(
    const float* __restrict__ araw, const float* __restrict__ aaaaa,
    float* __restrict__ aamt)
{
  size_t idx = (size_t)blockIdx.x * 256 + threadIdx.x;
  int c = idx & (C_ - 1);
  float z = aaaaa[c] + araw[idx];
  aamt[idx] = 2.f / (1.f + expf(-z));
}

__global__ __launch_bounds__(256) void kk_normalize(
    const float* __restrict__ kraw, const float* __restrict__ kkadd,
    float* __restrict__ kkout)
{
  const int bt = blockIdx.x;
  const int tid = threadIdx.x;
  const size_t o = (size_t)bt * C_;
  float vals[4]; float ss = 0.f;
#pragma unroll
  for (int q = 0; q < 4; ++q) {
    float u = kraw[o + tid + q*256] + kkadd[o + tid + q*256];
    vals[q] = u; ss += u * u;
  }
  ss = allred64(ss);
  __shared__ float red[4];
  const int wave = tid >> 6, lane = tid & 63;
  if (lane == 0) red[wave] = ss;
  __syncthreads();
  float tot = red[0] + red[1] + red[2] + red[3];
  float inv = 1.f / fmaxf(sqrtf(tot), 1e-12f);
#pragma unroll
  for (int q = 0; q < 4; ++q) kkout[o + tid + q*256] = vals[q] * inv;
}

// ============ Chunked RWKV-7 scan (fp32 core, bf16 transfer ops) ============
//   SA = (I-trilA)^{-1}(Achk S0^T + trilC V) = W S0^T + SA_loc
//   y[s] = rt_s S0^T + sum_{u<=s} ABy[s][u] SA_u + CKy[s][u] V_u
//   S_L = S0 diag(dL) + S0 G + U,  G=(W^T Bt).*dL_j, U=(SA_loc^T Bt+V^T Kt).*dL_j

__global__ __launch_bounds__(256, 3) void rwkv_chunk_pre(
    const float* __restrict__ rr, const float* __restrict__ lw,
    const float* __restrict__ kk_s, const float* __restrict__ kkv,
    const float* __restrict__ aam, const float* __restrict__ vv,
    float* __restrict__ wbuf, float* __restrict__ sabuf,
    float* __restrict__ abybuf, float* __restrict__ ckybuf,
    bf16* __restrict__ ubufb, bf16* __restrict__ gbufb,
    float* __restrict__ dlbuf)
{
  // stride 68: 16B-aligned rows, bank-rotation 4s%32 (conflict-free per the
  // u0+8m interleave below). aC becomes W and rC becomes SA_loc after solve.
  __shared__ float aC[LCH][68], bTl[LCH][68], kTl[LCH][68], rC[LCH][68], vL[LCH][68];
  __shared__ float Am[LCH][33], Cm[LCH][33];
  __shared__ float wtot[4][64];
  __shared__ float lcl[64];

  const int ch = blockIdx.x;
  const int c  = ch & (NCH - 1);
  const int bh = ch >> 6;
  const int b  = bh >> 4, h = bh & 15;
  const int tid = threadIdx.x, wv = tid >> 6, ln = tid & 63;
  const size_t base = ((size_t)(b*T_ + c*LCH) * C_) + h*N_ + ln;

  // --- phase 1: cumulative log-decay + load/scale into LDS ---
  float lwr[8], lcE[8];
  {
    float run = 0.f;
#pragma unroll
    for (int q = 0; q < 8; ++q) {
      lwr[q] = lw[base + (size_t)(wv*8 + q) * C_];
      lcE[q] = run; run += lwr[q];
    }
    wtot[wv][ln] = run;
  }
  __syncthreads();
  {
    float pre = 0.f;
    for (int w2 = 0; w2 < wv; ++w2) pre += wtot[w2][ln];
    if (wv == 0) lcl[ln] = wtot[0][ln] + wtot[1][ln] + wtot[2][ln] + wtot[3][ln];
#pragma unroll
    for (int q = 0; q < 8; ++q) lcE[q] += pre;
  }
#pragma unroll
  for (int q = 0; q < 8; ++q) {
    const int s = wv*8 + q;
    const size_t off = base + (size_t)s * C_;
    float kkx = kkv[off], aax = aam[off], kx = kk_s[off], rx = rr[off], vx = vv[off];
    float lcI = lcE[q] + lwr[q];
    float eIm = __expf(-lcI);
    aC[s][ln]  = -kkx * __expf(lcE[q]);
    bTl[s][ln] = kkx * aax * eIm;
    kTl[s][ln] = kx * eIm;
    rC[s][ln]  = rx * __expf(lcI);
    vL[s][ln]  = vx;
  }
  __syncthreads();

  // --- phase 2: Am, Cm (LDS) + ABy, CKy (global); b128 reads, u=u0+8m ---
  {
    const int s2 = tid >> 3, u0 = tid & 7;
    float accA[4] = {}, accC[4] = {}, accB[4] = {}, accK[4] = {};
    for (int j0 = 0; j0 < 64; j0 += 4) {
      float av[4], rv[4];
      *(float4*)av = *(const float4*)&aC[s2][j0];
      *(float4*)rv = *(const float4*)&rC[s2][j0];
#pragma unroll
      for (int m = 0; m < 4; ++m) {
        float bb[4], kk[4];
        *(float4*)bb = *(const float4*)&bTl[u0 + 8*m][j0];
        *(float4*)kk = *(const float4*)&kTl[u0 + 8*m][j0];
#pragma unroll
        for (int e = 0; e < 4; ++e) {
          accA[m] += av[e]*bb[e]; accC[m] += av[e]*kk[e];
          accB[m] += rv[e]*bb[e]; accK[m] += rv[e]*kk[e];
        }
      }
    }
#pragma unroll
    for (int m = 0; m < 4; ++m) {
      Am[s2][u0 + 8*m] = accA[m]; Cm[s2][u0 + 8*m] = accC[m];
      abybuf[(size_t)ch*1024 + s2*32 + u0 + 8*m] = accB[m];
      ckybuf[(size_t)ch*1024 + s2*32 + u0 + 8*m] = accK[m];
    }
  }
  __syncthreads();

  if (tid < 64) dlbuf[(size_t)ch*64 + tid] = __expf(lcl[tid]);

  // --- phase 3: register forward-substitution (wave0: W, wave1: SA_loc) ---
  if (wv < 2) {
    float Xr[32], amr[32];
#pragma unroll
    for (int s = 0; s < 32; ++s) amr[s] = Am[s][ln & 31];
    if (wv == 0) {
#pragma unroll
      for (int s = 0; s < 32; ++s) Xr[s] = aC[s][ln];
    } else {
      float cmr[32];
#pragma unroll
      for (int s = 0; s < 32; ++s) cmr[s] = Cm[s][ln & 31];
#pragma unroll
      for (int s = 0; s < 32; ++s) Xr[s] = 0.f;
#pragma unroll
      for (int u = 0; u < 31; ++u) {
        float v = vL[u][ln];
#pragma unroll
        for (int s = u + 1; s < 32; ++s) Xr[s] += rdlane(cmr[s], u) * v;
      }
    }
#pragma unroll
    for (int s = 1; s < 32; ++s) {
      float acc = Xr[s];
#pragma unroll
      for (int u = 0; u < s; ++u) acc += rdlane(amr[s], u) * Xr[u];
      Xr[s] = acc;
    }
    if (wv == 0) {
#pragma unroll
      for (int s = 0; s < 32; ++s) {
        aC[s][ln] = Xr[s];                              // aC := W
        wbuf[(size_t)ch*2048 + s*64 + ln] = Xr[s];
      }
    } else {
#pragma unroll
      for (int s = 0; s < 32; ++s) {
        rC[s][ln] = Xr[s];                              // rC := SA_loc
        sabuf[(size_t)ch*2048 + s*64 + ln] = Xr[s];
      }
    }
  }
  __syncthreads();

  // --- phase 5: U (64x64) and G (64x64), stored bf16; 4x4 register tiles ---
  {
    const int i0 = (tid >> 4) * 4, j0 = (tid & 15) * 4;
    float dl4[4];
#pragma unroll
    for (int e = 0; e < 4; ++e) dl4[e] = __expf(lcl[j0 + e]);
    float aU[4][4] = {}, aG[4][4] = {};
    for (int u = 0; u < 32; ++u) {
      float su[4], wm[4], vv4[4], bb[4], kk[4];
      *(float4*)su  = *(const float4*)&rC[u][i0];
      *(float4*)wm  = *(const float4*)&aC[u][i0];
      *(float4*)vv4 = *(const float4*)&vL[u][i0];
      *(float4*)bb  = *(const float4*)&bTl[u][j0];
      *(float4*)kk  = *(const float4*)&kTl[u][j0];
#pragma unroll
      for (int i = 0; i < 4; ++i)
#pragma unroll
        for (int j = 0; j < 4; ++j) {
          aU[i][j] += su[i]*bb[j] + vv4[i]*kk[j];
          aG[i][j] += wm[i]*bb[j];
        }
    }
#pragma unroll
    for (int i = 0; i < 4; ++i)
#pragma unroll
      for (int j = 0; j < 4; ++j) {
        ubufb[(size_t)ch*4096 + (i0+i)*64 + j0+j] = tobf(aU[i][j] * dl4[j]);
        gbufb[(size_t)ch*4096 + (i0+i)*64 + j0+j] = tobf(aG[i][j] * dl4[j]);
      }
  }
}

// Phase B: serial over chunks; 256 blocks = 32 heads x 8 rowgroups.
__global__ __launch_bounds__(256) void rwkv_chunk_state(
    const unsigned short* __restrict__ ubufb,
    const unsigned short* __restrict__ gbufb,
    const float* __restrict__ dlbuf, float* __restrict__ s0buf)
{
  __shared__ float Gf[2][64][68];
  const int bh = blockIdx.x >> 3, rg = blockIdx.x & 7;
  const int tid = threadIdx.x, wv = tid >> 6, ln = tid & 63;
  const int i0 = rg*8 + wv*2, i1 = i0 + 1;
  const int grow = tid >> 2, gcol = (tid & 3) * 16;
  float S0r = 0.f, S1r = 0.f;

  uint4 gp0, gp1; float u0p = 0.f, u1p = 0.f, dp = 0.f;
  auto prefetch = [&](int c) {
    const size_t chb = (size_t)(bh*NCH + c);
    const unsigned short* gp = gbufb + chb*4096 + (size_t)tid*16;
    gp0 = *(const uint4*)gp;
    gp1 = *(const uint4*)(gp + 8);
    u0p = bf2f(ubufb[chb*4096 + i0*64 + ln]);
    u1p = bf2f(ubufb[chb*4096 + i1*64 + ln]);
    dp  = dlbuf[chb*64 + ln];
  };
  prefetch(0);

  for (int cc = 0; cc < NCH; ++cc) {
    const size_t ch = (size_t)bh*NCH + cc;
    const int n = cc & 1;
    {
      const unsigned int* w0 = (const unsigned int*)&gp0;
      const unsigned int* w1 = (const unsigned int*)&gp1;
#pragma unroll
      for (int e = 0; e < 4; ++e) {
        *(float2*)&Gf[n][grow][gcol + e*2] =
            make_float2(bf2f((unsigned short)(w0[e] & 0xffff)),
                        bf2f((unsigned short)(w0[e] >> 16)));
        *(float2*)&Gf[n][grow][gcol + 8 + e*2] =
            make_float2(bf2f((unsigned short)(w1[e] & 0xffff)),
                        bf2f((unsigned short)(w1[e] >> 16)));
      }
    }
    const float ucur0 = u0p, ucur1 = u1p, dcur = dp;
    s0buf[(ch*64 + i0)*64 + ln] = S0r;
    s0buf[(ch*64 + i1)*64 + ln] = S1r;
    __syncthreads();
    if (cc + 1 < NCH) prefetch(cc + 1);
    float a0 = ucur0 + S0r * dcur;
    float a1 = ucur1 + S1r * dcur;
#pragma unroll
    for (int m = 0; m < 64; ++m) {
      float g = Gf[n][m][ln];
      a0 += rdlane(S0r, m) * g;
      a1 += rdlane(S1r, m) * g;
    }
    S0r = a0; S1r = a1;
  }
}

// Phase C: per chunk-head, compute SA then y. Recomputes rt from rr, lw.
__global__ __launch_bounds__(256) void rwkv_chunk_out(
    const float* __restrict__ rr, const float* __restrict__ lw,
    const float* __restrict__ vv, const float* __restrict__ s0buf,
    const float* __restrict__ wbuf, const float* __restrict__ sabuf,
    const float* __restrict__ abybuf, const float* __restrict__ ckybuf,
    float* __restrict__ y)
{
  __shared__ float S0l[64][65];
  __shared__ float Wl[LCH][65], SAll[LCH][65], Rl[LCH][65], Vl[LCH][65], SAo[LCH][65];
  __shared__ float ABl[LCH][33], CKl[LCH][33];
  __shared__ float wtot[4][64];
  const int ch = blockIdx.x;
  const int c = ch & (NCH - 1), bh = ch >> 6, b = bh >> 4, h = bh & 15;
  const int tid = threadIdx.x, wv = tid >> 6, ln = tid & 63;
  const size_t base = ((size_t)(b*T_ + c*LCH) * C_) + h*N_ + ln;

  float lwr[8], lcE[8];
  {
    float run = 0.f;
#pragma unroll
    for (int q = 0; q < 8; ++q) {
      lwr[q] = lw[base + (size_t)(wv*8 + q) * C_];
      lcE[q] = run; run += lwr[q];
    }
    wtot[wv][ln] = run;
  }
  __syncthreads();
  {
    float pre = 0.f;
    for (int w2 = 0; w2 < wv; ++w2) pre += wtot[w2][ln];
#pragma unroll
    for (int q = 0; q < 8; ++q) lcE[q] += pre;
  }
#pragma unroll
  for (int q = 0; q < 8; ++q) {
    const int s = wv*8 + q;
    const size_t off = base + (size_t)s * C_;
    Rl[s][ln] = rr[off] * __expf(lcE[q] + lwr[q]);
    Vl[s][ln] = vv[off];
  }
#pragma unroll
  for (int q = 0; q < 16; ++q) {
    int idx = q*256 + tid;
    S0l[idx>>6][idx&63] = s0buf[(size_t)ch*4096 + idx];
  }
#pragma unroll
  for (int q = 0; q < 8; ++q) {
    int idx = q*256 + tid; int s = idx >> 6, j = idx & 63;
    Wl[s][j]   = wbuf[(size_t)ch*2048 + idx];
    SAll[s][j] = sabuf[(size_t)ch*2048 + idx];
  }
#pragma unroll
  for (int q = 0; q < 4; ++q) {
    int idx = q*256 + tid; int s = idx >> 5, u = idx & 31;
    ABl[s][u] = abybuf[(size_t)ch*1024 + idx];
    CKl[s][u] = ckybuf[(size_t)ch*1024 + idx];
  }
  __syncthreads();

  const int s = tid >> 3, i0 = (tid & 7) * 8;
  {
    float acc[8] = {};
    for (int j = 0; j < 64; ++j) {
      float wvv = Wl[s][j];
#pragma unroll
      for (int ii = 0; ii < 8; ++ii) acc[ii] += wvv * S0l[i0+ii][j];
    }
#pragma unroll
    for (int ii = 0; ii < 8; ++ii) SAo[s][i0+ii] = acc[ii] + SAll[s][i0+ii];
  }
  __syncthreads();
  {
    float yacc[8] = {};
    for (int j = 0; j < 64; ++j) {
      float rvv = Rl[s][j];
#pragma unroll
      for (int ii = 0; ii < 8; ++ii) yacc[ii] += rvv * S0l[i0+ii][j];
    }
    for (int u = 0; u <= s; ++u) {
      float ab = ABl[s][u], ck = CKl[s][u];
#pragma unroll
      for (int ii = 0; ii < 8; ++ii)
        yacc[ii] += ab * SAo[u][i0+ii] + ck * Vl[u][i0+ii];
    }
    size_t yb = ((size_t)(b*T_ + c*LCH + s)) * C_ + h*N_ + i0;
#pragma unroll
    for (int ii = 0; ii < 8; ++ii) y[yb + ii] = yacc[ii];
  }
}

// ---------------- groupnorm + bonus + gate ---------------------------------
__global__ __launch_bounds__(256) void gn_bonus_gate(
    const float* __restrict__ y, const float* __restrict__ rr,
    const float* __restrict__ kk_s, const float* __restrict__ vv,
    const bf16* __restrict__ gg, const float* __restrict__ faaaa,
    const float* __restrict__ lnw, const float* __restrict__ lnb,
    bf16* __restrict__ zb)
{
  const int bt = blockIdx.x;
  const int wave = threadIdx.x >> 6, lane = threadIdx.x & 63;
  const float inv64 = 1.f / 64.f;
  for (int h = wave; h < H_; h += 4) {
    const int c = h * 64 + lane;
    const size_t o = (size_t)bt * C_ + c;
    float yv = y[o];
    float mean = allred64(yv) * inv64;
    float d = yv - mean;
    float var = allred64(d * d) * inv64;
    float xn = d * rsqrtf(var + 6.4e-4f);
    float gn = xn * lnw[c] + lnb[c];
    float rk = allred64(rr[o] * kk_s[o] * faaaa[c]);
    float z = (gn + rk * vv[o]) * __bfloat162float(gg[o]);
    zb[o] = tobf(z);
  }
}

// ---------------- driver ----------------------------------------------------
extern "C" void kernel_launch(void* const* d_in, const int* in_sizes, int n_in,
                              void* d_out, int out_size, void* d_ws, size_t ws_size,
                              hipStream_t stream)
{
  const float* x     = (const float*)d_in[0];
  const float* maa_x = (const float*)d_in[1];
  const float* maa_r = (const float*)d_in[2];
  const float* maa_w = (const float*)d_in[3];
  const float* maa_k = (const float*)d_in[4];
  const float* maa_v = (const float*)d_in[5];
  const float* maa_a = (const float*)d_in[6];
  const float* maa_g = (const float*)d_in[7];
  const float* tdec  = (const float*)d_in[8];
  const float* faaaa = (const float*)d_in[9];
  const float* aaaaa = (const float*)d_in[10];
  const float* maa_w1= (const float*)d_in[11];
  const float* maa_w2= (const float*)d_in[12];
  const float* dec_w1= (const float*)d_in[13];
  const float* dec_w2= (const float*)d_in[14];
  const float* aaa_w1= (const float*)d_in[15];
  const float* aaa_w2= (const float*)d_in[16];
  const float* kkk_w1= (const float*)d_in[17];
  const float* kkk_w2= (const float*)d_in[18];
  const float* gate_w1=(const float*)d_in[19];
  const float* gate_w2=(const float*)d_in[20];
  const float* W_r   = (const float*)d_in[21];
  const float* W_k   = (const float*)d_in[22];
  const float* W_v   = (const float*)d_in[23];
  const float* W_o   = (const float*)d_in[24];
  const float* lnw   = (const float*)d_in[25];
  const float* lnb   = (const float*)d_in[26];

  char* ws = (char*)d_ws;
  size_t cur = 0;
  auto alloc = [&](size_t bytes) -> void* {
    void* p = ws + cur; cur += (bytes + 255) & ~(size_t)255; return p;
  };
  const size_t FBT = (size_t)BT_ * C_ * sizeof(float);

  // ---- persistent ----
  float* rb   = (float*)alloc(FBT);
  float* kb   = (float*)alloc(FBT);
  float* vb   = (float*)alloc(FBT);
  bf16*  gbb  = (bf16*)alloc((size_t)BT_*C_*2);
  bf16* WtR  = (bf16*)alloc((size_t)C_*C_*2);
  bf16* WtK  = (bf16*)alloc((size_t)C_*C_*2);
  bf16* WtV  = (bf16*)alloc((size_t)C_*C_*2);
  bf16* WtO  = (bf16*)alloc((size_t)C_*C_*2);
  bf16* w1t  = (bf16*)alloc((size_t)192*C_*2);
  bf16* w2t  = (bf16*)alloc((size_t)6*C_*32*2);
  bf16* d1t  = (bf16*)alloc((size_t)64*C_*2);
  bf16* d2t  = (bf16*)alloc((size_t)C_*64*2);
  bf16* a1t  = (bf16*)alloc((size_t)64*C_*2);
  bf16* a2t  = (bf16*)alloc((size_t)C_*64*2);
  bf16* k1t  = (bf16*)alloc((size_t)64*C_*2);
  bf16* k2t  = (bf16*)alloc((size_t)C_*64*2);
  bf16* g1t  = (bf16*)alloc((size_t)128*C_*2);
  bf16* g2t  = (bf16*)alloc((size_t)C_*128*2);
  float* lwb  = (float*)alloc(FBT);
  float* kkb  = (float*)alloc(FBT);
  float* aamt = (float*)alloc(FBT);
  float* s0buf = kkb;   // overlay: kkb+aamt dead after chunk_pre

  // ---- union region ----
  const size_t ubase = cur;
  float* mtmp = (float*)alloc(FBT);
  bf16* xinb = (bf16*)alloc((size_t)BT_*C_*2);
  bf16* mixb = (bf16*)alloc((size_t)BT_*192*2);
  bf16* xbr[6];
  for (int s = 0; s < 6; ++s) xbr[s] = (bf16*)alloc((size_t)BT_*C_*2);
  bf16* h64b = (bf16*)alloc((size_t)BT_*64*2);
  bf16* h128b= (bf16*)alloc((size_t)BT_*128*2);
  const size_t tmp_end = cur;
  cur = ubase;  // overlay
  float* wbuf   = (float*)alloc((size_t)CHD*2048*4);
  float* sabuf  = (float*)alloc((size_t)CHD*2048*4);
  float* abybuf = (float*)alloc((size_t)CHD*1024*4);
  float* ckybuf = (float*)alloc((size_t)CHD*1024*4);
  bf16*  ubufb  = (bf16*)alloc((size_t)CHD*4096*2);
  bf16*  gbufb  = (bf16*)alloc((size_t)CHD*4096*2);
  float* dlbuf  = (float*)alloc((size_t)CHD*64*4);
  bf16*  zb     = (bf16*)ubufb;   // alias: ubufb dead after chunk_state
  if (tmp_end > cur) cur = tmp_end;
  const size_t need = cur;
  (void)in_sizes; (void)n_in; (void)out_size;

  if (ws_size < need) {
    ws_diag<<<1, 1, 0, stream>>>((float)ws_size, (float)need, (float*)d_out);
    return;
  }

  PrepArgs pa;
  pa.src[0] = W_r;  pa.dst[0] = WtR;
  pa.src[1] = W_k;  pa.dst[1] = WtK;
  pa.src[2] = W_v;  pa.dst[2] = WtV;
  pa.src[3] = W_o;  pa.dst[3] = WtO;
  pa.src[4] = maa_w1; pa.dst[4] = w1t;
  for (int s = 0; s < 6; ++s) { pa.src[5+s] = maa_w2 + (size_t)s*32*C_; pa.dst[5+s] = w2t + (size_t)s*C_*32; }
  pa.src[11] = dec_w1; pa.dst[11] = d1t;
  pa.src[12] = dec_w2; pa.dst[12] = d2t;
  pa.src[13] = aaa_w1; pa.dst[13] = a1t;
  pa.src[14] = aaa_w2; pa.dst[14] = a2t;
  pa.src[15] = kkk_w1; pa.dst[15] = k1t;
  pa.src[16] = kkk_w2; pa.dst[16] = k2t;
  pa.src[17] = gate_w1; pa.dst[17] = g1t;
  pa.src[18] = gate_w2; pa.dst[18] = g2t;
  prep_weights<<<dim3(1024, 19), 256, 0, stream>>>(pa);

  const int EW_GRID = (BT_ * C_) / 256;  // 16384
  xin_k<<<EW_GRID, 256, 0, stream>>>(x, maa_x, xinb);

  gemm_bt<1><<<dim3(64, 3), 256, 0, stream>>>(xinb, C_, w1t, C_, mixb, 192, C_);

  Mix6Args ma;
  ma.maa[0] = maa_r; ma.maa[1] = maa_w; ma.maa[2] = maa_k;
  ma.maa[3] = maa_v; ma.maa[4] = maa_a; ma.maa[5] = maa_g;
  for (int s = 0; s < 6; ++s) ma.out[s] = xbr[s];
  mix_combine<<<dim3(64, 16, 6), 256, 0, stream>>>(mixb, w2t, x, ma);

  gemm128<0><<<dim3(32, 8), 256, 0, stream>>>(xbr[0], C_, WtR, C_, rb, C_, C_);
  gemm128<0><<<dim3(32, 8), 256, 0, stream>>>(xbr[2], C_, WtK, C_, kb, C_, C_);
  gemm128<0><<<dim3(32, 8), 256, 0, stream>>>(xbr[3], C_, WtV, C_, vb, C_, C_);

  // kk path (uses UNscaled k)
  gemm_bt<1><<<dim3(64, 1), 256, 0, stream>>>(xbr[2], C_, k1t, C_, h64b, 64, C_);
  gemm128<0><<<dim3(32, 8), 256, 0, stream>>>(h64b, 64, k2t, 64, mtmp, C_, 64);
  kk_normalize<<<BT_, 256, 0, stream>>>(kb, mtmp, kkb);

  // w path (then scales k in place)
  gemm_bt<1><<<dim3(64, 1), 256, 0, stream>>>(xbr[1], C_, d1t, C_, h64b, 64, C_);
  gemm128<0><<<dim3(32, 8), 256, 0, stream>>>(h64b, 64, d2t, 64, mtmp, C_, 64);
  w_finalize<<<EW_GRID, 256, 0, stream>>>(mtmp, tdec, lwb, kb);

  // a path (NO tanh on inner projection)
  gemm_bt<2><<<dim3(64, 1), 256, 0, stream>>>(xbr[4], C_, a1t, C_, h64b, 64, C_);
  gemm128<0><<<dim3(32, 8), 256, 0, stream>>>(h64b, 64, a2t, 64, mtmp, C_, 64);
  a_finalize<<<EW_GRID, 256, 0, stream>>>(mtmp, aaaaa, aamt);

  // g path -> bf16 gate buffer
  gemm_bt<1><<<dim3(64, 2), 256, 0, stream>>>(xbr[5], C_, g1t, C_, h128b, 128, C_);
  gemm128<2><<<dim3(32, 8), 256, 0, stream>>>(h128b, 128, g2t, 128, gbb, C_, 128);

  // ---- chunked scan ----
  rwkv_chunk_pre<<<CHD, 256, 0, stream>>>(rb, lwb, kb, kkb, aamt, vb,
      wbuf, sabuf, abybuf, ckybuf, ubufb, gbufb, dlbuf);
  rwkv_chunk_state<<<256, 256, 0, stream>>>((const unsigned short*)ubufb,
      (const unsigned short*)gbufb, dlbuf, s0buf);
  rwkv_chunk_out<<<CHD, 256, 0, stream>>>(rb, lwb, vb, s0buf, wbuf, sabuf,
      abybuf, ckybuf, (float*)d_out);

  gn_bonus_gate<<<BT_, 256, 0, stream>>>((const float*)d_out, rb, kb, vb, gbb,
                                         faaaa, lnw, lnb, zb);

  gemm128<0><<<dim3(32, 8), 256, 0, stream>>>(zb, C_, WtO, C_, d_out, C_, C_);
}

// Round 7
// 458.100 us; speedup vs baseline: 3.5667x; 1.2020x over previous
//
#include <hip/hip_runtime.h>
#include <hip/hip_bf16.h>

using bf16 = __hip_bfloat16;
using bf16x8 = __attribute__((ext_vector_type(8))) short;  // 8 bf16 (4 VGPRs)
using f32x4 = __attribute__((ext_vector_type(4))) float;

#define B_ 2
#define T_ 2048
#define C_ 1024
#define BT_ (B_*T_)
#define H_ 16
#define N_ 64
#define LCH 32            // scan chunk length
#define NCH (T_/LCH)      // 64 chunks per head
#define CHD (B_*H_*NCH)   // 2048 chunk-heads

__device__ __forceinline__ float allred64(float v) {
#pragma unroll
  for (int m = 1; m < 64; m <<= 1) v += __shfl_xor(v, m, 64);
  return v;
}

__device__ __forceinline__ bf16 tobf(float f) { return __float2bfloat16(f); }
__device__ __forceinline__ float bf2f(unsigned short u) {
  unsigned int x = ((unsigned int)u) << 16;
  return __builtin_bit_cast(float, x);
}
__device__ __forceinline__ float rdlane(float v, int m) {
  return __builtin_bit_cast(float,
      __builtin_amdgcn_readlane(__builtin_bit_cast(int, v), m));
}

__device__ __forceinline__ f32x4 mfma16x16x32(bf16x8 a, bf16x8 b, f32x4 c) {
  return __builtin_amdgcn_mfma_f32_16x16x32_bf16(a, b, c, 0, 0, 0);
}

// async global->LDS, 16B per lane (dest = wave-uniform base + lane*16)
typedef const __attribute__((address_space(1))) unsigned int* gas_ptr;
typedef __attribute__((address_space(3))) unsigned int* las_ptr;
__device__ __forceinline__ void gload16(const void* g, void* l) {
  __builtin_amdgcn_global_load_lds((gas_ptr)g, (las_ptr)l, 16, 0, 0);
}

// ---------------- ws_size diagnostic ----------------------------------------
__global__ void ws_diag(float a, float b, float* out) { out[0] = a; out[1] = b; }

// ---------------- weight transpose + bf16 cast (19 jobs, one launch) -------
struct PrepArgs {
  const float* src[19];
  bf16* dst[19];
};
__constant__ int kTR[19] = {1024,1024,1024,1024, 1024, 32,32,32,32,32,32,
                            1024,64, 1024,64, 1024,64, 1024,128};
__constant__ int kTC[19] = {1024,1024,1024,1024, 192, 1024,1024,1024,1024,1024,1024,
                            64,1024, 64,1024, 64,1024, 128,1024};

__global__ __launch_bounds__(256) void prep_weights(PrepArgs pa) {
  const int job = blockIdx.y;
  const int R = kTR[job], Cc = kTC[job];
  const int ntx = Cc >> 5, nty = R >> 5;
  const int tile = blockIdx.x;
  if (tile >= ntx * nty) return;
  const int tx = tile % ntx, ty = tile / ntx;
  const float* __restrict__ src = pa.src[job];
  bf16* __restrict__ dst = pa.dst[job];
  __shared__ float tl[32][33];
  const int lx = threadIdx.x & 31, ly = threadIdx.x >> 5;  // 32 x 8
#pragma unroll
  for (int q = 0; q < 4; ++q)
    tl[ly + 8*q][lx] = src[(size_t)(ty*32 + ly + 8*q) * Cc + tx*32 + lx];
  __syncthreads();
#pragma unroll
  for (int q = 0; q < 4; ++q)
    dst[(size_t)(tx*32 + ly + 8*q) * R + ty*32 + lx] = tobf(tl[lx][ly + 8*q]);
}

// ------- GEMM 64-tile (used for small N / odd shapes) -----------------------
template<int EPI>
__global__ __launch_bounds__(256) void gemm_bt(
    const bf16* __restrict__ A, int lda,
    const bf16* __restrict__ Bt, int ldb,
    void* __restrict__ Cout, int ldc, int K)
{
  __shared__ short As[64][40];
  __shared__ short Bs[64][40];
  const int bm0 = blockIdx.x * 64;
  const int bn0 = blockIdx.y * 64;
  const int tid = threadIdx.x;
  const int wave = tid >> 6, lane = tid & 63;
  const int lm = lane & 15, kg = lane >> 4;
  const int srow = tid >> 2, scol = (tid & 3) * 8;
  f32x4 acc[4] = {};
  const size_t abase = (size_t)(bm0 + srow) * lda + scol;
  const size_t bbase = (size_t)(bn0 + srow) * ldb + scol;
  for (int k0 = 0; k0 < K; k0 += 32) {
    *(uint4*)&As[srow][scol] = *(const uint4*)(A + abase + k0);
    *(uint4*)&Bs[srow][scol] = *(const uint4*)(Bt + bbase + k0);
    __syncthreads();
    bf16x8 af = *(const bf16x8*)&As[wave*16 + lm][kg*8];
#pragma unroll
    for (int f = 0; f < 4; ++f) {
      bf16x8 bfr = *(const bf16x8*)&Bs[f*16 + lm][kg*8];
      acc[f] = mfma16x16x32(af, bfr, acc[f]);
    }
    __syncthreads();
  }
  const int row0 = bm0 + wave*16 + kg*4;
  const int col0 = bn0 + lm;
#pragma unroll
  for (int f = 0; f < 4; ++f) {
#pragma unroll
    for (int q = 0; q < 4; ++q) {
      float val = acc[f][q];
      size_t o = (size_t)(row0 + q) * ldc + col0 + f*16;
      if (EPI == 0)      ((float*)Cout)[o] = val;
      else if (EPI == 1) ((bf16*)Cout)[o] = tobf(tanhf(val));
      else               ((bf16*)Cout)[o] = tobf(val);
    }
  }
}

// ------- GEMM 128-tile, m97 structure (global_load_lds staging) -------------
template<int EPI>
__global__ __launch_bounds__(256) void gemm128(
    const bf16* __restrict__ A, int lda,
    const bf16* __restrict__ Bt, int ldb,
    void* __restrict__ Cout, int ldc, int K)
{
  __shared__ bf16 As[128][32];     // linear (required by global_load_lds)
  __shared__ bf16 Bs[128][32];
  const int bm0 = blockIdx.x * 128, bn0 = blockIdx.y * 128;
  const int tid = threadIdx.x, wv = tid >> 6, ln = tid & 63;
  const int wr = wv >> 1, wc = wv & 1;
  const int lm = ln & 15, kg = ln >> 4;
  const int srow = ln >> 2, scol = (ln & 3) * 8;
  f32x4 acc[4][4] = {};
  for (int k0 = 0; k0 < K; k0 += 32) {
#pragma unroll
    for (int i = 0; i < 2; ++i) {
      const int r0 = wv*32 + i*16;
      gload16(A  + (size_t)(bm0 + r0 + srow) * lda + k0 + scol, &As[r0][0]);
      gload16(Bt + (size_t)(bn0 + r0 + srow) * ldb + k0 + scol, &Bs[r0][0]);
    }
    asm volatile("s_waitcnt vmcnt(0)" ::: "memory");
    __syncthreads();
    bf16x8 af[4], bfr[4];
#pragma unroll
    for (int m = 0; m < 4; ++m) af[m] = *(const bf16x8*)&As[wr*64 + m*16 + lm][kg*8];
#pragma unroll
    for (int n = 0; n < 4; ++n) bfr[n] = *(const bf16x8*)&Bs[wc*64 + n*16 + lm][kg*8];
#pragma unroll
    for (int m = 0; m < 4; ++m)
#pragma unroll
      for (int n = 0; n < 4; ++n)
        acc[m][n] = mfma16x16x32(af[m], bfr[n], acc[m][n]);
    __syncthreads();
  }
#pragma unroll
  for (int m = 0; m < 4; ++m) {
    const int row0 = bm0 + wr*64 + m*16 + kg*4;
#pragma unroll
    for (int n = 0; n < 4; ++n) {
      const int col = bn0 + wc*64 + n*16 + lm;
#pragma unroll
      for (int q = 0; q < 4; ++q) {
        float val = acc[m][n][q];
        size_t o = (size_t)(row0 + q) * ldc + col;
        if (EPI == 0) ((float*)Cout)[o] = val;
        else          ((bf16*)Cout)[o] = tobf(val);
      }
    }
  }
}

// --------- fused 6-branch low-rank projection + combine ---------------------
struct Mix6Args { const float* maa[6]; bf16* out[6]; };

__global__ __launch_bounds__(256) void mix_combine(
    const bf16* __restrict__ mixb, const bf16* __restrict__ w2t,
    const float* __restrict__ x, Mix6Args ma)
{
  __shared__ short As[64][40];
  __shared__ short Bs[64][40];
  const int s6 = blockIdx.z;
  const bf16* __restrict__ A  = mixb + s6*32;            // lda = 192
  const bf16* __restrict__ Bt = w2t + (size_t)s6*C_*32;  // ldb = 32
  const float* __restrict__ maa = ma.maa[s6];
  bf16* __restrict__ out = ma.out[s6];
  const int bm0 = blockIdx.x * 64, bn0 = blockIdx.y * 64;
  const int tid = threadIdx.x, wave = tid >> 6, lane = tid & 63;
  const int lm = lane & 15, kg = lane >> 4;
  const int srow = tid >> 2, scol = (tid & 3) * 8;
  *(uint4*)&As[srow][scol] = *(const uint4*)(A + (size_t)(bm0 + srow)*192 + scol);
  *(uint4*)&Bs[srow][scol] = *(const uint4*)(Bt + (size_t)(bn0 + srow)*32 + scol);
  __syncthreads();
  bf16x8 af = *(const bf16x8*)&As[wave*16 + lm][kg*8];
  f32x4 acc[4] = {};
#pragma unroll
  for (int f = 0; f < 4; ++f) {
    bf16x8 bfr = *(const bf16x8*)&Bs[f*16 + lm][kg*8];
    acc[f] = mfma16x16x32(af, bfr, acc[f]);
  }
  const int row0 = bm0 + wave*16 + kg*4;
  const int col0 = bn0 + lm;
#pragma unroll
  for (int f = 0; f < 4; ++f) {
#pragma unroll
    for (int q = 0; q < 4; ++q) {
      const int row = row0 + q, col = col0 + f*16;
      const size_t o = (size_t)row * C_ + col;
      float xv = x[o];
      float xp = (row & (T_ - 1)) ? x[o - C_] : 0.f;
      out[o] = tobf(xv + (xp - xv) * (maa[col] + acc[f][q]));
    }
  }
}

// ---------------- elementwise ----------------------------------------------
__global__ __launch_bounds__(256) void xin_k(
    const float* __restrict__ x, const float* __restrict__ maa_x,
    bf16* __restrict__ xinb)
{
  size_t idx = (size_t)blockIdx.x * 256 + threadIdx.x;
  int c = idx & (C_ - 1);
  int t = (int)((idx >> 10) & (T_ - 1));
  float xv = x[idx];
  float xp = t ? x[idx - C_] : 0.f;
  xinb[idx] = tobf(xv + (xp - xv) * maa_x[c]);
}

__global__ __launch_bounds__(256) void w_finalize(
    const float* __restrict__ wraw, const float* __restrict__ td,
    float* __restrict__ lw_out, float* __restrict__ k)
{
  size_t idx = (size_t)blockIdx.x * 256 + threadIdx.x;
  int c = idx & (C_ - 1);
  float wr = wraw[idx] + td[c];
  float sp = fmaxf(-wr, 0.f) + log1pf(expf(-fabsf(wr)));
  float w = -sp - 0.5f;
  lw_out[idx] = -expf(w);
  k[idx] *= expf(fminf(0.5f * w, 0.f));
}

__global__ __launch_bounds__(256) void a_finalize(
    const float* __restrict__ araw, const float* __restrict__ aaaaa,
    float* __restrict__ aamt)
{
  size_t idx = (size_t)blockIdx.x * 256 + threadIdx.x;
  int c = idx & (C_ - 1);
  float z = aaaaa[c] + araw[idx];
  aamt[idx] = 2.f / (1.f + expf(-z));
}

__global__ __launch_bounds__(256) void kk_normalize(
    const float* __restrict__ kraw, const float* __restrict__ kkadd,
    float* __restrict__ kkout)
{
  const int bt = blockIdx.x;
  const int tid = threadIdx.x;
  const size_t o = (size_t)bt * C_;
  float vals[4]; float ss = 0.f;
#pragma unroll
  for (int q = 0; q < 4; ++q) {
    float u = kraw[o + tid + q*256] + kkadd[o + tid + q*256];
    vals[q] = u; ss += u * u;
  }
  ss = allred64(ss);
  __shared__ float red[4];
  const int wave = tid >> 6, lane = tid & 63;
  if (lane == 0) red[wave] = ss;
  __syncthreads();
  float tot = red[0] + red[1] + red[2] + red[3];
  float inv = 1.f / fmaxf(sqrtf(tot), 1e-12f);
#pragma unroll
  for (int q = 0; q < 4; ++q) kkout[o + tid + q*256] = vals[q] * inv;
}

// ============ Chunked RWKV-7 scan (fp32 recurrence, bf16 MFMA phases) =======
//   SA = (I-trilA)^{-1}(Achk S0^T + trilC V) = W S0^T + SA_loc
//   y[s] = rt_s S0^T + tril<=(ABy) SA + tril<=(CKy) V
//   S_L = S0 diag(dL) + S0 G + U,  G=(W^T Bt).*dL_j, U=(SA_loc^T Bt+V^T Kt).*dL_j
// MFMA fragment conventions (verified in gemm_bt / m89):
//   A-frag: lane holds A[row=lane&15][k=(lane>>4)*8+e]; B-frag: B^T[col][k];
//   D: col=lane&15, row=(lane>>4)*4+q.

__global__ __launch_bounds__(256, 2) void rwkv_chunk_pre(
    const float* __restrict__ rr, const float* __restrict__ lw,
    const float* __restrict__ kk_s, const float* __restrict__ kkv,
    const float* __restrict__ aam, const float* __restrict__ vv,
    bf16* __restrict__ wbufb, bf16* __restrict__ sabufb,
    bf16* __restrict__ abybufb, bf16* __restrict__ ckybufb,
    bf16* __restrict__ ubufb, bf16* __restrict__ gbufb,
    float* __restrict__ dlbuf)
{
  __shared__ float aC[LCH][68], vL[LCH][68];      // fp32 for the solve
  __shared__ float Am[LCH][33], Cm[LCH][33];
  __shared__ float wtot[4][64];
  __shared__ float lcl[64];
  // bf16 row-major [s|u][j] operands (phase 2); transposed [i|j][u] (phase 5)
  __shared__ bf16 aCb[LCH][72], rCb[LCH][72], bTb[LCH][72], kTb[LCH][72];
  __shared__ bf16 bTT[64][40], kTT[64][40], vLT[64][40];
  __shared__ bf16 WT[64][40], SAT[64][40];

  const int ch = blockIdx.x;
  const int c  = ch & (NCH - 1);
  const int bh = ch >> 6;
  const int b  = bh >> 4, h = bh & 15;
  const int tid = threadIdx.x, wv = tid >> 6, ln = tid & 63;
  const int lm = ln & 15, kg = ln >> 4;
  const size_t base = ((size_t)(b*T_ + c*LCH) * C_) + h*N_ + ln;

  // --- phase 1: cumulative log-decay + load/scale into LDS (both layouts) ---
  float lwr[8], lcE[8];
  {
    float run = 0.f;
#pragma unroll
    for (int q = 0; q < 8; ++q) {
      lwr[q] = lw[base + (size_t)(wv*8 + q) * C_];
      lcE[q] = run; run += lwr[q];
    }
    wtot[wv][ln] = run;
  }
  __syncthreads();
  {
    float pre = 0.f;
    for (int w2 = 0; w2 < wv; ++w2) pre += wtot[w2][ln];
    if (wv == 0) lcl[ln] = wtot[0][ln] + wtot[1][ln] + wtot[2][ln] + wtot[3][ln];
#pragma unroll
    for (int q = 0; q < 8; ++q) lcE[q] += pre;
  }
#pragma unroll
  for (int q = 0; q < 8; ++q) {
    const int s = wv*8 + q;
    const size_t off = base + (size_t)s * C_;
    float kkx = kkv[off], aax = aam[off], kx = kk_s[off], rx = rr[off], vx = vv[off];
    float lcI = lcE[q] + lwr[q];
    float eIm = __expf(-lcI);
    float av = -kkx * __expf(lcE[q]);
    float bv = kkx * aax * eIm;
    float kv2 = kx * eIm;
    float rv = rx * __expf(lcI);
    aC[s][ln] = av;  vL[s][ln] = vx;
    aCb[s][ln] = tobf(av);  rCb[s][ln] = tobf(rv);
    bTb[s][ln] = tobf(bv);  kTb[s][ln] = tobf(kv2);
    bTT[ln][s] = tobf(bv);  kTT[ln][s] = tobf(kv2);  vLT[ln][s] = tobf(vx);
  }
  __syncthreads();

  if (tid < 64) dlbuf[(size_t)ch*64 + tid] = __expf(lcl[tid]);

  // --- phase 2: MFMA, one 32x32 (K=64) product per wave ---
  // wv0: Am = aC*bT^T, wv1: Cm = aC*kT^T, wv2: ABy = rC*bT^T, wv3: CKy = rC*kT^T
  {
    const bf16 (*Ab)[72] = (wv < 2) ? aCb : rCb;
    const bf16 (*Bb)[72] = (wv & 1) ? kTb : bTb;
#pragma unroll
    for (int mt = 0; mt < 2; ++mt)
#pragma unroll
      for (int nt = 0; nt < 2; ++nt) {
        f32x4 acc = {};
#pragma unroll
        for (int ks = 0; ks < 2; ++ks) {
          bf16x8 af = *(const bf16x8*)&Ab[mt*16 + lm][ks*32 + kg*8];
          bf16x8 bq = *(const bf16x8*)&Bb[nt*16 + lm][ks*32 + kg*8];
          acc = mfma16x16x32(af, bq, acc);
        }
        const int row0 = mt*16 + kg*4, col = nt*16 + lm;
#pragma unroll
        for (int q = 0; q < 4; ++q) {
          float v = acc[q];
          if (wv == 0)      Am[row0+q][col] = v;
          else if (wv == 1) Cm[row0+q][col] = v;
          else {
            bf16 bv2 = tobf(col <= row0+q ? v : 0.f);  // tril<= mask
            if (wv == 2) abybufb[(size_t)ch*1024 + (row0+q)*32 + col] = bv2;
            else         ckybufb[(size_t)ch*1024 + (row0+q)*32 + col] = bv2;
          }
        }
      }
  }
  __syncthreads();

  // --- phase 3: register forward-substitution (wave0: W, wave1: SA_loc) ---
  if (wv < 2) {
    float Xr[32], amr[32];
#pragma unroll
    for (int s = 0; s < 32; ++s) amr[s] = Am[s][ln & 31];
    if (wv == 0) {
#pragma unroll
      for (int s = 0; s < 32; ++s) Xr[s] = aC[s][ln];
    } else {
      float cmr[32];
#pragma unroll
      for (int s = 0; s < 32; ++s) cmr[s] = Cm[s][ln & 31];
#pragma unroll
      for (int s = 0; s < 32; ++s) Xr[s] = 0.f;
#pragma unroll
      for (int u = 0; u < 31; ++u) {
        float v = vL[u][ln];
#pragma unroll
        for (int s = u + 1; s < 32; ++s) Xr[s] += rdlane(cmr[s], u) * v;
      }
    }
#pragma unroll
    for (int s = 1; s < 32; ++s) {
      float acc = Xr[s];
#pragma unroll
      for (int u = 0; u < s; ++u) acc += rdlane(amr[s], u) * Xr[u];
      Xr[s] = acc;
    }
    if (wv == 0) {
#pragma unroll
      for (int s = 0; s < 32; ++s) {
        bf16 bv = tobf(Xr[s]);
        WT[ln][s] = bv;
        wbufb[(size_t)ch*2048 + s*64 + ln] = bv;
      }
    } else {
#pragma unroll
      for (int s = 0; s < 32; ++s) {
        bf16 bv = tobf(Xr[s]);
        SAT[ln][s] = bv;
        sabufb[(size_t)ch*2048 + s*64 + ln] = bv;
      }
    }
  }
  __syncthreads();

  // --- phase 5: U, G (64x64, K=32) via MFMA; wave = i-stripe, loop j-tiles --
  {
    const int mt = wv;
    bf16x8 aS = *(const bf16x8*)&SAT[mt*16 + lm][kg*8];
    bf16x8 aV = *(const bf16x8*)&vLT[mt*16 + lm][kg*8];
    bf16x8 aW = *(const bf16x8*)&WT[mt*16 + lm][kg*8];
#pragma unroll
    for (int nt = 0; nt < 4; ++nt) {
      bf16x8 bB = *(const bf16x8*)&bTT[nt*16 + lm][kg*8];
      bf16x8 bK = *(const bf16x8*)&kTT[nt*16 + lm][kg*8];
      f32x4 aU = {}, aG = {};
      aU = mfma16x16x32(aS, bB, aU);
      aU = mfma16x16x32(aV, bK, aU);
      aG = mfma16x16x32(aW, bB, aG);
      const int i0r = mt*16 + kg*4, col = nt*16 + lm;
      float dl = __expf(lcl[col]);
#pragma unroll
      for (int q = 0; q < 4; ++q) {
        ubufb[(size_t)ch*4096 + (i0r+q)*64 + col] = tobf(aU[q] * dl);
        gbufb[(size_t)ch*4096 + (i0r+q)*64 + col] = tobf(aG[q] * dl);
      }
    }
  }
}

// Phase B: serial over chunks; 256 blocks = 32 heads x 8 rowgroups.
__global__ __launch_bounds__(256) void rwkv_chunk_state(
    const unsigned short* __restrict__ ubufb,
    const unsigned short* __restrict__ gbufb,
    const float* __restrict__ dlbuf, bf16* __restrict__ s0bufb)
{
  __shared__ float Gf[2][64][68];
  const int bh = blockIdx.x >> 3, rg = blockIdx.x & 7;
  const int tid = threadIdx.x, wv = tid >> 6, ln = tid & 63;
  const int i0 = rg*8 + wv*2, i1 = i0 + 1;
  const int grow = tid >> 2, gcol = (tid & 3) * 16;
  float S0r = 0.f, S1r = 0.f;

  uint4 gp0, gp1; float u0p = 0.f, u1p = 0.f, dp = 0.f;
  auto prefetch = [&](int c) {
    const size_t chb = (size_t)(bh*NCH + c);
    const unsigned short* gp = gbufb + chb*4096 + (size_t)tid*16;
    gp0 = *(const uint4*)gp;
    gp1 = *(const uint4*)(gp + 8);
    u0p = bf2f(ubufb[chb*4096 + i0*64 + ln]);
    u1p = bf2f(ubufb[chb*4096 + i1*64 + ln]);
    dp  = dlbuf[chb*64 + ln];
  };
  prefetch(0);

  for (int cc = 0; cc < NCH; ++cc) {
    const size_t ch = (size_t)bh*NCH + cc;
    const int n = cc & 1;
    {
      const unsigned int* w0 = (const unsigned int*)&gp0;
      const unsigned int* w1 = (const unsigned int*)&gp1;
#pragma unroll
      for (int e = 0; e < 4; ++e) {
        *(float2*)&Gf[n][grow][gcol + e*2] =
            make_float2(bf2f((unsigned short)(w0[e] & 0xffff)),
                        bf2f((unsigned short)(w0[e] >> 16)));
        *(float2*)&Gf[n][grow][gcol + 8 + e*2] =
            make_float2(bf2f((unsigned short)(w1[e] & 0xffff)),
                        bf2f((unsigned short)(w1[e] >> 16)));
      }
    }
    const float ucur0 = u0p, ucur1 = u1p, dcur = dp;
    s0bufb[(ch*64 + i0)*64 + ln] = tobf(S0r);
    s0bufb[(ch*64 + i1)*64 + ln] = tobf(S1r);
    __syncthreads();
    if (cc + 1 < NCH) prefetch(cc + 1);
    float a0 = ucur0 + S0r * dcur;
    float a1 = ucur1 + S1r * dcur;
#pragma unroll
    for (int m = 0; m < 64; ++m) {
      float g = Gf[n][m][ln];
      a0 += rdlane(S0r, m) * g;
      a1 += rdlane(S1r, m) * g;
    }
    S0r = a0; S1r = a1;
  }
}

// Phase C: per chunk-head, MFMA: SA = W*S0^T + SAll, then
// y = Rt*S0^T + ABl*SAo + CKl*V  (ABl/CKl pre-masked tril<=).
__global__ __launch_bounds__(256, 4) void rwkv_chunk_out(
    const float* __restrict__ rr, const float* __restrict__ lw,
    const float* __restrict__ vv, const bf16* __restrict__ s0bufb,
    const bf16* __restrict__ wbufb, const bf16* __restrict__ sabufb,
    const bf16* __restrict__ abybufb, const bf16* __restrict__ ckybufb,
    float* __restrict__ y)
{
  __shared__ bf16 S0b[64][72];                    // B^T layout: [i][j]
  __shared__ bf16 Wb[LCH][72], Rlb[LCH][72];      // A layouts: [s][j]
  __shared__ bf16 ABl[LCH][40], CKl[LCH][40];     // A layouts: [s][u]
  __shared__ bf16 SAot[64][40], VlT[64][40];      // B^T layouts: [i][u]
  __shared__ float wtot[4][64];
  const int ch = blockIdx.x;
  const int c = ch & (NCH - 1), bh = ch >> 6, b = bh >> 4, h = bh & 15;
  const int tid = threadIdx.x, wv = tid >> 6, ln = tid & 63;
  const int lm = ln & 15, kg = ln >> 4;
  const size_t base = ((size_t)(b*T_ + c*LCH) * C_) + h*N_ + ln;

  // cumsum of log-decay -> rt ; V transposed copy
  float lwr[8], lcE[8];
  {
    float run = 0.f;
#pragma unroll
    for (int q = 0; q < 8; ++q) {
      lwr[q] = lw[base + (size_t)(wv*8 + q) * C_];
      lcE[q] = run; run += lwr[q];
    }
    wtot[wv][ln] = run;
  }
  __syncthreads();
  {
    float pre = 0.f;
    for (int w2 = 0; w2 < wv; ++w2) pre += wtot[w2][ln];
#pragma unroll
    for (int q = 0; q < 8; ++q) lcE[q] += pre;
  }
#pragma unroll
  for (int q = 0; q < 8; ++q) {
    const int s = wv*8 + q;
    const size_t off = base + (size_t)s * C_;
    Rlb[s][ln] = tobf(rr[off] * __expf(lcE[q] + lwr[q]));
    VlT[ln][s] = tobf(vv[off]);
  }
  // stage S0 (4096 bf16), W (2048), ABl/CKl (1024 each) via 16B copies
#pragma unroll
  for (int t = 0; t < 2; ++t) {
    int cc2 = tid*2 + t; int ri = cc2 >> 3, co = (cc2 & 7) * 8;
    *(uint4*)&S0b[ri][co] = *(const uint4*)(s0bufb + (size_t)ch*4096 + ri*64 + co);
  }
  { int ri = tid >> 3, co = (tid & 7) * 8;
    *(uint4*)&Wb[ri][co] = *(const uint4*)(wbufb + (size_t)ch*2048 + ri*64 + co); }
  if (tid < 128) {
    int ri = tid >> 2, co = (tid & 3) * 8;
    *(uint4*)&ABl[ri][co] = *(const uint4*)(abybufb + (size_t)ch*1024 + ri*32 + co);
  } else {
    int t2 = tid - 128; int ri = t2 >> 2, co = (t2 & 3) * 8;
    *(uint4*)&CKl[ri][co] = *(const uint4*)(ckybufb + (size_t)ch*1024 + ri*32 + co);
  }
  __syncthreads();

  const int mt = wv >> 1, ntb = (wv & 1) * 2;
  // SA = W*S0^T + SAll (C-init from global), write transposed for y-step
#pragma unroll
  for (int t = 0; t < 2; ++t) {
    const int nt = ntb + t;
    const int row0 = mt*16 + kg*4, col = nt*16 + lm;
    f32x4 acc;
#pragma unroll
    for (int q = 0; q < 4; ++q)
      acc[q] = __bfloat162float(sabufb[(size_t)ch*2048 + (row0+q)*64 + col]);
#pragma unroll
    for (int ks = 0; ks < 2; ++ks) {
      bf16x8 af = *(const bf16x8*)&Wb[mt*16 + lm][ks*32 + kg*8];
      bf16x8 bq = *(const bf16x8*)&S0b[nt*16 + lm][ks*32 + kg*8];
      acc = mfma16x16x32(af, bq, acc);
    }
#pragma unroll
    for (int q = 0; q < 4; ++q) SAot[col][row0+q] = tobf(acc[q]);
  }
  __syncthreads();

  // y = Rt*S0^T + ABl*SAot^T + CKl*VlT^T
#pragma unroll
  for (int t = 0; t < 2; ++t) {
    const int nt = ntb + t;
    f32x4 acc = {};
#pragma unroll
    for (int ks = 0; ks < 2; ++ks) {
      bf16x8 af = *(const bf16x8*)&Rlb[mt*16 + lm][ks*32 + kg*8];
      bf16x8 bq = *(const bf16x8*)&S0b[nt*16 + lm][ks*32 + kg*8];
      acc = mfma16x16x32(af, bq, acc);
    }
    {
      bf16x8 af = *(const bf16x8*)&ABl[mt*16 + lm][kg*8];
      bf16x8 bq = *(const bf16x8*)&SAot[nt*16 + lm][kg*8];
      acc = mfma16x16x32(af, bq, acc);
    }
    {
      bf16x8 af = *(const bf16x8*)&CKl[mt*16 + lm][kg*8];
      bf16x8 bq = *(const bf16x8*)&VlT[nt*16 + lm][kg*8];
      acc = mfma16x16x32(af, bq, acc);
    }
    const int row0 = mt*16 + kg*4, col = nt*16 + lm;
#pragma unroll
    for (int q = 0; q < 4; ++q)
      y[((size_t)(b*T_ + c*LCH + row0 + q)) * C_ + h*N_ + col] = acc[q];
  }
}

// ---------------- groupnorm + bonus + gate ---------------------------------
__global__ __launch_bounds__(256) void gn_bonus_gate(
    const float* __restrict__ y, const float* __restrict__ rr,
    const float* __restrict__ kk_s, const float* __restrict__ vv,
    const bf16* __restrict__ gg, const float* __restrict__ faaaa,
    const float* __restrict__ lnw, const float* __restrict__ lnb,
    bf16* __restrict__ zb)
{
  const int bt = blockIdx.x;
  const int wave = threadIdx.x >> 6, lane = threadIdx.x & 63;
  const float inv64 = 1.f / 64.f;
  for (int h = wave; h < H_; h += 4) {
    const int c = h * 64 + lane;
    const size_t o = (size_t)bt * C_ + c;
    float yv = y[o];
    float mean = allred64(yv) * inv64;
    float d = yv - mean;
    float var = allred64(d * d) * inv64;
    float xn = d * rsqrtf(var + 6.4e-4f);
    float gn = xn * lnw[c] + lnb[c];
    float rk = allred64(rr[o] * kk_s[o] * faaaa[c]);
    float z = (gn + rk * vv[o]) * __bfloat162float(gg[o]);
    zb[o] = tobf(z);
  }
}

// ---------------- driver ----------------------------------------------------
extern "C" void kernel_launch(void* const* d_in, const int* in_sizes, int n_in,
                              void* d_out, int out_size, void* d_ws, size_t ws_size,
                              hipStream_t stream)
{
  const float* x     = (const float*)d_in[0];
  const float* maa_x = (const float*)d_in[1];
  const float* maa_r = (const float*)d_in[2];
  const float* maa_w = (const float*)d_in[3];
  const float* maa_k = (const float*)d_in[4];
  const float* maa_v = (const float*)d_in[5];
  const float* maa_a = (const float*)d_in[6];
  const float* maa_g = (const float*)d_in[7];
  const float* tdec  = (const float*)d_in[8];
  const float* faaaa = (const float*)d_in[9];
  const float* aaaaa = (const float*)d_in[10];
  const float* maa_w1= (const float*)d_in[11];
  const float* maa_w2= (const float*)d_in[12];
  const float* dec_w1= (const float*)d_in[13];
  const float* dec_w2= (const float*)d_in[14];
  const float* aaa_w1= (const float*)d_in[15];
  const float* aaa_w2= (const float*)d_in[16];
  const float* kkk_w1= (const float*)d_in[17];
  const float* kkk_w2= (const float*)d_in[18];
  const float* gate_w1=(const float*)d_in[19];
  const float* gate_w2=(const float*)d_in[20];
  const float* W_r   = (const float*)d_in[21];
  const float* W_k   = (const float*)d_in[22];
  const float* W_v   = (const float*)d_in[23];
  const float* W_o   = (const float*)d_in[24];
  const float* lnw   = (const float*)d_in[25];
  const float* lnb   = (const float*)d_in[26];

  char* ws = (char*)d_ws;
  size_t cur = 0;
  auto alloc = [&](size_t bytes) -> void* {
    void* p = ws + cur; cur += (bytes + 255) & ~(size_t)255; return p;
  };
  const size_t FBT = (size_t)BT_ * C_ * sizeof(float);

  // ---- persistent ----
  float* rb   = (float*)alloc(FBT);
  float* kb   = (float*)alloc(FBT);
  float* vb   = (float*)alloc(FBT);
  bf16*  gbb  = (bf16*)alloc((size_t)BT_*C_*2);
  bf16* WtR  = (bf16*)alloc((size_t)C_*C_*2);
  bf16* WtK  = (bf16*)alloc((size_t)C_*C_*2);
  bf16* WtV  = (bf16*)alloc((size_t)C_*C_*2);
  bf16* WtO  = (bf16*)alloc((size_t)C_*C_*2);
  bf16* w1t  = (bf16*)alloc((size_t)192*C_*2);
  bf16* w2t  = (bf16*)alloc((size_t)6*C_*32*2);
  bf16* d1t  = (bf16*)alloc((size_t)64*C_*2);
  bf16* d2t  = (bf16*)alloc((size_t)C_*64*2);
  bf16* a1t  = (bf16*)alloc((size_t)64*C_*2);
  bf16* a2t  = (bf16*)alloc((size_t)C_*64*2);
  bf16* k1t  = (bf16*)alloc((size_t)64*C_*2);
  bf16* k2t  = (bf16*)alloc((size_t)C_*64*2);
  bf16* g1t  = (bf16*)alloc((size_t)128*C_*2);
  bf16* g2t  = (bf16*)alloc((size_t)C_*128*2);
  float* lwb  = (float*)alloc(FBT);
  float* kkb  = (float*)alloc(FBT);   // dead after chunk_pre; s0bufb overlays
  float* aamt = (float*)alloc(FBT);
  bf16* s0bufb = (bf16*)kkb;          // CHD*4096*2 == FBT exactly

  // ---- union region ----
  const size_t ubase = cur;
  float* mtmp = (float*)alloc(FBT);
  bf16* xinb = (bf16*)alloc((size_t)BT_*C_*2);
  bf16* mixb = (bf16*)alloc((size_t)BT_*192*2);
  bf16* xbr[6];
  for (int s = 0; s < 6; ++s) xbr[s] = (bf16*)alloc((size_t)BT_*C_*2);
  bf16* h64b = (bf16*)alloc((size_t)BT_*64*2);
  bf16* h128b= (bf16*)alloc((size_t)BT_*128*2);
  const size_t tmp_end = cur;
  cur = ubase;  // overlay
  bf16*  wbufb   = (bf16*)alloc((size_t)CHD*2048*2);
  bf16*  sabufb  = (bf16*)alloc((size_t)CHD*2048*2);
  bf16*  abybufb = (bf16*)alloc((size_t)CHD*1024*2);
  bf16*  ckybufb = (bf16*)alloc((size_t)CHD*1024*2);
  bf16*  ubufb   = (bf16*)alloc((size_t)CHD*4096*2);
  bf16*  gbufb   = (bf16*)alloc((size_t)CHD*4096*2);
  float* dlbuf   = (float*)alloc((size_t)CHD*64*4);
  bf16*  zb      = (bf16*)ubufb;   // alias: ubufb dead after chunk_state
  if (tmp_end > cur) cur = tmp_end;
  const size_t need = cur;
  (void)in_sizes; (void)n_in; (void)out_size;

  if (ws_size < need) {
    ws_diag<<<1, 1, 0, stream>>>((float)ws_size, (float)need, (float*)d_out);
    return;
  }

  PrepArgs pa;
  pa.src[0] = W_r;  pa.dst[0] = WtR;
  pa.src[1] = W_k;  pa.dst[1] = WtK;
  pa.src[2] = W_v;  pa.dst[2] = WtV;
  pa.src[3] = W_o;  pa.dst[3] = WtO;
  pa.src[4] = maa_w1; pa.dst[4] = w1t;
  for (int s = 0; s < 6; ++s) { pa.src[5+s] = maa_w2 + (size_t)s*32*C_; pa.dst[5+s] = w2t + (size_t)s*C_*32; }
  pa.src[11] = dec_w1; pa.dst[11] = d1t;
  pa.src[12] = dec_w2; pa.dst[12] = d2t;
  pa.src[13] = aaa_w1; pa.dst[13] = a1t;
  pa.src[14] = aaa_w2; pa.dst[14] = a2t;
  pa.src[15] = kkk_w1; pa.dst[15] = k1t;
  pa.src[16] = kkk_w2; pa.dst[16] = k2t;
  pa.src[17] = gate_w1; pa.dst[17] = g1t;
  pa.src[18] = gate_w2; pa.dst[18] = g2t;
  prep_weights<<<dim3(1024, 19), 256, 0, stream>>>(pa);

  const int EW_GRID = (BT_ * C_) / 256;  // 16384
  xin_k<<<EW_GRID, 256, 0, stream>>>(x, maa_x, xinb);

  gemm_bt<1><<<dim3(64, 3), 256, 0, stream>>>(xinb, C_, w1t, C_, mixb, 192, C_);

  Mix6Args ma;
  ma.maa[0] = maa_r; ma.maa[1] = maa_w; ma.maa[2] = maa_k;
  ma.maa[3] = maa_v; ma.maa[4] = maa_a; ma.maa[5] = maa_g;
  for (int s = 0; s < 6; ++s) ma.out[s] = xbr[s];
  mix_combine<<<dim3(64, 16, 6), 256, 0, stream>>>(mixb, w2t, x, ma);

  gemm128<0><<<dim3(32, 8), 256, 0, stream>>>(xbr[0], C_, WtR, C_, rb, C_, C_);
  gemm128<0><<<dim3(32, 8), 256, 0, stream>>>(xbr[2], C_, WtK, C_, kb, C_, C_);
  gemm128<0><<<dim3(32, 8), 256, 0, stream>>>(xbr[3], C_, WtV, C_, vb, C_, C_);

  // kk path (uses UNscaled k)
  gemm_bt<1><<<dim3(64, 1), 256, 0, stream>>>(xbr[2], C_, k1t, C_, h64b, 64, C_);
  gemm128<0><<<dim3(32, 8), 256, 0, stream>>>(h64b, 64, k2t, 64, mtmp, C_, 64);
  kk_normalize<<<BT_, 256, 0, stream>>>(kb, mtmp, kkb);

  // w path (then scales k in place)
  gemm_bt<1><<<dim3(64, 1), 256, 0, stream>>>(xbr[1], C_, d1t, C_, h64b, 64, C_);
  gemm128<0><<<dim3(32, 8), 256, 0, stream>>>(h64b, 64, d2t, 64, mtmp, C_, 64);
  w_finalize<<<EW_GRID, 256, 0, stream>>>(mtmp, tdec, lwb, kb);

  // a path (NO tanh on inner projection)
  gemm_bt<2><<<dim3(64, 1), 256, 0, stream>>>(xbr[4], C_, a1t, C_, h64b, 64, C_);
  gemm128<0><<<dim3(32, 8), 256, 0, stream>>>(h64b, 64, a2t, 64, mtmp, C_, 64);
  a_finalize<<<EW_GRID, 256, 0, stream>>>(mtmp, aaaaa, aamt);

  // g path -> bf16 gate buffer
  gemm_bt<1><<<dim3(64, 2), 256, 0, stream>>>(xbr[5], C_, g1t, C_, h128b, 128, C_);
  gemm128<2><<<dim3(32, 8), 256, 0, stream>>>(h128b, 128, g2t, 128, gbb, C_, 128);

  // ---- chunked scan ----
  rwkv_chunk_pre<<<CHD, 256, 0, stream>>>(rb, lwb, kb, kkb, aamt, vb,
      wbufb, sabufb, abybufb, ckybufb, ubufb, gbufb, dlbuf);
  rwkv_chunk_state<<<256, 256, 0, stream>>>((const unsigned short*)ubufb,
      (const unsigned short*)gbufb, dlbuf, s0bufb);
  rwkv_chunk_out<<<CHD, 256, 0, stream>>>(rb, lwb, vb, s0bufb, wbufb, sabufb,
      abybufb, ckybufb, (float*)d_out);

  gn_bonus_gate<<<BT_, 256, 0, stream>>>((const float*)d_out, rb, kb, vb, gbb,
                                         faaaa, lnw, lnb, zb);

  gemm128<0><<<dim3(32, 8), 256, 0, stream>>>(zb, C_, WtO, C_, d_out, C_, C_);
}

// Round 8
// 453.009 us; speedup vs baseline: 3.6068x; 1.0112x over previous
//
#include <hip/hip_runtime.h>
#include <hip/hip_bf16.h>

using bf16 = __hip_bfloat16;
using bf16x8 = __attribute__((ext_vector_type(8))) short;  // 8 bf16 (4 VGPRs)
using f32x4 = __attribute__((ext_vector_type(4))) float;

#define B_ 2
#define T_ 2048
#define C_ 1024
#define BT_ (B_*T_)
#define H_ 16
#define N_ 64
#define LCH 32            // scan chunk length
#define NCH (T_/LCH)      // 64 chunks per head
#define CHD (B_*H_*NCH)   // 2048 chunk-heads

__device__ __forceinline__ float allred64(float v) {
#pragma unroll
  for (int m = 1; m < 64; m <<= 1) v += __shfl_xor(v, m, 64);
  return v;
}

__device__ __forceinline__ bf16 tobf(float f) { return __float2bfloat16(f); }
__device__ __forceinline__ float bf2f(unsigned short u) {
  unsigned int x = ((unsigned int)u) << 16;
  return __builtin_bit_cast(float, x);
}
__device__ __forceinline__ float rdlane(float v, int m) {
  return __builtin_bit_cast(float,
      __builtin_amdgcn_readlane(__builtin_bit_cast(int, v), m));
}

__device__ __forceinline__ f32x4 mfma16x16x32(bf16x8 a, bf16x8 b, f32x4 c) {
  return __builtin_amdgcn_mfma_f32_16x16x32_bf16(a, b, c, 0, 0, 0);
}

// async global->LDS, 16B per lane (dest = wave-uniform base + lane*16)
typedef const __attribute__((address_space(1))) unsigned int* gas_ptr;
typedef __attribute__((address_space(3))) unsigned int* las_ptr;
__device__ __forceinline__ void gload16(const void* g, void* l) {
  __builtin_amdgcn_global_load_lds((gas_ptr)g, (las_ptr)l, 16, 0, 0);
}

// ---------------- ws_size diagnostic ----------------------------------------
__global__ void ws_diag(float a, float b, float* out) { out[0] = a; out[1] = b; }

// ---------------- weight transpose + bf16 cast (19 jobs, one launch) -------
struct PrepArgs {
  const float* src[19];
  bf16* dst[19];
};
__constant__ int kTR[19] = {1024,1024,1024,1024, 1024, 32,32,32,32,32,32,
                            1024,64, 1024,64, 1024,64, 1024,128};
__constant__ int kTC[19] = {1024,1024,1024,1024, 192, 1024,1024,1024,1024,1024,1024,
                            64,1024, 64,1024, 64,1024, 128,1024};

__global__ __launch_bounds__(256) void prep_weights(PrepArgs pa) {
  const int job = blockIdx.y;
  const int R = kTR[job], Cc = kTC[job];
  const int ntx = Cc >> 5, nty = R >> 5;
  const int tile = blockIdx.x;
  if (tile >= ntx * nty) return;
  const int tx = tile % ntx, ty = tile / ntx;
  const float* __restrict__ src = pa.src[job];
  bf16* __restrict__ dst = pa.dst[job];
  __shared__ float tl[32][33];
  const int lx = threadIdx.x & 31, ly = threadIdx.x >> 5;  // 32 x 8
#pragma unroll
  for (int q = 0; q < 4; ++q)
    tl[ly + 8*q][lx] = src[(size_t)(ty*32 + ly + 8*q) * Cc + tx*32 + lx];
  __syncthreads();
#pragma unroll
  for (int q = 0; q < 4; ++q)
    dst[(size_t)(tx*32 + ly + 8*q) * R + ty*32 + lx] = tobf(tl[lx][ly + 8*q]);
}

// ------- GEMM 64-tile (used for small N / odd shapes) -----------------------
template<int EPI>
__global__ __launch_bounds__(256) void gemm_bt(
    const bf16* __restrict__ A, int lda,
    const bf16* __restrict__ Bt, int ldb,
    void* __restrict__ Cout, int ldc, int K)
{
  __shared__ short As[64][40];
  __shared__ short Bs[64][40];
  const int bm0 = blockIdx.x * 64;
  const int bn0 = blockIdx.y * 64;
  const int tid = threadIdx.x;
  const int wave = tid >> 6, lane = tid & 63;
  const int lm = lane & 15, kg = lane >> 4;
  const int srow = tid >> 2, scol = (tid & 3) * 8;
  f32x4 acc[4] = {};
  const size_t abase = (size_t)(bm0 + srow) * lda + scol;
  const size_t bbase = (size_t)(bn0 + srow) * ldb + scol;
  for (int k0 = 0; k0 < K; k0 += 32) {
    *(uint4*)&As[srow][scol] = *(const uint4*)(A + abase + k0);
    *(uint4*)&Bs[srow][scol] = *(const uint4*)(Bt + bbase + k0);
    __syncthreads();
    bf16x8 af = *(const bf16x8*)&As[wave*16 + lm][kg*8];
#pragma unroll
    for (int f = 0; f < 4; ++f) {
      bf16x8 bfr = *(const bf16x8*)&Bs[f*16 + lm][kg*8];
      acc[f] = mfma16x16x32(af, bfr, acc[f]);
    }
    __syncthreads();
  }
  const int row0 = bm0 + wave*16 + kg*4;
  const int col0 = bn0 + lm;
#pragma unroll
  for (int f = 0; f < 4; ++f) {
#pragma unroll
    for (int q = 0; q < 4; ++q) {
      float val = acc[f][q];
      size_t o = (size_t)(row0 + q) * ldc + col0 + f*16;
      if (EPI == 0)      ((float*)Cout)[o] = val;
      else if (EPI == 1) ((bf16*)Cout)[o] = tobf(tanhf(val));
      else               ((bf16*)Cout)[o] = tobf(val);
    }
  }
}

// ------- GEMM 128-tile, m97 structure (global_load_lds staging) -------------
// EPI: 0 f32 | 2 bf16 | 3 w-finalize (Cout=lw, aux1=td, aux2=k inplace)
//      4 a-finalize (Cout=aamt, aux1=aaaaa)
template<int EPI>
__global__ __launch_bounds__(256) void gemm128(
    const bf16* __restrict__ A, int lda,
    const bf16* __restrict__ Bt, int ldb,
    void* __restrict__ Cout, int ldc, int K,
    const float* __restrict__ aux1, float* __restrict__ aux2)
{
  __shared__ bf16 As[128][32];     // linear (required by global_load_lds)
  __shared__ bf16 Bs[128][32];
  const int bm0 = blockIdx.x * 128, bn0 = blockIdx.y * 128;
  const int tid = threadIdx.x, wv = tid >> 6, ln = tid & 63;
  const int wr = wv >> 1, wc = wv & 1;
  const int lm = ln & 15, kg = ln >> 4;
  const int srow = ln >> 2, scol = (ln & 3) * 8;
  f32x4 acc[4][4] = {};
  for (int k0 = 0; k0 < K; k0 += 32) {
#pragma unroll
    for (int i = 0; i < 2; ++i) {
      const int r0 = wv*32 + i*16;
      gload16(A  + (size_t)(bm0 + r0 + srow) * lda + k0 + scol, &As[r0][0]);
      gload16(Bt + (size_t)(bn0 + r0 + srow) * ldb + k0 + scol, &Bs[r0][0]);
    }
    asm volatile("s_waitcnt vmcnt(0)" ::: "memory");
    __syncthreads();
    bf16x8 af[4], bfr[4];
#pragma unroll
    for (int m = 0; m < 4; ++m) af[m] = *(const bf16x8*)&As[wr*64 + m*16 + lm][kg*8];
#pragma unroll
    for (int n = 0; n < 4; ++n) bfr[n] = *(const bf16x8*)&Bs[wc*64 + n*16 + lm][kg*8];
#pragma unroll
    for (int m = 0; m < 4; ++m)
#pragma unroll
      for (int n = 0; n < 4; ++n)
        acc[m][n] = mfma16x16x32(af[m], bfr[n], acc[m][n]);
    __syncthreads();
  }
#pragma unroll
  for (int m = 0; m < 4; ++m) {
    const int row0 = bm0 + wr*64 + m*16 + kg*4;
#pragma unroll
    for (int n = 0; n < 4; ++n) {
      const int col = bn0 + wc*64 + n*16 + lm;
#pragma unroll
      for (int q = 0; q < 4; ++q) {
        float val = acc[m][n][q];
        size_t o = (size_t)(row0 + q) * ldc + col;
        if (EPI == 0)      ((float*)Cout)[o] = val;
        else if (EPI == 2) ((bf16*)Cout)[o] = tobf(val);
        else if (EPI == 3) {
          float wr2 = val + aux1[col];
          float sp = fmaxf(-wr2, 0.f) + log1pf(expf(-fabsf(wr2)));
          float w = -sp - 0.5f;
          ((float*)Cout)[o] = -expf(w);              // lw
          aux2[o] *= expf(fminf(0.5f * w, 0.f));     // k scale in place
        } else if (EPI == 4) {
          float z = aux1[col] + val;
          ((float*)Cout)[o] = 2.f / (1.f + expf(-z));
        }
      }
    }
  }
}

// batched r/k/v: same shape (M=4096, N=1024, K=1024), z selects operands
struct RkvArgs { const bf16* A[3]; const bf16* Bt[3]; float* Cq[3]; };
__global__ __launch_bounds__(256) void gemm128_rkv(RkvArgs ra) {
  __shared__ bf16 As[128][32];
  __shared__ bf16 Bs[128][32];
  const bf16* __restrict__ A  = ra.A[blockIdx.z];
  const bf16* __restrict__ Bt = ra.Bt[blockIdx.z];
  float* __restrict__ Cout = ra.Cq[blockIdx.z];
  const int bm0 = blockIdx.x * 128, bn0 = blockIdx.y * 128;
  const int tid = threadIdx.x, wv = tid >> 6, ln = tid & 63;
  const int wr = wv >> 1, wc = wv & 1;
  const int lm = ln & 15, kg = ln >> 4;
  const int srow = ln >> 2, scol = (ln & 3) * 8;
  f32x4 acc[4][4] = {};
  for (int k0 = 0; k0 < C_; k0 += 32) {
#pragma unroll
    for (int i = 0; i < 2; ++i) {
      const int r0 = wv*32 + i*16;
      gload16(A  + (size_t)(bm0 + r0 + srow) * C_ + k0 + scol, &As[r0][0]);
      gload16(Bt + (size_t)(bn0 + r0 + srow) * C_ + k0 + scol, &Bs[r0][0]);
    }
    asm volatile("s_waitcnt vmcnt(0)" ::: "memory");
    __syncthreads();
    bf16x8 af[4], bfr[4];
#pragma unroll
    for (int m = 0; m < 4; ++m) af[m] = *(const bf16x8*)&As[wr*64 + m*16 + lm][kg*8];
#pragma unroll
    for (int n = 0; n < 4; ++n) bfr[n] = *(const bf16x8*)&Bs[wc*64 + n*16 + lm][kg*8];
#pragma unroll
    for (int m = 0; m < 4; ++m)
#pragma unroll
      for (int n = 0; n < 4; ++n)
        acc[m][n] = mfma16x16x32(af[m], bfr[n], acc[m][n]);
    __syncthreads();
  }
#pragma unroll
  for (int m = 0; m < 4; ++m) {
    const int row0 = bm0 + wr*64 + m*16 + kg*4;
#pragma unroll
    for (int n = 0; n < 4; ++n) {
      const int col = bn0 + wc*64 + n*16 + lm;
#pragma unroll
      for (int q = 0; q < 4; ++q)
        Cout[(size_t)(row0 + q) * C_ + col] = acc[m][n][q];
    }
  }
}

// --------- fused 6-branch low-rank projection + combine ---------------------
struct Mix6Args { const float* maa[6]; bf16* out[6]; };

__global__ __launch_bounds__(256) void mix_combine(
    const bf16* __restrict__ mixb, const bf16* __restrict__ w2t,
    const float* __restrict__ x, Mix6Args ma)
{
  __shared__ short As[64][40];
  __shared__ short Bs[64][40];
  const int s6 = blockIdx.z;
  const bf16* __restrict__ A  = mixb + s6*32;            // lda = 192
  const bf16* __restrict__ Bt = w2t + (size_t)s6*C_*32;  // ldb = 32
  const float* __restrict__ maa = ma.maa[s6];
  bf16* __restrict__ out = ma.out[s6];
  const int bm0 = blockIdx.x * 64, bn0 = blockIdx.y * 64;
  const int tid = threadIdx.x, wave = tid >> 6, lane = tid & 63;
  const int lm = lane & 15, kg = lane >> 4;
  const int srow = tid >> 2, scol = (tid & 3) * 8;
  *(uint4*)&As[srow][scol] = *(const uint4*)(A + (size_t)(bm0 + srow)*192 + scol);
  *(uint4*)&Bs[srow][scol] = *(const uint4*)(Bt + (size_t)(bn0 + srow)*32 + scol);
  __syncthreads();
  bf16x8 af = *(const bf16x8*)&As[wave*16 + lm][kg*8];
  f32x4 acc[4] = {};
#pragma unroll
  for (int f = 0; f < 4; ++f) {
    bf16x8 bfr = *(const bf16x8*)&Bs[f*16 + lm][kg*8];
    acc[f] = mfma16x16x32(af, bfr, acc[f]);
  }
  const int row0 = bm0 + wave*16 + kg*4;
  const int col0 = bn0 + lm;
#pragma unroll
  for (int f = 0; f < 4; ++f) {
#pragma unroll
    for (int q = 0; q < 4; ++q) {
      const int row = row0 + q, col = col0 + f*16;
      const size_t o = (size_t)row * C_ + col;
      float xv = x[o];
      float xp = (row & (T_ - 1)) ? x[o - C_] : 0.f;
      out[o] = tobf(xv + (xp - xv) * (maa[col] + acc[f][q]));
    }
  }
}

// ---------------- elementwise ----------------------------------------------
__global__ __launch_bounds__(256) void xin_k(
    const float* __restrict__ x, const float* __restrict__ maa_x,
    bf16* __restrict__ xinb)
{
  size_t idx = (size_t)blockIdx.x * 256 + threadIdx.x;
  int c = idx & (C_ - 1);
  int t = (int)((idx >> 10) & (T_ - 1));
  float xv = x[idx];
  float xp = t ? x[idx - C_] : 0.f;
  xinb[idx] = tobf(xv + (xp - xv) * maa_x[c]);
}

__global__ __launch_bounds__(256) void kk_normalize(
    const float* __restrict__ kraw, const float* __restrict__ kkadd,
    float* __restrict__ kkout)
{
  const int bt = blockIdx.x;
  const int tid = threadIdx.x;
  const size_t o = (size_t)bt * C_;
  float vals[4]; float ss = 0.f;
#pragma unroll
  for (int q = 0; q < 4; ++q) {
    float u = kraw[o + tid + q*256] + kkadd[o + tid + q*256];
    vals[q] = u; ss += u * u;
  }
  ss = allred64(ss);
  __shared__ float red[4];
  const int wave = tid >> 6, lane = tid & 63;
  if (lane == 0) red[wave] = ss;
  __syncthreads();
  float tot = red[0] + red[1] + red[2] + red[3];
  float inv = 1.f / fmaxf(sqrtf(tot), 1e-12f);
#pragma unroll
  for (int q = 0; q < 4; ++q) kkout[o + tid + q*256] = vals[q] * inv;
}

// ============ Chunked RWKV-7 scan (fp32 recurrence, bf16 MFMA phases) =======
//   SA = (I-trilA)^{-1}(Achk S0^T + trilC V) = W S0^T + SA_loc
//   y[s] = rt_s S0^T + tril<=(ABy) SA + tril<=(CKy) V
//   S_L = S0 * M + U  with M = diag(dL) + (W^T Bt).*dL_j  (stored fused, bf16)
//         U = (SA_loc^T Bt + V^T Kt).*dL_j

__global__ __launch_bounds__(256, 2) void rwkv_chunk_pre(
    const float* __restrict__ rr, const float* __restrict__ lw,
    const float* __restrict__ kk_s, const float* __restrict__ kkv,
    const float* __restrict__ aam, const float* __restrict__ vv,
    bf16* __restrict__ wbufb, bf16* __restrict__ sabufb,
    bf16* __restrict__ abybufb, bf16* __restrict__ ckybufb,
    bf16* __restrict__ ubufb, bf16* __restrict__ mbufb)
{
  __shared__ float aC[LCH][68], vL[LCH][68];      // fp32 for the solve
  __shared__ float Am[LCH][33], Cm[LCH][33];
  __shared__ float wtot[4][64];
  __shared__ float lcl[64];
  __shared__ bf16 aCb[LCH][72], rCb[LCH][72], bTb[LCH][72], kTb[LCH][72];
  __shared__ bf16 bTT[64][40], kTT[64][40], vLT[64][40];
  __shared__ bf16 WT[64][40], SAT[64][40];

  const int ch = blockIdx.x;
  const int c  = ch & (NCH - 1);
  const int bh = ch >> 6;
  const int b  = bh >> 4, h = bh & 15;
  const int tid = threadIdx.x, wv = tid >> 6, ln = tid & 63;
  const int lm = ln & 15, kg = ln >> 4;
  const size_t base = ((size_t)(b*T_ + c*LCH) * C_) + h*N_ + ln;

  // --- phase 1: cumulative log-decay + load/scale into LDS (both layouts) ---
  float lwr[8], lcE[8];
  {
    float run = 0.f;
#pragma unroll
    for (int q = 0; q < 8; ++q) {
      lwr[q] = lw[base + (size_t)(wv*8 + q) * C_];
      lcE[q] = run; run += lwr[q];
    }
    wtot[wv][ln] = run;
  }
  __syncthreads();
  {
    float pre = 0.f;
    for (int w2 = 0; w2 < wv; ++w2) pre += wtot[w2][ln];
    if (wv == 0) lcl[ln] = wtot[0][ln] + wtot[1][ln] + wtot[2][ln] + wtot[3][ln];
#pragma unroll
    for (int q = 0; q < 8; ++q) lcE[q] += pre;
  }
#pragma unroll
  for (int q = 0; q < 8; ++q) {
    const int s = wv*8 + q;
    const size_t off = base + (size_t)s * C_;
    float kkx = kkv[off], aax = aam[off], kx = kk_s[off], rx = rr[off], vx = vv[off];
    float lcI = lcE[q] + lwr[q];
    float eIm = __expf(-lcI);
    float av = -kkx * __expf(lcE[q]);
    float bv = kkx * aax * eIm;
    float kv2 = kx * eIm;
    float rv = rx * __expf(lcI);
    aC[s][ln] = av;  vL[s][ln] = vx;
    aCb[s][ln] = tobf(av);  rCb[s][ln] = tobf(rv);
    bTb[s][ln] = tobf(bv);  kTb[s][ln] = tobf(kv2);
    bTT[ln][s] = tobf(bv);  kTT[ln][s] = tobf(kv2);  vLT[ln][s] = tobf(vx);
  }
  __syncthreads();

  // --- phase 2: MFMA, one 32x32 (K=64) product per wave ---
  {
    const bf16 (*Ab)[72] = (wv < 2) ? aCb : rCb;
    const bf16 (*Bb)[72] = (wv & 1) ? kTb : bTb;
#pragma unroll
    for (int mt = 0; mt < 2; ++mt)
#pragma unroll
      for (int nt = 0; nt < 2; ++nt) {
        f32x4 acc = {};
#pragma unroll
        for (int ks = 0; ks < 2; ++ks) {
          bf16x8 af = *(const bf16x8*)&Ab[mt*16 + lm][ks*32 + kg*8];
          bf16x8 bq = *(const bf16x8*)&Bb[nt*16 + lm][ks*32 + kg*8];
          acc = mfma16x16x32(af, bq, acc);
        }
        const int row0 = mt*16 + kg*4, col = nt*16 + lm;
#pragma unroll
        for (int q = 0; q < 4; ++q) {
          float v = acc[q];
          if (wv == 0)      Am[row0+q][col] = v;
          else if (wv == 1) Cm[row0+q][col] = v;
          else {
            bf16 bv2 = tobf(col <= row0+q ? v : 0.f);  // tril<= mask
            if (wv == 2) abybufb[(size_t)ch*1024 + (row0+q)*32 + col] = bv2;
            else         ckybufb[(size_t)ch*1024 + (row0+q)*32 + col] = bv2;
          }
        }
      }
  }
  __syncthreads();

  // --- phase 3: register forward-substitution (wave0: W, wave1: SA_loc) ---
  if (wv < 2) {
    float Xr[32], amr[32];
#pragma unroll
    for (int s = 0; s < 32; ++s) amr[s] = Am[s][ln & 31];
    if (wv == 0) {
#pragma unroll
      for (int s = 0; s < 32; ++s) Xr[s] = aC[s][ln];
    } else {
      float cmr[32];
#pragma unroll
      for (int s = 0; s < 32; ++s) cmr[s] = Cm[s][ln & 31];
#pragma unroll
      for (int s = 0; s < 32; ++s) Xr[s] = 0.f;
#pragma unroll
      for (int u = 0; u < 31; ++u) {
        float v = vL[u][ln];
#pragma unroll
        for (int s = u + 1; s < 32; ++s) Xr[s] += rdlane(cmr[s], u) * v;
      }
    }
#pragma unroll
    for (int s = 1; s < 32; ++s) {
      float acc = Xr[s];
#pragma unroll
      for (int u = 0; u < s; ++u) acc += rdlane(amr[s], u) * Xr[u];
      Xr[s] = acc;
    }
    if (wv == 0) {
#pragma unroll
      for (int s = 0; s < 32; ++s) {
        bf16 bv = tobf(Xr[s]);
        WT[ln][s] = bv;
        wbufb[(size_t)ch*2048 + s*64 + ln] = bv;
      }
    } else {
#pragma unroll
      for (int s = 0; s < 32; ++s) {
        bf16 bv = tobf(Xr[s]);
        SAT[ln][s] = bv;
        sabufb[(size_t)ch*2048 + s*64 + ln] = bv;
      }
    }
  }
  __syncthreads();

  // --- phase 5: U, M (64x64, K=32) via MFMA; M = (G' + I).*dL_j fused ------
  {
    const int mt = wv;
    bf16x8 aS = *(const bf16x8*)&SAT[mt*16 + lm][kg*8];
    bf16x8 aV = *(const bf16x8*)&vLT[mt*16 + lm][kg*8];
    bf16x8 aW = *(const bf16x8*)&WT[mt*16 + lm][kg*8];
#pragma unroll
    for (int nt = 0; nt < 4; ++nt) {
      bf16x8 bB = *(const bf16x8*)&bTT[nt*16 + lm][kg*8];
      bf16x8 bK = *(const bf16x8*)&kTT[nt*16 + lm][kg*8];
      f32x4 aU = {}, aG = {};
      aU = mfma16x16x32(aS, bB, aU);
      aU = mfma16x16x32(aV, bK, aU);
      aG = mfma16x16x32(aW, bB, aG);
      const int i0r = mt*16 + kg*4, col = nt*16 + lm;
      float dl = __expf(lcl[col]);
#pragma unroll
      for (int q = 0; q < 4; ++q) {
        ubufb[(size_t)ch*4096 + (i0r+q)*64 + col] = tobf(aU[q] * dl);
        float diag = (i0r + q == col) ? 1.f : 0.f;
        mbufb[(size_t)ch*4096 + (i0r+q)*64 + col] = tobf((aG[q] + diag) * dl);
      }
    }
  }
}

// Phase B: serial over chunks; 256 blocks = 32 heads x 8 rowgroups.
// S <- S*M + U with distance-2 register prefetch + 2-deep LDS double buffer.
__global__ __launch_bounds__(256) void rwkv_chunk_state(
    const unsigned short* __restrict__ mbufb,
    const unsigned short* __restrict__ ubufb,
    bf16* __restrict__ s0bufb)
{
  __shared__ float Mf[2][64][68];
  const int bh = blockIdx.x >> 3, rg = blockIdx.x & 7;
  const int tid = threadIdx.x, wv = tid >> 6, ln = tid & 63;
  const int i0 = rg*8 + wv*2, i1 = i0 + 1;
  const int grow = tid >> 2, gcol = (tid & 3) * 16;
  float S0r = 0.f, S1r = 0.f;

  uint4 mA0, mA1, mB0, mB1;
  float uA0 = 0.f, uA1 = 0.f, uB0 = 0.f, uB1 = 0.f;

#define LOADSET(g0, g1, u0, u1, c)                                      \
  { const size_t chb = (size_t)(bh*NCH + (c));                          \
    const unsigned short* gp = mbufb + chb*4096 + (size_t)tid*16;       \
    g0 = *(const uint4*)gp; g1 = *(const uint4*)(gp + 8);               \
    u0 = bf2f(ubufb[chb*4096 + i0*64 + ln]);                            \
    u1 = bf2f(ubufb[chb*4096 + i1*64 + ln]); }

#define COMMIT(nb, g0, g1)                                              \
  { const unsigned int* w0 = (const unsigned int*)&g0;                  \
    const unsigned int* w1 = (const unsigned int*)&g1;                  \
    _Pragma("unroll")                                                   \
    for (int e = 0; e < 4; ++e) {                                       \
      *(float2*)&Mf[nb][grow][gcol + e*2] =                             \
          make_float2(bf2f((unsigned short)(w0[e] & 0xffff)),           \
                      bf2f((unsigned short)(w0[e] >> 16)));             \
      *(float2*)&Mf[nb][grow][gcol + 8 + e*2] =                         \
          make_float2(bf2f((unsigned short)(w1[e] & 0xffff)),           \
                      bf2f((unsigned short)(w1[e] >> 16)));             \
    } }

#define STEP(nb, uc0, uc1)                                              \
  { float a0 = uc0, a1 = uc1;                                           \
    _Pragma("unroll")                                                   \
    for (int m = 0; m < 64; ++m) {                                      \
      float g = Mf[nb][m][ln];                                          \
      a0 += rdlane(S0r, m) * g;                                         \
      a1 += rdlane(S1r, m) * g;                                         \
    }                                                                   \
    S0r = a0; S1r = a1; }

  LOADSET(mA0, mA1, uA0, uA1, 0);
  LOADSET(mB0, mB1, uB0, uB1, 1);

  for (int cc = 0; cc < NCH; cc += 2) {
    size_t ch = (size_t)bh*NCH + cc;
    // even step: buffer 0, reg set A
    COMMIT(0, mA0, mA1);
    const float ue0 = uA0, ue1 = uA1;
    s0bufb[(ch*64 + i0)*64 + ln] = tobf(S0r);
    s0bufb[(ch*64 + i1)*64 + ln] = tobf(S1r);
    __syncthreads();
    if (cc + 2 < NCH) LOADSET(mA0, mA1, uA0, uA1, cc + 2);
    STEP(0, ue0, ue1);
    // odd step: buffer 1, reg set B
    ch += 1;
    COMMIT(1, mB0, mB1);
    const float uo0 = uB0, uo1 = uB1;
    s0bufb[(ch*64 + i0)*64 + ln] = tobf(S0r);
    s0bufb[(ch*64 + i1)*64 + ln] = tobf(S1r);
    __syncthreads();
    if (cc + 3 < NCH) LOADSET(mB0, mB1, uB0, uB1, cc + 3);
    STEP(1, uo0, uo1);
  }
#undef LOADSET
#undef COMMIT
#undef STEP
}

// Phase C: per chunk-head, MFMA: SA = W*S0^T + SAll, then
// y = Rt*S0^T + ABl*SAo + CKl*V  (ABl/CKl pre-masked tril<=).
__global__ __launch_bounds__(256, 4) void rwkv_chunk_out(
    const float* __restrict__ rr, const float* __restrict__ lw,
    const float* __restrict__ vv, const bf16* __restrict__ s0bufb,
    const bf16* __restrict__ wbufb, const bf16* __restrict__ sabufb,
    const bf16* __restrict__ abybufb, const bf16* __restrict__ ckybufb,
    float* __restrict__ y)
{
  __shared__ bf16 S0b[64][72];                    // B^T layout: [i][j]
  __shared__ bf16 Wb[LCH][72], Rlb[LCH][72];      // A layouts: [s][j]
  __shared__ bf16 ABl[LCH][40], CKl[LCH][40];     // A layouts: [s][u]
  __shared__ bf16 SAot[64][40], VlT[64][40];      // B^T layouts: [i][u]
  __shared__ float wtot[4][64];
  const int ch = blockIdx.x;
  const int c = ch & (NCH - 1), bh = ch >> 6, b = bh >> 4, h = bh & 15;
  const int tid = threadIdx.x, wv = tid >> 6, ln = tid & 63;
  const int lm = ln & 15, kg = ln >> 4;
  const size_t base = ((size_t)(b*T_ + c*LCH) * C_) + h*N_ + ln;

  float lwr[8], lcE[8];
  {
    float run = 0.f;
#pragma unroll
    for (int q = 0; q < 8; ++q) {
      lwr[q] = lw[base + (size_t)(wv*8 + q) * C_];
      lcE[q] = run; run += lwr[q];
    }
    wtot[wv][ln] = run;
  }
  __syncthreads();
  {
    float pre = 0.f;
    for (int w2 = 0; w2 < wv; ++w2) pre += wtot[w2][ln];
#pragma unroll
    for (int q = 0; q < 8; ++q) lcE[q] += pre;
  }
#pragma unroll
  for (int q = 0; q < 8; ++q) {
    const int s = wv*8 + q;
    const size_t off = base + (size_t)s * C_;
    Rlb[s][ln] = tobf(rr[off] * __expf(lcE[q] + lwr[q]));
    VlT[ln][s] = tobf(vv[off]);
  }
#pragma unroll
  for (int t = 0; t < 2; ++t) {
    int cc2 = tid*2 + t; int ri = cc2 >> 3, co = (cc2 & 7) * 8;
    *(uint4*)&S0b[ri][co] = *(const uint4*)(s0bufb + (size_t)ch*4096 + ri*64 + co);
  }
  { int ri = tid >> 3, co = (tid & 7) * 8;
    *(uint4*)&Wb[ri][co] = *(const uint4*)(wbufb + (size_t)ch*2048 + ri*64 + co); }
  if (tid < 128) {
    int ri = tid >> 2, co = (tid & 3) * 8;
    *(uint4*)&ABl[ri][co] = *(const uint4*)(abybufb + (size_t)ch*1024 + ri*32 + co);
  } else {
    int t2 = tid - 128; int ri = t2 >> 2, co = (t2 & 3) * 8;
    *(uint4*)&CKl[ri][co] = *(const uint4*)(ckybufb + (size_t)ch*1024 + ri*32 + co);
  }
  __syncthreads();

  const int mt = wv >> 1, ntb = (wv & 1) * 2;
#pragma unroll
  for (int t = 0; t < 2; ++t) {
    const int nt = ntb + t;
    const int row0 = mt*16 + kg*4, col = nt*16 + lm;
    f32x4 acc;
#pragma unroll
    for (int q = 0; q < 4; ++q)
      acc[q] = __bfloat162float(sabufb[(size_t)ch*2048 + (row0+q)*64 + col]);
#pragma unroll
    for (int ks = 0; ks < 2; ++ks) {
      bf16x8 af = *(const bf16x8*)&Wb[mt*16 + lm][ks*32 + kg*8];
      bf16x8 bq = *(const bf16x8*)&S0b[nt*16 + lm][ks*32 + kg*8];
      acc = mfma16x16x32(af, bq, acc);
    }
#pragma unroll
    for (int q = 0; q < 4; ++q) SAot[col][row0+q] = tobf(acc[q]);
  }
  __syncthreads();

#pragma unroll
  for (int t = 0; t < 2; ++t) {
    const int nt = ntb + t;
    f32x4 acc = {};
#pragma unroll
    for (int ks = 0; ks < 2; ++ks) {
      bf16x8 af = *(const bf16x8*)&Rlb[mt*16 + lm][ks*32 + kg*8];
      bf16x8 bq = *(const bf16x8*)&S0b[nt*16 + lm][ks*32 + kg*8];
      acc = mfma16x16x32(af, bq, acc);
    }
    {
      bf16x8 af = *(const bf16x8*)&ABl[mt*16 + lm][kg*8];
      bf16x8 bq = *(const bf16x8*)&SAot[nt*16 + lm][kg*8];
      acc = mfma16x16x32(af, bq, acc);
    }
    {
      bf16x8 af = *(const bf16x8*)&CKl[mt*16 + lm][kg*8];
      bf16x8 bq = *(const bf16x8*)&VlT[nt*16 + lm][kg*8];
      acc = mfma16x16x32(af, bq, acc);
    }
    const int row0 = mt*16 + kg*4, col = nt*16 + lm;
#pragma unroll
    for (int q = 0; q < 4; ++q)
      y[((size_t)(b*T_ + c*LCH + row0 + q)) * C_ + h*N_ + col] = acc[q];
  }
}

// ---------------- groupnorm + bonus + gate ---------------------------------
__global__ __launch_bounds__(256) void gn_bonus_gate(
    const float* __restrict__ y, const float* __restrict__ rr,
    const float* __restrict__ kk_s, const float* __restrict__ vv,
    const bf16* __restrict__ gg, const float* __restrict__ faaaa,
    const float* __restrict__ lnw, const float* __restrict__ lnb,
    bf16* __restrict__ zb)
{
  const int bt = blockIdx.x;
  const int wave = threadIdx.x >> 6, lane = threadIdx.x & 63;
  const float inv64 = 1.f / 64.f;
  for (int h = wave; h < H_; h += 4) {
    const int c = h * 64 + lane;
    const size_t o = (size_t)bt * C_ + c;
    float yv = y[o];
    float mean = allred64(yv) * inv64;
    float d = yv - mean;
    float var = allred64(d * d) * inv64;
    float xn = d * rsqrtf(var + 6.4e-4f);
    float gn = xn * lnw[c] + lnb[c];
    float rk = allred64(rr[o] * kk_s[o] * faaaa[c]);
    float z = (gn + rk * vv[o]) * __bfloat162float(gg[o]);
    zb[o] = tobf(z);
  }
}

// ---------------- driver ----------------------------------------------------
extern "C" void kernel_launch(void* const* d_in, const int* in_sizes, int n_in,
                              void* d_out, int out_size, void* d_ws, size_t ws_size,
                              hipStream_t stream)
{
  const float* x     = (const float*)d_in[0];
  const float* maa_x = (const float*)d_in[1];
  const float* maa_r = (const float*)d_in[2];
  const float* maa_w = (const float*)d_in[3];
  const float* maa_k = (const float*)d_in[4];
  const float* maa_v = (const float*)d_in[5];
  const float* maa_a = (const float*)d_in[6];
  const float* maa_g = (const float*)d_in[7];
  const float* tdec  = (const float*)d_in[8];
  const float* faaaa = (const float*)d_in[9];
  const float* aaaaa = (const float*)d_in[10];
  const float* maa_w1= (const float*)d_in[11];
  const float* maa_w2= (const float*)d_in[12];
  const float* dec_w1= (const float*)d_in[13];
  const float* dec_w2= (const float*)d_in[14];
  const float* aaa_w1= (const float*)d_in[15];
  const float* aaa_w2= (const float*)d_in[16];
  const float* kkk_w1= (const float*)d_in[17];
  const float* kkk_w2= (const float*)d_in[18];
  const float* gate_w1=(const float*)d_in[19];
  const float* gate_w2=(const float*)d_in[20];
  const float* W_r   = (const float*)d_in[21];
  const float* W_k   = (const float*)d_in[22];
  const float* W_v   = (const float*)d_in[23];
  const float* W_o   = (const float*)d_in[24];
  const float* lnw   = (const float*)d_in[25];
  const float* lnb   = (const float*)d_in[26];

  char* ws = (char*)d_ws;
  size_t cur = 0;
  auto alloc = [&](size_t bytes) -> void* {
    void* p = ws + cur; cur += (bytes + 255) & ~(size_t)255; return p;
  };
  const size_t FBT = (size_t)BT_ * C_ * sizeof(float);

  // ---- persistent ----
  float* rb   = (float*)alloc(FBT);
  float* kb   = (float*)alloc(FBT);
  float* vb   = (float*)alloc(FBT);
  bf16*  gbb  = (bf16*)alloc((size_t)BT_*C_*2);
  bf16* WtR  = (bf16*)alloc((size_t)C_*C_*2);
  bf16* WtK  = (bf16*)alloc((size_t)C_*C_*2);
  bf16* WtV  = (bf16*)alloc((size_t)C_*C_*2);
  bf16* WtO  = (bf16*)alloc((size_t)C_*C_*2);
  bf16* w1t  = (bf16*)alloc((size_t)192*C_*2);
  bf16* w2t  = (bf16*)alloc((size_t)6*C_*32*2);
  bf16* d1t  = (bf16*)alloc((size_t)64*C_*2);
  bf16* d2t  = (bf16*)alloc((size_t)C_*64*2);
  bf16* a1t  = (bf16*)alloc((size_t)64*C_*2);
  bf16* a2t  = (bf16*)alloc((size_t)C_*64*2);
  bf16* k1t  = (bf16*)alloc((size_t)64*C_*2);
  bf16* k2t  = (bf16*)alloc((size_t)C_*64*2);
  bf16* g1t  = (bf16*)alloc((size_t)128*C_*2);
  bf16* g2t  = (bf16*)alloc((size_t)C_*128*2);
  float* lwb  = (float*)alloc(FBT);
  float* kkb  = (float*)alloc(FBT);   // dead after chunk_pre; s0bufb overlays
  float* aamt = (float*)alloc(FBT);
  bf16* s0bufb = (bf16*)kkb;          // CHD*4096*2 == FBT exactly

  // ---- union region ----
  const size_t ubase = cur;
  float* mtmp = (float*)alloc(FBT);
  bf16* xinb = (bf16*)alloc((size_t)BT_*C_*2);
  bf16* mixb = (bf16*)alloc((size_t)BT_*192*2);
  bf16* xbr[6];
  for (int s = 0; s < 6; ++s) xbr[s] = (bf16*)alloc((size_t)BT_*C_*2);
  bf16* h64b = (bf16*)alloc((size_t)BT_*64*2);
  bf16* h128b= (bf16*)alloc((size_t)BT_*128*2);
  const size_t tmp_end = cur;
  cur = ubase;  // overlay
  bf16*  wbufb   = (bf16*)alloc((size_t)CHD*2048*2);
  bf16*  sabufb  = (bf16*)alloc((size_t)CHD*2048*2);
  bf16*  abybufb = (bf16*)alloc((size_t)CHD*1024*2);
  bf16*  ckybufb = (bf16*)alloc((size_t)CHD*1024*2);
  bf16*  ubufb   = (bf16*)alloc((size_t)CHD*4096*2);
  bf16*  mbufb   = (bf16*)alloc((size_t)CHD*4096*2);
  bf16*  zb      = (bf16*)ubufb;   // alias: ubufb dead after chunk_state
  if (tmp_end > cur) cur = tmp_end;
  const size_t need = cur;
  (void)in_sizes; (void)n_in; (void)out_size;

  if (ws_size < need) {
    ws_diag<<<1, 1, 0, stream>>>((float)ws_size, (float)need, (float*)d_out);
    return;
  }

  PrepArgs pa;
  pa.src[0] = W_r;  pa.dst[0] = WtR;
  pa.src[1] = W_k;  pa.dst[1] = WtK;
  pa.src[2] = W_v;  pa.dst[2] = WtV;
  pa.src[3] = W_o;  pa.dst[3] = WtO;
  pa.src[4] = maa_w1; pa.dst[4] = w1t;
  for (int s = 0; s < 6; ++s) { pa.src[5+s] = maa_w2 + (size_t)s*32*C_; pa.dst[5+s] = w2t + (size_t)s*C_*32; }
  pa.src[11] = dec_w1; pa.dst[11] = d1t;
  pa.src[12] = dec_w2; pa.dst[12] = d2t;
  pa.src[13] = aaa_w1; pa.dst[13] = a1t;
  pa.src[14] = aaa_w2; pa.dst[14] = a2t;
  pa.src[15] = kkk_w1; pa.dst[15] = k1t;
  pa.src[16] = kkk_w2; pa.dst[16] = k2t;
  pa.src[17] = gate_w1; pa.dst[17] = g1t;
  pa.src[18] = gate_w2; pa.dst[18] = g2t;
  prep_weights<<<dim3(1024, 19), 256, 0, stream>>>(pa);

  const int EW_GRID = (BT_ * C_) / 256;  // 16384
  xin_k<<<EW_GRID, 256, 0, stream>>>(x, maa_x, xinb);

  gemm_bt<1><<<dim3(64, 3), 256, 0, stream>>>(xinb, C_, w1t, C_, mixb, 192, C_);

  Mix6Args ma;
  ma.maa[0] = maa_r; ma.maa[1] = maa_w; ma.maa[2] = maa_k;
  ma.maa[3] = maa_v; ma.maa[4] = maa_a; ma.maa[5] = maa_g;
  for (int s = 0; s < 6; ++s) ma.out[s] = xbr[s];
  mix_combine<<<dim3(64, 16, 6), 256, 0, stream>>>(mixb, w2t, x, ma);

  // r, k, v batched (one launch)
  RkvArgs ra;
  ra.A[0] = xbr[0]; ra.Bt[0] = WtR; ra.Cq[0] = rb;
  ra.A[1] = xbr[2]; ra.Bt[1] = WtK; ra.Cq[1] = kb;
  ra.A[2] = xbr[3]; ra.Bt[2] = WtV; ra.Cq[2] = vb;
  gemm128_rkv<<<dim3(32, 8, 3), 256, 0, stream>>>(ra);

  // kk path (uses UNscaled k)
  gemm_bt<1><<<dim3(64, 1), 256, 0, stream>>>(xbr[2], C_, k1t, C_, h64b, 64, C_);
  gemm128<0><<<dim3(32, 8), 256, 0, stream>>>(h64b, 64, k2t, 64, mtmp, C_, 64, nullptr, nullptr);
  kk_normalize<<<BT_, 256, 0, stream>>>(kb, mtmp, kkb);

  // w path: fused finalize epilogue (writes lwb, scales kb in place)
  gemm_bt<1><<<dim3(64, 1), 256, 0, stream>>>(xbr[1], C_, d1t, C_, h64b, 64, C_);
  gemm128<3><<<dim3(32, 8), 256, 0, stream>>>(h64b, 64, d2t, 64, lwb, C_, 64, tdec, kb);

  // a path: fused sigmoid epilogue
  gemm_bt<2><<<dim3(64, 1), 256, 0, stream>>>(xbr[4], C_, a1t, C_, h64b, 64, C_);
  gemm128<4><<<dim3(32, 8), 256, 0, stream>>>(h64b, 64, a2t, 64, aamt, C_, 64, aaaaa, nullptr);

  // g path -> bf16 gate buffer
  gemm_bt<1><<<dim3(64, 2), 256, 0, stream>>>(xbr[5], C_, g1t, C_, h128b, 128, C_);
  gemm128<2><<<dim3(32, 8), 256, 0, stream>>>(h128b, 128, g2t, 128, gbb, C_, 128, nullptr, nullptr);

  // ---- chunked scan ----
  rwkv_chunk_pre<<<CHD, 256, 0, stream>>>(rb, lwb, kb, kkb, aamt, vb,
      wbufb, sabufb, abybufb, ckybufb, ubufb, mbufb);
  rwkv_chunk_state<<<256, 256, 0, stream>>>((const unsigned short*)mbufb,
      (const unsigned short*)ubufb, s0bufb);
  rwkv_chunk_out<<<CHD, 256, 0, stream>>>(rb, lwb, vb, s0bufb, wbufb, sabufb,
      abybufb, ckybufb, (float*)d_out);

  gn_bonus_gate<<<BT_, 256, 0, stream>>>((const float*)d_out, rb, kb, vb, gbb,
                                         faaaa, lnw, lnb, zb);

  gemm128<0><<<dim3(32, 8), 256, 0, stream>>>(zb, C_, WtO, C_, d_out, C_, C_, nullptr, nullptr);
}

// Round 9
// 396.928 us; speedup vs baseline: 4.1164x; 1.1413x over previous
//
#include <hip/hip_runtime.h>
#include <hip/hip_bf16.h>

using bf16 = __hip_bfloat16;
using bf16x8 = __attribute__((ext_vector_type(8))) short;  // 8 bf16 (4 VGPRs)
using f32x4 = __attribute__((ext_vector_type(4))) float;

#define B_ 2
#define T_ 2048
#define C_ 1024
#define BT_ (B_*T_)
#define H_ 16
#define N_ 64
#define LCH 32            // scan chunk length
#define NCH (T_/LCH)      // 64 chunks per head
#define CHD (B_*H_*NCH)   // 2048 chunk-heads

__device__ __forceinline__ float allred64(float v) {
#pragma unroll
  for (int m = 1; m < 64; m <<= 1) v += __shfl_xor(v, m, 64);
  return v;
}

__device__ __forceinline__ bf16 tobf(float f) { return __float2bfloat16(f); }
__device__ __forceinline__ float bf2f(unsigned short u) {
  unsigned int x = ((unsigned int)u) << 16;
  return __builtin_bit_cast(float, x);
}
__device__ __forceinline__ float rdlane(float v, int m) {
  return __builtin_bit_cast(float,
      __builtin_amdgcn_readlane(__builtin_bit_cast(int, v), m));
}

__device__ __forceinline__ f32x4 mfma16x16x32(bf16x8 a, bf16x8 b, f32x4 c) {
  return __builtin_amdgcn_mfma_f32_16x16x32_bf16(a, b, c, 0, 0, 0);
}

// async global->LDS, 16B per lane (dest = wave-uniform base + lane*16)
typedef const __attribute__((address_space(1))) unsigned int* gas_ptr;
typedef __attribute__((address_space(3))) unsigned int* las_ptr;
__device__ __forceinline__ void gload16(const void* g, void* l) {
  __builtin_amdgcn_global_load_lds((gas_ptr)g, (las_ptr)l, 16, 0, 0);
}

// ---------------- ws_size diagnostic ----------------------------------------
__global__ void ws_diag(float a, float b, float* out) { out[0] = a; out[1] = b; }

// ---------------- weight transpose + bf16 cast (19 jobs, one launch) -------
struct PrepArgs {
  const float* src[19];
  bf16* dst[19];
};
__constant__ int kTR[19] = {1024,1024,1024,1024, 1024, 32,32,32,32,32,32,
                            1024,64, 1024,64, 1024,64, 1024,128};
__constant__ int kTC[19] = {1024,1024,1024,1024, 192, 1024,1024,1024,1024,1024,1024,
                            64,1024, 64,1024, 64,1024, 128,1024};

__global__ __launch_bounds__(256) void prep_weights(PrepArgs pa) {
  const int job = blockIdx.y;
  const int R = kTR[job], Cc = kTC[job];
  const int ntx = Cc >> 5, nty = R >> 5;
  const int tile = blockIdx.x;
  if (tile >= ntx * nty) return;
  const int tx = tile % ntx, ty = tile / ntx;
  const float* __restrict__ src = pa.src[job];
  bf16* __restrict__ dst = pa.dst[job];
  __shared__ float tl[32][33];
  const int lx = threadIdx.x & 31, ly = threadIdx.x >> 5;  // 32 x 8
#pragma unroll
  for (int q = 0; q < 4; ++q)
    tl[ly + 8*q][lx] = src[(size_t)(ty*32 + ly + 8*q) * Cc + tx*32 + lx];
  __syncthreads();
#pragma unroll
  for (int q = 0; q < 4; ++q)
    dst[(size_t)(tx*32 + ly + 8*q) * R + ty*32 + lx] = tobf(tl[lx][ly + 8*q]);
}

// ------- GEMM 64-tile -------------------------------------------------------
template<int EPI>
__global__ __launch_bounds__(256) void gemm_bt(
    const bf16* __restrict__ A, int lda,
    const bf16* __restrict__ Bt, int ldb,
    void* __restrict__ Cout, int ldc, int K)
{
  __shared__ short As[64][40];
  __shared__ short Bs[64][40];
  const int bm0 = blockIdx.x * 64;
  const int bn0 = blockIdx.y * 64;
  const int tid = threadIdx.x;
  const int wave = tid >> 6, lane = tid & 63;
  const int lm = lane & 15, kg = lane >> 4;
  const int srow = tid >> 2, scol = (tid & 3) * 8;
  f32x4 acc[4] = {};
  const size_t abase = (size_t)(bm0 + srow) * lda + scol;
  const size_t bbase = (size_t)(bn0 + srow) * ldb + scol;
  for (int k0 = 0; k0 < K; k0 += 32) {
    *(uint4*)&As[srow][scol] = *(const uint4*)(A + abase + k0);
    *(uint4*)&Bs[srow][scol] = *(const uint4*)(Bt + bbase + k0);
    __syncthreads();
    bf16x8 af = *(const bf16x8*)&As[wave*16 + lm][kg*8];
#pragma unroll
    for (int f = 0; f < 4; ++f) {
      bf16x8 bfr = *(const bf16x8*)&Bs[f*16 + lm][kg*8];
      acc[f] = mfma16x16x32(af, bfr, acc[f]);
    }
    __syncthreads();
  }
  const int row0 = bm0 + wave*16 + kg*4;
  const int col0 = bn0 + lm;
#pragma unroll
  for (int f = 0; f < 4; ++f) {
#pragma unroll
    for (int q = 0; q < 4; ++q) {
      float val = acc[f][q];
      size_t o = (size_t)(row0 + q) * ldc + col0 + f*16;
      if (EPI == 0)      ((float*)Cout)[o] = val;
      else if (EPI == 1) ((bf16*)Cout)[o] = tobf(tanhf(val));
      else               ((bf16*)Cout)[o] = tobf(val);
    }
  }
}

// ------- batched small projections: k1/d1/a1 (N=64) + g1 (N=128) -----------
struct Proj4Args { const bf16* A[4]; const bf16* Bt[4]; bf16* out[4];
                   int N[4]; int tnh[4]; };
__global__ __launch_bounds__(256) void proj4(Proj4Args p4) {
  const int z = blockIdx.z;
  const int Nn = p4.N[z];
  const int bn0 = blockIdx.y * 64;
  if (bn0 >= Nn) return;
  __shared__ short As[64][40];
  __shared__ short Bs[64][40];
  const bf16* __restrict__ A  = p4.A[z];
  const bf16* __restrict__ Bt = p4.Bt[z];
  bf16* __restrict__ out = p4.out[z];
  const int tnh = p4.tnh[z];
  const int bm0 = blockIdx.x * 64;
  const int tid = threadIdx.x;
  const int wave = tid >> 6, lane = tid & 63;
  const int lm = lane & 15, kg = lane >> 4;
  const int srow = tid >> 2, scol = (tid & 3) * 8;
  f32x4 acc[4] = {};
  const size_t abase = (size_t)(bm0 + srow) * C_ + scol;
  const size_t bbase = (size_t)(bn0 + srow) * C_ + scol;
  for (int k0 = 0; k0 < C_; k0 += 32) {
    *(uint4*)&As[srow][scol] = *(const uint4*)(A + abase + k0);
    *(uint4*)&Bs[srow][scol] = *(const uint4*)(Bt + bbase + k0);
    __syncthreads();
    bf16x8 af = *(const bf16x8*)&As[wave*16 + lm][kg*8];
#pragma unroll
    for (int f = 0; f < 4; ++f) {
      bf16x8 bfr = *(const bf16x8*)&Bs[f*16 + lm][kg*8];
      acc[f] = mfma16x16x32(af, bfr, acc[f]);
    }
    __syncthreads();
  }
  const int row0 = bm0 + wave*16 + kg*4;
  const int col0 = bn0 + lm;
#pragma unroll
  for (int f = 0; f < 4; ++f) {
#pragma unroll
    for (int q = 0; q < 4; ++q) {
      float val = acc[f][q];
      size_t o = (size_t)(row0 + q) * Nn + col0 + f*16;
      out[o] = tobf(tnh ? tanhf(val) : val);
    }
  }
}

// ------- GEMM 128-tile, m97 structure (global_load_lds staging) -------------
// EPI: 0 f32 | 2 bf16 | 3 w-finalize (Cout=lw, aux1=td, aux2=k inplace)
//      4 a-finalize (Cout=aamt, aux1=aaaaa)
template<int EPI>
__global__ __launch_bounds__(256) void gemm128(
    const bf16* __restrict__ A, int lda,
    const bf16* __restrict__ Bt, int ldb,
    void* __restrict__ Cout, int ldc, int K,
    const float* __restrict__ aux1, float* __restrict__ aux2)
{
  __shared__ bf16 As[128][32];     // linear (required by global_load_lds)
  __shared__ bf16 Bs[128][32];
  const int bm0 = blockIdx.x * 128, bn0 = blockIdx.y * 128;
  const int tid = threadIdx.x, wv = tid >> 6, ln = tid & 63;
  const int wr = wv >> 1, wc = wv & 1;
  const int lm = ln & 15, kg = ln >> 4;
  const int srow = ln >> 2, scol = (ln & 3) * 8;
  f32x4 acc[4][4] = {};
  for (int k0 = 0; k0 < K; k0 += 32) {
#pragma unroll
    for (int i = 0; i < 2; ++i) {
      const int r0 = wv*32 + i*16;
      gload16(A  + (size_t)(bm0 + r0 + srow) * lda + k0 + scol, &As[r0][0]);
      gload16(Bt + (size_t)(bn0 + r0 + srow) * ldb + k0 + scol, &Bs[r0][0]);
    }
    asm volatile("s_waitcnt vmcnt(0)" ::: "memory");
    __syncthreads();
    bf16x8 af[4], bfr[4];
#pragma unroll
    for (int m = 0; m < 4; ++m) af[m] = *(const bf16x8*)&As[wr*64 + m*16 + lm][kg*8];
#pragma unroll
    for (int n = 0; n < 4; ++n) bfr[n] = *(const bf16x8*)&Bs[wc*64 + n*16 + lm][kg*8];
#pragma unroll
    for (int m = 0; m < 4; ++m)
#pragma unroll
      for (int n = 0; n < 4; ++n)
        acc[m][n] = mfma16x16x32(af[m], bfr[n], acc[m][n]);
    __syncthreads();
  }
#pragma unroll
  for (int m = 0; m < 4; ++m) {
    const int row0 = bm0 + wr*64 + m*16 + kg*4;
#pragma unroll
    for (int n = 0; n < 4; ++n) {
      const int col = bn0 + wc*64 + n*16 + lm;
#pragma unroll
      for (int q = 0; q < 4; ++q) {
        float val = acc[m][n][q];
        size_t o = (size_t)(row0 + q) * ldc + col;
        if (EPI == 0)      ((float*)Cout)[o] = val;
        else if (EPI == 2) ((bf16*)Cout)[o] = tobf(val);
        else if (EPI == 3) {
          float wr2 = val + aux1[col];
          float sp = fmaxf(-wr2, 0.f) + log1pf(expf(-fabsf(wr2)));
          float w = -sp - 0.5f;
          ((float*)Cout)[o] = -expf(w);              // lw
          aux2[o] *= expf(fminf(0.5f * w, 0.f));     // k scale in place
        } else if (EPI == 4) {
          float z = aux1[col] + val;
          ((float*)Cout)[o] = 2.f / (1.f + expf(-z));
        }
      }
    }
  }
}

// batched r/k/v: same shape (M=4096, N=1024, K=1024), z selects operands
struct RkvArgs { const bf16* A[3]; const bf16* Bt[3]; float* Cq[3]; };
__global__ __launch_bounds__(256) void gemm128_rkv(RkvArgs ra) {
  __shared__ bf16 As[128][32];
  __shared__ bf16 Bs[128][32];
  const bf16* __restrict__ A  = ra.A[blockIdx.z];
  const bf16* __restrict__ Bt = ra.Bt[blockIdx.z];
  float* __restrict__ Cout = ra.Cq[blockIdx.z];
  const int bm0 = blockIdx.x * 128, bn0 = blockIdx.y * 128;
  const int tid = threadIdx.x, wv = tid >> 6, ln = tid & 63;
  const int wr = wv >> 1, wc = wv & 1;
  const int lm = ln & 15, kg = ln >> 4;
  const int srow = ln >> 2, scol = (ln & 3) * 8;
  f32x4 acc[4][4] = {};
  for (int k0 = 0; k0 < C_; k0 += 32) {
#pragma unroll
    for (int i = 0; i < 2; ++i) {
      const int r0 = wv*32 + i*16;
      gload16(A  + (size_t)(bm0 + r0 + srow) * C_ + k0 + scol, &As[r0][0]);
      gload16(Bt + (size_t)(bn0 + r0 + srow) * C_ + k0 + scol, &Bs[r0][0]);
    }
    asm volatile("s_waitcnt vmcnt(0)" ::: "memory");
    __syncthreads();
    bf16x8 af[4], bfr[4];
#pragma unroll
    for (int m = 0; m < 4; ++m) af[m] = *(const bf16x8*)&As[wr*64 + m*16 + lm][kg*8];
#pragma unroll
    for (int n = 0; n < 4; ++n) bfr[n] = *(const bf16x8*)&Bs[wc*64 + n*16 + lm][kg*8];
#pragma unroll
    for (int m = 0; m < 4; ++m)
#pragma unroll
      for (int n = 0; n < 4; ++n)
        acc[m][n] = mfma16x16x32(af[m], bfr[n], acc[m][n]);
    __syncthreads();
  }
#pragma unroll
  for (int m = 0; m < 4; ++m) {
    const int row0 = bm0 + wr*64 + m*16 + kg*4;
#pragma unroll
    for (int n = 0; n < 4; ++n) {
      const int col = bn0 + wc*64 + n*16 + lm;
#pragma unroll
      for (int q = 0; q < 4; ++q)
        Cout[(size_t)(row0 + q) * C_ + col] = acc[m][n][q];
    }
  }
}

// --------- fused 6-branch low-rank projection + combine ---------------------
struct Mix6Args { const float* maa[6]; bf16* out[6]; };

__global__ __launch_bounds__(256) void mix_combine(
    const bf16* __restrict__ mixb, const bf16* __restrict__ w2t,
    const float* __restrict__ x, Mix6Args ma)
{
  __shared__ short As[64][40];
  __shared__ short Bs[64][40];
  const int s6 = blockIdx.z;
  const bf16* __restrict__ A  = mixb + s6*32;            // lda = 192
  const bf16* __restrict__ Bt = w2t + (size_t)s6*C_*32;  // ldb = 32
  const float* __restrict__ maa = ma.maa[s6];
  bf16* __restrict__ out = ma.out[s6];
  const int bm0 = blockIdx.x * 64, bn0 = blockIdx.y * 64;
  const int tid = threadIdx.x, wave = tid >> 6, lane = tid & 63;
  const int lm = lane & 15, kg = lane >> 4;
  const int srow = tid >> 2, scol = (tid & 3) * 8;
  *(uint4*)&As[srow][scol] = *(const uint4*)(A + (size_t)(bm0 + srow)*192 + scol);
  *(uint4*)&Bs[srow][scol] = *(const uint4*)(Bt + (size_t)(bn0 + srow)*32 + scol);
  __syncthreads();
  bf16x8 af = *(const bf16x8*)&As[wave*16 + lm][kg*8];
  f32x4 acc[4] = {};
#pragma unroll
  for (int f = 0; f < 4; ++f) {
    bf16x8 bfr = *(const bf16x8*)&Bs[f*16 + lm][kg*8];
    acc[f] = mfma16x16x32(af, bfr, acc[f]);
  }
  const int row0 = bm0 + wave*16 + kg*4;
  const int col0 = bn0 + lm;
#pragma unroll
  for (int f = 0; f < 4; ++f) {
#pragma unroll
    for (int q = 0; q < 4; ++q) {
      const int row = row0 + q, col = col0 + f*16;
      const size_t o = (size_t)row * C_ + col;
      float xv = x[o];
      float xp = (row & (T_ - 1)) ? x[o - C_] : 0.f;
      out[o] = tobf(xv + (xp - xv) * (maa[col] + acc[f][q]));
    }
  }
}

// ---------------- elementwise ----------------------------------------------
__global__ __launch_bounds__(256) void xin_k(
    const float* __restrict__ x, const float* __restrict__ maa_x,
    bf16* __restrict__ xinb)
{
  size_t idx = (size_t)blockIdx.x * 256 + threadIdx.x;
  int c = idx & (C_ - 1);
  int t = (int)((idx >> 10) & (T_ - 1));
  float xv = x[idx];
  float xp = t ? x[idx - C_] : 0.f;
  xinb[idx] = tobf(xv + (xp - xv) * maa_x[c]);
}

__global__ __launch_bounds__(256) void kk_normalize(
    const float* __restrict__ kraw, const float* __restrict__ kkadd,
    float* __restrict__ kkout)
{
  const int bt = blockIdx.x;
  const int tid = threadIdx.x;
  const size_t o = (size_t)bt * C_;
  float vals[4]; float ss = 0.f;
#pragma unroll
  for (int q = 0; q < 4; ++q) {
    float u = kraw[o + tid + q*256] + kkadd[o + tid + q*256];
    vals[q] = u; ss += u * u;
  }
  ss = allred64(ss);
  __shared__ float red[4];
  const int wave = tid >> 6, lane = tid & 63;
  if (lane == 0) red[wave] = ss;
  __syncthreads();
  float tot = red[0] + red[1] + red[2] + red[3];
  float inv = 1.f / fmaxf(sqrtf(tot), 1e-12f);
#pragma unroll
  for (int q = 0; q < 4; ++q) kkout[o + tid + q*256] = vals[q] * inv;
}

// ============ Chunked RWKV-7 scan (fp32 recurrence, bf16 MFMA phases) =======
//   SA = (I-trilA)^{-1}(Achk S0^T + trilC V) = W S0^T + SA_loc
//   y[s] = rt_s S0^T + tril<=(ABy) SA + tril<=(CKy) V
//   S_L = S0 * M + U  with M = diag(dL) + (W^T Bt).*dL_j  (stored fused, bf16)
//         U = (SA_loc^T Bt + V^T Kt).*dL_j

__global__ __launch_bounds__(256, 2) void rwkv_chunk_pre(
    const float* __restrict__ rr, const float* __restrict__ lw,
    const float* __restrict__ kk_s, const float* __restrict__ kkv,
    const float* __restrict__ aam, const float* __restrict__ vv,
    bf16* __restrict__ wbufb, bf16* __restrict__ sabufb,
    bf16* __restrict__ abybufb, bf16* __restrict__ ckybufb,
    bf16* __restrict__ ubufb, bf16* __restrict__ mbufb)
{
  __shared__ float aC[LCH][68], vL[LCH][68];      // fp32 for the solve
  __shared__ float Am[LCH][33], Cm[LCH][33];
  __shared__ float wtot[4][64];
  __shared__ float lcl[64];
  __shared__ bf16 aCb[LCH][72], rCb[LCH][72], bTb[LCH][72], kTb[LCH][72];
  __shared__ bf16 bTT[64][40], kTT[64][40], vLT[64][40];
  __shared__ bf16 WT[64][40], SAT[64][40];

  const int ch = blockIdx.x;
  const int c  = ch & (NCH - 1);
  const int bh = ch >> 6;
  const int b  = bh >> 4, h = bh & 15;
  const int tid = threadIdx.x, wv = tid >> 6, ln = tid & 63;
  const int lm = ln & 15, kg = ln >> 4;
  const size_t base = ((size_t)(b*T_ + c*LCH) * C_) + h*N_ + ln;

  // --- phase 1: cumulative log-decay + load/scale into LDS (both layouts) ---
  float lwr[8], lcE[8];
  {
    float run = 0.f;
#pragma unroll
    for (int q = 0; q < 8; ++q) {
      lwr[q] = lw[base + (size_t)(wv*8 + q) * C_];
      lcE[q] = run; run += lwr[q];
    }
    wtot[wv][ln] = run;
  }
  __syncthreads();
  {
    float pre = 0.f;
    for (int w2 = 0; w2 < wv; ++w2) pre += wtot[w2][ln];
    if (wv == 0) lcl[ln] = wtot[0][ln] + wtot[1][ln] + wtot[2][ln] + wtot[3][ln];
#pragma unroll
    for (int q = 0; q < 8; ++q) lcE[q] += pre;
  }
#pragma unroll
  for (int q = 0; q < 8; ++q) {
    const int s = wv*8 + q;
    const size_t off = base + (size_t)s * C_;
    float kkx = kkv[off], aax = aam[off], kx = kk_s[off], rx = rr[off], vx = vv[off];
    float lcI = lcE[q] + lwr[q];
    float eIm = __expf(-lcI);
    float av = -kkx * __expf(lcE[q]);
    float bv = kkx * aax * eIm;
    float kv2 = kx * eIm;
    float rv = rx * __expf(lcI);
    aC[s][ln] = av;  vL[s][ln] = vx;
    aCb[s][ln] = tobf(av);  rCb[s][ln] = tobf(rv);
    bTb[s][ln] = tobf(bv);  kTb[s][ln] = tobf(kv2);
    bTT[ln][s] = tobf(bv);  kTT[ln][s] = tobf(kv2);  vLT[ln][s] = tobf(vx);
  }
  __syncthreads();

  // --- phase 2: MFMA, one 32x32 (K=64) product per wave ---
  {
    const bf16 (*Ab)[72] = (wv < 2) ? aCb : rCb;
    const bf16 (*Bb)[72] = (wv & 1) ? kTb : bTb;
#pragma unroll
    for (int mt = 0; mt < 2; ++mt)
#pragma unroll
      for (int nt = 0; nt < 2; ++nt) {
        f32x4 acc = {};
#pragma unroll
        for (int ks = 0; ks < 2; ++ks) {
          bf16x8 af = *(const bf16x8*)&Ab[mt*16 + lm][ks*32 + kg*8];
          bf16x8 bq = *(const bf16x8*)&Bb[nt*16 + lm][ks*32 + kg*8];
          acc = mfma16x16x32(af, bq, acc);
        }
        const int row0 = mt*16 + kg*4, col = nt*16 + lm;
#pragma unroll
        for (int q = 0; q < 4; ++q) {
          float v = acc[q];
          if (wv == 0)      Am[row0+q][col] = v;
          else if (wv == 1) Cm[row0+q][col] = v;
          else {
            bf16 bv2 = tobf(col <= row0+q ? v : 0.f);  // tril<= mask
            if (wv == 2) abybufb[(size_t)ch*1024 + (row0+q)*32 + col] = bv2;
            else         ckybufb[(size_t)ch*1024 + (row0+q)*32 + col] = bv2;
          }
        }
      }
  }
  __syncthreads();

  // --- phase 3: register forward-substitution (wave0: W, wave1: SA_loc) ---
  if (wv < 2) {
    float Xr[32], amr[32];
#pragma unroll
    for (int s = 0; s < 32; ++s) amr[s] = Am[s][ln & 31];
    if (wv == 0) {
#pragma unroll
      for (int s = 0; s < 32; ++s) Xr[s] = aC[s][ln];
    } else {
      float cmr[32];
#pragma unroll
      for (int s = 0; s < 32; ++s) cmr[s] = Cm[s][ln & 31];
#pragma unroll
      for (int s = 0; s < 32; ++s) Xr[s] = 0.f;
#pragma unroll
      for (int u = 0; u < 31; ++u) {
        float v = vL[u][ln];
#pragma unroll
        for (int s = u + 1; s < 32; ++s) Xr[s] += rdlane(cmr[s], u) * v;
      }
    }
#pragma unroll
    for (int s = 1; s < 32; ++s) {
      float acc = Xr[s];
#pragma unroll
      for (int u = 0; u < s; ++u) acc += rdlane(amr[s], u) * Xr[u];
      Xr[s] = acc;
    }
    if (wv == 0) {
#pragma unroll
      for (int s = 0; s < 32; ++s) {
        bf16 bv = tobf(Xr[s]);
        WT[ln][s] = bv;
        wbufb[(size_t)ch*2048 + s*64 + ln] = bv;
      }
    } else {
#pragma unroll
      for (int s = 0; s < 32; ++s) {
        bf16 bv = tobf(Xr[s]);
        SAT[ln][s] = bv;
        sabufb[(size_t)ch*2048 + s*64 + ln] = bv;
      }
    }
  }
  __syncthreads();

  // --- phase 5: U, M (64x64, K=32) via MFMA; M = (G' + I).*dL_j fused ------
  {
    const int mt = wv;
    bf16x8 aS = *(const bf16x8*)&SAT[mt*16 + lm][kg*8];
    bf16x8 aV = *(const bf16x8*)&vLT[mt*16 + lm][kg*8];
    bf16x8 aW = *(const bf16x8*)&WT[mt*16 + lm][kg*8];
#pragma unroll
    for (int nt = 0; nt < 4; ++nt) {
      bf16x8 bB = *(const bf16x8*)&bTT[nt*16 + lm][kg*8];
      bf16x8 bK = *(const bf16x8*)&kTT[nt*16 + lm][kg*8];
      f32x4 aU = {}, aG = {};
      aU = mfma16x16x32(aS, bB, aU);
      aU = mfma16x16x32(aV, bK, aU);
      aG = mfma16x16x32(aW, bB, aG);
      const int i0r = mt*16 + kg*4, col = nt*16 + lm;
      float dl = __expf(lcl[col]);
#pragma unroll
      for (int q = 0; q < 4; ++q) {
        ubufb[(size_t)ch*4096 + (i0r+q)*64 + col] = tobf(aU[q] * dl);
        float diag = (i0r + q == col) ? 1.f : 0.f;
        mbufb[(size_t)ch*4096 + (i0r+q)*64 + col] = tobf((aG[q] + diag) * dl);
      }
    }
  }
}

// Phase B: serial over chunks; 256 blocks = 32 heads x 8 rowgroups.
// XCD-aware decode: bh = blk&31 so all 8 rowgroups of a bh share blk%8
// (-> same XCD L2; M fetched from HBM once per XCD, not 8x).
__global__ __launch_bounds__(256) void rwkv_chunk_state(
    const unsigned short* __restrict__ mbufb,
    const unsigned short* __restrict__ ubufb,
    bf16* __restrict__ s0bufb)
{
  __shared__ float Mf[2][64][68];
  const int blk = blockIdx.x;
  const int bh = blk & 31, rg = blk >> 5;
  const int tid = threadIdx.x, wv = tid >> 6, ln = tid & 63;
  const int i0 = rg*8 + wv*2, i1 = i0 + 1;
  const int grow = tid >> 2, gcol = (tid & 3) * 16;
  float S0r = 0.f, S1r = 0.f;

  uint4 gp0, gp1; float u0p = 0.f, u1p = 0.f;
  auto prefetch = [&](int c) {
    const size_t chb = (size_t)(bh*NCH + c);
    const unsigned short* gp = mbufb + chb*4096 + (size_t)tid*16;
    gp0 = *(const uint4*)gp;
    gp1 = *(const uint4*)(gp + 8);
    u0p = bf2f(ubufb[chb*4096 + i0*64 + ln]);
    u1p = bf2f(ubufb[chb*4096 + i1*64 + ln]);
  };
  prefetch(0);

  for (int cc = 0; cc < NCH; ++cc) {
    const size_t ch = (size_t)bh*NCH + cc;
    const int n = cc & 1;
    // commit prefetched M(cc) -> LDS[n] as f32
    {
      const unsigned int* w0 = (const unsigned int*)&gp0;
      const unsigned int* w1 = (const unsigned int*)&gp1;
#pragma unroll
      for (int e = 0; e < 4; ++e) {
        *(float2*)&Mf[n][grow][gcol + e*2] =
            make_float2(bf2f((unsigned short)(w0[e] & 0xffff)),
                        bf2f((unsigned short)(w0[e] >> 16)));
        *(float2*)&Mf[n][grow][gcol + 8 + e*2] =
            make_float2(bf2f((unsigned short)(w1[e] & 0xffff)),
                        bf2f((unsigned short)(w1[e] >> 16)));
      }
    }
    const float uc0 = u0p, uc1 = u1p;
    s0bufb[(ch*64 + i0)*64 + ln] = tobf(S0r);
    s0bufb[(ch*64 + i1)*64 + ln] = tobf(S1r);
    __syncthreads();
    if (cc + 1 < NCH) prefetch(cc + 1);
    // S <- S*M + U ; 4-way split accumulator chains (ILP)
    float p00 = 0.f, p01 = 0.f, p02 = 0.f, p03 = 0.f;
    float p10 = 0.f, p11 = 0.f, p12 = 0.f, p13 = 0.f;
#pragma unroll
    for (int m = 0; m < 16; ++m) {
      float g = Mf[n][m][ln];
      p00 += rdlane(S0r, m) * g;  p10 += rdlane(S1r, m) * g;
    }
#pragma unroll
    for (int m = 16; m < 32; ++m) {
      float g = Mf[n][m][ln];
      p01 += rdlane(S0r, m) * g;  p11 += rdlane(S1r, m) * g;
    }
#pragma unroll
    for (int m = 32; m < 48; ++m) {
      float g = Mf[n][m][ln];
      p02 += rdlane(S0r, m) * g;  p12 += rdlane(S1r, m) * g;
    }
#pragma unroll
    for (int m = 48; m < 64; ++m) {
      float g = Mf[n][m][ln];
      p03 += rdlane(S0r, m) * g;  p13 += rdlane(S1r, m) * g;
    }
    S0r = uc0 + ((p00 + p01) + (p02 + p03));
    S1r = uc1 + ((p10 + p11) + (p12 + p13));
  }
}

// Phase C: per chunk-head, MFMA: SA = W*S0^T + SAll, then
// y = Rt*S0^T + ABl*SAo + CKl*V  (ABl/CKl pre-masked tril<=).
__global__ __launch_bounds__(256, 4) void rwkv_chunk_out(
    const float* __restrict__ rr, const float* __restrict__ lw,
    const float* __restrict__ vv, const bf16* __restrict__ s0bufb,
    const bf16* __restrict__ wbufb, const bf16* __restrict__ sabufb,
    const bf16* __restrict__ abybufb, const bf16* __restrict__ ckybufb,
    float* __restrict__ y)
{
  __shared__ bf16 S0b[64][72];                    // B^T layout: [i][j]
  __shared__ bf16 Wb[LCH][72], Rlb[LCH][72];      // A layouts: [s][j]
  __shared__ bf16 ABl[LCH][40], CKl[LCH][40];     // A layouts: [s][u]
  __shared__ bf16 SAot[64][40], VlT[64][40];      // B^T layouts: [i][u]
  __shared__ float wtot[4][64];
  const int ch = blockIdx.x;
  const int c = ch & (NCH - 1), bh = ch >> 6, b = bh >> 4, h = bh & 15;
  const int tid = threadIdx.x, wv = tid >> 6, ln = tid & 63;
  const int lm = ln & 15, kg = ln >> 4;
  const size_t base = ((size_t)(b*T_ + c*LCH) * C_) + h*N_ + ln;

  float lwr[8], lcE[8];
  {
    float run = 0.f;
#pragma unroll
    for (int q = 0; q < 8; ++q) {
      lwr[q] = lw[base + (size_t)(wv*8 + q) * C_];
      lcE[q] = run; run += lwr[q];
    }
    wtot[wv][ln] = run;
  }
  __syncthreads();
  {
    float pre = 0.f;
    for (int w2 = 0; w2 < wv; ++w2) pre += wtot[w2][ln];
#pragma unroll
    for (int q = 0; q < 8; ++q) lcE[q] += pre;
  }
#pragma unroll
  for (int q = 0; q < 8; ++q) {
    const int s = wv*8 + q;
    const size_t off = base + (size_t)s * C_;
    Rlb[s][ln] = tobf(rr[off] * __expf(lcE[q] + lwr[q]));
    VlT[ln][s] = tobf(vv[off]);
  }
#pragma unroll
  for (int t = 0; t < 2; ++t) {
    int cc2 = tid*2 + t; int ri = cc2 >> 3, co = (cc2 & 7) * 8;
    *(uint4*)&S0b[ri][co] = *(const uint4*)(s0bufb + (size_t)ch*4096 + ri*64 + co);
  }
  { int ri = tid >> 3, co = (tid & 7) * 8;
    *(uint4*)&Wb[ri][co] = *(const uint4*)(wbufb + (size_t)ch*2048 + ri*64 + co); }
  if (tid < 128) {
    int ri = tid >> 2, co = (tid & 3) * 8;
    *(uint4*)&ABl[ri][co] = *(const uint4*)(abybufb + (size_t)ch*1024 + ri*32 + co);
  } else {
    int t2 = tid - 128; int ri = t2 >> 2, co = (t2 & 3) * 8;
    *(uint4*)&CKl[ri][co] = *(const uint4*)(ckybufb + (size_t)ch*1024 + ri*32 + co);
  }
  __syncthreads();

  const int mt = wv >> 1, ntb = (wv & 1) * 2;
#pragma unroll
  for (int t = 0; t < 2; ++t) {
    const int nt = ntb + t;
    const int row0 = mt*16 + kg*4, col = nt*16 + lm;
    f32x4 acc;
#pragma unroll
    for (int q = 0; q < 4; ++q)
      acc[q] = __bfloat162float(sabufb[(size_t)ch*2048 + (row0+q)*64 + col]);
#pragma unroll
    for (int ks = 0; ks < 2; ++ks) {
      bf16x8 af = *(const bf16x8*)&Wb[mt*16 + lm][ks*32 + kg*8];
      bf16x8 bq = *(const bf16x8*)&S0b[nt*16 + lm][ks*32 + kg*8];
      acc = mfma16x16x32(af, bq, acc);
    }
#pragma unroll
    for (int q = 0; q < 4; ++q) SAot[col][row0+q] = tobf(acc[q]);
  }
  __syncthreads();

#pragma unroll
  for (int t = 0; t < 2; ++t) {
    const int nt = ntb + t;
    f32x4 acc = {};
#pragma unroll
    for (int ks = 0; ks < 2; ++ks) {
      bf16x8 af = *(const bf16x8*)&Rlb[mt*16 + lm][ks*32 + kg*8];
      bf16x8 bq = *(const bf16x8*)&S0b[nt*16 + lm][ks*32 + kg*8];
      acc = mfma16x16x32(af, bq, acc);
    }
    {
      bf16x8 af = *(const bf16x8*)&ABl[mt*16 + lm][kg*8];
      bf16x8 bq = *(const bf16x8*)&SAot[nt*16 + lm][kg*8];
      acc = mfma16x16x32(af, bq, acc);
    }
    {
      bf16x8 af = *(const bf16x8*)&CKl[mt*16 + lm][kg*8];
      bf16x8 bq = *(const bf16x8*)&VlT[nt*16 + lm][kg*8];
      acc = mfma16x16x32(af, bq, acc);
    }
    const int row0 = mt*16 + kg*4, col = nt*16 + lm;
#pragma unroll
    for (int q = 0; q < 4; ++q)
      y[((size_t)(b*T_ + c*LCH + row0 + q)) * C_ + h*N_ + col] = acc[q];
  }
}

// ---------------- groupnorm + bonus + gate ---------------------------------
__global__ __launch_bounds__(256) void gn_bonus_gate(
    const float* __restrict__ y, const float* __restrict__ rr,
    const float* __restrict__ kk_s, const float* __restrict__ vv,
    const bf16* __restrict__ gg, const float* __restrict__ faaaa,
    const float* __restrict__ lnw, const float* __restrict__ lnb,
    bf16* __restrict__ zb)
{
  const int bt = blockIdx.x;
  const int wave = threadIdx.x >> 6, lane = threadIdx.x & 63;
  const float inv64 = 1.f / 64.f;
  for (int h = wave; h < H_; h += 4) {
    const int c = h * 64 + lane;
    const size_t o = (size_t)bt * C_ + c;
    float yv = y[o];
    float mean = allred64(yv) * inv64;
    float d = yv - mean;
    float var = allred64(d * d) * inv64;
    float xn = d * rsqrtf(var + 6.4e-4f);
    float gn = xn * lnw[c] + lnb[c];
    float rk = allred64(rr[o] * kk_s[o] * faaaa[c]);
    float z = (gn + rk * vv[o]) * __bfloat162float(gg[o]);
    zb[o] = tobf(z);
  }
}

// ---------------- driver ----------------------------------------------------
extern "C" void kernel_launch(void* const* d_in, const int* in_sizes, int n_in,
                              void* d_out, int out_size, void* d_ws, size_t ws_size,
                              hipStream_t stream)
{
  const float* x     = (const float*)d_in[0];
  const float* maa_x = (const float*)d_in[1];
  const float* maa_r = (const float*)d_in[2];
  const float* maa_w = (const float*)d_in[3];
  const float* maa_k = (const float*)d_in[4];
  const float* maa_v = (const float*)d_in[5];
  const float* maa_a = (const float*)d_in[6];
  const float* maa_g = (const float*)d_in[7];
  const float* tdec  = (const float*)d_in[8];
  const float* faaaa = (const float*)d_in[9];
  const float* aaaaa = (const float*)d_in[10];
  const float* maa_w1= (const float*)d_in[11];
  const float* maa_w2= (const float*)d_in[12];
  const float* dec_w1= (const float*)d_in[13];
  const float* dec_w2= (const float*)d_in[14];
  const float* aaa_w1= (const float*)d_in[15];
  const float* aaa_w2= (const float*)d_in[16];
  const float* kkk_w1= (const float*)d_in[17];
  const float* kkk_w2= (const float*)d_in[18];
  const float* gate_w1=(const float*)d_in[19];
  const float* gate_w2=(const float*)d_in[20];
  const float* W_r   = (const float*)d_in[21];
  const float* W_k   = (const float*)d_in[22];
  const float* W_v   = (const float*)d_in[23];
  const float* W_o   = (const float*)d_in[24];
  const float* lnw   = (const float*)d_in[25];
  const float* lnb   = (const float*)d_in[26];

  char* ws = (char*)d_ws;
  size_t cur = 0;
  auto alloc = [&](size_t bytes) -> void* {
    void* p = ws + cur; cur += (bytes + 255) & ~(size_t)255; return p;
  };
  const size_t FBT = (size_t)BT_ * C_ * sizeof(float);

  // ---- persistent ----
  float* rb   = (float*)alloc(FBT);
  float* kb   = (float*)alloc(FBT);
  float* vb   = (float*)alloc(FBT);
  bf16*  gbb  = (bf16*)alloc((size_t)BT_*C_*2);
  bf16* WtR  = (bf16*)alloc((size_t)C_*C_*2);
  bf16* WtK  = (bf16*)alloc((size_t)C_*C_*2);
  bf16* WtV  = (bf16*)alloc((size_t)C_*C_*2);
  bf16* WtO  = (bf16*)alloc((size_t)C_*C_*2);
  bf16* w1t  = (bf16*)alloc((size_t)192*C_*2);
  bf16* w2t  = (bf16*)alloc((size_t)6*C_*32*2);
  bf16* d1t  = (bf16*)alloc((size_t)64*C_*2);
  bf16* d2t  = (bf16*)alloc((size_t)C_*64*2);
  bf16* a1t  = (bf16*)alloc((size_t)64*C_*2);
  bf16* a2t  = (bf16*)alloc((size_t)C_*64*2);
  bf16* k1t  = (bf16*)alloc((size_t)64*C_*2);
  bf16* k2t  = (bf16*)alloc((size_t)C_*64*2);
  bf16* g1t  = (bf16*)alloc((size_t)128*C_*2);
  bf16* g2t  = (bf16*)alloc((size_t)C_*128*2);
  float* lwb  = (float*)alloc(FBT);
  float* kkb  = (float*)alloc(FBT);   // dead after chunk_pre; s0bufb overlays
  float* aamt = (float*)alloc(FBT);
  bf16* s0bufb = (bf16*)kkb;          // CHD*4096*2 == FBT exactly

  // ---- union region ----
  const size_t ubase = cur;
  float* mtmp = (float*)alloc(FBT);
  bf16* xinb = (bf16*)alloc((size_t)BT_*C_*2);
  bf16* mixb = (bf16*)alloc((size_t)BT_*192*2);
  bf16* xbr[6];
  for (int s = 0; s < 6; ++s) xbr[s] = (bf16*)alloc((size_t)BT_*C_*2);
  bf16* h64k = (bf16*)alloc((size_t)BT_*64*2);
  bf16* h64d = (bf16*)alloc((size_t)BT_*64*2);
  bf16* h64a = (bf16*)alloc((size_t)BT_*64*2);
  bf16* h128b= (bf16*)alloc((size_t)BT_*128*2);
  const size_t tmp_end = cur;
  cur = ubase;  // overlay
  bf16*  wbufb   = (bf16*)alloc((size_t)CHD*2048*2);
  bf16*  sabufb  = (bf16*)alloc((size_t)CHD*2048*2);
  bf16*  abybufb = (bf16*)alloc((size_t)CHD*1024*2);
  bf16*  ckybufb = (bf16*)alloc((size_t)CHD*1024*2);
  bf16*  ubufb   = (bf16*)alloc((size_t)CHD*4096*2);
  bf16*  mbufb   = (bf16*)alloc((size_t)CHD*4096*2);
  bf16*  zb      = (bf16*)ubufb;   // alias: ubufb dead after chunk_state
  if (tmp_end > cur) cur = tmp_end;
  const size_t need = cur;
  (void)in_sizes; (void)n_in; (void)out_size;

  if (ws_size < need) {
    ws_diag<<<1, 1, 0, stream>>>((float)ws_size, (float)need, (float*)d_out);
    return;
  }

  PrepArgs pa;
  pa.src[0] = W_r;  pa.dst[0] = WtR;
  pa.src[1] = W_k;  pa.dst[1] = WtK;
  pa.src[2] = W_v;  pa.dst[2] = WtV;
  pa.src[3] = W_o;  pa.dst[3] = WtO;
  pa.src[4] = maa_w1; pa.dst[4] = w1t;
  for (int s = 0; s < 6; ++s) { pa.src[5+s] = maa_w2 + (size_t)s*32*C_; pa.dst[5+s] = w2t + (size_t)s*C_*32; }
  pa.src[11] = dec_w1; pa.dst[11] = d1t;
  pa.src[12] = dec_w2; pa.dst[12] = d2t;
  pa.src[13] = aaa_w1; pa.dst[13] = a1t;
  pa.src[14] = aaa_w2; pa.dst[14] = a2t;
  pa.src[15] = kkk_w1; pa.dst[15] = k1t;
  pa.src[16] = kkk_w2; pa.dst[16] = k2t;
  pa.src[17] = gate_w1; pa.dst[17] = g1t;
  pa.src[18] = gate_w2; pa.dst[18] = g2t;
  prep_weights<<<dim3(1024, 19), 256, 0, stream>>>(pa);

  const int EW_GRID = (BT_ * C_) / 256;  // 16384
  xin_k<<<EW_GRID, 256, 0, stream>>>(x, maa_x, xinb);

  gemm_bt<1><<<dim3(64, 3), 256, 0, stream>>>(xinb, C_, w1t, C_, mixb, 192, C_);

  Mix6Args ma;
  ma.maa[0] = maa_r; ma.maa[1] = maa_w; ma.maa[2] = maa_k;
  ma.maa[3] = maa_v; ma.maa[4] = maa_a; ma.maa[5] = maa_g;
  for (int s = 0; s < 6; ++s) ma.out[s] = xbr[s];
  mix_combine<<<dim3(64, 16, 6), 256, 0, stream>>>(mixb, w2t, x, ma);

  // r, k, v batched (one launch)
  RkvArgs ra;
  ra.A[0] = xbr[0]; ra.Bt[0] = WtR; ra.Cq[0] = rb;
  ra.A[1] = xbr[2]; ra.Bt[1] = WtK; ra.Cq[1] = kb;
  ra.A[2] = xbr[3]; ra.Bt[2] = WtV; ra.Cq[2] = vb;
  gemm128_rkv<<<dim3(32, 8, 3), 256, 0, stream>>>(ra);

  // batched small projections: k1 (tanh), d1 (tanh), a1 (raw), g1 (tanh)
  Proj4Args p4;
  p4.A[0] = xbr[2]; p4.Bt[0] = k1t; p4.out[0] = h64k; p4.N[0] = 64;  p4.tnh[0] = 1;
  p4.A[1] = xbr[1]; p4.Bt[1] = d1t; p4.out[1] = h64d; p4.N[1] = 64;  p4.tnh[1] = 1;
  p4.A[2] = xbr[4]; p4.Bt[2] = a1t; p4.out[2] = h64a; p4.N[2] = 64;  p4.tnh[2] = 0;
  p4.A[3] = xbr[5]; p4.Bt[3] = g1t; p4.out[3] = h128b; p4.N[3] = 128; p4.tnh[3] = 1;
  proj4<<<dim3(64, 2, 4), 256, 0, stream>>>(p4);

  // kk path (uses UNscaled k)
  gemm128<0><<<dim3(32, 8), 256, 0, stream>>>(h64k, 64, k2t, 64, mtmp, C_, 64, nullptr, nullptr);
  kk_normalize<<<BT_, 256, 0, stream>>>(kb, mtmp, kkb);

  // w path: fused finalize epilogue (writes lwb, scales kb in place)
  gemm128<3><<<dim3(32, 8), 256, 0, stream>>>(h64d, 64, d2t, 64, lwb, C_, 64, tdec, kb);

  // a path: fused sigmoid epilogue
  gemm128<4><<<dim3(32, 8), 256, 0, stream>>>(h64a, 64, a2t, 64, aamt, C_, 64, aaaaa, nullptr);

  // g path -> bf16 gate buffer
  gemm128<2><<<dim3(32, 8), 256, 0, stream>>>(h128b, 128, g2t, 128, gbb, C_, 128, nullptr, nullptr);

  // ---- chunked scan ----
  rwkv_chunk_pre<<<CHD, 256, 0, stream>>>(rb, lwb, kb, kkb, aamt, vb,
      wbufb, sabufb, abybufb, ckybufb, ubufb, mbufb);
  rwkv_chunk_state<<<256, 256, 0, stream>>>((const unsigned short*)mbufb,
      (const unsigned short*)ubufb, s0bufb);
  rwkv_chunk_out<<<CHD, 256, 0, stream>>>(rb, lwb, vb, s0bufb, wbufb, sabufb,
      abybufb, ckybufb, (float*)d_out);

  gn_bonus_gate<<<BT_, 256, 0, stream>>>((const float*)d_out, rb, kb, vb, gbb,
                                         faaaa, lnw, lnb, zb);

  gemm128<0><<<dim3(32, 8), 256, 0, stream>>>(zb, C_, WtO, C_, d_out, C_, C_, nullptr, nullptr);
}

// Round 10
// 363.261 us; speedup vs baseline: 4.4979x; 1.0927x over previous
//
#include <hip/hip_runtime.h>
#include <hip/hip_bf16.h>

using bf16 = __hip_bfloat16;
using bf16x8 = __attribute__((ext_vector_type(8))) short;  // 8 bf16 (4 VGPRs)
using f32x4 = __attribute__((ext_vector_type(4))) float;

#define B_ 2
#define T_ 2048
#define C_ 1024
#define BT_ (B_*T_)
#define H_ 16
#define N_ 64
#define LCH 32            // scan chunk length
#define NCH (T_/LCH)      // 64 chunks per head
#define CHD (B_*H_*NCH)   // 2048 chunk-heads

__device__ __forceinline__ float allred64(float v) {
#pragma unroll
  for (int m = 1; m < 64; m <<= 1) v += __shfl_xor(v, m, 64);
  return v;
}

__device__ __forceinline__ bf16 tobf(float f) { return __float2bfloat16(f); }
__device__ __forceinline__ float bf2f(unsigned short u) {
  unsigned int x = ((unsigned int)u) << 16;
  return __builtin_bit_cast(float, x);
}
__device__ __forceinline__ unsigned short bfbits(float f) {
  return __builtin_bit_cast(unsigned short, __float2bfloat16(f));
}
__device__ __forceinline__ float rdlane(float v, int m) {
  return __builtin_bit_cast(float,
      __builtin_amdgcn_readlane(__builtin_bit_cast(int, v), m));
}

__device__ __forceinline__ f32x4 mfma16x16x32(bf16x8 a, bf16x8 b, f32x4 c) {
  return __builtin_amdgcn_mfma_f32_16x16x32_bf16(a, b, c, 0, 0, 0);
}

// async global->LDS, 16B per lane (dest = wave-uniform base + lane*16)
typedef const __attribute__((address_space(1))) unsigned int* gas_ptr;
typedef __attribute__((address_space(3))) unsigned int* las_ptr;
__device__ __forceinline__ void gload16(const void* g, void* l) {
  __builtin_amdgcn_global_load_lds((gas_ptr)g, (las_ptr)l, 16, 0, 0);
}

// ---------------- ws_size diagnostic ----------------------------------------
__global__ void ws_diag(float a, float b, float* out) { out[0] = a; out[1] = b; }

// ---------------- weight transpose + bf16 cast (19 jobs, one launch) -------
struct PrepArgs {
  const float* src[19];
  bf16* dst[19];
};
__constant__ int kTR[19] = {1024,1024,1024,1024, 1024, 32,32,32,32,32,32,
                            1024,64, 1024,64, 1024,64, 1024,128};
__constant__ int kTC[19] = {1024,1024,1024,1024, 192, 1024,1024,1024,1024,1024,1024,
                            64,1024, 64,1024, 64,1024, 128,1024};

__global__ __launch_bounds__(256) void prep_weights(PrepArgs pa) {
  const int job = blockIdx.y;
  const int R = kTR[job], Cc = kTC[job];
  const int ntx = Cc >> 5, nty = R >> 5;
  const int tile = blockIdx.x;
  if (tile >= ntx * nty) return;
  const int tx = tile % ntx, ty = tile / ntx;
  const float* __restrict__ src = pa.src[job];
  bf16* __restrict__ dst = pa.dst[job];
  __shared__ float tl[32][33];
  const int lx = threadIdx.x & 31, ly = threadIdx.x >> 5;  // 32 x 8
#pragma unroll
  for (int q = 0; q < 4; ++q)
    tl[ly + 8*q][lx] = src[(size_t)(ty*32 + ly + 8*q) * Cc + tx*32 + lx];
  __syncthreads();
#pragma unroll
  for (int q = 0; q < 4; ++q)
    dst[(size_t)(tx*32 + ly + 8*q) * R + ty*32 + lx] = tobf(tl[lx][ly + 8*q]);
}

// ------- GEMM 64-tile -------------------------------------------------------
template<int EPI>
__global__ __launch_bounds__(256) void gemm_bt(
    const bf16* __restrict__ A, int lda,
    const bf16* __restrict__ Bt, int ldb,
    void* __restrict__ Cout, int ldc, int K)
{
  __shared__ short As[64][40];
  __shared__ short Bs[64][40];
  const int bm0 = blockIdx.x * 64;
  const int bn0 = blockIdx.y * 64;
  const int tid = threadIdx.x;
  const int wave = tid >> 6, lane = tid & 63;
  const int lm = lane & 15, kg = lane >> 4;
  const int srow = tid >> 2, scol = (tid & 3) * 8;
  f32x4 acc[4] = {};
  const size_t abase = (size_t)(bm0 + srow) * lda + scol;
  const size_t bbase = (size_t)(bn0 + srow) * ldb + scol;
  for (int k0 = 0; k0 < K; k0 += 32) {
    *(uint4*)&As[srow][scol] = *(const uint4*)(A + abase + k0);
    *(uint4*)&Bs[srow][scol] = *(const uint4*)(Bt + bbase + k0);
    __syncthreads();
    bf16x8 af = *(const bf16x8*)&As[wave*16 + lm][kg*8];
#pragma unroll
    for (int f = 0; f < 4; ++f) {
      bf16x8 bfr = *(const bf16x8*)&Bs[f*16 + lm][kg*8];
      acc[f] = mfma16x16x32(af, bfr, acc[f]);
    }
    __syncthreads();
  }
  const int row0 = bm0 + wave*16 + kg*4;
  const int col0 = bn0 + lm;
#pragma unroll
  for (int f = 0; f < 4; ++f) {
#pragma unroll
    for (int q = 0; q < 4; ++q) {
      float val = acc[f][q];
      size_t o = (size_t)(row0 + q) * ldc + col0 + f*16;
      if (EPI == 0)      ((float*)Cout)[o] = val;
      else if (EPI == 1) ((bf16*)Cout)[o] = tobf(tanhf(val));
      else               ((bf16*)Cout)[o] = tobf(val);
    }
  }
}

// ------- batched small projections: k1/d1/a1 (N=64) + g1 (N=128) -----------
struct Proj4Args { const bf16* A[4]; const bf16* Bt[4]; bf16* out[4];
                   int N[4]; int tnh[4]; };
__global__ __launch_bounds__(256) void proj4(Proj4Args p4) {
  const int z = blockIdx.z;
  const int Nn = p4.N[z];
  const int bn0 = blockIdx.y * 64;
  if (bn0 >= Nn) return;
  __shared__ short As[64][40];
  __shared__ short Bs[64][40];
  const bf16* __restrict__ A  = p4.A[z];
  const bf16* __restrict__ Bt = p4.Bt[z];
  bf16* __restrict__ out = p4.out[z];
  const int tnh = p4.tnh[z];
  const int bm0 = blockIdx.x * 64;
  const int tid = threadIdx.x;
  const int wave = tid >> 6, lane = tid & 63;
  const int lm = lane & 15, kg = lane >> 4;
  const int srow = tid >> 2, scol = (tid & 3) * 8;
  f32x4 acc[4] = {};
  const size_t abase = (size_t)(bm0 + srow) * C_ + scol;
  const size_t bbase = (size_t)(bn0 + srow) * C_ + scol;
  for (int k0 = 0; k0 < C_; k0 += 32) {
    *(uint4*)&As[srow][scol] = *(const uint4*)(A + abase + k0);
    *(uint4*)&Bs[srow][scol] = *(const uint4*)(Bt + bbase + k0);
    __syncthreads();
    bf16x8 af = *(const bf16x8*)&As[wave*16 + lm][kg*8];
#pragma unroll
    for (int f = 0; f < 4; ++f) {
      bf16x8 bfr = *(const bf16x8*)&Bs[f*16 + lm][kg*8];
      acc[f] = mfma16x16x32(af, bfr, acc[f]);
    }
    __syncthreads();
  }
  const int row0 = bm0 + wave*16 + kg*4;
  const int col0 = bn0 + lm;
#pragma unroll
  for (int f = 0; f < 4; ++f) {
#pragma unroll
    for (int q = 0; q < 4; ++q) {
      float val = acc[f][q];
      size_t o = (size_t)(row0 + q) * Nn + col0 + f*16;
      out[o] = tobf(tnh ? tanhf(val) : val);
    }
  }
}

// ------- GEMM 128-tile, m97 structure (global_load_lds staging) -------------
// EPI: 0 f32 | 2 bf16 | 3 w-finalize (Cout=lw, aux1=td, aux2=k inplace)
//      4 a-finalize (Cout=aamt, aux1=aaaaa)
template<int EPI>
__global__ __launch_bounds__(256) void gemm128(
    const bf16* __restrict__ A, int lda,
    const bf16* __restrict__ Bt, int ldb,
    void* __restrict__ Cout, int ldc, int K,
    const float* __restrict__ aux1, float* __restrict__ aux2)
{
  __shared__ bf16 As[128][32];     // linear (required by global_load_lds)
  __shared__ bf16 Bs[128][32];
  const int bm0 = blockIdx.x * 128, bn0 = blockIdx.y * 128;
  const int tid = threadIdx.x, wv = tid >> 6, ln = tid & 63;
  const int wr = wv >> 1, wc = wv & 1;
  const int lm = ln & 15, kg = ln >> 4;
  const int srow = ln >> 2, scol = (ln & 3) * 8;
  f32x4 acc[4][4] = {};
  for (int k0 = 0; k0 < K; k0 += 32) {
#pragma unroll
    for (int i = 0; i < 2; ++i) {
      const int r0 = wv*32 + i*16;
      gload16(A  + (size_t)(bm0 + r0 + srow) * lda + k0 + scol, &As[r0][0]);
      gload16(Bt + (size_t)(bn0 + r0 + srow) * ldb + k0 + scol, &Bs[r0][0]);
    }
    asm volatile("s_waitcnt vmcnt(0)" ::: "memory");
    __syncthreads();
    bf16x8 af[4], bfr[4];
#pragma unroll
    for (int m = 0; m < 4; ++m) af[m] = *(const bf16x8*)&As[wr*64 + m*16 + lm][kg*8];
#pragma unroll
    for (int n = 0; n < 4; ++n) bfr[n] = *(const bf16x8*)&Bs[wc*64 + n*16 + lm][kg*8];
#pragma unroll
    for (int m = 0; m < 4; ++m)
#pragma unroll
      for (int n = 0; n < 4; ++n)
        acc[m][n] = mfma16x16x32(af[m], bfr[n], acc[m][n]);
    __syncthreads();
  }
#pragma unroll
  for (int m = 0; m < 4; ++m) {
    const int row0 = bm0 + wr*64 + m*16 + kg*4;
#pragma unroll
    for (int n = 0; n < 4; ++n) {
      const int col = bn0 + wc*64 + n*16 + lm;
#pragma unroll
      for (int q = 0; q < 4; ++q) {
        float val = acc[m][n][q];
        size_t o = (size_t)(row0 + q) * ldc + col;
        if (EPI == 0)      ((float*)Cout)[o] = val;
        else if (EPI == 2) ((bf16*)Cout)[o] = tobf(val);
        else if (EPI == 3) {
          float wr2 = val + aux1[col];
          float sp = fmaxf(-wr2, 0.f) + log1pf(expf(-fabsf(wr2)));
          float w = -sp - 0.5f;
          ((float*)Cout)[o] = -expf(w);              // lw
          aux2[o] *= expf(fminf(0.5f * w, 0.f));     // k scale in place
        } else if (EPI == 4) {
          float z = aux1[col] + val;
          ((float*)Cout)[o] = 2.f / (1.f + expf(-z));
        }
      }
    }
  }
}

// batched r/k/v: same shape (M=4096, N=1024, K=1024), z selects operands
struct RkvArgs { const bf16* A[3]; const bf16* Bt[3]; float* Cq[3]; };
__global__ __launch_bounds__(256) void gemm128_rkv(RkvArgs ra) {
  __shared__ bf16 As[128][32];
  __shared__ bf16 Bs[128][32];
  const bf16* __restrict__ A  = ra.A[blockIdx.z];
  const bf16* __restrict__ Bt = ra.Bt[blockIdx.z];
  float* __restrict__ Cout = ra.Cq[blockIdx.z];
  const int bm0 = blockIdx.x * 128, bn0 = blockIdx.y * 128;
  const int tid = threadIdx.x, wv = tid >> 6, ln = tid & 63;
  const int wr = wv >> 1, wc = wv & 1;
  const int lm = ln & 15, kg = ln >> 4;
  const int srow = ln >> 2, scol = (ln & 3) * 8;
  f32x4 acc[4][4] = {};
  for (int k0 = 0; k0 < C_; k0 += 32) {
#pragma unroll
    for (int i = 0; i < 2; ++i) {
      const int r0 = wv*32 + i*16;
      gload16(A  + (size_t)(bm0 + r0 + srow) * C_ + k0 + scol, &As[r0][0]);
      gload16(Bt + (size_t)(bn0 + r0 + srow) * C_ + k0 + scol, &Bs[r0][0]);
    }
    asm volatile("s_waitcnt vmcnt(0)" ::: "memory");
    __syncthreads();
    bf16x8 af[4], bfr[4];
#pragma unroll
    for (int m = 0; m < 4; ++m) af[m] = *(const bf16x8*)&As[wr*64 + m*16 + lm][kg*8];
#pragma unroll
    for (int n = 0; n < 4; ++n) bfr[n] = *(const bf16x8*)&Bs[wc*64 + n*16 + lm][kg*8];
#pragma unroll
    for (int m = 0; m < 4; ++m)
#pragma unroll
      for (int n = 0; n < 4; ++n)
        acc[m][n] = mfma16x16x32(af[m], bfr[n], acc[m][n]);
    __syncthreads();
  }
#pragma unroll
  for (int m = 0; m < 4; ++m) {
    const int row0 = bm0 + wr*64 + m*16 + kg*4;
#pragma unroll
    for (int n = 0; n < 4; ++n) {
      const int col = bn0 + wc*64 + n*16 + lm;
#pragma unroll
      for (int q = 0; q < 4; ++q)
        Cout[(size_t)(row0 + q) * C_ + col] = acc[m][n][q];
    }
  }
}

// --------- fused 6-branch low-rank projection + combine ---------------------
struct Mix6Args { const float* maa[6]; bf16* out[6]; };

__global__ __launch_bounds__(256) void mix_combine(
    const bf16* __restrict__ mixb, const bf16* __restrict__ w2t,
    const float* __restrict__ x, Mix6Args ma)
{
  __shared__ short As[64][40];
  __shared__ short Bs[64][40];
  const int s6 = blockIdx.z;
  const bf16* __restrict__ A  = mixb + s6*32;            // lda = 192
  const bf16* __restrict__ Bt = w2t + (size_t)s6*C_*32;  // ldb = 32
  const float* __restrict__ maa = ma.maa[s6];
  bf16* __restrict__ out = ma.out[s6];
  const int bm0 = blockIdx.x * 64, bn0 = blockIdx.y * 64;
  const int tid = threadIdx.x, wave = tid >> 6, lane = tid & 63;
  const int lm = lane & 15, kg = lane >> 4;
  const int srow = tid >> 2, scol = (tid & 3) * 8;
  *(uint4*)&As[srow][scol] = *(const uint4*)(A + (size_t)(bm0 + srow)*192 + scol);
  *(uint4*)&Bs[srow][scol] = *(const uint4*)(Bt + (size_t)(bn0 + srow)*32 + scol);
  __syncthreads();
  bf16x8 af = *(const bf16x8*)&As[wave*16 + lm][kg*8];
  f32x4 acc[4] = {};
#pragma unroll
  for (int f = 0; f < 4; ++f) {
    bf16x8 bfr = *(const bf16x8*)&Bs[f*16 + lm][kg*8];
    acc[f] = mfma16x16x32(af, bfr, acc[f]);
  }
  const int row0 = bm0 + wave*16 + kg*4;
  const int col0 = bn0 + lm;
#pragma unroll
  for (int f = 0; f < 4; ++f) {
#pragma unroll
    for (int q = 0; q < 4; ++q) {
      const int row = row0 + q, col = col0 + f*16;
      const size_t o = (size_t)row * C_ + col;
      float xv = x[o];
      float xp = (row & (T_ - 1)) ? x[o - C_] : 0.f;
      out[o] = tobf(xv + (xp - xv) * (maa[col] + acc[f][q]));
    }
  }
}

// ---------------- elementwise ----------------------------------------------
__global__ __launch_bounds__(256) void xin_k(
    const float* __restrict__ x, const float* __restrict__ maa_x,
    bf16* __restrict__ xinb)
{
  size_t idx = (size_t)blockIdx.x * 256 + threadIdx.x;
  int c = idx & (C_ - 1);
  int t = (int)((idx >> 10) & (T_ - 1));
  float xv = x[idx];
  float xp = t ? x[idx - C_] : 0.f;
  xinb[idx] = tobf(xv + (xp - xv) * maa_x[c]);
}

__global__ __launch_bounds__(256) void kk_normalize(
    const float* __restrict__ kraw, const float* __restrict__ kkadd,
    float* __restrict__ kkout)
{
  const int bt = blockIdx.x;
  const int tid = threadIdx.x;
  const size_t o = (size_t)bt * C_;
  float vals[4]; float ss = 0.f;
#pragma unroll
  for (int q = 0; q < 4; ++q) {
    float u = kraw[o + tid + q*256] + kkadd[o + tid + q*256];
    vals[q] = u; ss += u * u;
  }
  ss = allred64(ss);
  __shared__ float red[4];
  const int wave = tid >> 6, lane = tid & 63;
  if (lane == 0) red[wave] = ss;
  __syncthreads();
  float tot = red[0] + red[1] + red[2] + red[3];
  float inv = 1.f / fmaxf(sqrtf(tot), 1e-12f);
#pragma unroll
  for (int q = 0; q < 4; ++q) kkout[o + tid + q*256] = vals[q] * inv;
}

// ============ Chunked RWKV-7 scan (fp32 recurrence, bf16 MFMA phases) =======
//   SA = (I-trilA)^{-1}(Achk S0^T + trilC V) = W S0^T + SA_loc
//   y[s] = rt_s S0^T + tril<=(ABy) SA + tril<=(CKy) V
//   S_L = S0 * M + U  with M = diag(dL) + (W^T Bt).*dL_j
// M stored TRANSPOSED in MFMA-B-fragment-packed layout (mbufT):
//   slot(ch, nt, ks, lane, e) = M[m][j], j=nt*16+(lane&15), m=ks*32+(lane>>4)*8+e
// U stored in accumulator-packed layout (ubufP):
//   slot(ch, mt*4+nt, lane, q) = U[mt*16+(lane>>4)*4+q][nt*16+(lane&15)]

__global__ __launch_bounds__(256, 2) void rwkv_chunk_pre(
    const float* __restrict__ rr, const float* __restrict__ lw,
    const float* __restrict__ kk_s, const float* __restrict__ kkv,
    const float* __restrict__ aam, const float* __restrict__ vv,
    bf16* __restrict__ wbufb, bf16* __restrict__ sabufb,
    bf16* __restrict__ abybufb, bf16* __restrict__ ckybufb,
    bf16* __restrict__ ubufP, bf16* __restrict__ mbufT)
{
  __shared__ float aC[LCH][68], vL[LCH][68];      // fp32 for the solve
  __shared__ float Am[LCH][33], Cm[LCH][33];
  __shared__ float wtot[4][64];
  __shared__ float lcl[64];
  __shared__ bf16 aCb[LCH][72], rCb[LCH][72], bTb[LCH][72], kTb[LCH][72];
  __shared__ bf16 bTT[64][40], kTT[64][40], vLT[64][40];
  __shared__ bf16 WT[64][40], SAT[64][40];

  const int ch = blockIdx.x;
  const int c  = ch & (NCH - 1);
  const int bh = ch >> 6;
  const int b  = bh >> 4, h = bh & 15;
  const int tid = threadIdx.x, wv = tid >> 6, ln = tid & 63;
  const int lm = ln & 15, kg = ln >> 4;
  const size_t base = ((size_t)(b*T_ + c*LCH) * C_) + h*N_ + ln;

  // --- phase 1: cumulative log-decay + load/scale into LDS (both layouts) ---
  float lwr[8], lcE[8];
  {
    float run = 0.f;
#pragma unroll
    for (int q = 0; q < 8; ++q) {
      lwr[q] = lw[base + (size_t)(wv*8 + q) * C_];
      lcE[q] = run; run += lwr[q];
    }
    wtot[wv][ln] = run;
  }
  __syncthreads();
  {
    float pre = 0.f;
    for (int w2 = 0; w2 < wv; ++w2) pre += wtot[w2][ln];
    if (wv == 0) lcl[ln] = wtot[0][ln] + wtot[1][ln] + wtot[2][ln] + wtot[3][ln];
#pragma unroll
    for (int q = 0; q < 8; ++q) lcE[q] += pre;
  }
#pragma unroll
  for (int q = 0; q < 8; ++q) {
    const int s = wv*8 + q;
    const size_t off = base + (size_t)s * C_;
    float kkx = kkv[off], aax = aam[off], kx = kk_s[off], rx = rr[off], vx = vv[off];
    float lcI = lcE[q] + lwr[q];
    float eIm = __expf(-lcI);
    float av = -kkx * __expf(lcE[q]);
    float bv = kkx * aax * eIm;
    float kv2 = kx * eIm;
    float rv = rx * __expf(lcI);
    aC[s][ln] = av;  vL[s][ln] = vx;
    aCb[s][ln] = tobf(av);  rCb[s][ln] = tobf(rv);
    bTb[s][ln] = tobf(bv);  kTb[s][ln] = tobf(kv2);
    bTT[ln][s] = tobf(bv);  kTT[ln][s] = tobf(kv2);  vLT[ln][s] = tobf(vx);
  }
  __syncthreads();

  // --- phase 2: MFMA, one 32x32 (K=64) product per wave ---
  {
    const bf16 (*Ab)[72] = (wv < 2) ? aCb : rCb;
    const bf16 (*Bb)[72] = (wv & 1) ? kTb : bTb;
#pragma unroll
    for (int mt = 0; mt < 2; ++mt)
#pragma unroll
      for (int nt = 0; nt < 2; ++nt) {
        f32x4 acc = {};
#pragma unroll
        for (int ks = 0; ks < 2; ++ks) {
          bf16x8 af = *(const bf16x8*)&Ab[mt*16 + lm][ks*32 + kg*8];
          bf16x8 bq = *(const bf16x8*)&Bb[nt*16 + lm][ks*32 + kg*8];
          acc = mfma16x16x32(af, bq, acc);
        }
        const int row0 = mt*16 + kg*4, col = nt*16 + lm;
#pragma unroll
        for (int q = 0; q < 4; ++q) {
          float v = acc[q];
          if (wv == 0)      Am[row0+q][col] = v;
          else if (wv == 1) Cm[row0+q][col] = v;
          else {
            bf16 bv2 = tobf(col <= row0+q ? v : 0.f);  // tril<= mask
            if (wv == 2) abybufb[(size_t)ch*1024 + (row0+q)*32 + col] = bv2;
            else         ckybufb[(size_t)ch*1024 + (row0+q)*32 + col] = bv2;
          }
        }
      }
  }
  __syncthreads();

  // --- phase 3: register forward-substitution (wave0: W, wave1: SA_loc) ---
  if (wv < 2) {
    float Xr[32], amr[32];
#pragma unroll
    for (int s = 0; s < 32; ++s) amr[s] = Am[s][ln & 31];
    if (wv == 0) {
#pragma unroll
      for (int s = 0; s < 32; ++s) Xr[s] = aC[s][ln];
    } else {
      float cmr[32];
#pragma unroll
      for (int s = 0; s < 32; ++s) cmr[s] = Cm[s][ln & 31];
#pragma unroll
      for (int s = 0; s < 32; ++s) Xr[s] = 0.f;
#pragma unroll
      for (int u = 0; u < 31; ++u) {
        float v = vL[u][ln];
#pragma unroll
        for (int s = u + 1; s < 32; ++s) Xr[s] += rdlane(cmr[s], u) * v;
      }
    }
#pragma unroll
    for (int s = 1; s < 32; ++s) {
      float acc = Xr[s];
#pragma unroll
      for (int u = 0; u < s; ++u) acc += rdlane(amr[s], u) * Xr[u];
      Xr[s] = acc;
    }
    if (wv == 0) {
#pragma unroll
      for (int s = 0; s < 32; ++s) {
        bf16 bv = tobf(Xr[s]);
        WT[ln][s] = bv;
        wbufb[(size_t)ch*2048 + s*64 + ln] = bv;
      }
    } else {
#pragma unroll
      for (int s = 0; s < 32; ++s) {
        bf16 bv = tobf(Xr[s]);
        SAT[ln][s] = bv;
        sabufb[(size_t)ch*2048 + s*64 + ln] = bv;
      }
    }
  }
  __syncthreads();

  // --- phase 5: U, M (64x64, K=32) via MFMA; packed-layout b64 stores ------
  {
    const int mt = wv;
    bf16x8 aS = *(const bf16x8*)&SAT[mt*16 + lm][kg*8];
    bf16x8 aV = *(const bf16x8*)&vLT[mt*16 + lm][kg*8];
    bf16x8 aW = *(const bf16x8*)&WT[mt*16 + lm][kg*8];
#pragma unroll
    for (int nt = 0; nt < 4; ++nt) {
      bf16x8 bB = *(const bf16x8*)&bTT[nt*16 + lm][kg*8];
      bf16x8 bK = *(const bf16x8*)&kTT[nt*16 + lm][kg*8];
      f32x4 aU = {}, aG = {};
      aU = mfma16x16x32(aS, bB, aU);
      aU = mfma16x16x32(aV, bK, aU);
      aG = mfma16x16x32(aW, bB, aG);
      const int i0r = mt*16 + kg*4, col = nt*16 + lm;
      float dl = __expf(lcl[col]);
      // U packed (acc layout): one b64 per tile
      uint2 up;
      up.x = (unsigned int)bfbits(aU[0]*dl) | ((unsigned int)bfbits(aU[1]*dl) << 16);
      up.y = (unsigned int)bfbits(aU[2]*dl) | ((unsigned int)bfbits(aU[3]*dl) << 16);
      *(uint2*)(ubufP + (size_t)ch*4096 + (mt*4 + nt)*256 + ln*4) = up;
      // M^T B-frag packed: e = (kg&1)*4+q consecutive -> one b64 per tile
      float m0 = (aG[0] + (i0r+0 == col ? 1.f : 0.f)) * dl;
      float m1 = (aG[1] + (i0r+1 == col ? 1.f : 0.f)) * dl;
      float m2 = (aG[2] + (i0r+2 == col ? 1.f : 0.f)) * dl;
      float m3 = (aG[3] + (i0r+3 == col ? 1.f : 0.f)) * dl;
      uint2 mp;
      mp.x = (unsigned int)bfbits(m0) | ((unsigned int)bfbits(m1) << 16);
      mp.y = (unsigned int)bfbits(m2) | ((unsigned int)bfbits(m3) << 16);
      const int laned = (((mt*2) + (kg >> 1)) & 3) * 16 + lm;
      *(uint2*)(mbufT + (size_t)ch*4096 + (nt*2 + (mt >> 1))*512
                + laned*8 + (kg & 1)*4) = mp;
    }
  }
}

// Phase B: serial over chunks; 32 blocks (one per bh) x 4 waves.
// Wave = 16-row stripe of S; S_new[stripe] = S[stripe]*M + U[stripe] via MFMA.
// Waves fully independent: NO barriers. M^T B-frags load global->reg
// (coalesced b128, distance-2 double set); S round-trips wave-private LDS.
__global__ __launch_bounds__(256) void rwkv_chunk_state(
    const bf16* __restrict__ mbufT, const bf16* __restrict__ ubufP,
    bf16* __restrict__ s0bufb)
{
  __shared__ bf16 Sst[4][16][72];
  const int bh = blockIdx.x;
  const int tid = threadIdx.x, wv = tid >> 6, ln = tid & 63;
  const int lm = ln & 15, kg = ln >> 4;

  // zero own stripe (S_init = 0)
#pragma unroll
  for (int r = 0; r < 16; ++r) {
    Sst[wv][r][ln] = tobf(0.f);
    if (ln < 8) Sst[wv][r][64 + ln] = tobf(0.f);
  }

  bf16x8 BfA[4][2], BfB[4][2];
  uint2 UpA[4], UpB[4];
  auto prefetch = [&](bf16x8 (&Bf)[4][2], uint2 (&Up)[4], int c) {
    const size_t chp = (size_t)(bh*NCH + c) * 4096;
#pragma unroll
    for (int nt = 0; nt < 4; ++nt) {
      Bf[nt][0] = *(const bf16x8*)(mbufT + chp + (nt*2 + 0)*512 + ln*8);
      Bf[nt][1] = *(const bf16x8*)(mbufT + chp + (nt*2 + 1)*512 + ln*8);
      Up[nt]    = *(const uint2*) (ubufP + chp + (wv*4 + nt)*256 + ln*4);
    }
  };
  prefetch(BfA, UpA, 0);
  prefetch(BfB, UpB, 1);

  auto body = [&](bf16x8 (&Bf)[4][2], uint2 (&Up)[4], int c) {
    const size_t ch4 = (size_t)(bh*NCH + c) * 4096;
    // store s0 (= S before this chunk) from LDS, coalesced 2x b128
    const int sr = ln >> 2, sc = (ln & 3) * 16;
    uint4 v0 = *(const uint4*)&Sst[wv][sr][sc];
    uint4 v1 = *(const uint4*)&Sst[wv][sr][sc + 8];
    *(uint4*)(s0bufb + ch4 + (size_t)(wv*16 + sr)*64 + sc) = v0;
    *(uint4*)(s0bufb + ch4 + (size_t)(wv*16 + sr)*64 + sc + 8) = v1;
    // A-frags of own stripe
    bf16x8 A0 = *(const bf16x8*)&Sst[wv][lm][kg*8];
    bf16x8 A1 = *(const bf16x8*)&Sst[wv][lm][32 + kg*8];
    // MFMA: 4 col-tiles, acc init = U
    f32x4 acc[4];
#pragma unroll
    for (int nt = 0; nt < 4; ++nt) {
      acc[nt][0] = bf2f((unsigned short)(Up[nt].x & 0xffff));
      acc[nt][1] = bf2f((unsigned short)(Up[nt].x >> 16));
      acc[nt][2] = bf2f((unsigned short)(Up[nt].y & 0xffff));
      acc[nt][3] = bf2f((unsigned short)(Up[nt].y >> 16));
      acc[nt] = mfma16x16x32(A0, Bf[nt][0], acc[nt]);
      acc[nt] = mfma16x16x32(A1, Bf[nt][1], acc[nt]);
    }
    // prefetch c+2 into this set (clamped; tail values unused)
    int cp = c + 2; if (cp > NCH - 1) cp = NCH - 1;
    prefetch(Bf, Up, cp);
    // write S_new back to own stripe (compiler orders vs reads above)
#pragma unroll
    for (int nt = 0; nt < 4; ++nt)
#pragma unroll
      for (int q = 0; q < 4; ++q)
        Sst[wv][kg*4 + q][nt*16 + lm] = tobf(acc[nt][q]);
  };

  for (int cc = 0; cc < NCH; cc += 2) {
    body(BfA, UpA, cc);
    body(BfB, UpB, cc + 1);
  }
}

// Phase C: per chunk-head, MFMA: SA = W*S0^T + SAll, then
// y = Rt*S0^T + ABl*SAo + CKl*V  (ABl/CKl pre-masked tril<=).
__global__ __launch_bounds__(256, 4) void rwkv_chunk_out(
    const float* __restrict__ rr, const float* __restrict__ lw,
    const float* __restrict__ vv, const bf16* __restrict__ s0bufb,
    const bf16* __restrict__ wbufb, const bf16* __restrict__ sabufb,
    const bf16* __restrict__ abybufb, const bf16* __restrict__ ckybufb,
    float* __restrict__ y)
{
  __shared__ bf16 S0b[64][72];                    // B^T layout: [i][j]
  __shared__ bf16 Wb[LCH][72], Rlb[LCH][72];      // A layouts: [s][j]
  __shared__ bf16 ABl[LCH][40], CKl[LCH][40];     // A layouts: [s][u]
  __shared__ bf16 SAot[64][40], VlT[64][40];      // B^T layouts: [i][u]
  __shared__ float wtot[4][64];
  const int ch = blockIdx.x;
  const int c = ch & (NCH - 1), bh = ch >> 6, b = bh >> 4, h = bh & 15;
  const int tid = threadIdx.x, wv = tid >> 6, ln = tid & 63;
  const int lm = ln & 15, kg = ln >> 4;
  const size_t base = ((size_t)(b*T_ + c*LCH) * C_) + h*N_ + ln;

  float lwr[8], lcE[8];
  {
    float run = 0.f;
#pragma unroll
    for (int q = 0; q < 8; ++q) {
      lwr[q] = lw[base + (size_t)(wv*8 + q) * C_];
      lcE[q] = run; run += lwr[q];
    }
    wtot[wv][ln] = run;
  }
  __syncthreads();
  {
    float pre = 0.f;
    for (int w2 = 0; w2 < wv; ++w2) pre += wtot[w2][ln];
#pragma unroll
    for (int q = 0; q < 8; ++q) lcE[q] += pre;
  }
#pragma unroll
  for (int q = 0; q < 8; ++q) {
    const int s = wv*8 + q;
    const size_t off = base + (size_t)s * C_;
    Rlb[s][ln] = tobf(rr[off] * __expf(lcE[q] + lwr[q]));
    VlT[ln][s] = tobf(vv[off]);
  }
#pragma unroll
  for (int t = 0; t < 2; ++t) {
    int cc2 = tid*2 + t; int ri = cc2 >> 3, co = (cc2 & 7) * 8;
    *(uint4*)&S0b[ri][co] = *(const uint4*)(s0bufb + (size_t)ch*4096 + ri*64 + co);
  }
  { int ri = tid >> 3, co = (tid & 7) * 8;
    *(uint4*)&Wb[ri][co] = *(const uint4*)(wbufb + (size_t)ch*2048 + ri*64 + co); }
  if (tid < 128) {
    int ri = tid >> 2, co = (tid & 3) * 8;
    *(uint4*)&ABl[ri][co] = *(const uint4*)(abybufb + (size_t)ch*1024 + ri*32 + co);
  } else {
    int t2 = tid - 128; int ri = t2 >> 2, co = (t2 & 3) * 8;
    *(uint4*)&CKl[ri][co] = *(const uint4*)(ckybufb + (size_t)ch*1024 + ri*32 + co);
  }
  __syncthreads();

  const int mt = wv >> 1, ntb = (wv & 1) * 2;
#pragma unroll
  for (int t = 0; t < 2; ++t) {
    const int nt = ntb + t;
    const int row0 = mt*16 + kg*4, col = nt*16 + lm;
    f32x4 acc;
#pragma unroll
    for (int q = 0; q < 4; ++q)
      acc[q] = __bfloat162float(sabufb[(size_t)ch*2048 + (row0+q)*64 + col]);
#pragma unroll
    for (int ks = 0; ks < 2; ++ks) {
      bf16x8 af = *(const bf16x8*)&Wb[mt*16 + lm][ks*32 + kg*8];
      bf16x8 bq = *(const bf16x8*)&S0b[nt*16 + lm][ks*32 + kg*8];
      acc = mfma16x16x32(af, bq, acc);
    }
#pragma unroll
    for (int q = 0; q < 4; ++q) SAot[col][row0+q] = tobf(acc[q]);
  }
  __syncthreads();

#pragma unroll
  for (int t = 0; t < 2; ++t) {
    const int nt = ntb + t;
    f32x4 acc = {};
#pragma unroll
    for (int ks = 0; ks < 2; ++ks) {
      bf16x8 af = *(const bf16x8*)&Rlb[mt*16 + lm][ks*32 + kg*8];
      bf16x8 bq = *(const bf16x8*)&S0b[nt*16 + lm][ks*32 + kg*8];
      acc = mfma16x16x32(af, bq, acc);
    }
    {
      bf16x8 af = *(const bf16x8*)&ABl[mt*16 + lm][kg*8];
      bf16x8 bq = *(const bf16x8*)&SAot[nt*16 + lm][kg*8];
      acc = mfma16x16x32(af, bq, acc);
    }
    {
      bf16x8 af = *(const bf16x8*)&CKl[mt*16 + lm][kg*8];
      bf16x8 bq = *(const bf16x8*)&VlT[nt*16 + lm][kg*8];
      acc = mfma16x16x32(af, bq, acc);
    }
    const int row0 = mt*16 + kg*4, col = nt*16 + lm;
#pragma unroll
    for (int q = 0; q < 4; ++q)
      y[((size_t)(b*T_ + c*LCH + row0 + q)) * C_ + h*N_ + col] = acc[q];
  }
}

// ---------------- groupnorm + bonus + gate ---------------------------------
__global__ __launch_bounds__(256) void gn_bonus_gate(
    const float* __restrict__ y, const float* __restrict__ rr,
    const float* __restrict__ kk_s, const float* __restrict__ vv,
    const bf16* __restrict__ gg, const float* __restrict__ faaaa,
    const float* __restrict__ lnw, const float* __restrict__ lnb,
    bf16* __restrict__ zb)
{
  const int bt = blockIdx.x;
  const int wave = threadIdx.x >> 6, lane = threadIdx.x & 63;
  const float inv64 = 1.f / 64.f;
  for (int h = wave; h < H_; h += 4) {
    const int c = h * 64 + lane;
    const size_t o = (size_t)bt * C_ + c;
    float yv = y[o];
    float mean = allred64(yv) * inv64;
    float d = yv - mean;
    float var = allred64(d * d) * inv64;
    float xn = d * rsqrtf(var + 6.4e-4f);
    float gn = xn * lnw[c] + lnb[c];
    float rk = allred64(rr[o] * kk_s[o] * faaaa[c]);
    float z = (gn + rk * vv[o]) * __bfloat162float(gg[o]);
    zb[o] = tobf(z);
  }
}

// ---------------- driver ----------------------------------------------------
extern "C" void kernel_launch(void* const* d_in, const int* in_sizes, int n_in,
                              void* d_out, int out_size, void* d_ws, size_t ws_size,
                              hipStream_t stream)
{
  const float* x     = (const float*)d_in[0];
  const float* maa_x = (const float*)d_in[1];
  const float* maa_r = (const float*)d_in[2];
  const float* maa_w = (const float*)d_in[3];
  const float* maa_k = (const float*)d_in[4];
  const float* maa_v = (const float*)d_in[5];
  const float* maa_a = (const float*)d_in[6];
  const float* maa_g = (const float*)d_in[7];
  const float* tdec  = (const float*)d_in[8];
  const float* faaaa = (const float*)d_in[9];
  const float* aaaaa = (const float*)d_in[10];
  const float* maa_w1= (const float*)d_in[11];
  const float* maa_w2= (const float*)d_in[12];
  const float* dec_w1= (const float*)d_in[13];
  const float* dec_w2= (const float*)d_in[14];
  const float* aaa_w1= (const float*)d_in[15];
  const float* aaa_w2= (const float*)d_in[16];
  const float* kkk_w1= (const float*)d_in[17];
  const float* kkk_w2= (const float*)d_in[18];
  const float* gate_w1=(const float*)d_in[19];
  const float* gate_w2=(const float*)d_in[20];
  const float* W_r   = (const float*)d_in[21];
  const float* W_k   = (const float*)d_in[22];
  const float* W_v   = (const float*)d_in[23];
  const float* W_o   = (const float*)d_in[24];
  const float* lnw   = (const float*)d_in[25];
  const float* lnb   = (const float*)d_in[26];

  char* ws = (char*)d_ws;
  size_t cur = 0;
  auto alloc = [&](size_t bytes) -> void* {
    void* p = ws + cur; cur += (bytes + 255) & ~(size_t)255; return p;
  };
  const size_t FBT = (size_t)BT_ * C_ * sizeof(float);

  // ---- persistent ----
  float* rb   = (float*)alloc(FBT);
  float* kb   = (float*)alloc(FBT);
  float* vb   = (float*)alloc(FBT);
  bf16*  gbb  = (bf16*)alloc((size_t)BT_*C_*2);
  bf16* WtR  = (bf16*)alloc((size_t)C_*C_*2);
  bf16* WtK  = (bf16*)alloc((size_t)C_*C_*2);
  bf16* WtV  = (bf16*)alloc((size_t)C_*C_*2);
  bf16* WtO  = (bf16*)alloc((size_t)C_*C_*2);
  bf16* w1t  = (bf16*)alloc((size_t)192*C_*2);
  bf16* w2t  = (bf16*)alloc((size_t)6*C_*32*2);
  bf16* d1t  = (bf16*)alloc((size_t)64*C_*2);
  bf16* d2t  = (bf16*)alloc((size_t)C_*64*2);
  bf16* a1t  = (bf16*)alloc((size_t)64*C_*2);
  bf16* a2t  = (bf16*)alloc((size_t)C_*64*2);
  bf16* k1t  = (bf16*)alloc((size_t)64*C_*2);
  bf16* k2t  = (bf16*)alloc((size_t)C_*64*2);
  bf16* g1t  = (bf16*)alloc((size_t)128*C_*2);
  bf16* g2t  = (bf16*)alloc((size_t)C_*128*2);
  float* lwb  = (float*)alloc(FBT);
  float* kkb  = (float*)alloc(FBT);   // dead after chunk_pre; s0bufb overlays
  float* aamt = (float*)alloc(FBT);
  bf16* s0bufb = (bf16*)kkb;          // CHD*4096*2 == FBT exactly

  // ---- union region ----
  const size_t ubase = cur;
  float* mtmp = (float*)alloc(FBT);
  bf16* xinb = (bf16*)alloc((size_t)BT_*C_*2);
  bf16* mixb = (bf16*)alloc((size_t)BT_*192*2);
  bf16* xbr[6];
  for (int s = 0; s < 6; ++s) xbr[s] = (bf16*)alloc((size_t)BT_*C_*2);
  bf16* h64k = (bf16*)alloc((size_t)BT_*64*2);
  bf16* h64d = (bf16*)alloc((size_t)BT_*64*2);
  bf16* h64a = (bf16*)alloc((size_t)BT_*64*2);
  bf16* h128b= (bf16*)alloc((size_t)BT_*128*2);
  const size_t tmp_end = cur;
  cur = ubase;  // overlay
  bf16*  wbufb   = (bf16*)alloc((size_t)CHD*2048*2);
  bf16*  sabufb  = (bf16*)alloc((size_t)CHD*2048*2);
  bf16*  abybufb = (bf16*)alloc((size_t)CHD*1024*2);
  bf16*  ckybufb = (bf16*)alloc((size_t)CHD*1024*2);
  bf16*  ubufP   = (bf16*)alloc((size_t)CHD*4096*2);
  bf16*  mbufT   = (bf16*)alloc((size_t)CHD*4096*2);
  bf16*  zb      = (bf16*)ubufP;   // alias: ubufP dead after chunk_state
  if (tmp_end > cur) cur = tmp_end;
  const size_t need = cur;
  (void)in_sizes; (void)n_in; (void)out_size;

  if (ws_size < need) {
    ws_diag<<<1, 1, 0, stream>>>((float)ws_size, (float)need, (float*)d_out);
    return;
  }

  PrepArgs pa;
  pa.src[0] = W_r;  pa.dst[0] = WtR;
  pa.src[1] = W_k;  pa.dst[1] = WtK;
  pa.src[2] = W_v;  pa.dst[2] = WtV;
  pa.src[3] = W_o;  pa.dst[3] = WtO;
  pa.src[4] = maa_w1; pa.dst[4] = w1t;
  for (int s = 0; s < 6; ++s) { pa.src[5+s] = maa_w2 + (size_t)s*32*C_; pa.dst[5+s] = w2t + (size_t)s*C_*32; }
  pa.src[11] = dec_w1; pa.dst[11] = d1t;
  pa.src[12] = dec_w2; pa.dst[12] = d2t;
  pa.src[13] = aaa_w1; pa.dst[13] = a1t;
  pa.src[14] = aaa_w2; pa.dst[14] = a2t;
  pa.src[15] = kkk_w1; pa.dst[15] = k1t;
  pa.src[16] = kkk_w2; pa.dst[16] = k2t;
  pa.src[17] = gate_w1; pa.dst[17] = g1t;
  pa.src[18] = gate_w2; pa.dst[18] = g2t;
  prep_weights<<<dim3(1024, 19), 256, 0, stream>>>(pa);

  const int EW_GRID = (BT_ * C_) / 256;  // 16384
  xin_k<<<EW_GRID, 256, 0, stream>>>(x, maa_x, xinb);

  gemm_bt<1><<<dim3(64, 3), 256, 0, stream>>>(xinb, C_, w1t, C_, mixb, 192, C_);

  Mix6Args ma;
  ma.maa[0] = maa_r; ma.maa[1] = maa_w; ma.maa[2] = maa_k;
  ma.maa[3] = maa_v; ma.maa[4] = maa_a; ma.maa[5] = maa_g;
  for (int s = 0; s < 6; ++s) ma.out[s] = xbr[s];
  mix_combine<<<dim3(64, 16, 6), 256, 0, stream>>>(mixb, w2t, x, ma);

  // r, k, v batched (one launch)
  RkvArgs ra;
  ra.A[0] = xbr[0]; ra.Bt[0] = WtR; ra.Cq[0] = rb;
  ra.A[1] = xbr[2]; ra.Bt[1] = WtK; ra.Cq[1] = kb;
  ra.A[2] = xbr[3]; ra.Bt[2] = WtV; ra.Cq[2] = vb;
  gemm128_rkv<<<dim3(32, 8, 3), 256, 0, stream>>>(ra);

  // batched small projections: k1 (tanh), d1 (tanh), a1 (raw), g1 (tanh)
  Proj4Args p4;
  p4.A[0] = xbr[2]; p4.Bt[0] = k1t; p4.out[0] = h64k; p4.N[0] = 64;  p4.tnh[0] = 1;
  p4.A[1] = xbr[1]; p4.Bt[1] = d1t; p4.out[1] = h64d; p4.N[1] = 64;  p4.tnh[1] = 1;
  p4.A[2] = xbr[4]; p4.Bt[2] = a1t; p4.out[2] = h64a; p4.N[2] = 64;  p4.tnh[2] = 0;
  p4.A[3] = xbr[5]; p4.Bt[3] = g1t; p4.out[3] = h128b; p4.N[3] = 128; p4.tnh[3] = 1;
  proj4<<<dim3(64, 2, 4), 256, 0, stream>>>(p4);

  // kk path (uses UNscaled k)
  gemm128<0><<<dim3(32, 8), 256, 0, stream>>>(h64k, 64, k2t, 64, mtmp, C_, 64, nullptr, nullptr);
  kk_normalize<<<BT_, 256, 0, stream>>>(kb, mtmp, kkb);

  // w path: fused finalize epilogue (writes lwb, scales kb in place)
  gemm128<3><<<dim3(32, 8), 256, 0, stream>>>(h64d, 64, d2t, 64, lwb, C_, 64, tdec, kb);

  // a path: fused sigmoid epilogue
  gemm128<4><<<dim3(32, 8), 256, 0, stream>>>(h64a, 64, a2t, 64, aamt, C_, 64, aaaaa, nullptr);

  // g path -> bf16 gate buffer
  gemm128<2><<<dim3(32, 8), 256, 0, stream>>>(h128b, 128, g2t, 128, gbb, C_, 128, nullptr, nullptr);

  // ---- chunked scan ----
  rwkv_chunk_pre<<<CHD, 256, 0, stream>>>(rb, lwb, kb, kkb, aamt, vb,
      wbufb, sabufb, abybufb, ckybufb, ubufP, mbufT);
  rwkv_chunk_state<<<32, 256, 0, stream>>>(mbufT, ubufP, s0bufb);
  rwkv_chunk_out<<<CHD, 256, 0, stream>>>(rb, lwb, vb, s0bufb, wbufb, sabufb,
      abybufb, ckybufb, (float*)d_out);

  gn_bonus_gate<<<BT_, 256, 0, stream>>>((const float*)d_out, rb, kb, vb, gbb,
                                         faaaa, lnw, lnb, zb);

  gemm128<0><<<dim3(32, 8), 256, 0, stream>>>(zb, C_, WtO, C_, d_out, C_, C_, nullptr, nullptr);
}

// Round 11
// 329.180 us; speedup vs baseline: 4.9636x; 1.1035x over previous
//
#include <hip/hip_runtime.h>
#include <hip/hip_bf16.h>

using bf16 = __hip_bfloat16;
using bf16x8 = __attribute__((ext_vector_type(8))) short;  // 8 bf16 (4 VGPRs)
using f32x4 = __attribute__((ext_vector_type(4))) float;

#define B_ 2
#define T_ 2048
#define C_ 1024
#define BT_ (B_*T_)
#define H_ 16
#define N_ 64
#define LCH 32            // scan chunk length
#define NCH (T_/LCH)      // 64 chunks per head
#define CHD (B_*H_*NCH)   // 2048 chunk-heads

__device__ __forceinline__ float allred64(float v) {
#pragma unroll
  for (int m = 1; m < 64; m <<= 1) v += __shfl_xor(v, m, 64);
  return v;
}

__device__ __forceinline__ bf16 tobf(float f) { return __float2bfloat16(f); }
__device__ __forceinline__ float frombf(bf16 b) { return __bfloat162float(b); }
__device__ __forceinline__ float bf2f(unsigned short u) {
  unsigned int x = ((unsigned int)u) << 16;
  return __builtin_bit_cast(float, x);
}
__device__ __forceinline__ unsigned short bfbits(float f) {
  return __builtin_bit_cast(unsigned short, __float2bfloat16(f));
}
__device__ __forceinline__ float rdlane(float v, int m) {
  return __builtin_bit_cast(float,
      __builtin_amdgcn_readlane(__builtin_bit_cast(int, v), m));
}

__device__ __forceinline__ f32x4 mfma16x16x32(bf16x8 a, bf16x8 b, f32x4 c) {
  return __builtin_amdgcn_mfma_f32_16x16x32_bf16(a, b, c, 0, 0, 0);
}

// async global->LDS, 16B per lane (dest = wave-uniform base + lane*16)
typedef const __attribute__((address_space(1))) unsigned int* gas_ptr;
typedef __attribute__((address_space(3))) unsigned int* las_ptr;
__device__ __forceinline__ void gload16(const void* g, void* l) {
  __builtin_amdgcn_global_load_lds((gas_ptr)g, (las_ptr)l, 16, 0, 0);
}

// ---------------- ws_size diagnostic ----------------------------------------
__global__ void ws_diag(float a, float b, float* out) { out[0] = a; out[1] = b; }

// ---------------- weight transpose + bf16 cast (19 jobs, one launch) -------
struct PrepArgs {
  const float* src[19];
  bf16* dst[19];
};
__constant__ int kTR[19] = {1024,1024,1024,1024, 1024, 32,32,32,32,32,32,
                            1024,64, 1024,64, 1024,64, 1024,128};
__constant__ int kTC[19] = {1024,1024,1024,1024, 192, 1024,1024,1024,1024,1024,1024,
                            64,1024, 64,1024, 64,1024, 128,1024};

__global__ __launch_bounds__(256) void prep_weights(PrepArgs pa) {
  const int job = blockIdx.y;
  const int R = kTR[job], Cc = kTC[job];
  const int ntx = Cc >> 5, nty = R >> 5;
  const int tile = blockIdx.x;
  if (tile >= ntx * nty) return;
  const int tx = tile % ntx, ty = tile / ntx;
  const float* __restrict__ src = pa.src[job];
  bf16* __restrict__ dst = pa.dst[job];
  __shared__ float tl[32][33];
  const int lx = threadIdx.x & 31, ly = threadIdx.x >> 5;  // 32 x 8
#pragma unroll
  for (int q = 0; q < 4; ++q)
    tl[ly + 8*q][lx] = src[(size_t)(ty*32 + ly + 8*q) * Cc + tx*32 + lx];
  __syncthreads();
#pragma unroll
  for (int q = 0; q < 4; ++q)
    dst[(size_t)(tx*32 + ly + 8*q) * R + ty*32 + lx] = tobf(tl[lx][ly + 8*q]);
}

// ------- GEMM 64-tile -------------------------------------------------------
template<int EPI>
__global__ __launch_bounds__(256) void gemm_bt(
    const bf16* __restrict__ A, int lda,
    const bf16* __restrict__ Bt, int ldb,
    void* __restrict__ Cout, int ldc, int K)
{
  __shared__ short As[64][40];
  __shared__ short Bs[64][40];
  const int bm0 = blockIdx.x * 64;
  const int bn0 = blockIdx.y * 64;
  const int tid = threadIdx.x;
  const int wave = tid >> 6, lane = tid & 63;
  const int lm = lane & 15, kg = lane >> 4;
  const int srow = tid >> 2, scol = (tid & 3) * 8;
  f32x4 acc[4] = {};
  const size_t abase = (size_t)(bm0 + srow) * lda + scol;
  const size_t bbase = (size_t)(bn0 + srow) * ldb + scol;
  for (int k0 = 0; k0 < K; k0 += 32) {
    *(uint4*)&As[srow][scol] = *(const uint4*)(A + abase + k0);
    *(uint4*)&Bs[srow][scol] = *(const uint4*)(Bt + bbase + k0);
    __syncthreads();
    bf16x8 af = *(const bf16x8*)&As[wave*16 + lm][kg*8];
#pragma unroll
    for (int f = 0; f < 4; ++f) {
      bf16x8 bfr = *(const bf16x8*)&Bs[f*16 + lm][kg*8];
      acc[f] = mfma16x16x32(af, bfr, acc[f]);
    }
    __syncthreads();
  }
  const int row0 = bm0 + wave*16 + kg*4;
  const int col0 = bn0 + lm;
#pragma unroll
  for (int f = 0; f < 4; ++f) {
#pragma unroll
    for (int q = 0; q < 4; ++q) {
      float val = acc[f][q];
      size_t o = (size_t)(row0 + q) * ldc + col0 + f*16;
      if (EPI == 0)      ((float*)Cout)[o] = val;
      else if (EPI == 1) ((bf16*)Cout)[o] = tobf(tanhf(val));
      else               ((bf16*)Cout)[o] = tobf(val);
    }
  }
}

// ------- batched small projections: k1/d1/a1 (N=64) + g1 (N=128) -----------
struct Proj4Args { const bf16* A[4]; const bf16* Bt[4]; bf16* out[4];
                   int N[4]; int tnh[4]; };
__global__ __launch_bounds__(256) void proj4(Proj4Args p4) {
  const int z = blockIdx.z;
  const int Nn = p4.N[z];
  const int bn0 = blockIdx.y * 64;
  if (bn0 >= Nn) return;
  __shared__ short As[64][40];
  __shared__ short Bs[64][40];
  const bf16* __restrict__ A  = p4.A[z];
  const bf16* __restrict__ Bt = p4.Bt[z];
  bf16* __restrict__ out = p4.out[z];
  const int tnh = p4.tnh[z];
  const int bm0 = blockIdx.x * 64;
  const int tid = threadIdx.x;
  const int wave = tid >> 6, lane = tid & 63;
  const int lm = lane & 15, kg = lane >> 4;
  const int srow = tid >> 2, scol = (tid & 3) * 8;
  f32x4 acc[4] = {};
  const size_t abase = (size_t)(bm0 + srow) * C_ + scol;
  const size_t bbase = (size_t)(bn0 + srow) * C_ + scol;
  for (int k0 = 0; k0 < C_; k0 += 32) {
    *(uint4*)&As[srow][scol] = *(const uint4*)(A + abase + k0);
    *(uint4*)&Bs[srow][scol] = *(const uint4*)(Bt + bbase + k0);
    __syncthreads();
    bf16x8 af = *(const bf16x8*)&As[wave*16 + lm][kg*8];
#pragma unroll
    for (int f = 0; f < 4; ++f) {
      bf16x8 bfr = *(const bf16x8*)&Bs[f*16 + lm][kg*8];
      acc[f] = mfma16x16x32(af, bfr, acc[f]);
    }
    __syncthreads();
  }
  const int row0 = bm0 + wave*16 + kg*4;
  const int col0 = bn0 + lm;
#pragma unroll
  for (int f = 0; f < 4; ++f) {
#pragma unroll
    for (int q = 0; q < 4; ++q) {
      float val = acc[f][q];
      size_t o = (size_t)(row0 + q) * Nn + col0 + f*16;
      out[o] = tobf(tnh ? tanhf(val) : val);
    }
  }
}

// ------- GEMM 128-tile, m97 structure (global_load_lds staging) -------------
// EPI: 0 f32 | 2 bf16 | 3 w-finalize (Cout=lw bf16, aux1=td, aux2=k bf16 inplace)
//      4 a-finalize (Cout=aamt bf16, aux1=aaaaa)
template<int EPI>
__global__ __launch_bounds__(256) void gemm128(
    const bf16* __restrict__ A, int lda,
    const bf16* __restrict__ Bt, int ldb,
    void* __restrict__ Cout, int ldc, int K,
    const float* __restrict__ aux1, bf16* __restrict__ aux2)
{
  __shared__ bf16 As[128][32];     // linear (required by global_load_lds)
  __shared__ bf16 Bs[128][32];
  const int bm0 = blockIdx.x * 128, bn0 = blockIdx.y * 128;
  const int tid = threadIdx.x, wv = tid >> 6, ln = tid & 63;
  const int wr = wv >> 1, wc = wv & 1;
  const int lm = ln & 15, kg = ln >> 4;
  const int srow = ln >> 2, scol = (ln & 3) * 8;
  f32x4 acc[4][4] = {};
  for (int k0 = 0; k0 < K; k0 += 32) {
#pragma unroll
    for (int i = 0; i < 2; ++i) {
      const int r0 = wv*32 + i*16;
      gload16(A  + (size_t)(bm0 + r0 + srow) * lda + k0 + scol, &As[r0][0]);
      gload16(Bt + (size_t)(bn0 + r0 + srow) * ldb + k0 + scol, &Bs[r0][0]);
    }
    asm volatile("s_waitcnt vmcnt(0)" ::: "memory");
    __syncthreads();
    bf16x8 af[4], bfr[4];
#pragma unroll
    for (int m = 0; m < 4; ++m) af[m] = *(const bf16x8*)&As[wr*64 + m*16 + lm][kg*8];
#pragma unroll
    for (int n = 0; n < 4; ++n) bfr[n] = *(const bf16x8*)&Bs[wc*64 + n*16 + lm][kg*8];
#pragma unroll
    for (int m = 0; m < 4; ++m)
#pragma unroll
      for (int n = 0; n < 4; ++n)
        acc[m][n] = mfma16x16x32(af[m], bfr[n], acc[m][n]);
    __syncthreads();
  }
#pragma unroll
  for (int m = 0; m < 4; ++m) {
    const int row0 = bm0 + wr*64 + m*16 + kg*4;
#pragma unroll
    for (int n = 0; n < 4; ++n) {
      const int col = bn0 + wc*64 + n*16 + lm;
#pragma unroll
      for (int q = 0; q < 4; ++q) {
        float val = acc[m][n][q];
        size_t o = (size_t)(row0 + q) * ldc + col;
        if (EPI == 0)      ((float*)Cout)[o] = val;
        else if (EPI == 2) ((bf16*)Cout)[o] = tobf(val);
        else if (EPI == 3) {
          float wr2 = val + aux1[col];
          float sp = fmaxf(-wr2, 0.f) + log1pf(expf(-fabsf(wr2)));
          float w = -sp - 0.5f;
          ((bf16*)Cout)[o] = tobf(-expf(w));                       // lw
          aux2[o] = tobf(frombf(aux2[o]) * expf(fminf(0.5f*w, 0.f))); // k scale
        } else if (EPI == 4) {
          float z = aux1[col] + val;
          ((bf16*)Cout)[o] = tobf(2.f / (1.f + expf(-z)));
        }
      }
    }
  }
}

// batched r/k/v: same shape (M=4096, N=1024, K=1024), bf16 outputs
struct RkvArgs { const bf16* A[3]; const bf16* Bt[3]; bf16* Cq[3]; };
__global__ __launch_bounds__(256) void gemm128_rkv(RkvArgs ra) {
  __shared__ bf16 As[128][32];
  __shared__ bf16 Bs[128][32];
  const bf16* __restrict__ A  = ra.A[blockIdx.z];
  const bf16* __restrict__ Bt = ra.Bt[blockIdx.z];
  bf16* __restrict__ Cout = ra.Cq[blockIdx.z];
  const int bm0 = blockIdx.x * 128, bn0 = blockIdx.y * 128;
  const int tid = threadIdx.x, wv = tid >> 6, ln = tid & 63;
  const int wr = wv >> 1, wc = wv & 1;
  const int lm = ln & 15, kg = ln >> 4;
  const int srow = ln >> 2, scol = (ln & 3) * 8;
  f32x4 acc[4][4] = {};
  for (int k0 = 0; k0 < C_; k0 += 32) {
#pragma unroll
    for (int i = 0; i < 2; ++i) {
      const int r0 = wv*32 + i*16;
      gload16(A  + (size_t)(bm0 + r0 + srow) * C_ + k0 + scol, &As[r0][0]);
      gload16(Bt + (size_t)(bn0 + r0 + srow) * C_ + k0 + scol, &Bs[r0][0]);
    }
    asm volatile("s_waitcnt vmcnt(0)" ::: "memory");
    __syncthreads();
    bf16x8 af[4], bfr[4];
#pragma unroll
    for (int m = 0; m < 4; ++m) af[m] = *(const bf16x8*)&As[wr*64 + m*16 + lm][kg*8];
#pragma unroll
    for (int n = 0; n < 4; ++n) bfr[n] = *(const bf16x8*)&Bs[wc*64 + n*16 + lm][kg*8];
#pragma unroll
    for (int m = 0; m < 4; ++m)
#pragma unroll
      for (int n = 0; n < 4; ++n)
        acc[m][n] = mfma16x16x32(af[m], bfr[n], acc[m][n]);
    __syncthreads();
  }
#pragma unroll
  for (int m = 0; m < 4; ++m) {
    const int row0 = bm0 + wr*64 + m*16 + kg*4;
#pragma unroll
    for (int n = 0; n < 4; ++n) {
      const int col = bn0 + wc*64 + n*16 + lm;
#pragma unroll
      for (int q = 0; q < 4; ++q)
        Cout[(size_t)(row0 + q) * C_ + col] = tobf(acc[m][n][q]);
    }
  }
}

// --------- fused 6-branch low-rank projection + combine ---------------------
struct Mix6Args { const float* maa[6]; bf16* out[6]; };

__global__ __launch_bounds__(256) void mix_combine(
    const bf16* __restrict__ mixb, const bf16* __restrict__ w2t,
    const float* __restrict__ x, Mix6Args ma)
{
  __shared__ short As[64][40];
  __shared__ short Bs[64][40];
  const int s6 = blockIdx.z;
  const bf16* __restrict__ A  = mixb + s6*32;            // lda = 192
  const bf16* __restrict__ Bt = w2t + (size_t)s6*C_*32;  // ldb = 32
  const float* __restrict__ maa = ma.maa[s6];
  bf16* __restrict__ out = ma.out[s6];
  const int bm0 = blockIdx.x * 64, bn0 = blockIdx.y * 64;
  const int tid = threadIdx.x, wave = tid >> 6, lane = tid & 63;
  const int lm = lane & 15, kg = lane >> 4;
  const int srow = tid >> 2, scol = (tid & 3) * 8;
  *(uint4*)&As[srow][scol] = *(const uint4*)(A + (size_t)(bm0 + srow)*192 + scol);
  *(uint4*)&Bs[srow][scol] = *(const uint4*)(Bt + (size_t)(bn0 + srow)*32 + scol);
  __syncthreads();
  bf16x8 af = *(const bf16x8*)&As[wave*16 + lm][kg*8];
  f32x4 acc[4] = {};
#pragma unroll
  for (int f = 0; f < 4; ++f) {
    bf16x8 bfr = *(const bf16x8*)&Bs[f*16 + lm][kg*8];
    acc[f] = mfma16x16x32(af, bfr, acc[f]);
  }
  const int row0 = bm0 + wave*16 + kg*4;
  const int col0 = bn0 + lm;
#pragma unroll
  for (int f = 0; f < 4; ++f) {
#pragma unroll
    for (int q = 0; q < 4; ++q) {
      const int row = row0 + q, col = col0 + f*16;
      const size_t o = (size_t)row * C_ + col;
      float xv = x[o];
      float xp = (row & (T_ - 1)) ? x[o - C_] : 0.f;
      out[o] = tobf(xv + (xp - xv) * (maa[col] + acc[f][q]));
    }
  }
}

// ---------------- elementwise ----------------------------------------------
__global__ __launch_bounds__(256) void xin_k(
    const float* __restrict__ x, const float* __restrict__ maa_x,
    bf16* __restrict__ xinb)
{
  size_t idx = (size_t)blockIdx.x * 256 + threadIdx.x;
  int c = idx & (C_ - 1);
  int t = (int)((idx >> 10) & (T_ - 1));
  float xv = x[idx];
  float xp = t ? x[idx - C_] : 0.f;
  xinb[idx] = tobf(xv + (xp - xv) * maa_x[c]);
}

__global__ __launch_bounds__(256) void kk_normalize(
    const bf16* __restrict__ kraw, const float* __restrict__ kkadd,
    bf16* __restrict__ kkout)
{
  const int bt = blockIdx.x;
  const int tid = threadIdx.x;
  const size_t o = (size_t)bt * C_;
  float vals[4]; float ss = 0.f;
#pragma unroll
  for (int q = 0; q < 4; ++q) {
    float u = frombf(kraw[o + tid + q*256]) + kkadd[o + tid + q*256];
    vals[q] = u; ss += u * u;
  }
  ss = allred64(ss);
  __shared__ float red[4];
  const int wave = tid >> 6, lane = tid & 63;
  if (lane == 0) red[wave] = ss;
  __syncthreads();
  float tot = red[0] + red[1] + red[2] + red[3];
  float inv = 1.f / fmaxf(sqrtf(tot), 1e-12f);
#pragma unroll
  for (int q = 0; q < 4; ++q) kkout[o + tid + q*256] = tobf(vals[q] * inv);
}

// ============ Chunked RWKV-7 scan (fp32 recurrence, bf16 MFMA phases) =======
//   SA = (I-trilA)^{-1}(Achk S0^T + trilC V) = W S0^T + SA_loc
//   y[s] = rt_s S0^T + tril<=(ABy) SA + tril<=(CKy) V
//   S_L = S0 * M + U  with M = diag(dL) + (W^T Bt).*dL_j
// M stored TRANSPOSED in MFMA-B-fragment-packed layout (mbufT);
// U stored in accumulator-packed layout (ubufP).

__global__ __launch_bounds__(256, 2) void rwkv_chunk_pre(
    const bf16* __restrict__ rr, const bf16* __restrict__ lw,
    const bf16* __restrict__ kk_s, const bf16* __restrict__ kkv,
    const bf16* __restrict__ aam, const bf16* __restrict__ vv,
    bf16* __restrict__ wbufb, bf16* __restrict__ sabufb,
    bf16* __restrict__ abybufb, bf16* __restrict__ ckybufb,
    bf16* __restrict__ ubufP, bf16* __restrict__ mbufT)
{
  __shared__ float Am[LCH][33], Cm[LCH][33];
  __shared__ float wtot[4][64];
  __shared__ float lcl[64];
  __shared__ bf16 aCb[LCH][72], rCb[LCH][72], bTb[LCH][72], kTb[LCH][72], vLb[LCH][72];
  __shared__ bf16 bTT[64][40], kTT[64][40], vLT[64][40];
  __shared__ bf16 WT[64][40], SAT[64][40];

  const int ch = blockIdx.x;
  const int c  = ch & (NCH - 1);
  const int bh = ch >> 6;
  const int b  = bh >> 4, h = bh & 15;
  const int tid = threadIdx.x, wv = tid >> 6, ln = tid & 63;
  const int lm = ln & 15, kg = ln >> 4;
  const size_t base = ((size_t)(b*T_ + c*LCH) * C_) + h*N_ + ln;

  // --- phase 1: cumulative log-decay + load/scale into LDS (both layouts) ---
  float lwr[8], lcE[8];
  {
    float run = 0.f;
#pragma unroll
    for (int q = 0; q < 8; ++q) {
      lwr[q] = frombf(lw[base + (size_t)(wv*8 + q) * C_]);
      lcE[q] = run; run += lwr[q];
    }
    wtot[wv][ln] = run;
  }
  __syncthreads();
  {
    float pre = 0.f;
    for (int w2 = 0; w2 < wv; ++w2) pre += wtot[w2][ln];
    if (wv == 0) lcl[ln] = wtot[0][ln] + wtot[1][ln] + wtot[2][ln] + wtot[3][ln];
#pragma unroll
    for (int q = 0; q < 8; ++q) lcE[q] += pre;
  }
#pragma unroll
  for (int q = 0; q < 8; ++q) {
    const int s = wv*8 + q;
    const size_t off = base + (size_t)s * C_;
    float kkx = frombf(kkv[off]), aax = frombf(aam[off]);
    float kx = frombf(kk_s[off]), rx = frombf(rr[off]);
    float lcI = lcE[q] + lwr[q];
    float eIm = __expf(-lcI);
    float av = -kkx * __expf(lcE[q]);
    float bv = kkx * aax * eIm;
    float kv2 = kx * eIm;
    float rv = rx * __expf(lcI);
    bf16 vxb = vv[off];
    aCb[s][ln] = tobf(av);  rCb[s][ln] = tobf(rv);
    bTb[s][ln] = tobf(bv);  kTb[s][ln] = tobf(kv2);
    vLb[s][ln] = vxb;
    bTT[ln][s] = tobf(bv);  kTT[ln][s] = tobf(kv2);  vLT[ln][s] = vxb;
  }
  __syncthreads();

  // --- phase 2: MFMA, one 32x32 (K=64) product per wave ---
  {
    const bf16 (*Ab)[72] = (wv < 2) ? aCb : rCb;
    const bf16 (*Bb)[72] = (wv & 1) ? kTb : bTb;
#pragma unroll
    for (int mt = 0; mt < 2; ++mt)
#pragma unroll
      for (int nt = 0; nt < 2; ++nt) {
        f32x4 acc = {};
#pragma unroll
        for (int ks = 0; ks < 2; ++ks) {
          bf16x8 af = *(const bf16x8*)&Ab[mt*16 + lm][ks*32 + kg*8];
          bf16x8 bq = *(const bf16x8*)&Bb[nt*16 + lm][ks*32 + kg*8];
          acc = mfma16x16x32(af, bq, acc);
        }
        const int row0 = mt*16 + kg*4, col = nt*16 + lm;
#pragma unroll
        for (int q = 0; q < 4; ++q) {
          float v = acc[q];
          if (wv == 0)      Am[row0+q][col] = v;
          else if (wv == 1) Cm[row0+q][col] = v;
          else {
            bf16 bv2 = tobf(col <= row0+q ? v : 0.f);  // tril<= mask
            if (wv == 2) abybufb[(size_t)ch*1024 + (row0+q)*32 + col] = bv2;
            else         ckybufb[(size_t)ch*1024 + (row0+q)*32 + col] = bv2;
          }
        }
      }
  }
  __syncthreads();

  // --- phase 3: register forward-substitution (wave0: W, wave1: SA_loc) ---
  if (wv < 2) {
    float Xr[32], amr[32];
#pragma unroll
    for (int s = 0; s < 32; ++s) amr[s] = Am[s][ln & 31];
    if (wv == 0) {
#pragma unroll
      for (int s = 0; s < 32; ++s) Xr[s] = frombf(aCb[s][ln]);
    } else {
      float cmr[32];
#pragma unroll
      for (int s = 0; s < 32; ++s) cmr[s] = Cm[s][ln & 31];
#pragma unroll
      for (int s = 0; s < 32; ++s) Xr[s] = 0.f;
#pragma unroll
      for (int u = 0; u < 31; ++u) {
        float v = frombf(vLb[u][ln]);
#pragma unroll
        for (int s = u + 1; s < 32; ++s) Xr[s] += rdlane(cmr[s], u) * v;
      }
    }
#pragma unroll
    for (int s = 1; s < 32; ++s) {
      float acc = Xr[s];
#pragma unroll
      for (int u = 0; u < s; ++u) acc += rdlane(amr[s], u) * Xr[u];
      Xr[s] = acc;
    }
    if (wv == 0) {
#pragma unroll
      for (int s = 0; s < 32; ++s) {
        bf16 bv = tobf(Xr[s]);
        WT[ln][s] = bv;
        wbufb[(size_t)ch*2048 + s*64 + ln] = bv;
      }
    } else {
#pragma unroll
      for (int s = 0; s < 32; ++s) {
        bf16 bv = tobf(Xr[s]);
        SAT[ln][s] = bv;
        sabufb[(size_t)ch*2048 + s*64 + ln] = bv;
      }
    }
  }
  __syncthreads();

  // --- phase 5: U, M (64x64, K=32) via MFMA; packed-layout b64 stores ------
  {
    const int mt = wv;
    bf16x8 aS = *(const bf16x8*)&SAT[mt*16 + lm][kg*8];
    bf16x8 aV = *(const bf16x8*)&vLT[mt*16 + lm][kg*8];
    bf16x8 aW = *(const bf16x8*)&WT[mt*16 + lm][kg*8];
#pragma unroll
    for (int nt = 0; nt < 4; ++nt) {
      bf16x8 bB = *(const bf16x8*)&bTT[nt*16 + lm][kg*8];
      bf16x8 bK = *(const bf16x8*)&kTT[nt*16 + lm][kg*8];
      f32x4 aU = {}, aG = {};
      aU = mfma16x16x32(aS, bB, aU);
      aU = mfma16x16x32(aV, bK, aU);
      aG = mfma16x16x32(aW, bB, aG);
      const int i0r = mt*16 + kg*4, col = nt*16 + lm;
      float dl = __expf(lcl[col]);
      uint2 up;
      up.x = (unsigned int)bfbits(aU[0]*dl) | ((unsigned int)bfbits(aU[1]*dl) << 16);
      up.y = (unsigned int)bfbits(aU[2]*dl) | ((unsigned int)bfbits(aU[3]*dl) << 16);
      *(uint2*)(ubufP + (size_t)ch*4096 + (mt*4 + nt)*256 + ln*4) = up;
      float m0 = (aG[0] + (i0r+0 == col ? 1.f : 0.f)) * dl;
      float m1 = (aG[1] + (i0r+1 == col ? 1.f : 0.f)) * dl;
      float m2 = (aG[2] + (i0r+2 == col ? 1.f : 0.f)) * dl;
      float m3 = (aG[3] + (i0r+3 == col ? 1.f : 0.f)) * dl;
      uint2 mp;
      mp.x = (unsigned int)bfbits(m0) | ((unsigned int)bfbits(m1) << 16);
      mp.y = (unsigned int)bfbits(m2) | ((unsigned int)bfbits(m3) << 16);
      const int laned = (((mt*2) + (kg >> 1)) & 3) * 16 + lm;
      *(uint2*)(mbufT + (size_t)ch*4096 + (nt*2 + (mt >> 1))*512
                + laned*8 + (kg & 1)*4) = mp;
    }
  }
}

// Phase B: serial over chunks; 32 blocks (one per bh) x 4 waves, no barriers.
__global__ __launch_bounds__(256) void rwkv_chunk_state(
    const bf16* __restrict__ mbufT, const bf16* __restrict__ ubufP,
    bf16* __restrict__ s0bufb)
{
  __shared__ bf16 Sst[4][16][72];
  const int bh = blockIdx.x;
  const int tid = threadIdx.x, wv = tid >> 6, ln = tid & 63;
  const int lm = ln & 15, kg = ln >> 4;

#pragma unroll
  for (int r = 0; r < 16; ++r) {
    Sst[wv][r][ln] = tobf(0.f);
    if (ln < 8) Sst[wv][r][64 + ln] = tobf(0.f);
  }

  bf16x8 BfA[4][2], BfB[4][2];
  uint2 UpA[4], UpB[4];
  auto prefetch = [&](bf16x8 (&Bf)[4][2], uint2 (&Up)[4], int c) {
    const size_t chp = (size_t)(bh*NCH + c) * 4096;
#pragma unroll
    for (int nt = 0; nt < 4; ++nt) {
      Bf[nt][0] = *(const bf16x8*)(mbufT + chp + (nt*2 + 0)*512 + ln*8);
      Bf[nt][1] = *(const bf16x8*)(mbufT + chp + (nt*2 + 1)*512 + ln*8);
      Up[nt]    = *(const uint2*) (ubufP + chp + (wv*4 + nt)*256 + ln*4);
    }
  };
  prefetch(BfA, UpA, 0);
  prefetch(BfB, UpB, 1);

  auto body = [&](bf16x8 (&Bf)[4][2], uint2 (&Up)[4], int c) {
    const size_t ch4 = (size_t)(bh*NCH + c) * 4096;
    const int sr = ln >> 2, sc = (ln & 3) * 16;
    uint4 v0 = *(const uint4*)&Sst[wv][sr][sc];
    uint4 v1 = *(const uint4*)&Sst[wv][sr][sc + 8];
    *(uint4*)(s0bufb + ch4 + (size_t)(wv*16 + sr)*64 + sc) = v0;
    *(uint4*)(s0bufb + ch4 + (size_t)(wv*16 + sr)*64 + sc + 8) = v1;
    bf16x8 A0 = *(const bf16x8*)&Sst[wv][lm][kg*8];
    bf16x8 A1 = *(const bf16x8*)&Sst[wv][lm][32 + kg*8];
    f32x4 acc[4];
#pragma unroll
    for (int nt = 0; nt < 4; ++nt) {
      acc[nt][0] = bf2f((unsigned short)(Up[nt].x & 0xffff));
      acc[nt][1] = bf2f((unsigned short)(Up[nt].x >> 16));
      acc[nt][2] = bf2f((unsigned short)(Up[nt].y & 0xffff));
      acc[nt][3] = bf2f((unsigned short)(Up[nt].y >> 16));
      acc[nt] = mfma16x16x32(A0, Bf[nt][0], acc[nt]);
      acc[nt] = mfma16x16x32(A1, Bf[nt][1], acc[nt]);
    }
    int cp = c + 2; if (cp > NCH - 1) cp = NCH - 1;
    prefetch(Bf, Up, cp);
#pragma unroll
    for (int nt = 0; nt < 4; ++nt)
#pragma unroll
      for (int q = 0; q < 4; ++q)
        Sst[wv][kg*4 + q][nt*16 + lm] = tobf(acc[nt][q]);
  };

  for (int cc = 0; cc < NCH; cc += 2) {
    body(BfA, UpA, cc);
    body(BfB, UpB, cc + 1);
  }
}

// Phase C: per chunk-head, MFMA: SA = W*S0^T + SAll, then
// y = Rt*S0^T + ABl*SAo + CKl*V  (ABl/CKl pre-masked tril<=).
__global__ __launch_bounds__(256, 4) void rwkv_chunk_out(
    const bf16* __restrict__ rr, const bf16* __restrict__ lw,
    const bf16* __restrict__ vv, const bf16* __restrict__ s0bufb,
    const bf16* __restrict__ wbufb, const bf16* __restrict__ sabufb,
    const bf16* __restrict__ abybufb, const bf16* __restrict__ ckybufb,
    float* __restrict__ y)
{
  __shared__ bf16 S0b[64][72];                    // B^T layout: [i][j]
  __shared__ bf16 Wb[LCH][72], Rlb[LCH][72];      // A layouts: [s][j]
  __shared__ bf16 ABl[LCH][40], CKl[LCH][40];     // A layouts: [s][u]
  __shared__ bf16 SAot[64][40], VlT[64][40];      // B^T layouts: [i][u]
  __shared__ float wtot[4][64];
  const int ch = blockIdx.x;
  const int c = ch & (NCH - 1), bh = ch >> 6, b = bh >> 4, h = bh & 15;
  const int tid = threadIdx.x, wv = tid >> 6, ln = tid & 63;
  const int lm = ln & 15, kg = ln >> 4;
  const size_t base = ((size_t)(b*T_ + c*LCH) * C_) + h*N_ + ln;

  float lwr[8], lcE[8];
  {
    float run = 0.f;
#pragma unroll
    for (int q = 0; q < 8; ++q) {
      lwr[q] = frombf(lw[base + (size_t)(wv*8 + q) * C_]);
      lcE[q] = run; run += lwr[q];
    }
    wtot[wv][ln] = run;
  }
  __syncthreads();
  {
    float pre = 0.f;
    for (int w2 = 0; w2 < wv; ++w2) pre += wtot[w2][ln];
#pragma unroll
    for (int q = 0; q < 8; ++q) lcE[q] += pre;
  }
#pragma unroll
  for (int q = 0; q < 8; ++q) {
    const int s = wv*8 + q;
    const size_t off = base + (size_t)s * C_;
    Rlb[s][ln] = tobf(frombf(rr[off]) * __expf(lcE[q] + lwr[q]));
    VlT[ln][s] = vv[off];
  }
#pragma unroll
  for (int t = 0; t < 2; ++t) {
    int cc2 = tid*2 + t; int ri = cc2 >> 3, co = (cc2 & 7) * 8;
    *(uint4*)&S0b[ri][co] = *(const uint4*)(s0bufb + (size_t)ch*4096 + ri*64 + co);
  }
  { int ri = tid >> 3, co = (tid & 7) * 8;
    *(uint4*)&Wb[ri][co] = *(const uint4*)(wbufb + (size_t)ch*2048 + ri*64 + co); }
  if (tid < 128) {
    int ri = tid >> 2, co = (tid & 3) * 8;
    *(uint4*)&ABl[ri][co] = *(const uint4*)(abybufb + (size_t)ch*1024 + ri*32 + co);
  } else {
    int t2 = tid - 128; int ri = t2 >> 2, co = (t2 & 3) * 8;
    *(uint4*)&CKl[ri][co] = *(const uint4*)(ckybufb + (size_t)ch*1024 + ri*32 + co);
  }
  __syncthreads();

  const int mt = wv >> 1, ntb = (wv & 1) * 2;
#pragma unroll
  for (int t = 0; t < 2; ++t) {
    const int nt = ntb + t;
    const int row0 = mt*16 + kg*4, col = nt*16 + lm;
    f32x4 acc;
#pragma unroll
    for (int q = 0; q < 4; ++q)
      acc[q] = frombf(sabufb[(size_t)ch*2048 + (row0+q)*64 + col]);
#pragma unroll
    for (int ks = 0; ks < 2; ++ks) {
      bf16x8 af = *(const bf16x8*)&Wb[mt*16 + lm][ks*32 + kg*8];
      bf16x8 bq = *(const bf16x8*)&S0b[nt*16 + lm][ks*32 + kg*8];
      acc = mfma16x16x32(af, bq, acc);
    }
#pragma unroll
    for (int q = 0; q < 4; ++q) SAot[col][row0+q] = tobf(acc[q]);
  }
  __syncthreads();

#pragma unroll
  for (int t = 0; t < 2; ++t) {
    const int nt = ntb + t;
    f32x4 acc = {};
#pragma unroll
    for (int ks = 0; ks < 2; ++ks) {
      bf16x8 af = *(const bf16x8*)&Rlb[mt*16 + lm][ks*32 + kg*8];
      bf16x8 bq = *(const bf16x8*)&S0b[nt*16 + lm][ks*32 + kg*8];
      acc = mfma16x16x32(af, bq, acc);
    }
    {
      bf16x8 af = *(const bf16x8*)&ABl[mt*16 + lm][kg*8];
      bf16x8 bq = *(const bf16x8*)&SAot[nt*16 + lm][kg*8];
      acc = mfma16x16x32(af, bq, acc);
    }
    {
      bf16x8 af = *(const bf16x8*)&CKl[mt*16 + lm][kg*8];
      bf16x8 bq = *(const bf16x8*)&VlT[nt*16 + lm][kg*8];
      acc = mfma16x16x32(af, bq, acc);
    }
    const int row0 = mt*16 + kg*4, col = nt*16 + lm;
#pragma unroll
    for (int q = 0; q < 4; ++q)
      y[((size_t)(b*T_ + c*LCH + row0 + q)) * C_ + h*N_ + col] = acc[q];
  }
}

// ---------------- groupnorm + bonus + gate ---------------------------------
__global__ __launch_bounds__(256) void gn_bonus_gate(
    const float* __restrict__ y, const bf16* __restrict__ rr,
    const bf16* __restrict__ kk_s, const bf16* __restrict__ vv,
    const bf16* __restrict__ gg, const float* __restrict__ faaaa,
    const float* __restrict__ lnw, const float* __restrict__ lnb,
    bf16* __restrict__ zb)
{
  const int bt = blockIdx.x;
  const int wave = threadIdx.x >> 6, lane = threadIdx.x & 63;
  const float inv64 = 1.f / 64.f;
  for (int h = wave; h < H_; h += 4) {
    const int c = h * 64 + lane;
    const size_t o = (size_t)bt * C_ + c;
    float yv = y[o];
    float mean = allred64(yv) * inv64;
    float d = yv - mean;
    float var = allred64(d * d) * inv64;
    float xn = d * rsqrtf(var + 6.4e-4f);
    float gn = xn * lnw[c] + lnb[c];
    float rk = allred64(frombf(rr[o]) * frombf(kk_s[o]) * faaaa[c]);
    float z = (gn + rk * frombf(vv[o])) * frombf(gg[o]);
    zb[o] = tobf(z);
  }
}

// ---------------- driver ----------------------------------------------------
extern "C" void kernel_launch(void* const* d_in, const int* in_sizes, int n_in,
                              void* d_out, int out_size, void* d_ws, size_t ws_size,
                              hipStream_t stream)
{
  const float* x     = (const float*)d_in[0];
  const float* maa_x = (const float*)d_in[1];
  const float* maa_r = (const float*)d_in[2];
  const float* maa_w = (const float*)d_in[3];
  const float* maa_k = (const float*)d_in[4];
  const float* maa_v = (const float*)d_in[5];
  const float* maa_a = (const float*)d_in[6];
  const float* maa_g = (const float*)d_in[7];
  const float* tdec  = (const float*)d_in[8];
  const float* faaaa = (const float*)d_in[9];
  const float* aaaaa = (const float*)d_in[10];
  const float* maa_w1= (const float*)d_in[11];
  const float* maa_w2= (const float*)d_in[12];
  const float* dec_w1= (const float*)d_in[13];
  const float* dec_w2= (const float*)d_in[14];
  const float* aaa_w1= (const float*)d_in[15];
  const float* aaa_w2= (const float*)d_in[16];
  const float* kkk_w1= (const float*)d_in[17];
  const float* kkk_w2= (const float*)d_in[18];
  const float* gate_w1=(const float*)d_in[19];
  const float* gate_w2=(const float*)d_in[20];
  const float* W_r   = (const float*)d_in[21];
  const float* W_k   = (const float*)d_in[22];
  const float* W_v   = (const float*)d_in[23];
  const float* W_o   = (const float*)d_in[24];
  const float* lnw   = (const float*)d_in[25];
  const float* lnb   = (const float*)d_in[26];

  char* ws = (char*)d_ws;
  size_t cur = 0;
  auto alloc = [&](size_t bytes) -> void* {
    void* p = ws + cur; cur += (bytes + 255) & ~(size_t)255; return p;
  };
  const size_t FBT = (size_t)BT_ * C_ * sizeof(float);
  const size_t HBT = (size_t)BT_ * C_ * 2;  // bf16 activation buffer

  // ---- persistent (activations now bf16) ----
  bf16* rb   = (bf16*)alloc(HBT);
  bf16* kb   = (bf16*)alloc(HBT);
  bf16* vb   = (bf16*)alloc(HBT);
  bf16* gbb  = (bf16*)alloc(HBT);
  bf16* WtR  = (bf16*)alloc((size_t)C_*C_*2);
  bf16* WtK  = (bf16*)alloc((size_t)C_*C_*2);
  bf16* WtV  = (bf16*)alloc((size_t)C_*C_*2);
  bf16* WtO  = (bf16*)alloc((size_t)C_*C_*2);
  bf16* w1t  = (bf16*)alloc((size_t)192*C_*2);
  bf16* w2t  = (bf16*)alloc((size_t)6*C_*32*2);
  bf16* d1t  = (bf16*)alloc((size_t)64*C_*2);
  bf16* d2t  = (bf16*)alloc((size_t)C_*64*2);
  bf16* a1t  = (bf16*)alloc((size_t)64*C_*2);
  bf16* a2t  = (bf16*)alloc((size_t)C_*64*2);
  bf16* k1t  = (bf16*)alloc((size_t)64*C_*2);
  bf16* k2t  = (bf16*)alloc((size_t)C_*64*2);
  bf16* g1t  = (bf16*)alloc((size_t)128*C_*2);
  bf16* g2t  = (bf16*)alloc((size_t)C_*128*2);
  bf16* lwb  = (bf16*)alloc(HBT);
  // kkb + aamt (bf16, 8MB each, contiguous) dead after chunk_pre;
  // s0bufb (16MB) overlays both.
  bf16* kkb  = (bf16*)alloc(HBT);
  bf16* aamt = (bf16*)alloc(HBT);
  bf16* s0bufb = kkb;                 // CHD*4096*2 == 2*HBT exactly

  // ---- union region ----
  const size_t ubase = cur;
  float* mtmp = (float*)alloc(FBT);
  bf16* xinb = (bf16*)alloc(HBT);
  bf16* mixb = (bf16*)alloc((size_t)BT_*192*2);
  bf16* xbr[6];
  for (int s = 0; s < 6; ++s) xbr[s] = (bf16*)alloc(HBT);
  bf16* h64k = (bf16*)alloc((size_t)BT_*64*2);
  bf16* h64d = (bf16*)alloc((size_t)BT_*64*2);
  bf16* h64a = (bf16*)alloc((size_t)BT_*64*2);
  bf16* h128b= (bf16*)alloc((size_t)BT_*128*2);
  const size_t tmp_end = cur;
  cur = ubase;  // overlay
  bf16*  wbufb   = (bf16*)alloc((size_t)CHD*2048*2);
  bf16*  sabufb  = (bf16*)alloc((size_t)CHD*2048*2);
  bf16*  abybufb = (bf16*)alloc((size_t)CHD*1024*2);
  bf16*  ckybufb = (bf16*)alloc((size_t)CHD*1024*2);
  bf16*  ubufP   = (bf16*)alloc((size_t)CHD*4096*2);
  bf16*  mbufT   = (bf16*)alloc((size_t)CHD*4096*2);
  bf16*  zb      = (bf16*)ubufP;   // alias: ubufP dead after chunk_state
  if (tmp_end > cur) cur = tmp_end;
  const size_t need = cur;
  (void)in_sizes; (void)n_in; (void)out_size;

  if (ws_size < need) {
    ws_diag<<<1, 1, 0, stream>>>((float)ws_size, (float)need, (float*)d_out);
    return;
  }

  PrepArgs pa;
  pa.src[0] = W_r;  pa.dst[0] = WtR;
  pa.src[1] = W_k;  pa.dst[1] = WtK;
  pa.src[2] = W_v;  pa.dst[2] = WtV;
  pa.src[3] = W_o;  pa.dst[3] = WtO;
  pa.src[4] = maa_w1; pa.dst[4] = w1t;
  for (int s = 0; s < 6; ++s) { pa.src[5+s] = maa_w2 + (size_t)s*32*C_; pa.dst[5+s] = w2t + (size_t)s*C_*32; }
  pa.src[11] = dec_w1; pa.dst[11] = d1t;
  pa.src[12] = dec_w2; pa.dst[12] = d2t;
  pa.src[13] = aaa_w1; pa.dst[13] = a1t;
  pa.src[14] = aaa_w2; pa.dst[14] = a2t;
  pa.src[15] = kkk_w1; pa.dst[15] = k1t;
  pa.src[16] = kkk_w2; pa.dst[16] = k2t;
  pa.src[17] = gate_w1; pa.dst[17] = g1t;
  pa.src[18] = gate_w2; pa.dst[18] = g2t;
  prep_weights<<<dim3(1024, 19), 256, 0, stream>>>(pa);

  const int EW_GRID = (BT_ * C_) / 256;  // 16384
  xin_k<<<EW_GRID, 256, 0, stream>>>(x, maa_x, xinb);

  gemm_bt<1><<<dim3(64, 3), 256, 0, stream>>>(xinb, C_, w1t, C_, mixb, 192, C_);

  Mix6Args ma;
  ma.maa[0] = maa_r; ma.maa[1] = maa_w; ma.maa[2] = maa_k;
  ma.maa[3] = maa_v; ma.maa[4] = maa_a; ma.maa[5] = maa_g;
  for (int s = 0; s < 6; ++s) ma.out[s] = xbr[s];
  mix_combine<<<dim3(64, 16, 6), 256, 0, stream>>>(mixb, w2t, x, ma);

  // r, k, v batched (one launch, bf16 out)
  RkvArgs ra;
  ra.A[0] = xbr[0]; ra.Bt[0] = WtR; ra.Cq[0] = rb;
  ra.A[1] = xbr[2]; ra.Bt[1] = WtK; ra.Cq[1] = kb;
  ra.A[2] = xbr[3]; ra.Bt[2] = WtV; ra.Cq[2] = vb;
  gemm128_rkv<<<dim3(32, 8, 3), 256, 0, stream>>>(ra);

  // batched small projections: k1 (tanh), d1 (tanh), a1 (raw), g1 (tanh)
  Proj4Args p4;
  p4.A[0] = xbr[2]; p4.Bt[0] = k1t; p4.out[0] = h64k; p4.N[0] = 64;  p4.tnh[0] = 1;
  p4.A[1] = xbr[1]; p4.Bt[1] = d1t; p4.out[1] = h64d; p4.N[1] = 64;  p4.tnh[1] = 1;
  p4.A[2] = xbr[4]; p4.Bt[2] = a1t; p4.out[2] = h64a; p4.N[2] = 64;  p4.tnh[2] = 0;
  p4.A[3] = xbr[5]; p4.Bt[3] = g1t; p4.out[3] = h128b; p4.N[3] = 128; p4.tnh[3] = 1;
  proj4<<<dim3(64, 2, 4), 256, 0, stream>>>(p4);

  // kk path (uses UNscaled k)
  gemm128<0><<<dim3(32, 8), 256, 0, stream>>>(h64k, 64, k2t, 64, mtmp, C_, 64, nullptr, nullptr);
  kk_normalize<<<BT_, 256, 0, stream>>>(kb, mtmp, kkb);

  // w path: fused finalize epilogue (writes lwb bf16, scales kb in place)
  gemm128<3><<<dim3(32, 8), 256, 0, stream>>>(h64d, 64, d2t, 64, lwb, C_, 64, tdec, kb);

  // a path: fused sigmoid epilogue (bf16)
  gemm128<4><<<dim3(32, 8), 256, 0, stream>>>(h64a, 64, a2t, 64, aamt, C_, 64, aaaaa, nullptr);

  // g path -> bf16 gate buffer
  gemm128<2><<<dim3(32, 8), 256, 0, stream>>>(h128b, 128, g2t, 128, gbb, C_, 128, nullptr, nullptr);

  // ---- chunked scan ----
  rwkv_chunk_pre<<<CHD, 256, 0, stream>>>(rb, lwb, kb, kkb, aamt, vb,
      wbufb, sabufb, abybufb, ckybufb, ubufP, mbufT);
  rwkv_chunk_state<<<32, 256, 0, stream>>>(mbufT, ubufP, s0bufb);
  rwkv_chunk_out<<<CHD, 256, 0, stream>>>(rb, lwb, vb, s0bufb, wbufb, sabufb,
      abybufb, ckybufb, (float*)d_out);

  gn_bonus_gate<<<BT_, 256, 0, stream>>>((const float*)d_out, rb, kb, vb, gbb,
                                         faaaa, lnw, lnb, zb);

  gemm128<0><<<dim3(32, 8), 256, 0, stream>>>(zb, C_, WtO, C_, d_out, C_, C_, nullptr, nullptr);
}

// Round 12
// 320.291 us; speedup vs baseline: 5.1013x; 1.0278x over previous
//
#include <hip/hip_runtime.h>
#include <hip/hip_bf16.h>

using bf16 = __hip_bfloat16;
using bf16x8 = __attribute__((ext_vector_type(8))) short;  // 8 bf16 (4 VGPRs)
using f32x4 = __attribute__((ext_vector_type(4))) float;

#define B_ 2
#define T_ 2048
#define C_ 1024
#define BT_ (B_*T_)
#define H_ 16
#define N_ 64
#define LCH 32            // scan chunk length
#define NCH (T_/LCH)      // 64 chunks per head
#define CHD (B_*H_*NCH)   // 2048 chunk-heads

__device__ __forceinline__ float allred64(float v) {
#pragma unroll
  for (int m = 1; m < 64; m <<= 1) v += __shfl_xor(v, m, 64);
  return v;
}

__device__ __forceinline__ bf16 tobf(float f) { return __float2bfloat16(f); }
__device__ __forceinline__ float frombf(bf16 b) { return __bfloat162float(b); }
__device__ __forceinline__ float bf2f(unsigned short u) {
  unsigned int x = ((unsigned int)u) << 16;
  return __builtin_bit_cast(float, x);
}
__device__ __forceinline__ unsigned short bfbits(float f) {
  return __builtin_bit_cast(unsigned short, __float2bfloat16(f));
}
__device__ __forceinline__ float rdlane(float v, int m) {
  return __builtin_bit_cast(float,
      __builtin_amdgcn_readlane(__builtin_bit_cast(int, v), m));
}

__device__ __forceinline__ f32x4 mfma16x16x32(bf16x8 a, bf16x8 b, f32x4 c) {
  return __builtin_amdgcn_mfma_f32_16x16x32_bf16(a, b, c, 0, 0, 0);
}

// async global->LDS, 16B per lane (dest = wave-uniform base + lane*16)
typedef const __attribute__((address_space(1))) unsigned int* gas_ptr;
typedef __attribute__((address_space(3))) unsigned int* las_ptr;
__device__ __forceinline__ void gload16(const void* g, void* l) {
  __builtin_amdgcn_global_load_lds((gas_ptr)g, (las_ptr)l, 16, 0, 0);
}

// ---------------- ws_size diagnostic ----------------------------------------
__global__ void ws_diag(float a, float b, float* out) { out[0] = a; out[1] = b; }

// ---------------- weight transpose + bf16 cast (19 jobs, one launch) -------
struct PrepArgs {
  const float* src[19];
  bf16* dst[19];
};
__constant__ int kTR[19] = {1024,1024,1024,1024, 1024, 32,32,32,32,32,32,
                            1024,64, 1024,64, 1024,64, 1024,128};
__constant__ int kTC[19] = {1024,1024,1024,1024, 192, 1024,1024,1024,1024,1024,1024,
                            64,1024, 64,1024, 64,1024, 128,1024};

__global__ __launch_bounds__(256) void prep_weights(PrepArgs pa) {
  const int job = blockIdx.y;
  const int R = kTR[job], Cc = kTC[job];
  const int ntx = Cc >> 5, nty = R >> 5;
  const int tile = blockIdx.x;
  if (tile >= ntx * nty) return;
  const int tx = tile % ntx, ty = tile / ntx;
  const float* __restrict__ src = pa.src[job];
  bf16* __restrict__ dst = pa.dst[job];
  __shared__ float tl[32][33];
  const int lx = threadIdx.x & 31, ly = threadIdx.x >> 5;  // 32 x 8
#pragma unroll
  for (int q = 0; q < 4; ++q)
    tl[ly + 8*q][lx] = src[(size_t)(ty*32 + ly + 8*q) * Cc + tx*32 + lx];
  __syncthreads();
#pragma unroll
  for (int q = 0; q < 4; ++q)
    dst[(size_t)(tx*32 + ly + 8*q) * R + ty*32 + lx] = tobf(tl[lx][ly + 8*q]);
}

// ------- GEMM 64-tile -------------------------------------------------------
template<int EPI>
__global__ __launch_bounds__(256) void gemm_bt(
    const bf16* __restrict__ A, int lda,
    const bf16* __restrict__ Bt, int ldb,
    void* __restrict__ Cout, int ldc, int K)
{
  __shared__ short As[64][40];
  __shared__ short Bs[64][40];
  const int bm0 = blockIdx.x * 64;
  const int bn0 = blockIdx.y * 64;
  const int tid = threadIdx.x;
  const int wave = tid >> 6, lane = tid & 63;
  const int lm = lane & 15, kg = lane >> 4;
  const int srow = tid >> 2, scol = (tid & 3) * 8;
  f32x4 acc[4] = {};
  const size_t abase = (size_t)(bm0 + srow) * lda + scol;
  const size_t bbase = (size_t)(bn0 + srow) * ldb + scol;
  for (int k0 = 0; k0 < K; k0 += 32) {
    *(uint4*)&As[srow][scol] = *(const uint4*)(A + abase + k0);
    *(uint4*)&Bs[srow][scol] = *(const uint4*)(Bt + bbase + k0);
    __syncthreads();
    bf16x8 af = *(const bf16x8*)&As[wave*16 + lm][kg*8];
#pragma unroll
    for (int f = 0; f < 4; ++f) {
      bf16x8 bfr = *(const bf16x8*)&Bs[f*16 + lm][kg*8];
      acc[f] = mfma16x16x32(af, bfr, acc[f]);
    }
    __syncthreads();
  }
  const int row0 = bm0 + wave*16 + kg*4;
  const int col0 = bn0 + lm;
#pragma unroll
  for (int f = 0; f < 4; ++f) {
#pragma unroll
    for (int q = 0; q < 4; ++q) {
      float val = acc[f][q];
      size_t o = (size_t)(row0 + q) * ldc + col0 + f*16;
      if (EPI == 0)      ((float*)Cout)[o] = val;
      else if (EPI == 1) ((bf16*)Cout)[o] = tobf(tanhf(val));
      else               ((bf16*)Cout)[o] = tobf(val);
    }
  }
}

// ------- batched small projections: k1/d1/a1 (N=64) + g1 (N=128) -----------
struct Proj4Args { const bf16* A[4]; const bf16* Bt[4]; bf16* out[4];
                   int N[4]; int tnh[4]; };
__global__ __launch_bounds__(256) void proj4(Proj4Args p4) {
  const int z = blockIdx.z;
  const int Nn = p4.N[z];
  const int bn0 = blockIdx.y * 64;
  if (bn0 >= Nn) return;
  __shared__ short As[64][40];
  __shared__ short Bs[64][40];
  const bf16* __restrict__ A  = p4.A[z];
  const bf16* __restrict__ Bt = p4.Bt[z];
  bf16* __restrict__ out = p4.out[z];
  const int tnh = p4.tnh[z];
  const int bm0 = blockIdx.x * 64;
  const int tid = threadIdx.x;
  const int wave = tid >> 6, lane = tid & 63;
  const int lm = lane & 15, kg = lane >> 4;
  const int srow = tid >> 2, scol = (tid & 3) * 8;
  f32x4 acc[4] = {};
  const size_t abase = (size_t)(bm0 + srow) * C_ + scol;
  const size_t bbase = (size_t)(bn0 + srow) * C_ + scol;
  for (int k0 = 0; k0 < C_; k0 += 32) {
    *(uint4*)&As[srow][scol] = *(const uint4*)(A + abase + k0);
    *(uint4*)&Bs[srow][scol] = *(const uint4*)(Bt + bbase + k0);
    __syncthreads();
    bf16x8 af = *(const bf16x8*)&As[wave*16 + lm][kg*8];
#pragma unroll
    for (int f = 0; f < 4; ++f) {
      bf16x8 bfr = *(const bf16x8*)&Bs[f*16 + lm][kg*8];
      acc[f] = mfma16x16x32(af, bfr, acc[f]);
    }
    __syncthreads();
  }
  const int row0 = bm0 + wave*16 + kg*4;
  const int col0 = bn0 + lm;
#pragma unroll
  for (int f = 0; f < 4; ++f) {
#pragma unroll
    for (int q = 0; q < 4; ++q) {
      float val = acc[f][q];
      size_t o = (size_t)(row0 + q) * Nn + col0 + f*16;
      out[o] = tobf(tnh ? tanhf(val) : val);
    }
  }
}

// ------- GEMM 128-tile, m97 structure (global_load_lds staging) -------------
// EPI: 2 bf16 | 3 w-finalize (Cout=lw bf16, aux1=td, aux2=k bf16 inplace)
//      4 a-finalize (Cout=aamt bf16, aux1=aaaaa)
template<int EPI>
__global__ __launch_bounds__(256) void gemm128(
    const bf16* __restrict__ A, int lda,
    const bf16* __restrict__ Bt, int ldb,
    void* __restrict__ Cout, int ldc, int K,
    const float* __restrict__ aux1, bf16* __restrict__ aux2)
{
  __shared__ bf16 As[128][32];     // linear (required by global_load_lds)
  __shared__ bf16 Bs[128][32];
  const int bm0 = blockIdx.x * 128, bn0 = blockIdx.y * 128;
  const int tid = threadIdx.x, wv = tid >> 6, ln = tid & 63;
  const int wr = wv >> 1, wc = wv & 1;
  const int lm = ln & 15, kg = ln >> 4;
  const int srow = ln >> 2, scol = (ln & 3) * 8;
  f32x4 acc[4][4] = {};
  for (int k0 = 0; k0 < K; k0 += 32) {
#pragma unroll
    for (int i = 0; i < 2; ++i) {
      const int r0 = wv*32 + i*16;
      gload16(A  + (size_t)(bm0 + r0 + srow) * lda + k0 + scol, &As[r0][0]);
      gload16(Bt + (size_t)(bn0 + r0 + srow) * ldb + k0 + scol, &Bs[r0][0]);
    }
    asm volatile("s_waitcnt vmcnt(0)" ::: "memory");
    __syncthreads();
    bf16x8 af[4], bfr[4];
#pragma unroll
    for (int m = 0; m < 4; ++m) af[m] = *(const bf16x8*)&As[wr*64 + m*16 + lm][kg*8];
#pragma unroll
    for (int n = 0; n < 4; ++n) bfr[n] = *(const bf16x8*)&Bs[wc*64 + n*16 + lm][kg*8];
#pragma unroll
    for (int m = 0; m < 4; ++m)
#pragma unroll
      for (int n = 0; n < 4; ++n)
        acc[m][n] = mfma16x16x32(af[m], bfr[n], acc[m][n]);
    __syncthreads();
  }
#pragma unroll
  for (int m = 0; m < 4; ++m) {
    const int row0 = bm0 + wr*64 + m*16 + kg*4;
#pragma unroll
    for (int n = 0; n < 4; ++n) {
      const int col = bn0 + wc*64 + n*16 + lm;
#pragma unroll
      for (int q = 0; q < 4; ++q) {
        float val = acc[m][n][q];
        size_t o = (size_t)(row0 + q) * ldc + col;
        if (EPI == 0)      ((float*)Cout)[o] = val;
        else if (EPI == 2) ((bf16*)Cout)[o] = tobf(val);
        else if (EPI == 3) {
          float wr2 = val + aux1[col];
          float sp = fmaxf(-wr2, 0.f) + log1pf(expf(-fabsf(wr2)));
          float w = -sp - 0.5f;
          ((bf16*)Cout)[o] = tobf(-expf(w));                       // lw
          aux2[o] = tobf(frombf(aux2[o]) * expf(fminf(0.5f*w, 0.f))); // k scale
        } else if (EPI == 4) {
          float z = aux1[col] + val;
          ((bf16*)Cout)[o] = tobf(2.f / (1.f + expf(-z)));
        }
      }
    }
  }
}

// batched r/k/v: same shape (M=4096, N=1024, K=1024), bf16 outputs
struct RkvArgs { const bf16* A[3]; const bf16* Bt[3]; bf16* Cq[3]; };
__global__ __launch_bounds__(256) void gemm128_rkv(RkvArgs ra) {
  __shared__ bf16 As[128][32];
  __shared__ bf16 Bs[128][32];
  const bf16* __restrict__ A  = ra.A[blockIdx.z];
  const bf16* __restrict__ Bt = ra.Bt[blockIdx.z];
  bf16* __restrict__ Cout = ra.Cq[blockIdx.z];
  const int bm0 = blockIdx.x * 128, bn0 = blockIdx.y * 128;
  const int tid = threadIdx.x, wv = tid >> 6, ln = tid & 63;
  const int wr = wv >> 1, wc = wv & 1;
  const int lm = ln & 15, kg = ln >> 4;
  const int srow = ln >> 2, scol = (ln & 3) * 8;
  f32x4 acc[4][4] = {};
  for (int k0 = 0; k0 < C_; k0 += 32) {
#pragma unroll
    for (int i = 0; i < 2; ++i) {
      const int r0 = wv*32 + i*16;
      gload16(A  + (size_t)(bm0 + r0 + srow) * C_ + k0 + scol, &As[r0][0]);
      gload16(Bt + (size_t)(bn0 + r0 + srow) * C_ + k0 + scol, &Bs[r0][0]);
    }
    asm volatile("s_waitcnt vmcnt(0)" ::: "memory");
    __syncthreads();
    bf16x8 af[4], bfr[4];
#pragma unroll
    for (int m = 0; m < 4; ++m) af[m] = *(const bf16x8*)&As[wr*64 + m*16 + lm][kg*8];
#pragma unroll
    for (int n = 0; n < 4; ++n) bfr[n] = *(const bf16x8*)&Bs[wc*64 + n*16 + lm][kg*8];
#pragma unroll
    for (int m = 0; m < 4; ++m)
#pragma unroll
      for (int n = 0; n < 4; ++n)
        acc[m][n] = mfma16x16x32(af[m], bfr[n], acc[m][n]);
    __syncthreads();
  }
#pragma unroll
  for (int m = 0; m < 4; ++m) {
    const int row0 = bm0 + wr*64 + m*16 + kg*4;
#pragma unroll
    for (int n = 0; n < 4; ++n) {
      const int col = bn0 + wc*64 + n*16 + lm;
#pragma unroll
      for (int q = 0; q < 4; ++q)
        Cout[(size_t)(row0 + q) * C_ + col] = tobf(acc[m][n][q]);
    }
  }
}

// --------- fused 6-branch low-rank projection + combine (bf16 x copy) -------
struct Mix6Args { const float* maa[6]; bf16* out[6]; };

__global__ __launch_bounds__(256) void mix_combine(
    const bf16* __restrict__ mixb, const bf16* __restrict__ w2t,
    const bf16* __restrict__ xb, Mix6Args ma)
{
  __shared__ short As[64][40];
  __shared__ short Bs[64][40];
  const int s6 = blockIdx.z;
  const bf16* __restrict__ A  = mixb + s6*32;            // lda = 192
  const bf16* __restrict__ Bt = w2t + (size_t)s6*C_*32;  // ldb = 32
  const float* __restrict__ maa = ma.maa[s6];
  bf16* __restrict__ out = ma.out[s6];
  const int bm0 = blockIdx.x * 64, bn0 = blockIdx.y * 64;
  const int tid = threadIdx.x, wave = tid >> 6, lane = tid & 63;
  const int lm = lane & 15, kg = lane >> 4;
  const int srow = tid >> 2, scol = (tid & 3) * 8;
  *(uint4*)&As[srow][scol] = *(const uint4*)(A + (size_t)(bm0 + srow)*192 + scol);
  *(uint4*)&Bs[srow][scol] = *(const uint4*)(Bt + (size_t)(bn0 + srow)*32 + scol);
  __syncthreads();
  bf16x8 af = *(const bf16x8*)&As[wave*16 + lm][kg*8];
  f32x4 acc[4] = {};
#pragma unroll
  for (int f = 0; f < 4; ++f) {
    bf16x8 bfr = *(const bf16x8*)&Bs[f*16 + lm][kg*8];
    acc[f] = mfma16x16x32(af, bfr, acc[f]);
  }
  const int row0 = bm0 + wave*16 + kg*4;
  const int col0 = bn0 + lm;
#pragma unroll
  for (int f = 0; f < 4; ++f) {
#pragma unroll
    for (int q = 0; q < 4; ++q) {
      const int row = row0 + q, col = col0 + f*16;
      const size_t o = (size_t)row * C_ + col;
      float xv = frombf(xb[o]);
      float xp = (row & (T_ - 1)) ? frombf(xb[o - C_]) : 0.f;
      out[o] = tobf(xv + (xp - xv) * (maa[col] + acc[f][q]));
    }
  }
}

// ---------------- elementwise ----------------------------------------------
__global__ __launch_bounds__(256) void xin_k(
    const float* __restrict__ x, const float* __restrict__ maa_x,
    bf16* __restrict__ xinb, bf16* __restrict__ xb)
{
  size_t idx = (size_t)blockIdx.x * 256 + threadIdx.x;
  int c = idx & (C_ - 1);
  int t = (int)((idx >> 10) & (T_ - 1));
  float xv = x[idx];
  float xp = t ? x[idx - C_] : 0.f;
  xinb[idx] = tobf(xv + (xp - xv) * maa_x[c]);
  xb[idx] = tobf(xv);
}

__global__ __launch_bounds__(256) void kk_normalize(
    const bf16* __restrict__ kraw, const bf16* __restrict__ kkadd,
    bf16* __restrict__ kkout)
{
  const int bt = blockIdx.x;
  const int tid = threadIdx.x;
  const size_t o = (size_t)bt * C_;
  float vals[4]; float ss = 0.f;
#pragma unroll
  for (int q = 0; q < 4; ++q) {
    float u = frombf(kraw[o + tid + q*256]) + frombf(kkadd[o + tid + q*256]);
    vals[q] = u; ss += u * u;
  }
  ss = allred64(ss);
  __shared__ float red[4];
  const int wave = tid >> 6, lane = tid & 63;
  if (lane == 0) red[wave] = ss;
  __syncthreads();
  float tot = red[0] + red[1] + red[2] + red[3];
  float inv = 1.f / fmaxf(sqrtf(tot), 1e-12f);
#pragma unroll
  for (int q = 0; q < 4; ++q) kkout[o + tid + q*256] = tobf(vals[q] * inv);
}

// ============ Chunked RWKV-7 scan (fp32 recurrence, bf16 MFMA phases) =======
//   SA = (I-trilA)^{-1}(Achk S0^T + trilC V) = W S0^T + SA_loc
//   y[s] = rt_s S0^T + tril<=(ABy) SA + tril<=(CKy) V
//   S_L = S0 * M + U  with M = diag(dL) + (W^T Bt).*dL_j
// LDS alias: {aCb,rCb} (dead after solve-init) overlays {WT,SAT} -> 48 KB,
// 3 blocks/CU. Solve-init preloads aCb into registers behind a barrier.

__global__ __launch_bounds__(256, 3) void rwkv_chunk_pre(
    const bf16* __restrict__ rr, const bf16* __restrict__ lw,
    const bf16* __restrict__ kk_s, const bf16* __restrict__ kkv,
    const bf16* __restrict__ aam, const bf16* __restrict__ vv,
    bf16* __restrict__ wbufb, bf16* __restrict__ sabufb,
    bf16* __restrict__ abybufb, bf16* __restrict__ ckybufb,
    bf16* __restrict__ ubufP, bf16* __restrict__ mbufT)
{
  __shared__ float Am[LCH][33], Cm[LCH][33];
  __shared__ float wtot[4][64];
  __shared__ float lcl[64];
  __shared__ bf16 bTb[LCH][72], kTb[LCH][72], vLb[LCH][72];
  __shared__ bf16 bTT[64][40], kTT[64][40], vLT[64][40];
  __shared__ bf16 uni[5120];   // {aCb,rCb}[32][72] (4608) | {WT,SAT}[64][40] (5120)
  bf16 (*aCb)[72] = (bf16(*)[72])uni;
  bf16 (*rCb)[72] = (bf16(*)[72])(uni + 2304);
  bf16 (*WT)[40]  = (bf16(*)[40])uni;
  bf16 (*SAT)[40] = (bf16(*)[40])(uni + 2560);

  const int ch = blockIdx.x;
  const int c  = ch & (NCH - 1);
  const int bh = ch >> 6;
  const int b  = bh >> 4, h = bh & 15;
  const int tid = threadIdx.x, wv = tid >> 6, ln = tid & 63;
  const int lm = ln & 15, kg = ln >> 4;
  const size_t base = ((size_t)(b*T_ + c*LCH) * C_) + h*N_ + ln;

  // --- phase 1: cumulative log-decay + load/scale into LDS (both layouts) ---
  float lwr[8], lcE[8];
  {
    float run = 0.f;
#pragma unroll
    for (int q = 0; q < 8; ++q) {
      lwr[q] = frombf(lw[base + (size_t)(wv*8 + q) * C_]);
      lcE[q] = run; run += lwr[q];
    }
    wtot[wv][ln] = run;
  }
  __syncthreads();
  {
    float pre = 0.f;
    for (int w2 = 0; w2 < wv; ++w2) pre += wtot[w2][ln];
    if (wv == 0) lcl[ln] = wtot[0][ln] + wtot[1][ln] + wtot[2][ln] + wtot[3][ln];
#pragma unroll
    for (int q = 0; q < 8; ++q) lcE[q] += pre;
  }
#pragma unroll
  for (int q = 0; q < 8; ++q) {
    const int s = wv*8 + q;
    const size_t off = base + (size_t)s * C_;
    float kkx = frombf(kkv[off]), aax = frombf(aam[off]);
    float kx = frombf(kk_s[off]), rx = frombf(rr[off]);
    float lcI = lcE[q] + lwr[q];
    float eIm = __expf(-lcI);
    float av = -kkx * __expf(lcE[q]);
    float bv = kkx * aax * eIm;
    float kv2 = kx * eIm;
    float rv = rx * __expf(lcI);
    bf16 vxb = vv[off];
    aCb[s][ln] = tobf(av);  rCb[s][ln] = tobf(rv);
    bTb[s][ln] = tobf(bv);  kTb[s][ln] = tobf(kv2);
    vLb[s][ln] = vxb;
    bTT[ln][s] = tobf(bv);  kTT[ln][s] = tobf(kv2);  vLT[ln][s] = vxb;
  }
  __syncthreads();

  // --- phase 2: MFMA, one 32x32 (K=64) product per wave ---
  {
    const bf16 (*Ab)[72] = (wv < 2) ? aCb : rCb;
    const bf16 (*Bb)[72] = (wv & 1) ? kTb : bTb;
#pragma unroll
    for (int mt = 0; mt < 2; ++mt)
#pragma unroll
      for (int nt = 0; nt < 2; ++nt) {
        f32x4 acc = {};
#pragma unroll
        for (int ks = 0; ks < 2; ++ks) {
          bf16x8 af = *(const bf16x8*)&Ab[mt*16 + lm][ks*32 + kg*8];
          bf16x8 bq = *(const bf16x8*)&Bb[nt*16 + lm][ks*32 + kg*8];
          acc = mfma16x16x32(af, bq, acc);
        }
        const int row0 = mt*16 + kg*4, col = nt*16 + lm;
#pragma unroll
        for (int q = 0; q < 4; ++q) {
          float v = acc[q];
          if (wv == 0)      Am[row0+q][col] = v;
          else if (wv == 1) Cm[row0+q][col] = v;
          else {
            bf16 bv2 = tobf(col <= row0+q ? v : 0.f);  // tril<= mask
            if (wv == 2) abybufb[(size_t)ch*1024 + (row0+q)*32 + col] = bv2;
            else         ckybufb[(size_t)ch*1024 + (row0+q)*32 + col] = bv2;
          }
        }
      }
  }
  __syncthreads();

  // --- phase 3a: preload solve inputs to registers (aCb/Cm/vLb reads) ------
  float Xr[32], amr[32];
  if (wv == 0) {
#pragma unroll
    for (int s = 0; s < 32; ++s) amr[s] = Am[s][ln & 31];
#pragma unroll
    for (int s = 0; s < 32; ++s) Xr[s] = frombf(aCb[s][ln]);
  } else if (wv == 1) {
    float cmr[32];
#pragma unroll
    for (int s = 0; s < 32; ++s) { amr[s] = Am[s][ln & 31]; cmr[s] = Cm[s][ln & 31]; }
#pragma unroll
    for (int s = 0; s < 32; ++s) Xr[s] = 0.f;
#pragma unroll
    for (int u = 0; u < 31; ++u) {
      float v = frombf(vLb[u][ln]);
#pragma unroll
      for (int s = u + 1; s < 32; ++s) Xr[s] += rdlane(cmr[s], u) * v;
    }
  }
  __syncthreads();   // aCb reads complete before WT/SAT writes into alias

  // --- phase 3b: register forward-substitution; write WT/SAT --------------
  if (wv < 2) {
#pragma unroll
    for (int s = 1; s < 32; ++s) {
      float acc = Xr[s];
#pragma unroll
      for (int u = 0; u < s; ++u) acc += rdlane(amr[s], u) * Xr[u];
      Xr[s] = acc;
    }
    if (wv == 0) {
#pragma unroll
      for (int s = 0; s < 32; ++s) {
        bf16 bv = tobf(Xr[s]);
        WT[ln][s] = bv;
        wbufb[(size_t)ch*2048 + s*64 + ln] = bv;
      }
    } else {
#pragma unroll
      for (int s = 0; s < 32; ++s) {
        bf16 bv = tobf(Xr[s]);
        SAT[ln][s] = bv;
        sabufb[(size_t)ch*2048 + s*64 + ln] = bv;
      }
    }
  }
  __syncthreads();

  // --- phase 5: U, M (64x64, K=32) via MFMA; packed-layout b64 stores ------
  {
    const int mt = wv;
    bf16x8 aS = *(const bf16x8*)&SAT[mt*16 + lm][kg*8];
    bf16x8 aV = *(const bf16x8*)&vLT[mt*16 + lm][kg*8];
    bf16x8 aW = *(const bf16x8*)&WT[mt*16 + lm][kg*8];
#pragma unroll
    for (int nt = 0; nt < 4; ++nt) {
      bf16x8 bB = *(const bf16x8*)&bTT[nt*16 + lm][kg*8];
      bf16x8 bK = *(const bf16x8*)&kTT[nt*16 + lm][kg*8];
      f32x4 aU = {}, aG = {};
      aU = mfma16x16x32(aS, bB, aU);
      aU = mfma16x16x32(aV, bK, aU);
      aG = mfma16x16x32(aW, bB, aG);
      const int i0r = mt*16 + kg*4, col = nt*16 + lm;
      float dl = __expf(lcl[col]);
      uint2 up;
      up.x = (unsigned int)bfbits(aU[0]*dl) | ((unsigned int)bfbits(aU[1]*dl) << 16);
      up.y = (unsigned int)bfbits(aU[2]*dl) | ((unsigned int)bfbits(aU[3]*dl) << 16);
      *(uint2*)(ubufP + (size_t)ch*4096 + (mt*4 + nt)*256 + ln*4) = up;
      float m0 = (aG[0] + (i0r+0 == col ? 1.f : 0.f)) * dl;
      float m1 = (aG[1] + (i0r+1 == col ? 1.f : 0.f)) * dl;
      float m2 = (aG[2] + (i0r+2 == col ? 1.f : 0.f)) * dl;
      float m3 = (aG[3] + (i0r+3 == col ? 1.f : 0.f)) * dl;
      uint2 mp;
      mp.x = (unsigned int)bfbits(m0) | ((unsigned int)bfbits(m1) << 16);
      mp.y = (unsigned int)bfbits(m2) | ((unsigned int)bfbits(m3) << 16);
      const int laned = (((mt*2) + (kg >> 1)) & 3) * 16 + lm;
      *(uint2*)(mbufT + (size_t)ch*4096 + (nt*2 + (mt >> 1))*512
                + laned*8 + (kg & 1)*4) = mp;
    }
  }
}

// Phase B: serial over chunks; 32 blocks (one per bh) x 4 waves, no barriers.
__global__ __launch_bounds__(256) void rwkv_chunk_state(
    const bf16* __restrict__ mbufT, const bf16* __restrict__ ubufP,
    bf16* __restrict__ s0bufb)
{
  __shared__ bf16 Sst[4][16][72];
  const int bh = blockIdx.x;
  const int tid = threadIdx.x, wv = tid >> 6, ln = tid & 63;
  const int lm = ln & 15, kg = ln >> 4;

#pragma unroll
  for (int r = 0; r < 16; ++r) {
    Sst[wv][r][ln] = tobf(0.f);
    if (ln < 8) Sst[wv][r][64 + ln] = tobf(0.f);
  }

  bf16x8 BfA[4][2], BfB[4][2];
  uint2 UpA[4], UpB[4];
  auto prefetch = [&](bf16x8 (&Bf)[4][2], uint2 (&Up)[4], int c) {
    const size_t chp = (size_t)(bh*NCH + c) * 4096;
#pragma unroll
    for (int nt = 0; nt < 4; ++nt) {
      Bf[nt][0] = *(const bf16x8*)(mbufT + chp + (nt*2 + 0)*512 + ln*8);
      Bf[nt][1] = *(const bf16x8*)(mbufT + chp + (nt*2 + 1)*512 + ln*8);
      Up[nt]    = *(const uint2*) (ubufP + chp + (wv*4 + nt)*256 + ln*4);
    }
  };
  prefetch(BfA, UpA, 0);
  prefetch(BfB, UpB, 1);

  auto body = [&](bf16x8 (&Bf)[4][2], uint2 (&Up)[4], int c) {
    const size_t ch4 = (size_t)(bh*NCH + c) * 4096;
    const int sr = ln >> 2, sc = (ln & 3) * 16;
    uint4 v0 = *(const uint4*)&Sst[wv][sr][sc];
    uint4 v1 = *(const uint4*)&Sst[wv][sr][sc + 8];
    *(uint4*)(s0bufb + ch4 + (size_t)(wv*16 + sr)*64 + sc) = v0;
    *(uint4*)(s0bufb + ch4 + (size_t)(wv*16 + sr)*64 + sc + 8) = v1;
    bf16x8 A0 = *(const bf16x8*)&Sst[wv][lm][kg*8];
    bf16x8 A1 = *(const bf16x8*)&Sst[wv][lm][32 + kg*8];
    f32x4 acc[4];
#pragma unroll
    for (int nt = 0; nt < 4; ++nt) {
      acc[nt][0] = bf2f((unsigned short)(Up[nt].x & 0xffff));
      acc[nt][1] = bf2f((unsigned short)(Up[nt].x >> 16));
      acc[nt][2] = bf2f((unsigned short)(Up[nt].y & 0xffff));
      acc[nt][3] = bf2f((unsigned short)(Up[nt].y >> 16));
      acc[nt] = mfma16x16x32(A0, Bf[nt][0], acc[nt]);
      acc[nt] = mfma16x16x32(A1, Bf[nt][1], acc[nt]);
    }
    int cp = c + 2; if (cp > NCH - 1) cp = NCH - 1;
    prefetch(Bf, Up, cp);
#pragma unroll
    for (int nt = 0; nt < 4; ++nt)
#pragma unroll
      for (int q = 0; q < 4; ++q)
        Sst[wv][kg*4 + q][nt*16 + lm] = tobf(acc[nt][q]);
  };

  for (int cc = 0; cc < NCH; cc += 2) {
    body(BfA, UpA, cc);
    body(BfB, UpB, cc + 1);
  }
}

// Phase C: per chunk-head, MFMA: SA = W*S0^T + SAll, then
// y = Rt*S0^T + ABl*SAo + CKl*V  (ABl/CKl pre-masked tril<=).
__global__ __launch_bounds__(256, 4) void rwkv_chunk_out(
    const bf16* __restrict__ rr, const bf16* __restrict__ lw,
    const bf16* __restrict__ vv, const bf16* __restrict__ s0bufb,
    const bf16* __restrict__ wbufb, const bf16* __restrict__ sabufb,
    const bf16* __restrict__ abybufb, const bf16* __restrict__ ckybufb,
    float* __restrict__ y)
{
  __shared__ bf16 S0b[64][72];                    // B^T layout: [i][j]
  __shared__ bf16 Wb[LCH][72], Rlb[LCH][72];      // A layouts: [s][j]
  __shared__ bf16 ABl[LCH][40], CKl[LCH][40];     // A layouts: [s][u]
  __shared__ bf16 SAot[64][40], VlT[64][40];      // B^T layouts: [i][u]
  __shared__ float wtot[4][64];
  const int ch = blockIdx.x;
  const int c = ch & (NCH - 1), bh = ch >> 6, b = bh >> 4, h = bh & 15;
  const int tid = threadIdx.x, wv = tid >> 6, ln = tid & 63;
  const int lm = ln & 15, kg = ln >> 4;
  const size_t base = ((size_t)(b*T_ + c*LCH) * C_) + h*N_ + ln;

  float lwr[8], lcE[8];
  {
    float run = 0.f;
#pragma unroll
    for (int q = 0; q < 8; ++q) {
      lwr[q] = frombf(lw[base + (size_t)(wv*8 + q) * C_]);
      lcE[q] = run; run += lwr[q];
    }
    wtot[wv][ln] = run;
  }
  __syncthreads();
  {
    float pre = 0.f;
    for (int w2 = 0; w2 < wv; ++w2) pre += wtot[w2][ln];
#pragma unroll
    for (int q = 0; q < 8; ++q) lcE[q] += pre;
  }
#pragma unroll
  for (int q = 0; q < 8; ++q) {
    const int s = wv*8 + q;
    const size_t off = base + (size_t)s * C_;
    Rlb[s][ln] = tobf(frombf(rr[off]) * __expf(lcE[q] + lwr[q]));
    VlT[ln][s] = vv[off];
  }
#pragma unroll
  for (int t = 0; t < 2; ++t) {
    int cc2 = tid*2 + t; int ri = cc2 >> 3, co = (cc2 & 7) * 8;
    *(uint4*)&S0b[ri][co] = *(const uint4*)(s0bufb + (size_t)ch*4096 + ri*64 + co);
  }
  { int ri = tid >> 3, co = (tid & 7) * 8;
    *(uint4*)&Wb[ri][co] = *(const uint4*)(wbufb + (size_t)ch*2048 + ri*64 + co); }
  if (tid < 128) {
    int ri = tid >> 2, co = (tid & 3) * 8;
    *(uint4*)&ABl[ri][co] = *(const uint4*)(abybufb + (size_t)ch*1024 + ri*32 + co);
  } else {
    int t2 = tid - 128; int ri = t2 >> 2, co = (t2 & 3) * 8;
    *(uint4*)&CKl[ri][co] = *(const uint4*)(ckybufb + (size_t)ch*1024 + ri*32 + co);
  }
  __syncthreads();

  const int mt = wv >> 1, ntb = (wv & 1) * 2;
#pragma unroll
  for (int t = 0; t < 2; ++t) {
    const int nt = ntb + t;
    const int row0 = mt*16 + kg*4, col = nt*16 + lm;
    f32x4 acc;
#pragma unroll
    for (int q = 0; q < 4; ++q)
      acc[q] = frombf(sabufb[(size_t)ch*2048 + (row0+q)*64 + col]);
#pragma unroll
    for (int ks = 0; ks < 2; ++ks) {
      bf16x8 af = *(const bf16x8*)&Wb[mt*16 + lm][ks*32 + kg*8];
      bf16x8 bq = *(const bf16x8*)&S0b[nt*16 + lm][ks*32 + kg*8];
      acc = mfma16x16x32(af, bq, acc);
    }
#pragma unroll
    for (int q = 0; q < 4; ++q) SAot[col][row0+q] = tobf(acc[q]);
  }
  __syncthreads();

#pragma unroll
  for (int t = 0; t < 2; ++t) {
    const int nt = ntb + t;
    f32x4 acc = {};
#pragma unroll
    for (int ks = 0; ks < 2; ++ks) {
      bf16x8 af = *(const bf16x8*)&Rlb[mt*16 + lm][ks*32 + kg*8];
      bf16x8 bq = *(const bf16x8*)&S0b[nt*16 + lm][ks*32 + kg*8];
      acc = mfma16x16x32(af, bq, acc);
    }
    {
      bf16x8 af = *(const bf16x8*)&ABl[mt*16 + lm][kg*8];
      bf16x8 bq = *(const bf16x8*)&SAot[nt*16 + lm][kg*8];
      acc = mfma16x16x32(af, bq, acc);
    }
    {
      bf16x8 af = *(const bf16x8*)&CKl[mt*16 + lm][kg*8];
      bf16x8 bq = *(const bf16x8*)&VlT[nt*16 + lm][kg*8];
      acc = mfma16x16x32(af, bq, acc);
    }
    const int row0 = mt*16 + kg*4, col = nt*16 + lm;
#pragma unroll
    for (int q = 0; q < 4; ++q)
      y[((size_t)(b*T_ + c*LCH + row0 + q)) * C_ + h*N_ + col] = acc[q];
  }
}

// ---------------- groupnorm + bonus + gate ---------------------------------
__global__ __launch_bounds__(256) void gn_bonus_gate(
    const float* __restrict__ y, const bf16* __restrict__ rr,
    const bf16* __restrict__ kk_s, const bf16* __restrict__ vv,
    const bf16* __restrict__ gg, const float* __restrict__ faaaa,
    const float* __restrict__ lnw, const float* __restrict__ lnb,
    bf16* __restrict__ zb)
{
  const int bt = blockIdx.x;
  const int wave = threadIdx.x >> 6, lane = threadIdx.x & 63;
  const float inv64 = 1.f / 64.f;
  for (int h = wave; h < H_; h += 4) {
    const int c = h * 64 + lane;
    const size_t o = (size_t)bt * C_ + c;
    float yv = y[o];
    float mean = allred64(yv) * inv64;
    float d = yv - mean;
    float var = allred64(d * d) * inv64;
    float xn = d * rsqrtf(var + 6.4e-4f);
    float gn = xn * lnw[c] + lnb[c];
    float rk = allred64(frombf(rr[o]) * frombf(kk_s[o]) * faaaa[c]);
    float z = (gn + rk * frombf(vv[o])) * frombf(gg[o]);
    zb[o] = tobf(z);
  }
}

// ---------------- driver ----------------------------------------------------
extern "C" void kernel_launch(void* const* d_in, const int* in_sizes, int n_in,
                              void* d_out, int out_size, void* d_ws, size_t ws_size,
                              hipStream_t stream)
{
  const float* x     = (const float*)d_in[0];
  const float* maa_x = (const float*)d_in[1];
  const float* maa_r = (const float*)d_in[2];
  const float* maa_w = (const float*)d_in[3];
  const float* maa_k = (const float*)d_in[4];
  const float* maa_v = (const float*)d_in[5];
  const float* maa_a = (const float*)d_in[6];
  const float* maa_g = (const float*)d_in[7];
  const float* tdec  = (const float*)d_in[8];
  const float* faaaa = (const float*)d_in[9];
  const float* aaaaa = (const float*)d_in[10];
  const float* maa_w1= (const float*)d_in[11];
  const float* maa_w2= (const float*)d_in[12];
  const float* dec_w1= (const float*)d_in[13];
  const float* dec_w2= (const float*)d_in[14];
  const float* aaa_w1= (const float*)d_in[15];
  const float* aaa_w2= (const float*)d_in[16];
  const float* kkk_w1= (const float*)d_in[17];
  const float* kkk_w2= (const float*)d_in[18];
  const float* gate_w1=(const float*)d_in[19];
  const float* gate_w2=(const float*)d_in[20];
  const float* W_r   = (const float*)d_in[21];
  const float* W_k   = (const float*)d_in[22];
  const float* W_v   = (const float*)d_in[23];
  const float* W_o   = (const float*)d_in[24];
  const float* lnw   = (const float*)d_in[25];
  const float* lnb   = (const float*)d_in[26];

  char* ws = (char*)d_ws;
  size_t cur = 0;
  auto alloc = [&](size_t bytes) -> void* {
    void* p = ws + cur; cur += (bytes + 255) & ~(size_t)255; return p;
  };
  const size_t HBT = (size_t)BT_ * C_ * 2;  // bf16 activation buffer

  // ---- persistent (activations bf16) ----
  bf16* rb   = (bf16*)alloc(HBT);
  bf16* kb   = (bf16*)alloc(HBT);
  bf16* vb   = (bf16*)alloc(HBT);
  bf16* gbb  = (bf16*)alloc(HBT);
  bf16* WtR  = (bf16*)alloc((size_t)C_*C_*2);
  bf16* WtK  = (bf16*)alloc((size_t)C_*C_*2);
  bf16* WtV  = (bf16*)alloc((size_t)C_*C_*2);
  bf16* WtO  = (bf16*)alloc((size_t)C_*C_*2);
  bf16* w1t  = (bf16*)alloc((size_t)192*C_*2);
  bf16* w2t  = (bf16*)alloc((size_t)6*C_*32*2);
  bf16* d1t  = (bf16*)alloc((size_t)64*C_*2);
  bf16* d2t  = (bf16*)alloc((size_t)C_*64*2);
  bf16* a1t  = (bf16*)alloc((size_t)64*C_*2);
  bf16* a2t  = (bf16*)alloc((size_t)C_*64*2);
  bf16* k1t  = (bf16*)alloc((size_t)64*C_*2);
  bf16* k2t  = (bf16*)alloc((size_t)C_*64*2);
  bf16* g1t  = (bf16*)alloc((size_t)128*C_*2);
  bf16* g2t  = (bf16*)alloc((size_t)C_*128*2);
  bf16* lwb  = (bf16*)alloc(HBT);
  // kkb + aamt (bf16, 8MB each, contiguous) dead after chunk_pre;
  // s0bufb (16MB) overlays both.
  bf16* kkb  = (bf16*)alloc(HBT);
  bf16* aamt = (bf16*)alloc(HBT);
  bf16* s0bufb = kkb;                 // CHD*4096*2 == 2*HBT exactly

  // ---- union region ----
  const size_t ubase = cur;
  bf16* mtmpb = (bf16*)alloc(HBT);
  bf16* xinb = (bf16*)alloc(HBT);
  bf16* xb   = (bf16*)alloc(HBT);
  bf16* mixb = (bf16*)alloc((size_t)BT_*192*2);
  bf16* xbr[6];
  for (int s = 0; s < 6; ++s) xbr[s] = (bf16*)alloc(HBT);
  bf16* h64k = (bf16*)alloc((size_t)BT_*64*2);
  bf16* h64d = (bf16*)alloc((size_t)BT_*64*2);
  bf16* h64a = (bf16*)alloc((size_t)BT_*64*2);
  bf16* h128b= (bf16*)alloc((size_t)BT_*128*2);
  const size_t tmp_end = cur;
  cur = ubase;  // overlay
  bf16*  wbufb   = (bf16*)alloc((size_t)CHD*2048*2);
  bf16*  sabufb  = (bf16*)alloc((size_t)CHD*2048*2);
  bf16*  abybufb = (bf16*)alloc((size_t)CHD*1024*2);
  bf16*  ckybufb = (bf16*)alloc((size_t)CHD*1024*2);
  bf16*  ubufP   = (bf16*)alloc((size_t)CHD*4096*2);
  bf16*  mbufT   = (bf16*)alloc((size_t)CHD*4096*2);
  bf16*  zb      = (bf16*)ubufP;   // alias: ubufP dead after chunk_state
  if (tmp_end > cur) cur = tmp_end;
  const size_t need = cur;
  (void)in_sizes; (void)n_in; (void)out_size;

  if (ws_size < need) {
    ws_diag<<<1, 1, 0, stream>>>((float)ws_size, (float)need, (float*)d_out);
    return;
  }

  PrepArgs pa;
  pa.src[0] = W_r;  pa.dst[0] = WtR;
  pa.src[1] = W_k;  pa.dst[1] = WtK;
  pa.src[2] = W_v;  pa.dst[2] = WtV;
  pa.src[3] = W_o;  pa.dst[3] = WtO;
  pa.src[4] = maa_w1; pa.dst[4] = w1t;
  for (int s = 0; s < 6; ++s) { pa.src[5+s] = maa_w2 + (size_t)s*32*C_; pa.dst[5+s] = w2t + (size_t)s*C_*32; }
  pa.src[11] = dec_w1; pa.dst[11] = d1t;
  pa.src[12] = dec_w2; pa.dst[12] = d2t;
  pa.src[13] = aaa_w1; pa.dst[13] = a1t;
  pa.src[14] = aaa_w2; pa.dst[14] = a2t;
  pa.src[15] = kkk_w1; pa.dst[15] = k1t;
  pa.src[16] = kkk_w2; pa.dst[16] = k2t;
  pa.src[17] = gate_w1; pa.dst[17] = g1t;
  pa.src[18] = gate_w2; pa.dst[18] = g2t;
  prep_weights<<<dim3(1024, 19), 256, 0, stream>>>(pa);

  const int EW_GRID = (BT_ * C_) / 256;  // 16384
  xin_k<<<EW_GRID, 256, 0, stream>>>(x, maa_x, xinb, xb);

  gemm_bt<1><<<dim3(64, 3), 256, 0, stream>>>(xinb, C_, w1t, C_, mixb, 192, C_);

  Mix6Args ma;
  ma.maa[0] = maa_r; ma.maa[1] = maa_w; ma.maa[2] = maa_k;
  ma.maa[3] = maa_v; ma.maa[4] = maa_a; ma.maa[5] = maa_g;
  for (int s = 0; s < 6; ++s) ma.out[s] = xbr[s];
  mix_combine<<<dim3(64, 16, 6), 256, 0, stream>>>(mixb, w2t, xb, ma);

  // r, k, v batched (one launch, bf16 out)
  RkvArgs ra;
  ra.A[0] = xbr[0]; ra.Bt[0] = WtR; ra.Cq[0] = rb;
  ra.A[1] = xbr[2]; ra.Bt[1] = WtK; ra.Cq[1] = kb;
  ra.A[2] = xbr[3]; ra.Bt[2] = WtV; ra.Cq[2] = vb;
  gemm128_rkv<<<dim3(32, 8, 3), 256, 0, stream>>>(ra);

  // batched small projections: k1 (tanh), d1 (tanh), a1 (raw), g1 (tanh)
  Proj4Args p4;
  p4.A[0] = xbr[2]; p4.Bt[0] = k1t; p4.out[0] = h64k; p4.N[0] = 64;  p4.tnh[0] = 1;
  p4.A[1] = xbr[1]; p4.Bt[1] = d1t; p4.out[1] = h64d; p4.N[1] = 64;  p4.tnh[1] = 1;
  p4.A[2] = xbr[4]; p4.Bt[2] = a1t; p4.out[2] = h64a; p4.N[2] = 64;  p4.tnh[2] = 0;
  p4.A[3] = xbr[5]; p4.Bt[3] = g1t; p4.out[3] = h128b; p4.N[3] = 128; p4.tnh[3] = 1;
  proj4<<<dim3(64, 2, 4), 256, 0, stream>>>(p4);

  // kk path (uses UNscaled k); bf16 intermediate
  gemm128<2><<<dim3(32, 8), 256, 0, stream>>>(h64k, 64, k2t, 64, mtmpb, C_, 64, nullptr, nullptr);
  kk_normalize<<<BT_, 256, 0, stream>>>(kb, mtmpb, kkb);

  // w path: fused finalize epilogue (writes lwb bf16, scales kb in place)
  gemm128<3><<<dim3(32, 8), 256, 0, stream>>>(h64d, 64, d2t, 64, lwb, C_, 64, tdec, kb);

  // a path: fused sigmoid epilogue (bf16)
  gemm128<4><<<dim3(32, 8), 256, 0, stream>>>(h64a, 64, a2t, 64, aamt, C_, 64, aaaaa, nullptr);

  // g path -> bf16 gate buffer
  gemm128<2><<<dim3(32, 8), 256, 0, stream>>>(h128b, 128, g2t, 128, gbb, C_, 128, nullptr, nullptr);

  // ---- chunked scan ----
  rwkv_chunk_pre<<<CHD, 256, 0, stream>>>(rb, lwb, kb, kkb, aamt, vb,
      wbufb, sabufb, abybufb, ckybufb, ubufP, mbufT);
  rwkv_chunk_state<<<32, 256, 0, stream>>>(mbufT, ubufP, s0bufb);
  rwkv_chunk_out<<<CHD, 256, 0, stream>>>(rb, lwb, vb, s0bufb, wbufb, sabufb,
      abybufb, ckybufb, (float*)d_out);

  gn_bonus_gate<<<BT_, 256, 0, stream>>>((const float*)d_out, rb, kb, vb, gbb,
                                         faaaa, lnw, lnb, zb);

  gemm128<0><<<dim3(32, 8), 256, 0, stream>>>(zb, C_, WtO, C_, d_out, C_, C_, nullptr, nullptr);
}

// Round 13
// 311.709 us; speedup vs baseline: 5.2418x; 1.0275x over previous
//
#include <hip/hip_runtime.h>
#include <hip/hip_bf16.h>

using bf16 = __hip_bfloat16;
using bf16x8 = __attribute__((ext_vector_type(8))) short;  // 8 bf16 (4 VGPRs)
using f32x4 = __attribute__((ext_vector_type(4))) float;

#define B_ 2
#define T_ 2048
#define C_ 1024
#define BT_ (B_*T_)
#define H_ 16
#define N_ 64
#define LCH 32            // scan chunk length
#define NCH (T_/LCH)      // 64 chunks per head
#define CHD (B_*H_*NCH)   // 2048 chunk-heads

__device__ __forceinline__ float allred64(float v) {
#pragma unroll
  for (int m = 1; m < 64; m <<= 1) v += __shfl_xor(v, m, 64);
  return v;
}

__device__ __forceinline__ bf16 tobf(float f) { return __float2bfloat16(f); }
__device__ __forceinline__ float frombf(bf16 b) { return __bfloat162float(b); }
__device__ __forceinline__ float bf2f(unsigned short u) {
  unsigned int x = ((unsigned int)u) << 16;
  return __builtin_bit_cast(float, x);
}
__device__ __forceinline__ unsigned short bfbits(float f) {
  return __builtin_bit_cast(unsigned short, __float2bfloat16(f));
}
__device__ __forceinline__ float rdlane(float v, int m) {
  return __builtin_bit_cast(float,
      __builtin_amdgcn_readlane(__builtin_bit_cast(int, v), m));
}

__device__ __forceinline__ f32x4 mfma16x16x32(bf16x8 a, bf16x8 b, f32x4 c) {
  return __builtin_amdgcn_mfma_f32_16x16x32_bf16(a, b, c, 0, 0, 0);
}

// async global->LDS, 16B per lane (dest = wave-uniform base + lane*16)
typedef const __attribute__((address_space(1))) unsigned int* gas_ptr;
typedef __attribute__((address_space(3))) unsigned int* las_ptr;
__device__ __forceinline__ void gload16(const void* g, void* l) {
  __builtin_amdgcn_global_load_lds((gas_ptr)g, (las_ptr)l, 16, 0, 0);
}

// ---------------- ws_size diagnostic ----------------------------------------
__global__ void ws_diag(float a, float b, float* out) { out[0] = a; out[1] = b; }

// ---------------- weight transpose + bf16 cast (19 jobs, one launch) -------
struct PrepArgs {
  const float* src[19];
  bf16* dst[19];
};
__constant__ int kTR[19] = {1024,1024,1024,1024, 1024, 32,32,32,32,32,32,
                            1024,64, 1024,64, 1024,64, 1024,128};
__constant__ int kTC[19] = {1024,1024,1024,1024, 192, 1024,1024,1024,1024,1024,1024,
                            64,1024, 64,1024, 64,1024, 128,1024};

__global__ __launch_bounds__(256) void prep_weights(PrepArgs pa) {
  const int job = blockIdx.y;
  const int R = kTR[job], Cc = kTC[job];
  const int ntx = Cc >> 5, nty = R >> 5;
  const int tile = blockIdx.x;
  if (tile >= ntx * nty) return;
  const int tx = tile % ntx, ty = tile / ntx;
  const float* __restrict__ src = pa.src[job];
  bf16* __restrict__ dst = pa.dst[job];
  __shared__ float tl[32][33];
  const int lx = threadIdx.x & 31, ly = threadIdx.x >> 5;  // 32 x 8
#pragma unroll
  for (int q = 0; q < 4; ++q)
    tl[ly + 8*q][lx] = src[(size_t)(ty*32 + ly + 8*q) * Cc + tx*32 + lx];
  __syncthreads();
#pragma unroll
  for (int q = 0; q < 4; ++q)
    dst[(size_t)(tx*32 + ly + 8*q) * R + ty*32 + lx] = tobf(tl[lx][ly + 8*q]);
}

// ------- GEMM 64-tile -------------------------------------------------------
template<int EPI>
__global__ __launch_bounds__(256) void gemm_bt(
    const bf16* __restrict__ A, int lda,
    const bf16* __restrict__ Bt, int ldb,
    void* __restrict__ Cout, int ldc, int K)
{
  __shared__ short As[64][40];
  __shared__ short Bs[64][40];
  const int bm0 = blockIdx.x * 64;
  const int bn0 = blockIdx.y * 64;
  const int tid = threadIdx.x;
  const int wave = tid >> 6, lane = tid & 63;
  const int lm = lane & 15, kg = lane >> 4;
  const int srow = tid >> 2, scol = (tid & 3) * 8;
  f32x4 acc[4] = {};
  const size_t abase = (size_t)(bm0 + srow) * lda + scol;
  const size_t bbase = (size_t)(bn0 + srow) * ldb + scol;
  for (int k0 = 0; k0 < K; k0 += 32) {
    *(uint4*)&As[srow][scol] = *(const uint4*)(A + abase + k0);
    *(uint4*)&Bs[srow][scol] = *(const uint4*)(Bt + bbase + k0);
    __syncthreads();
    bf16x8 af = *(const bf16x8*)&As[wave*16 + lm][kg*8];
#pragma unroll
    for (int f = 0; f < 4; ++f) {
      bf16x8 bfr = *(const bf16x8*)&Bs[f*16 + lm][kg*8];
      acc[f] = mfma16x16x32(af, bfr, acc[f]);
    }
    __syncthreads();
  }
  const int row0 = bm0 + wave*16 + kg*4;
  const int col0 = bn0 + lm;
#pragma unroll
  for (int f = 0; f < 4; ++f) {
#pragma unroll
    for (int q = 0; q < 4; ++q) {
      float val = acc[f][q];
      size_t o = (size_t)(row0 + q) * ldc + col0 + f*16;
      if (EPI == 0)      ((float*)Cout)[o] = val;
      else if (EPI == 1) ((bf16*)Cout)[o] = tobf(tanhf(val));
      else               ((bf16*)Cout)[o] = tobf(val);
    }
  }
}

// ------- batched small projections: k1/d1/a1 (N=64) + g1 (N=128) -----------
struct Proj4Args { const bf16* A[4]; const bf16* Bt[4]; bf16* out[4];
                   int N[4]; int tnh[4]; };
__global__ __launch_bounds__(256) void proj4(Proj4Args p4) {
  const int z = blockIdx.z;
  const int Nn = p4.N[z];
  const int bn0 = blockIdx.y * 64;
  if (bn0 >= Nn) return;
  __shared__ short As[64][40];
  __shared__ short Bs[64][40];
  const bf16* __restrict__ A  = p4.A[z];
  const bf16* __restrict__ Bt = p4.Bt[z];
  bf16* __restrict__ out = p4.out[z];
  const int tnh = p4.tnh[z];
  const int bm0 = blockIdx.x * 64;
  const int tid = threadIdx.x;
  const int wave = tid >> 6, lane = tid & 63;
  const int lm = lane & 15, kg = lane >> 4;
  const int srow = tid >> 2, scol = (tid & 3) * 8;
  f32x4 acc[4] = {};
  const size_t abase = (size_t)(bm0 + srow) * C_ + scol;
  const size_t bbase = (size_t)(bn0 + srow) * C_ + scol;
  for (int k0 = 0; k0 < C_; k0 += 32) {
    *(uint4*)&As[srow][scol] = *(const uint4*)(A + abase + k0);
    *(uint4*)&Bs[srow][scol] = *(const uint4*)(Bt + bbase + k0);
    __syncthreads();
    bf16x8 af = *(const bf16x8*)&As[wave*16 + lm][kg*8];
#pragma unroll
    for (int f = 0; f < 4; ++f) {
      bf16x8 bfr = *(const bf16x8*)&Bs[f*16 + lm][kg*8];
      acc[f] = mfma16x16x32(af, bfr, acc[f]);
    }
    __syncthreads();
  }
  const int row0 = bm0 + wave*16 + kg*4;
  const int col0 = bn0 + lm;
#pragma unroll
  for (int f = 0; f < 4; ++f) {
#pragma unroll
    for (int q = 0; q < 4; ++q) {
      float val = acc[f][q];
      size_t o = (size_t)(row0 + q) * Nn + col0 + f*16;
      out[o] = tobf(tnh ? tanhf(val) : val);
    }
  }
}

// ------- GEMM 128-tile, m97 structure (global_load_lds staging) -------------
// EPI: 0 f32 | 2 bf16 | 3 w-finalize (Cout=lw bf16, aux1=td, aux2=k bf16 inplace)
//      4 a-finalize (Cout=aamt bf16, aux1=aaaaa)
template<int EPI>
__global__ __launch_bounds__(256) void gemm128(
    const bf16* __restrict__ A, int lda,
    const bf16* __restrict__ Bt, int ldb,
    void* __restrict__ Cout, int ldc, int K,
    const float* __restrict__ aux1, bf16* __restrict__ aux2)
{
  __shared__ bf16 As[128][32];     // linear (required by global_load_lds)
  __shared__ bf16 Bs[128][32];
  const int bm0 = blockIdx.x * 128, bn0 = blockIdx.y * 128;
  const int tid = threadIdx.x, wv = tid >> 6, ln = tid & 63;
  const int wr = wv >> 1, wc = wv & 1;
  const int lm = ln & 15, kg = ln >> 4;
  const int srow = ln >> 2, scol = (ln & 3) * 8;
  f32x4 acc[4][4] = {};
  for (int k0 = 0; k0 < K; k0 += 32) {
#pragma unroll
    for (int i = 0; i < 2; ++i) {
      const int r0 = wv*32 + i*16;
      gload16(A  + (size_t)(bm0 + r0 + srow) * lda + k0 + scol, &As[r0][0]);
      gload16(Bt + (size_t)(bn0 + r0 + srow) * ldb + k0 + scol, &Bs[r0][0]);
    }
    asm volatile("s_waitcnt vmcnt(0)" ::: "memory");
    __syncthreads();
    bf16x8 af[4], bfr[4];
#pragma unroll
    for (int m = 0; m < 4; ++m) af[m] = *(const bf16x8*)&As[wr*64 + m*16 + lm][kg*8];
#pragma unroll
    for (int n = 0; n < 4; ++n) bfr[n] = *(const bf16x8*)&Bs[wc*64 + n*16 + lm][kg*8];
#pragma unroll
    for (int m = 0; m < 4; ++m)
#pragma unroll
      for (int n = 0; n < 4; ++n)
        acc[m][n] = mfma16x16x32(af[m], bfr[n], acc[m][n]);
    __syncthreads();
  }
#pragma unroll
  for (int m = 0; m < 4; ++m) {
    const int row0 = bm0 + wr*64 + m*16 + kg*4;
#pragma unroll
    for (int n = 0; n < 4; ++n) {
      const int col = bn0 + wc*64 + n*16 + lm;
#pragma unroll
      for (int q = 0; q < 4; ++q) {
        float val = acc[m][n][q];
        size_t o = (size_t)(row0 + q) * ldc + col;
        if (EPI == 0)      ((float*)Cout)[o] = val;
        else if (EPI == 2) ((bf16*)Cout)[o] = tobf(val);
        else if (EPI == 3) {
          float wr2 = val + aux1[col];
          float sp = fmaxf(-wr2, 0.f) + log1pf(expf(-fabsf(wr2)));
          float w = -sp - 0.5f;
          ((bf16*)Cout)[o] = tobf(-expf(w));                       // lw
          aux2[o] = tobf(frombf(aux2[o]) * expf(fminf(0.5f*w, 0.f))); // k scale
        } else if (EPI == 4) {
          float z = aux1[col] + val;
          ((bf16*)Cout)[o] = tobf(2.f / (1.f + expf(-z)));
        }
      }
    }
  }
}

// batched r/k/v: same shape (M=4096, N=1024, K=1024), bf16 outputs
struct RkvArgs { const bf16* A[3]; const bf16* Bt[3]; bf16* Cq[3]; };
__global__ __launch_bounds__(256) void gemm128_rkv(RkvArgs ra) {
  __shared__ bf16 As[128][32];
  __shared__ bf16 Bs[128][32];
  const bf16* __restrict__ A  = ra.A[blockIdx.z];
  const bf16* __restrict__ Bt = ra.Bt[blockIdx.z];
  bf16* __restrict__ Cout = ra.Cq[blockIdx.z];
  const int bm0 = blockIdx.x * 128, bn0 = blockIdx.y * 128;
  const int tid = threadIdx.x, wv = tid >> 6, ln = tid & 63;
  const int wr = wv >> 1, wc = wv & 1;
  const int lm = ln & 15, kg = ln >> 4;
  const int srow = ln >> 2, scol = (ln & 3) * 8;
  f32x4 acc[4][4] = {};
  for (int k0 = 0; k0 < C_; k0 += 32) {
#pragma unroll
    for (int i = 0; i < 2; ++i) {
      const int r0 = wv*32 + i*16;
      gload16(A  + (size_t)(bm0 + r0 + srow) * C_ + k0 + scol, &As[r0][0]);
      gload16(Bt + (size_t)(bn0 + r0 + srow) * C_ + k0 + scol, &Bs[r0][0]);
    }
    asm volatile("s_waitcnt vmcnt(0)" ::: "memory");
    __syncthreads();
    bf16x8 af[4], bfr[4];
#pragma unroll
    for (int m = 0; m < 4; ++m) af[m] = *(const bf16x8*)&As[wr*64 + m*16 + lm][kg*8];
#pragma unroll
    for (int n = 0; n < 4; ++n) bfr[n] = *(const bf16x8*)&Bs[wc*64 + n*16 + lm][kg*8];
#pragma unroll
    for (int m = 0; m < 4; ++m)
#pragma unroll
      for (int n = 0; n < 4; ++n)
        acc[m][n] = mfma16x16x32(af[m], bfr[n], acc[m][n]);
    __syncthreads();
  }
#pragma unroll
  for (int m = 0; m < 4; ++m) {
    const int row0 = bm0 + wr*64 + m*16 + kg*4;
#pragma unroll
    for (int n = 0; n < 4; ++n) {
      const int col = bn0 + wc*64 + n*16 + lm;
#pragma unroll
      for (int q = 0; q < 4; ++q)
        Cout[(size_t)(row0 + q) * C_ + col] = tobf(acc[m][n][q]);
    }
  }
}

// --------- fused 6-branch low-rank projection + combine (bf16 x copy) -------
struct Mix6Args { const float* maa[6]; bf16* out[6]; };

__global__ __launch_bounds__(256) void mix_combine(
    const bf16* __restrict__ mixb, const bf16* __restrict__ w2t,
    const bf16* __restrict__ xb, Mix6Args ma)
{
  __shared__ short As[64][40];
  __shared__ short Bs[64][40];
  const int s6 = blockIdx.z;
  const bf16* __restrict__ A  = mixb + s6*32;            // lda = 192
  const bf16* __restrict__ Bt = w2t + (size_t)s6*C_*32;  // ldb = 32
  const float* __restrict__ maa = ma.maa[s6];
  bf16* __restrict__ out = ma.out[s6];
  const int bm0 = blockIdx.x * 64, bn0 = blockIdx.y * 64;
  const int tid = threadIdx.x, wave = tid >> 6, lane = tid & 63;
  const int lm = lane & 15, kg = lane >> 4;
  const int srow = tid >> 2, scol = (tid & 3) * 8;
  *(uint4*)&As[srow][scol] = *(const uint4*)(A + (size_t)(bm0 + srow)*192 + scol);
  *(uint4*)&Bs[srow][scol] = *(const uint4*)(Bt + (size_t)(bn0 + srow)*32 + scol);
  __syncthreads();
  bf16x8 af = *(const bf16x8*)&As[wave*16 + lm][kg*8];
  f32x4 acc[4] = {};
#pragma unroll
  for (int f = 0; f < 4; ++f) {
    bf16x8 bfr = *(const bf16x8*)&Bs[f*16 + lm][kg*8];
    acc[f] = mfma16x16x32(af, bfr, acc[f]);
  }
  const int row0 = bm0 + wave*16 + kg*4;
  const int col0 = bn0 + lm;
#pragma unroll
  for (int f = 0; f < 4; ++f) {
#pragma unroll
    for (int q = 0; q < 4; ++q) {
      const int row = row0 + q, col = col0 + f*16;
      const size_t o = (size_t)row * C_ + col;
      float xv = frombf(xb[o]);
      float xp = (row & (T_ - 1)) ? frombf(xb[o - C_]) : 0.f;
      out[o] = tobf(xv + (xp - xv) * (maa[col] + acc[f][q]));
    }
  }
}

// ---------------- elementwise ----------------------------------------------
__global__ __launch_bounds__(256) void xin_k(
    const float* __restrict__ x, const float* __restrict__ maa_x,
    bf16* __restrict__ xinb, bf16* __restrict__ xb)
{
  size_t idx = (size_t)blockIdx.x * 256 + threadIdx.x;
  int c = idx & (C_ - 1);
  int t = (int)((idx >> 10) & (T_ - 1));
  float xv = x[idx];
  float xp = t ? x[idx - C_] : 0.f;
  xinb[idx] = tobf(xv + (xp - xv) * maa_x[c]);
  xb[idx] = tobf(xv);
}

__global__ __launch_bounds__(256) void kk_normalize(
    const bf16* __restrict__ kraw, const bf16* __restrict__ kkadd,
    bf16* __restrict__ kkout)
{
  const int bt = blockIdx.x;
  const int tid = threadIdx.x;
  const size_t o = (size_t)bt * C_;
  float vals[4]; float ss = 0.f;
#pragma unroll
  for (int q = 0; q < 4; ++q) {
    float u = frombf(kraw[o + tid + q*256]) + frombf(kkadd[o + tid + q*256]);
    vals[q] = u; ss += u * u;
  }
  ss = allred64(ss);
  __shared__ float red[4];
  const int wave = tid >> 6, lane = tid & 63;
  if (lane == 0) red[wave] = ss;
  __syncthreads();
  float tot = red[0] + red[1] + red[2] + red[3];
  float inv = 1.f / fmaxf(sqrtf(tot), 1e-12f);
#pragma unroll
  for (int q = 0; q < 4; ++q) kkout[o + tid + q*256] = tobf(vals[q] * inv);
}

// ============ Chunked RWKV-7 scan (fp32 recurrence, bf16 MFMA phases) =======
//   SA = (I-trilA)^{-1}(Achk S0^T + trilC V) = W S0^T + SA_loc
//   y[s] = rt_s S0^T + tril<=(ABy) SA + tril<=(CKy) V
//   S_L = S0 * M + U  with M = diag(dL) + (W^T Bt).*dL_j
// LDS alias: {aCb,rCb} (dead after solve-init) overlays {WT,SAT} -> 48 KB.

__global__ __launch_bounds__(256, 3) void rwkv_chunk_pre(
    const bf16* __restrict__ rr, const bf16* __restrict__ lw,
    const bf16* __restrict__ kk_s, const bf16* __restrict__ kkv,
    const bf16* __restrict__ aam, const bf16* __restrict__ vv,
    bf16* __restrict__ wbufb, bf16* __restrict__ sabufb,
    bf16* __restrict__ abybufb, bf16* __restrict__ ckybufb,
    bf16* __restrict__ ubufP, bf16* __restrict__ mbufT)
{
  __shared__ float Am[LCH][33], Cm[LCH][33];
  __shared__ float wtot[4][64];
  __shared__ float lcl[64];
  __shared__ bf16 bTb[LCH][72], kTb[LCH][72], vLb[LCH][72];
  __shared__ bf16 bTT[64][40], kTT[64][40], vLT[64][40];
  __shared__ bf16 uni[5120];   // {aCb,rCb}[32][72] | {WT,SAT}[64][40]
  bf16 (*aCb)[72] = (bf16(*)[72])uni;
  bf16 (*rCb)[72] = (bf16(*)[72])(uni + 2304);
  bf16 (*WT)[40]  = (bf16(*)[40])uni;
  bf16 (*SAT)[40] = (bf16(*)[40])(uni + 2560);

  const int ch = blockIdx.x;
  const int c  = ch & (NCH - 1);
  const int bh = ch >> 6;
  const int b  = bh >> 4, h = bh & 15;
  const int tid = threadIdx.x, wv = tid >> 6, ln = tid & 63;
  const int lm = ln & 15, kg = ln >> 4;
  const size_t base = ((size_t)(b*T_ + c*LCH) * C_) + h*N_ + ln;

  // --- phase 1: cumulative log-decay + load/scale into LDS (both layouts) ---
  float lwr[8], lcE[8];
  {
    float run = 0.f;
#pragma unroll
    for (int q = 0; q < 8; ++q) {
      lwr[q] = frombf(lw[base + (size_t)(wv*8 + q) * C_]);
      lcE[q] = run; run += lwr[q];
    }
    wtot[wv][ln] = run;
  }
  __syncthreads();
  {
    float pre = 0.f;
    for (int w2 = 0; w2 < wv; ++w2) pre += wtot[w2][ln];
    if (wv == 0) lcl[ln] = wtot[0][ln] + wtot[1][ln] + wtot[2][ln] + wtot[3][ln];
#pragma unroll
    for (int q = 0; q < 8; ++q) lcE[q] += pre;
  }
#pragma unroll
  for (int q = 0; q < 8; ++q) {
    const int s = wv*8 + q;
    const size_t off = base + (size_t)s * C_;
    float kkx = frombf(kkv[off]), aax = frombf(aam[off]);
    float kx = frombf(kk_s[off]), rx = frombf(rr[off]);
    float lcI = lcE[q] + lwr[q];
    float eIm = __expf(-lcI);
    float av = -kkx * __expf(lcE[q]);
    float bv = kkx * aax * eIm;
    float kv2 = kx * eIm;
    float rv = rx * __expf(lcI);
    bf16 vxb = vv[off];
    aCb[s][ln] = tobf(av);  rCb[s][ln] = tobf(rv);
    bTb[s][ln] = tobf(bv);  kTb[s][ln] = tobf(kv2);
    vLb[s][ln] = vxb;
    bTT[ln][s] = tobf(bv);  kTT[ln][s] = tobf(kv2);  vLT[ln][s] = vxb;
  }
  __syncthreads();

  // --- phase 2: MFMA, one 32x32 (K=64) product per wave ---
  {
    const bf16 (*Ab)[72] = (wv < 2) ? aCb : rCb;
    const bf16 (*Bb)[72] = (wv & 1) ? kTb : bTb;
#pragma unroll
    for (int mt = 0; mt < 2; ++mt)
#pragma unroll
      for (int nt = 0; nt < 2; ++nt) {
        f32x4 acc = {};
#pragma unroll
        for (int ks = 0; ks < 2; ++ks) {
          bf16x8 af = *(const bf16x8*)&Ab[mt*16 + lm][ks*32 + kg*8];
          bf16x8 bq = *(const bf16x8*)&Bb[nt*16 + lm][ks*32 + kg*8];
          acc = mfma16x16x32(af, bq, acc);
        }
        const int row0 = mt*16 + kg*4, col = nt*16 + lm;
#pragma unroll
        for (int q = 0; q < 4; ++q) {
          float v = acc[q];
          if (wv == 0)      Am[row0+q][col] = v;
          else if (wv == 1) Cm[row0+q][col] = v;
          else {
            bf16 bv2 = tobf(col <= row0+q ? v : 0.f);  // tril<= mask
            if (wv == 2) abybufb[(size_t)ch*1024 + (row0+q)*32 + col] = bv2;
            else         ckybufb[(size_t)ch*1024 + (row0+q)*32 + col] = bv2;
          }
        }
      }
  }
  __syncthreads();

  // --- phase 3a: preload solve inputs to registers (aCb/Cm/vLb reads) ------
  float Xr[32], amr[32];
  if (wv == 0) {
#pragma unroll
    for (int s = 0; s < 32; ++s) amr[s] = Am[s][ln & 31];
#pragma unroll
    for (int s = 0; s < 32; ++s) Xr[s] = frombf(aCb[s][ln]);
  } else if (wv == 1) {
    float cmr[32];
#pragma unroll
    for (int s = 0; s < 32; ++s) { amr[s] = Am[s][ln & 31]; cmr[s] = Cm[s][ln & 31]; }
#pragma unroll
    for (int s = 0; s < 32; ++s) Xr[s] = 0.f;
#pragma unroll
    for (int u = 0; u < 31; ++u) {
      float v = frombf(vLb[u][ln]);
#pragma unroll
      for (int s = u + 1; s < 32; ++s) Xr[s] += rdlane(cmr[s], u) * v;
    }
  }
  __syncthreads();   // aCb reads complete before WT/SAT writes into alias

  // --- phase 3b: register forward-substitution; write WT/SAT --------------
  if (wv < 2) {
#pragma unroll
    for (int s = 1; s < 32; ++s) {
      float acc = Xr[s];
#pragma unroll
      for (int u = 0; u < s; ++u) acc += rdlane(amr[s], u) * Xr[u];
      Xr[s] = acc;
    }
    if (wv == 0) {
#pragma unroll
      for (int s = 0; s < 32; ++s) {
        bf16 bv = tobf(Xr[s]);
        WT[ln][s] = bv;
        wbufb[(size_t)ch*2048 + s*64 + ln] = bv;
      }
    } else {
#pragma unroll
      for (int s = 0; s < 32; ++s) {
        bf16 bv = tobf(Xr[s]);
        SAT[ln][s] = bv;
        sabufb[(size_t)ch*2048 + s*64 + ln] = bv;
      }
    }
  }
  __syncthreads();

  // --- phase 5: U, M (64x64, K=32) via MFMA; packed-layout b64 stores ------
  {
    const int mt = wv;
    bf16x8 aS = *(const bf16x8*)&SAT[mt*16 + lm][kg*8];
    bf16x8 aV = *(const bf16x8*)&vLT[mt*16 + lm][kg*8];
    bf16x8 aW = *(const bf16x8*)&WT[mt*16 + lm][kg*8];
#pragma unroll
    for (int nt = 0; nt < 4; ++nt) {
      bf16x8 bB = *(const bf16x8*)&bTT[nt*16 + lm][kg*8];
      bf16x8 bK = *(const bf16x8*)&kTT[nt*16 + lm][kg*8];
      f32x4 aU = {}, aG = {};
      aU = mfma16x16x32(aS, bB, aU);
      aU = mfma16x16x32(aV, bK, aU);
      aG = mfma16x16x32(aW, bB, aG);
      const int i0r = mt*16 + kg*4, col = nt*16 + lm;
      float dl = __expf(lcl[col]);
      uint2 up;
      up.x = (unsigned int)bfbits(aU[0]*dl) | ((unsigned int)bfbits(aU[1]*dl) << 16);
      up.y = (unsigned int)bfbits(aU[2]*dl) | ((unsigned int)bfbits(aU[3]*dl) << 16);
      *(uint2*)(ubufP + (size_t)ch*4096 + (mt*4 + nt)*256 + ln*4) = up;
      float m0 = (aG[0] + (i0r+0 == col ? 1.f : 0.f)) * dl;
      float m1 = (aG[1] + (i0r+1 == col ? 1.f : 0.f)) * dl;
      float m2 = (aG[2] + (i0r+2 == col ? 1.f : 0.f)) * dl;
      float m3 = (aG[3] + (i0r+3 == col ? 1.f : 0.f)) * dl;
      uint2 mp;
      mp.x = (unsigned int)bfbits(m0) | ((unsigned int)bfbits(m1) << 16);
      mp.y = (unsigned int)bfbits(m2) | ((unsigned int)bfbits(m3) << 16);
      const int laned = (((mt*2) + (kg >> 1)) & 3) * 16 + lm;
      *(uint2*)(mbufT + (size_t)ch*4096 + (nt*2 + (mt >> 1))*512
                + laned*8 + (kg & 1)*4) = mp;
    }
  }
}

// Phase B: serial over chunks; 32 blocks (one per bh) x 4 waves, no barriers.
__global__ __launch_bounds__(256) void rwkv_chunk_state(
    const bf16* __restrict__ mbufT, const bf16* __restrict__ ubufP,
    bf16* __restrict__ s0bufb)
{
  __shared__ bf16 Sst[4][16][72];
  const int bh = blockIdx.x;
  const int tid = threadIdx.x, wv = tid >> 6, ln = tid & 63;
  const int lm = ln & 15, kg = ln >> 4;

#pragma unroll
  for (int r = 0; r < 16; ++r) {
    Sst[wv][r][ln] = tobf(0.f);
    if (ln < 8) Sst[wv][r][64 + ln] = tobf(0.f);
  }

  bf16x8 BfA[4][2], BfB[4][2];
  uint2 UpA[4], UpB[4];
  auto prefetch = [&](bf16x8 (&Bf)[4][2], uint2 (&Up)[4], int c) {
    const size_t chp = (size_t)(bh*NCH + c) * 4096;
#pragma unroll
    for (int nt = 0; nt < 4; ++nt) {
      Bf[nt][0] = *(const bf16x8*)(mbufT + chp + (nt*2 + 0)*512 + ln*8);
      Bf[nt][1] = *(const bf16x8*)(mbufT + chp + (nt*2 + 1)*512 + ln*8);
      Up[nt]    = *(const uint2*) (ubufP + chp + (wv*4 + nt)*256 + ln*4);
    }
  };
  prefetch(BfA, UpA, 0);
  prefetch(BfB, UpB, 1);

  auto body = [&](bf16x8 (&Bf)[4][2], uint2 (&Up)[4], int c) {
    const size_t ch4 = (size_t)(bh*NCH + c) * 4096;
    const int sr = ln >> 2, sc = (ln & 3) * 16;
    uint4 v0 = *(const uint4*)&Sst[wv][sr][sc];
    uint4 v1 = *(const uint4*)&Sst[wv][sr][sc + 8];
    *(uint4*)(s0bufb + ch4 + (size_t)(wv*16 + sr)*64 + sc) = v0;
    *(uint4*)(s0bufb + ch4 + (size_t)(wv*16 + sr)*64 + sc + 8) = v1;
    bf16x8 A0 = *(const bf16x8*)&Sst[wv][lm][kg*8];
    bf16x8 A1 = *(const bf16x8*)&Sst[wv][lm][32 + kg*8];
    f32x4 acc[4];
#pragma unroll
    for (int nt = 0; nt < 4; ++nt) {
      acc[nt][0] = bf2f((unsigned short)(Up[nt].x & 0xffff));
      acc[nt][1] = bf2f((unsigned short)(Up[nt].x >> 16));
      acc[nt][2] = bf2f((unsigned short)(Up[nt].y & 0xffff));
      acc[nt][3] = bf2f((unsigned short)(Up[nt].y >> 16));
      acc[nt] = mfma16x16x32(A0, Bf[nt][0], acc[nt]);
      acc[nt] = mfma16x16x32(A1, Bf[nt][1], acc[nt]);
    }
    int cp = c + 2; if (cp > NCH - 1) cp = NCH - 1;
    prefetch(Bf, Up, cp);
#pragma unroll
    for (int nt = 0; nt < 4; ++nt)
#pragma unroll
      for (int q = 0; q < 4; ++q)
        Sst[wv][kg*4 + q][nt*16 + lm] = tobf(acc[nt][q]);
  };

  for (int cc = 0; cc < NCH; cc += 2) {
    body(BfA, UpA, cc);
    body(BfB, UpB, cc + 1);
  }
}

// Phase C: per chunk-head: SA = W*S0^T + SAll; y = Rt*S0^T + ABl*SAo + CKl*V;
// then FUSED groupnorm (group == head, size 64) + bonus + gate -> zb (bf16).
__global__ __launch_bounds__(256, 4) void rwkv_chunk_out(
    const bf16* __restrict__ rr, const bf16* __restrict__ lw,
    const bf16* __restrict__ vv, const bf16* __restrict__ kks,
    const bf16* __restrict__ gg, const bf16* __restrict__ s0bufb,
    const bf16* __restrict__ wbufb, const bf16* __restrict__ sabufb,
    const bf16* __restrict__ abybufb, const bf16* __restrict__ ckybufb,
    const float* __restrict__ faaaa, const float* __restrict__ lnw,
    const float* __restrict__ lnb, bf16* __restrict__ zb)
{
  __shared__ bf16 S0b[64][72];                    // B^T layout: [i][j]
  __shared__ bf16 ABl[LCH][40], CKl[LCH][40];     // A layouts: [s][u]
  __shared__ bf16 SAot[64][40], VlT[64][40];      // B^T layouts: [i][u]
  __shared__ float wtot[4][64];
  __shared__ float bonus[LCH];
  __shared__ float uni2f[2304];  // {Wb,Rlb}[32][72] bf16 | Yl[32][68] f32
  bf16 (*Wb)[72]  = (bf16(*)[72])uni2f;
  bf16 (*Rlb)[72] = (bf16(*)[72])((bf16*)uni2f + 2304);
  float (*Yl)[68] = (float(*)[68])uni2f;

  const int ch = blockIdx.x;
  const int c = ch & (NCH - 1), bh = ch >> 6, b = bh >> 4, h = bh & 15;
  const int tid = threadIdx.x, wv = tid >> 6, ln = tid & 63;
  const int lm = ln & 15, kg = ln >> 4;
  const size_t base = ((size_t)(b*T_ + c*LCH) * C_) + h*N_ + ln;

  float lwr[8], lcE[8];
  {
    float run = 0.f;
#pragma unroll
    for (int q = 0; q < 8; ++q) {
      lwr[q] = frombf(lw[base + (size_t)(wv*8 + q) * C_]);
      lcE[q] = run; run += lwr[q];
    }
    wtot[wv][ln] = run;
  }
  __syncthreads();
  {
    float pre = 0.f;
    for (int w2 = 0; w2 < wv; ++w2) pre += wtot[w2][ln];
#pragma unroll
    for (int q = 0; q < 8; ++q) lcE[q] += pre;
  }
  const float fa = faaaa[h*N_ + ln];
#pragma unroll
  for (int q = 0; q < 8; ++q) {
    const int s = wv*8 + q;
    const size_t off = base + (size_t)s * C_;
    float rf = frombf(rr[off]);
    Rlb[s][ln] = tobf(rf * __expf(lcE[q] + lwr[q]));
    VlT[ln][s] = vv[off];
    float rk = allred64(rf * frombf(kks[off]) * fa);   // bonus dot
    if (ln == 0) bonus[s] = rk;
  }
#pragma unroll
  for (int t = 0; t < 2; ++t) {
    int cc2 = tid*2 + t; int ri = cc2 >> 3, co = (cc2 & 7) * 8;
    *(uint4*)&S0b[ri][co] = *(const uint4*)(s0bufb + (size_t)ch*4096 + ri*64 + co);
  }
  { int ri = tid >> 3, co = (tid & 7) * 8;
    *(uint4*)&Wb[ri][co] = *(const uint4*)(wbufb + (size_t)ch*2048 + ri*64 + co); }
  if (tid < 128) {
    int ri = tid >> 2, co = (tid & 3) * 8;
    *(uint4*)&ABl[ri][co] = *(const uint4*)(abybufb + (size_t)ch*1024 + ri*32 + co);
  } else {
    int t2 = tid - 128; int ri = t2 >> 2, co = (t2 & 3) * 8;
    *(uint4*)&CKl[ri][co] = *(const uint4*)(ckybufb + (size_t)ch*1024 + ri*32 + co);
  }
  __syncthreads();

  const int mt = wv >> 1, ntb = (wv & 1) * 2;
#pragma unroll
  for (int t = 0; t < 2; ++t) {
    const int nt = ntb + t;
    const int row0 = mt*16 + kg*4, col = nt*16 + lm;
    f32x4 acc;
#pragma unroll
    for (int q = 0; q < 4; ++q)
      acc[q] = frombf(sabufb[(size_t)ch*2048 + (row0+q)*64 + col]);
#pragma unroll
    for (int ks = 0; ks < 2; ++ks) {
      bf16x8 af = *(const bf16x8*)&Wb[mt*16 + lm][ks*32 + kg*8];
      bf16x8 bq = *(const bf16x8*)&S0b[nt*16 + lm][ks*32 + kg*8];
      acc = mfma16x16x32(af, bq, acc);
    }
#pragma unroll
    for (int q = 0; q < 4; ++q) SAot[col][row0+q] = tobf(acc[q]);
  }
  __syncthreads();

  f32x4 yacc[2];
#pragma unroll
  for (int t = 0; t < 2; ++t) {
    const int nt = ntb + t;
    f32x4 acc = {};
#pragma unroll
    for (int ks = 0; ks < 2; ++ks) {
      bf16x8 af = *(const bf16x8*)&Rlb[mt*16 + lm][ks*32 + kg*8];
      bf16x8 bq = *(const bf16x8*)&S0b[nt*16 + lm][ks*32 + kg*8];
      acc = mfma16x16x32(af, bq, acc);
    }
    {
      bf16x8 af = *(const bf16x8*)&ABl[mt*16 + lm][kg*8];
      bf16x8 bq = *(const bf16x8*)&SAot[nt*16 + lm][kg*8];
      acc = mfma16x16x32(af, bq, acc);
    }
    {
      bf16x8 af = *(const bf16x8*)&CKl[mt*16 + lm][kg*8];
      bf16x8 bq = *(const bf16x8*)&VlT[nt*16 + lm][kg*8];
      acc = mfma16x16x32(af, bq, acc);
    }
    yacc[t] = acc;
  }
  __syncthreads();   // all Rlb reads done before Yl overwrites the alias

  // stage y in LDS (fp32), overwriting Wb/Rlb
#pragma unroll
  for (int t = 0; t < 2; ++t) {
    const int nt = ntb + t;
    const int row0 = mt*16 + kg*4, col = nt*16 + lm;
#pragma unroll
    for (int q = 0; q < 4; ++q) Yl[row0 + q][col] = yacc[t][q];
  }
  __syncthreads();

  // fused groupnorm + bonus + gate: thread = (row s2, 8 cols)
  {
    const int s2 = tid >> 3, c0 = (tid & 7) * 8;
    float yv[8]; float sum = 0.f;
#pragma unroll
    for (int i = 0; i < 8; ++i) { yv[i] = Yl[s2][c0 + i]; sum += yv[i]; }
#pragma unroll
    for (int m = 1; m < 8; m <<= 1) sum += __shfl_xor(sum, m, 64);
    const float mean = sum * (1.f/64.f);
    float ss = 0.f;
#pragma unroll
    for (int i = 0; i < 8; ++i) { float d = yv[i] - mean; ss += d * d; }
#pragma unroll
    for (int m = 1; m < 8; m <<= 1) ss += __shfl_xor(ss, m, 64);
    const float inv = rsqrtf(ss * (1.f/64.f) + 6.4e-4f);
    const float bn = bonus[s2];
    const size_t trow = (size_t)(b*T_ + c*LCH + s2) * C_ + h*N_ + c0;
    bf16 zout[8];
#pragma unroll
    for (int i = 0; i < 8; ++i) {
      const int col = c0 + i, cidx = h*N_ + col;
      float gn = (yv[i] - mean) * inv * lnw[cidx] + lnb[cidx];
      float z = (gn + bn * frombf(VlT[col][s2])) * frombf(gg[trow + i - trow % 1]);
      zout[i] = tobf(z);
    }
    // note: gg index == trow + i (written plainly below)
#pragma unroll
    for (int i = 0; i < 8; ++i) {
      float gn = (yv[i] - mean) * inv * lnw[h*N_ + c0 + i] + lnb[h*N_ + c0 + i];
      float z = (gn + bn * frombf(VlT[c0 + i][s2])) * frombf(gg[trow + i]);
      zout[i] = tobf(z);
    }
    *(uint4*)(zb + trow) = *(const uint4*)&zout[0];
  }
}

// ---------------- driver ----------------------------------------------------
extern "C" void kernel_launch(void* const* d_in, const int* in_sizes, int n_in,
                              void* d_out, int out_size, void* d_ws, size_t ws_size,
                              hipStream_t stream)
{
  const float* x     = (const float*)d_in[0];
  const float* maa_x = (const float*)d_in[1];
  const float* maa_r = (const float*)d_in[2];
  const float* maa_w = (const float*)d_in[3];
  const float* maa_k = (const float*)d_in[4];
  const float* maa_v = (const float*)d_in[5];
  const float* maa_a = (const float*)d_in[6];
  const float* maa_g = (const float*)d_in[7];
  const float* tdec  = (const float*)d_in[8];
  const float* faaaa = (const float*)d_in[9];
  const float* aaaaa = (const float*)d_in[10];
  const float* maa_w1= (const float*)d_in[11];
  const float* maa_w2= (const float*)d_in[12];
  const float* dec_w1= (const float*)d_in[13];
  const float* dec_w2= (const float*)d_in[14];
  const float* aaa_w1= (const float*)d_in[15];
  const float* aaa_w2= (const float*)d_in[16];
  const float* kkk_w1= (const float*)d_in[17];
  const float* kkk_w2= (const float*)d_in[18];
  const float* gate_w1=(const float*)d_in[19];
  const float* gate_w2=(const float*)d_in[20];
  const float* W_r   = (const float*)d_in[21];
  const float* W_k   = (const float*)d_in[22];
  const float* W_v   = (const float*)d_in[23];
  const float* W_o   = (const float*)d_in[24];
  const float* lnw   = (const float*)d_in[25];
  const float* lnb   = (const float*)d_in[26];

  char* ws = (char*)d_ws;
  size_t cur = 0;
  auto alloc = [&](size_t bytes) -> void* {
    void* p = ws + cur; cur += (bytes + 255) & ~(size_t)255; return p;
  };
  const size_t HBT = (size_t)BT_ * C_ * 2;  // bf16 activation buffer

  // ---- persistent (activations bf16) ----
  bf16* rb   = (bf16*)alloc(HBT);
  bf16* kb   = (bf16*)alloc(HBT);
  bf16* vb   = (bf16*)alloc(HBT);
  bf16* gbb  = (bf16*)alloc(HBT);
  bf16* WtR  = (bf16*)alloc((size_t)C_*C_*2);
  bf16* WtK  = (bf16*)alloc((size_t)C_*C_*2);
  bf16* WtV  = (bf16*)alloc((size_t)C_*C_*2);
  bf16* WtO  = (bf16*)alloc((size_t)C_*C_*2);
  bf16* w1t  = (bf16*)alloc((size_t)192*C_*2);
  bf16* w2t  = (bf16*)alloc((size_t)6*C_*32*2);
  bf16* d1t  = (bf16*)alloc((size_t)64*C_*2);
  bf16* d2t  = (bf16*)alloc((size_t)C_*64*2);
  bf16* a1t  = (bf16*)alloc((size_t)64*C_*2);
  bf16* a2t  = (bf16*)alloc((size_t)C_*64*2);
  bf16* k1t  = (bf16*)alloc((size_t)64*C_*2);
  bf16* k2t  = (bf16*)alloc((size_t)C_*64*2);
  bf16* g1t  = (bf16*)alloc((size_t)128*C_*2);
  bf16* g2t  = (bf16*)alloc((size_t)C_*128*2);
  bf16* lwb  = (bf16*)alloc(HBT);
  bf16* kkb  = (bf16*)alloc(HBT);
  bf16* aamt = (bf16*)alloc(HBT);
  bf16* s0bufb = kkb;                 // overlay: kkb+aamt dead after chunk_pre

  // ---- union region ----
  const size_t ubase = cur;
  bf16* mtmpb = (bf16*)alloc(HBT);
  bf16* xinb = (bf16*)alloc(HBT);
  bf16* xb   = (bf16*)alloc(HBT);
  bf16* mixb = (bf16*)alloc((size_t)BT_*192*2);
  bf16* xbr[6];
  for (int s = 0; s < 6; ++s) xbr[s] = (bf16*)alloc(HBT);
  bf16* h64k = (bf16*)alloc((size_t)BT_*64*2);
  bf16* h64d = (bf16*)alloc((size_t)BT_*64*2);
  bf16* h64a = (bf16*)alloc((size_t)BT_*64*2);
  bf16* h128b= (bf16*)alloc((size_t)BT_*128*2);
  const size_t tmp_end = cur;
  cur = ubase;  // overlay
  bf16*  wbufb   = (bf16*)alloc((size_t)CHD*2048*2);
  bf16*  sabufb  = (bf16*)alloc((size_t)CHD*2048*2);
  bf16*  abybufb = (bf16*)alloc((size_t)CHD*1024*2);
  bf16*  ckybufb = (bf16*)alloc((size_t)CHD*1024*2);
  bf16*  ubufP   = (bf16*)alloc((size_t)CHD*4096*2);
  bf16*  mbufT   = (bf16*)alloc((size_t)CHD*4096*2);
  bf16*  zb      = (bf16*)ubufP;   // alias: ubufP dead after chunk_state
  if (tmp_end > cur) cur = tmp_end;
  const size_t need = cur;
  (void)in_sizes; (void)n_in; (void)out_size;

  if (ws_size < need) {
    ws_diag<<<1, 1, 0, stream>>>((float)ws_size, (float)need, (float*)d_out);
    return;
  }

  PrepArgs pa;
  pa.src[0] = W_r;  pa.dst[0] = WtR;
  pa.src[1] = W_k;  pa.dst[1] = WtK;
  pa.src[2] = W_v;  pa.dst[2] = WtV;
  pa.src[3] = W_o;  pa.dst[3] = WtO;
  pa.src[4] = maa_w1; pa.dst[4] = w1t;
  for (int s = 0; s < 6; ++s) { pa.src[5+s] = maa_w2 + (size_t)s*32*C_; pa.dst[5+s] = w2t + (size_t)s*C_*32; }
  pa.src[11] = dec_w1; pa.dst[11] = d1t;
  pa.src[12] = dec_w2; pa.dst[12] = d2t;
  pa.src[13] = aaa_w1; pa.dst[13] = a1t;
  pa.src[14] = aaa_w2; pa.dst[14] = a2t;
  pa.src[15] = kkk_w1; pa.dst[15] = k1t;
  pa.src[16] = kkk_w2; pa.dst[16] = k2t;
  pa.src[17] = gate_w1; pa.dst[17] = g1t;
  pa.src[18] = gate_w2; pa.dst[18] = g2t;
  prep_weights<<<dim3(1024, 19), 256, 0, stream>>>(pa);

  const int EW_GRID = (BT_ * C_) / 256;  // 16384
  xin_k<<<EW_GRID, 256, 0, stream>>>(x, maa_x, xinb, xb);

  gemm_bt<1><<<dim3(64, 3), 256, 0, stream>>>(xinb, C_, w1t, C_, mixb, 192, C_);

  Mix6Args ma;
  ma.maa[0] = maa_r; ma.maa[1] = maa_w; ma.maa[2] = maa_k;
  ma.maa[3] = maa_v; ma.maa[4] = maa_a; ma.maa[5] = maa_g;
  for (int s = 0; s < 6; ++s) ma.out[s] = xbr[s];
  mix_combine<<<dim3(64, 16, 6), 256, 0, stream>>>(mixb, w2t, xb, ma);

  // r, k, v batched (one launch, bf16 out)
  RkvArgs ra;
  ra.A[0] = xbr[0]; ra.Bt[0] = WtR; ra.Cq[0] = rb;
  ra.A[1] = xbr[2]; ra.Bt[1] = WtK; ra.Cq[1] = kb;
  ra.A[2] = xbr[3]; ra.Bt[2] = WtV; ra.Cq[2] = vb;
  gemm128_rkv<<<dim3(32, 8, 3), 256, 0, stream>>>(ra);

  // batched small projections: k1 (tanh), d1 (tanh), a1 (raw), g1 (tanh)
  Proj4Args p4;
  p4.A[0] = xbr[2]; p4.Bt[0] = k1t; p4.out[0] = h64k; p4.N[0] = 64;  p4.tnh[0] = 1;
  p4.A[1] = xbr[1]; p4.Bt[1] = d1t; p4.out[1] = h64d; p4.N[1] = 64;  p4.tnh[1] = 1;
  p4.A[2] = xbr[4]; p4.Bt[2] = a1t; p4.out[2] = h64a; p4.N[2] = 64;  p4.tnh[2] = 0;
  p4.A[3] = xbr[5]; p4.Bt[3] = g1t; p4.out[3] = h128b; p4.N[3] = 128; p4.tnh[3] = 1;
  proj4<<<dim3(64, 2, 4), 256, 0, stream>>>(p4);

  // kk path (uses UNscaled k); bf16 intermediate
  gemm128<2><<<dim3(32, 8), 256, 0, stream>>>(h64k, 64, k2t, 64, mtmpb, C_, 64, nullptr, nullptr);
  kk_normalize<<<BT_, 256, 0, stream>>>(kb, mtmpb, kkb);

  // w path: fused finalize epilogue (writes lwb bf16, scales kb in place)
  gemm128<3><<<dim3(32, 8), 256, 0, stream>>>(h64d, 64, d2t, 64, lwb, C_, 64, tdec, kb);

  // a path: fused sigmoid epilogue (bf16)
  gemm128<4><<<dim3(32, 8), 256, 0, stream>>>(h64a, 64, a2t, 64, aamt, C_, 64, aaaaa, nullptr);

  // g path -> bf16 gate buffer
  gemm128<2><<<dim3(32, 8), 256, 0, stream>>>(h128b, 128, g2t, 128, gbb, C_, 128, nullptr, nullptr);

  // ---- chunked scan ----
  rwkv_chunk_pre<<<CHD, 256, 0, stream>>>(rb, lwb, kb, kkb, aamt, vb,
      wbufb, sabufb, abybufb, ckybufb, ubufP, mbufT);
  rwkv_chunk_state<<<32, 256, 0, stream>>>(mbufT, ubufP, s0bufb);
  // fused: scan output + groupnorm + bonus + gate -> zb
  rwkv_chunk_out<<<CHD, 256, 0, stream>>>(rb, lwb, vb, kb, gbb, s0bufb,
      wbufb, sabufb, abybufb, ckybufb, faaaa, lnw, lnb, zb);

  gemm128<0><<<dim3(32, 8), 256, 0, stream>>>(zb, C_, WtO, C_, d_out, C_, C_, nullptr, nullptr);
}

// Round 15
// 307.603 us; speedup vs baseline: 5.3118x; 1.0133x over previous
//
#include <hip/hip_runtime.h>
#include <hip/hip_bf16.h>

using bf16 = __hip_bfloat16;
using bf16x8 = __attribute__((ext_vector_type(8))) short;  // 8 bf16 (4 VGPRs)
using f32x4 = __attribute__((ext_vector_type(4))) float;

#define B_ 2
#define T_ 2048
#define C_ 1024
#define BT_ (B_*T_)
#define H_ 16
#define N_ 64
#define LCH 32            // scan chunk length
#define NCH (T_/LCH)      // 64 chunks per head
#define CHD (B_*H_*NCH)   // 2048 chunk-heads

__device__ __forceinline__ float allred64(float v) {
#pragma unroll
  for (int m = 1; m < 64; m <<= 1) v += __shfl_xor(v, m, 64);
  return v;
}

__device__ __forceinline__ bf16 tobf(float f) { return __float2bfloat16(f); }
__device__ __forceinline__ float frombf(bf16 b) { return __bfloat162float(b); }
__device__ __forceinline__ float bf2f(unsigned short u) {
  unsigned int x = ((unsigned int)u) << 16;
  return __builtin_bit_cast(float, x);
}
__device__ __forceinline__ unsigned short bfbits(float f) {
  return __builtin_bit_cast(unsigned short, __float2bfloat16(f));
}
__device__ __forceinline__ float rdlane(float v, int m) {
  return __builtin_bit_cast(float,
      __builtin_amdgcn_readlane(__builtin_bit_cast(int, v), m));
}

__device__ __forceinline__ f32x4 mfma16x16x32(bf16x8 a, bf16x8 b, f32x4 c) {
  return __builtin_amdgcn_mfma_f32_16x16x32_bf16(a, b, c, 0, 0, 0);
}

// async global->LDS, 16B per lane (dest = wave-uniform base + lane*16)
typedef const __attribute__((address_space(1))) unsigned int* gas_ptr;
typedef __attribute__((address_space(3))) unsigned int* las_ptr;
__device__ __forceinline__ void gload16(const void* g, void* l) {
  __builtin_amdgcn_global_load_lds((gas_ptr)g, (las_ptr)l, 16, 0, 0);
}

// ---------------- ws_size diagnostic ----------------------------------------
__global__ void ws_diag(float a, float b, float* out) { out[0] = a; out[1] = b; }

// ---------------- weight transpose + bf16 cast (19 jobs, one launch) -------
struct PrepArgs {
  const float* src[19];
  bf16* dst[19];
};
__constant__ int kTR[19] = {1024,1024,1024,1024, 1024, 32,32,32,32,32,32,
                            1024,64, 1024,64, 1024,64, 1024,128};
__constant__ int kTC[19] = {1024,1024,1024,1024, 192, 1024,1024,1024,1024,1024,1024,
                            64,1024, 64,1024, 64,1024, 128,1024};

__global__ __launch_bounds__(256) void prep_weights(PrepArgs pa) {
  const int job = blockIdx.y;
  const int R = kTR[job], Cc = kTC[job];
  const int ntx = Cc >> 5, nty = R >> 5;
  const int tile = blockIdx.x;
  if (tile >= ntx * nty) return;
  const int tx = tile % ntx, ty = tile / ntx;
  const float* __restrict__ src = pa.src[job];
  bf16* __restrict__ dst = pa.dst[job];
  __shared__ float tl[32][33];
  const int lx = threadIdx.x & 31, ly = threadIdx.x >> 5;  // 32 x 8
#pragma unroll
  for (int q = 0; q < 4; ++q)
    tl[ly + 8*q][lx] = src[(size_t)(ty*32 + ly + 8*q) * Cc + tx*32 + lx];
  __syncthreads();
#pragma unroll
  for (int q = 0; q < 4; ++q)
    dst[(size_t)(tx*32 + ly + 8*q) * R + ty*32 + lx] = tobf(tl[lx][ly + 8*q]);
}

// ------- GEMM 64-tile -------------------------------------------------------
template<int EPI>
__global__ __launch_bounds__(256) void gemm_bt(
    const bf16* __restrict__ A, int lda,
    const bf16* __restrict__ Bt, int ldb,
    void* __restrict__ Cout, int ldc, int K)
{
  __shared__ short As[64][40];
  __shared__ short Bs[64][40];
  const int bm0 = blockIdx.x * 64;
  const int bn0 = blockIdx.y * 64;
  const int tid = threadIdx.x;
  const int wave = tid >> 6, lane = tid & 63;
  const int lm = lane & 15, kg = lane >> 4;
  const int srow = tid >> 2, scol = (tid & 3) * 8;
  f32x4 acc[4] = {};
  const size_t abase = (size_t)(bm0 + srow) * lda + scol;
  const size_t bbase = (size_t)(bn0 + srow) * ldb + scol;
  for (int k0 = 0; k0 < K; k0 += 32) {
    *(uint4*)&As[srow][scol] = *(const uint4*)(A + abase + k0);
    *(uint4*)&Bs[srow][scol] = *(const uint4*)(Bt + bbase + k0);
    __syncthreads();
    bf16x8 af = *(const bf16x8*)&As[wave*16 + lm][kg*8];
#pragma unroll
    for (int f = 0; f < 4; ++f) {
      bf16x8 bfr = *(const bf16x8*)&Bs[f*16 + lm][kg*8];
      acc[f] = mfma16x16x32(af, bfr, acc[f]);
    }
    __syncthreads();
  }
  const int row0 = bm0 + wave*16 + kg*4;
  const int col0 = bn0 + lm;
#pragma unroll
  for (int f = 0; f < 4; ++f) {
#pragma unroll
    for (int q = 0; q < 4; ++q) {
      float val = acc[f][q];
      size_t o = (size_t)(row0 + q) * ldc + col0 + f*16;
      if (EPI == 0)      ((float*)Cout)[o] = val;
      else if (EPI == 1) ((bf16*)Cout)[o] = tobf(tanhf(val));
      else               ((bf16*)Cout)[o] = tobf(val);
    }
  }
}

// ------- batched small projections: k1/d1/a1 (N=64) + g1 (N=128) -----------
struct Proj4Args { const bf16* A[4]; const bf16* Bt[4]; bf16* out[4];
                   int N[4]; int tnh[4]; };
__global__ __launch_bounds__(256) void proj4(Proj4Args p4) {
  const int z = blockIdx.z;
  const int Nn = p4.N[z];
  const int bn0 = blockIdx.y * 64;
  if (bn0 >= Nn) return;
  __shared__ short As[64][40];
  __shared__ short Bs[64][40];
  const bf16* __restrict__ A  = p4.A[z];
  const bf16* __restrict__ Bt = p4.Bt[z];
  bf16* __restrict__ out = p4.out[z];
  const int tnh = p4.tnh[z];
  const int bm0 = blockIdx.x * 64;
  const int tid = threadIdx.x;
  const int wave = tid >> 6, lane = tid & 63;
  const int lm = lane & 15, kg = lane >> 4;
  const int srow = tid >> 2, scol = (tid & 3) * 8;
  f32x4 acc[4] = {};
  const size_t abase = (size_t)(bm0 + srow) * C_ + scol;
  const size_t bbase = (size_t)(bn0 + srow) * C_ + scol;
  for (int k0 = 0; k0 < C_; k0 += 32) {
    *(uint4*)&As[srow][scol] = *(const uint4*)(A + abase + k0);
    *(uint4*)&Bs[srow][scol] = *(const uint4*)(Bt + bbase + k0);
    __syncthreads();
    bf16x8 af = *(const bf16x8*)&As[wave*16 + lm][kg*8];
#pragma unroll
    for (int f = 0; f < 4; ++f) {
      bf16x8 bfr = *(const bf16x8*)&Bs[f*16 + lm][kg*8];
      acc[f] = mfma16x16x32(af, bfr, acc[f]);
    }
    __syncthreads();
  }
  const int row0 = bm0 + wave*16 + kg*4;
  const int col0 = bn0 + lm;
#pragma unroll
  for (int f = 0; f < 4; ++f) {
#pragma unroll
    for (int q = 0; q < 4; ++q) {
      float val = acc[f][q];
      size_t o = (size_t)(row0 + q) * Nn + col0 + f*16;
      out[o] = tobf(tnh ? tanhf(val) : val);
    }
  }
}

// ------- GEMM 128-tile, m97 structure (global_load_lds staging) -------------
// EPI: 0 f32 | 2 bf16
template<int EPI>
__global__ __launch_bounds__(256) void gemm128(
    const bf16* __restrict__ A, int lda,
    const bf16* __restrict__ Bt, int ldb,
    void* __restrict__ Cout, int ldc, int K)
{
  __shared__ bf16 As[128][32];     // linear (required by global_load_lds)
  __shared__ bf16 Bs[128][32];
  const int bm0 = blockIdx.x * 128, bn0 = blockIdx.y * 128;
  const int tid = threadIdx.x, wv = tid >> 6, ln = tid & 63;
  const int wr = wv >> 1, wc = wv & 1;
  const int lm = ln & 15, kg = ln >> 4;
  const int srow = ln >> 2, scol = (ln & 3) * 8;
  f32x4 acc[4][4] = {};
  for (int k0 = 0; k0 < K; k0 += 32) {
#pragma unroll
    for (int i = 0; i < 2; ++i) {
      const int r0 = wv*32 + i*16;
      gload16(A  + (size_t)(bm0 + r0 + srow) * lda + k0 + scol, &As[r0][0]);
      gload16(Bt + (size_t)(bn0 + r0 + srow) * ldb + k0 + scol, &Bs[r0][0]);
    }
    asm volatile("s_waitcnt vmcnt(0)" ::: "memory");
    __syncthreads();
    bf16x8 af[4], bfr[4];
#pragma unroll
    for (int m = 0; m < 4; ++m) af[m] = *(const bf16x8*)&As[wr*64 + m*16 + lm][kg*8];
#pragma unroll
    for (int n = 0; n < 4; ++n) bfr[n] = *(const bf16x8*)&Bs[wc*64 + n*16 + lm][kg*8];
#pragma unroll
    for (int m = 0; m < 4; ++m)
#pragma unroll
      for (int n = 0; n < 4; ++n)
        acc[m][n] = mfma16x16x32(af[m], bfr[n], acc[m][n]);
    __syncthreads();
  }
#pragma unroll
  for (int m = 0; m < 4; ++m) {
    const int row0 = bm0 + wr*64 + m*16 + kg*4;
#pragma unroll
    for (int n = 0; n < 4; ++n) {
      const int col = bn0 + wc*64 + n*16 + lm;
#pragma unroll
      for (int q = 0; q < 4; ++q) {
        float val = acc[m][n][q];
        size_t o = (size_t)(row0 + q) * ldc + col;
        if (EPI == 0) ((float*)Cout)[o] = val;
        else          ((bf16*)Cout)[o] = tobf(val);
      }
    }
  }
}

// batched r/k/v: same shape (M=4096, N=1024, K=1024), bf16 outputs
struct RkvArgs { const bf16* A[3]; const bf16* Bt[3]; bf16* Cq[3]; };
__global__ __launch_bounds__(256) void gemm128_rkv(RkvArgs ra) {
  __shared__ bf16 As[128][32];
  __shared__ bf16 Bs[128][32];
  const bf16* __restrict__ A  = ra.A[blockIdx.z];
  const bf16* __restrict__ Bt = ra.Bt[blockIdx.z];
  bf16* __restrict__ Cout = ra.Cq[blockIdx.z];
  const int bm0 = blockIdx.x * 128, bn0 = blockIdx.y * 128;
  const int tid = threadIdx.x, wv = tid >> 6, ln = tid & 63;
  const int wr = wv >> 1, wc = wv & 1;
  const int lm = ln & 15, kg = ln >> 4;
  const int srow = ln >> 2, scol = (ln & 3) * 8;
  f32x4 acc[4][4] = {};
  for (int k0 = 0; k0 < C_; k0 += 32) {
#pragma unroll
    for (int i = 0; i < 2; ++i) {
      const int r0 = wv*32 + i*16;
      gload16(A  + (size_t)(bm0 + r0 + srow) * C_ + k0 + scol, &As[r0][0]);
      gload16(Bt + (size_t)(bn0 + r0 + srow) * C_ + k0 + scol, &Bs[r0][0]);
    }
    asm volatile("s_waitcnt vmcnt(0)" ::: "memory");
    __syncthreads();
    bf16x8 af[4], bfr[4];
#pragma unroll
    for (int m = 0; m < 4; ++m) af[m] = *(const bf16x8*)&As[wr*64 + m*16 + lm][kg*8];
#pragma unroll
    for (int n = 0; n < 4; ++n) bfr[n] = *(const bf16x8*)&Bs[wc*64 + n*16 + lm][kg*8];
#pragma unroll
    for (int m = 0; m < 4; ++m)
#pragma unroll
      for (int n = 0; n < 4; ++n)
        acc[m][n] = mfma16x16x32(af[m], bfr[n], acc[m][n]);
    __syncthreads();
  }
#pragma unroll
  for (int m = 0; m < 4; ++m) {
    const int row0 = bm0 + wr*64 + m*16 + kg*4;
#pragma unroll
    for (int n = 0; n < 4; ++n) {
      const int col = bn0 + wc*64 + n*16 + lm;
#pragma unroll
      for (int q = 0; q < 4; ++q)
        Cout[(size_t)(row0 + q) * C_ + col] = tobf(acc[m][n][q]);
    }
  }
}

// ------- batched epilogue GEMMs: kk-add / w-finalize / a-sigmoid / g --------
// all M=4096, N=1024; K per z; epi: 2=bf16 raw, 4=sigmoid, 5=w-finalize
struct Ep4Args {
  const bf16* A[4]; const bf16* Bt[4]; bf16* Cout[4];
  int K[4]; int epi[4];
  const float* aux[4];          // z1: tdec, z2: aaaaa
  const bf16* kin; bf16* ksout; // z1: unscaled k in, scaled k out
};
__global__ __launch_bounds__(256) void gemm128_ep4(Ep4Args ea) {
  __shared__ bf16 As[128][32];
  __shared__ bf16 Bs[128][32];
  const int z = blockIdx.z;
  const bf16* __restrict__ A  = ea.A[z];
  const bf16* __restrict__ Bt = ea.Bt[z];
  bf16* __restrict__ Cout = ea.Cout[z];
  const int K = ea.K[z], epi = ea.epi[z];
  const float* __restrict__ aux = ea.aux[z];
  const int bm0 = blockIdx.x * 128, bn0 = blockIdx.y * 128;
  const int tid = threadIdx.x, wv = tid >> 6, ln = tid & 63;
  const int wr = wv >> 1, wc = wv & 1;
  const int lm = ln & 15, kg = ln >> 4;
  const int srow = ln >> 2, scol = (ln & 3) * 8;
  f32x4 acc[4][4] = {};
  for (int k0 = 0; k0 < K; k0 += 32) {
#pragma unroll
    for (int i = 0; i < 2; ++i) {
      const int r0 = wv*32 + i*16;
      gload16(A  + (size_t)(bm0 + r0 + srow) * K + k0 + scol, &As[r0][0]);
      gload16(Bt + (size_t)(bn0 + r0 + srow) * K + k0 + scol, &Bs[r0][0]);
    }
    asm volatile("s_waitcnt vmcnt(0)" ::: "memory");
    __syncthreads();
    bf16x8 af[4], bfr[4];
#pragma unroll
    for (int m = 0; m < 4; ++m) af[m] = *(const bf16x8*)&As[wr*64 + m*16 + lm][kg*8];
#pragma unroll
    for (int n = 0; n < 4; ++n) bfr[n] = *(const bf16x8*)&Bs[wc*64 + n*16 + lm][kg*8];
#pragma unroll
    for (int m = 0; m < 4; ++m)
#pragma unroll
      for (int n = 0; n < 4; ++n)
        acc[m][n] = mfma16x16x32(af[m], bfr[n], acc[m][n]);
    __syncthreads();
  }
#pragma unroll
  for (int m = 0; m < 4; ++m) {
    const int row0 = bm0 + wr*64 + m*16 + kg*4;
#pragma unroll
    for (int n = 0; n < 4; ++n) {
      const int col = bn0 + wc*64 + n*16 + lm;
#pragma unroll
      for (int q = 0; q < 4; ++q) {
        float val = acc[m][n][q];
        size_t o = (size_t)(row0 + q) * C_ + col;
        if (epi == 2) {
          Cout[o] = tobf(val);
        } else if (epi == 4) {
          float zz = aux[col] + val;
          Cout[o] = tobf(2.f / (1.f + expf(-zz)));
        } else {  // epi == 5: w-finalize
          float wr2 = val + aux[col];
          float sp = fmaxf(-wr2, 0.f) + log1pf(expf(-fabsf(wr2)));
          float w = -sp - 0.5f;
          Cout[o] = tobf(-expf(w));                                  // lw
          ea.ksout[o] = tobf(frombf(ea.kin[o]) * expf(fminf(0.5f*w, 0.f)));
        }
      }
    }
  }
}

// --------- fused 6-branch low-rank projection + combine (bf16 x copy) -------
struct Mix6Args { const float* maa[6]; bf16* out[6]; };

__global__ __launch_bounds__(256) void mix_combine(
    const bf16* __restrict__ mixb, const bf16* __restrict__ w2t,
    const bf16* __restrict__ xb, Mix6Args ma)
{
  __shared__ short As[64][40];
  __shared__ short Bs[64][40];
  const int s6 = blockIdx.z;
  const bf16* __restrict__ A  = mixb + s6*32;            // lda = 192
  const bf16* __restrict__ Bt = w2t + (size_t)s6*C_*32;  // ldb = 32
  const float* __restrict__ maa = ma.maa[s6];
  bf16* __restrict__ out = ma.out[s6];
  const int bm0 = blockIdx.x * 64, bn0 = blockIdx.y * 64;
  const int tid = threadIdx.x, wave = tid >> 6, lane = tid & 63;
  const int lm = lane & 15, kg = lane >> 4;
  const int srow = tid >> 2, scol = (tid & 3) * 8;
  *(uint4*)&As[srow][scol] = *(const uint4*)(A + (size_t)(bm0 + srow)*192 + scol);
  *(uint4*)&Bs[srow][scol] = *(const uint4*)(Bt + (size_t)(bn0 + srow)*32 + scol);
  __syncthreads();
  bf16x8 af = *(const bf16x8*)&As[wave*16 + lm][kg*8];
  f32x4 acc[4] = {};
#pragma unroll
  for (int f = 0; f < 4; ++f) {
    bf16x8 bfr = *(const bf16x8*)&Bs[f*16 + lm][kg*8];
    acc[f] = mfma16x16x32(af, bfr, acc[f]);
  }
  const int row0 = bm0 + wave*16 + kg*4;
  const int col0 = bn0 + lm;
#pragma unroll
  for (int f = 0; f < 4; ++f) {
#pragma unroll
    for (int q = 0; q < 4; ++q) {
      const int row = row0 + q, col = col0 + f*16;
      const size_t o = (size_t)row * C_ + col;
      float xv = frombf(xb[o]);
      float xp = (row & (T_ - 1)) ? frombf(xb[o - C_]) : 0.f;
      out[o] = tobf(xv + (xp - xv) * (maa[col] + acc[f][q]));
    }
  }
}

// ---------------- elementwise ----------------------------------------------
__global__ __launch_bounds__(256) void xin_k(
    const float* __restrict__ x, const float* __restrict__ maa_x,
    bf16* __restrict__ xinb, bf16* __restrict__ xb)
{
  size_t idx = (size_t)blockIdx.x * 256 + threadIdx.x;
  int c = idx & (C_ - 1);
  int t = (int)((idx >> 10) & (T_ - 1));
  float xv = x[idx];
  float xp = t ? x[idx - C_] : 0.f;
  xinb[idx] = tobf(xv + (xp - xv) * maa_x[c]);
  xb[idx] = tobf(xv);
}

__global__ __launch_bounds__(256) void kk_normalize(
    const bf16* __restrict__ kraw, const bf16* __restrict__ kkadd,
    bf16* __restrict__ kkout)
{
  const int bt = blockIdx.x;
  const int tid = threadIdx.x;
  const size_t o = (size_t)bt * C_;
  float vals[4]; float ss = 0.f;
#pragma unroll
  for (int q = 0; q < 4; ++q) {
    float u = frombf(kraw[o + tid + q*256]) + frombf(kkadd[o + tid + q*256]);
    vals[q] = u; ss += u * u;
  }
  ss = allred64(ss);
  __shared__ float red[4];
  const int wave = tid >> 6, lane = tid & 63;
  if (lane == 0) red[wave] = ss;
  __syncthreads();
  float tot = red[0] + red[1] + red[2] + red[3];
  float inv = 1.f / fmaxf(sqrtf(tot), 1e-12f);
#pragma unroll
  for (int q = 0; q < 4; ++q) kkout[o + tid + q*256] = tobf(vals[q] * inv);
}

// ============ Chunked RWKV-7 scan (fp32 recurrence, bf16 MFMA phases) =======
//   SA = (I-trilA)^{-1}(Achk S0^T + trilC V) = W S0^T + SA_loc
//   y[s] = rt_s S0^T + tril<=(ABy) SA + tril<=(CKy) V
//   S_L = S0 * M + U  with M = diag(dL) + (W^T Bt).*dL_j
// LDS alias: {aCb,rCb} (dead after solve-init) overlays {WT,SAT} -> 48 KB.

__global__ __launch_bounds__(256, 3) void rwkv_chunk_pre(
    const bf16* __restrict__ rr, const bf16* __restrict__ lw,
    const bf16* __restrict__ kk_s, const bf16* __restrict__ kkv,
    const bf16* __restrict__ aam, const bf16* __restrict__ vv,
    bf16* __restrict__ wbufb, bf16* __restrict__ sabufb,
    bf16* __restrict__ abybufb, bf16* __restrict__ ckybufb,
    bf16* __restrict__ ubufP, bf16* __restrict__ mbufT)
{
  __shared__ float Am[LCH][33], Cm[LCH][33];
  __shared__ float wtot[4][64];
  __shared__ float lcl[64];
  __shared__ float dll[64];
  __shared__ bf16 bTb[LCH][72], kTb[LCH][72], vLb[LCH][72];
  __shared__ bf16 bTT[64][40], kTT[64][40], vLT[64][40];
  __shared__ bf16 uni[5120];   // {aCb,rCb}[32][72] | {WT,SAT}[64][40]
  bf16 (*aCb)[72] = (bf16(*)[72])uni;
  bf16 (*rCb)[72] = (bf16(*)[72])(uni + 2304);
  bf16 (*WT)[40]  = (bf16(*)[40])uni;
  bf16 (*SAT)[40] = (bf16(*)[40])(uni + 2560);

  const int ch = blockIdx.x;
  const int c  = ch & (NCH - 1);
  const int bh = ch >> 6;
  const int b  = bh >> 4, h = bh & 15;
  const int tid = threadIdx.x, wv = tid >> 6, ln = tid & 63;
  const int lm = ln & 15, kg = ln >> 4;
  const size_t base = ((size_t)(b*T_ + c*LCH) * C_) + h*N_ + ln;

  // --- phase 1: cumulative log-decay + load/scale into LDS (both layouts) ---
  float lwr[8], lcE[8];
  {
    float run = 0.f;
#pragma unroll
    for (int q = 0; q < 8; ++q) {
      lwr[q] = frombf(lw[base + (size_t)(wv*8 + q) * C_]);
      lcE[q] = run; run += lwr[q];
    }
    wtot[wv][ln] = run;
  }
  __syncthreads();
  {
    float pre = 0.f;
    for (int w2 = 0; w2 < wv; ++w2) pre += wtot[w2][ln];
    if (wv == 0) lcl[ln] = wtot[0][ln] + wtot[1][ln] + wtot[2][ln] + wtot[3][ln];
#pragma unroll
    for (int q = 0; q < 8; ++q) lcE[q] += pre;
  }
#pragma unroll
  for (int q = 0; q < 8; ++q) {
    const int s = wv*8 + q;
    const size_t off = base + (size_t)s * C_;
    float kkx = frombf(kkv[off]), aax = frombf(aam[off]);
    float kx = frombf(kk_s[off]), rx = frombf(rr[off]);
    float lcI = lcE[q] + lwr[q];
    float eIm = __expf(-lcI);
    float eI  = __builtin_amdgcn_rcpf(eIm);   // exp(lcI) = 1/exp(-lcI)
    float av = -kkx * __expf(lcE[q]);
    float bv = kkx * aax * eIm;
    float kv2 = kx * eIm;
    float rv = rx * eI;
    bf16 vxb = vv[off];
    aCb[s][ln] = tobf(av);  rCb[s][ln] = tobf(rv);
    bTb[s][ln] = tobf(bv);  kTb[s][ln] = tobf(kv2);
    vLb[s][ln] = vxb;
    bTT[ln][s] = tobf(bv);  kTT[ln][s] = tobf(kv2);  vLT[ln][s] = vxb;
  }
  __syncthreads();
  if (tid < 64) dll[tid] = __expf(lcl[tid]);  // barriers below make it visible

  // --- phase 2: MFMA, one 32x32 (K=64) product per wave ---
  {
    const bf16 (*Ab)[72] = (wv < 2) ? aCb : rCb;
    const bf16 (*Bb)[72] = (wv & 1) ? kTb : bTb;
#pragma unroll
    for (int mt = 0; mt < 2; ++mt)
#pragma unroll
      for (int nt = 0; nt < 2; ++nt) {
        f32x4 acc = {};
#pragma unroll
        for (int ks = 0; ks < 2; ++ks) {
          bf16x8 af = *(const bf16x8*)&Ab[mt*16 + lm][ks*32 + kg*8];
          bf16x8 bq = *(const bf16x8*)&Bb[nt*16 + lm][ks*32 + kg*8];
          acc = mfma16x16x32(af, bq, acc);
        }
        const int row0 = mt*16 + kg*4, col = nt*16 + lm;
#pragma unroll
        for (int q = 0; q < 4; ++q) {
          float v = acc[q];
          if (wv == 0)      Am[row0+q][col] = v;
          else if (wv == 1) Cm[row0+q][col] = v;
          else {
            bf16 bv2 = tobf(col <= row0+q ? v : 0.f);  // tril<= mask
            if (wv == 2) abybufb[(size_t)ch*1024 + (row0+q)*32 + col] = bv2;
            else         ckybufb[(size_t)ch*1024 + (row0+q)*32 + col] = bv2;
          }
        }
      }
  }
  __syncthreads();

  // --- phase 3a: preload solve inputs to registers (aCb/Cm/vLb reads) ------
  float Xr[32], amr[32];
  if (wv == 0) {
#pragma unroll
    for (int s = 0; s < 32; ++s) amr[s] = Am[s][ln & 31];
#pragma unroll
    for (int s = 0; s < 32; ++s) Xr[s] = frombf(aCb[s][ln]);
  } else if (wv == 1) {
    float cmr[32];
#pragma unroll
    for (int s = 0; s < 32; ++s) { amr[s] = Am[s][ln & 31]; cmr[s] = Cm[s][ln & 31]; }
#pragma unroll
    for (int s = 0; s < 32; ++s) Xr[s] = 0.f;
#pragma unroll
    for (int u = 0; u < 31; ++u) {
      float v = frombf(vLb[u][ln]);
#pragma unroll
      for (int s = u + 1; s < 32; ++s) Xr[s] += rdlane(cmr[s], u) * v;
    }
  }
  __syncthreads();   // aCb reads complete before WT/SAT writes into alias

  // --- phase 3b: register forward-substitution; write WT/SAT --------------
  if (wv < 2) {
#pragma unroll
    for (int s = 1; s < 32; ++s) {
      float acc = Xr[s];
#pragma unroll
      for (int u = 0; u < s; ++u) acc += rdlane(amr[s], u) * Xr[u];
      Xr[s] = acc;
    }
    if (wv == 0) {
#pragma unroll
      for (int s = 0; s < 32; ++s) {
        bf16 bv = tobf(Xr[s]);
        WT[ln][s] = bv;
        wbufb[(size_t)ch*2048 + s*64 + ln] = bv;
      }
    } else {
#pragma unroll
      for (int s = 0; s < 32; ++s) {
        bf16 bv = tobf(Xr[s]);
        SAT[ln][s] = bv;
        sabufb[(size_t)ch*2048 + s*64 + ln] = bv;
      }
    }
  }
  __syncthreads();

  // --- phase 5: U, M (64x64, K=32) via MFMA; packed-layout b64 stores ------
  {
    const int mt = wv;
    bf16x8 aS = *(const bf16x8*)&SAT[mt*16 + lm][kg*8];
    bf16x8 aV = *(const bf16x8*)&vLT[mt*16 + lm][kg*8];
    bf16x8 aW = *(const bf16x8*)&WT[mt*16 + lm][kg*8];
#pragma unroll
    for (int nt = 0; nt < 4; ++nt) {
      bf16x8 bB = *(const bf16x8*)&bTT[nt*16 + lm][kg*8];
      bf16x8 bK = *(const bf16x8*)&kTT[nt*16 + lm][kg*8];
      f32x4 aU = {}, aG = {};
      aU = mfma16x16x32(aS, bB, aU);
      aU = mfma16x16x32(aV, bK, aU);
      aG = mfma16x16x32(aW, bB, aG);
      const int i0r = mt*16 + kg*4, col = nt*16 + lm;
      float dl = dll[col];
      uint2 up;
      up.x = (unsigned int)bfbits(aU[0]*dl) | ((unsigned int)bfbits(aU[1]*dl) << 16);
      up.y = (unsigned int)bfbits(aU[2]*dl) | ((unsigned int)bfbits(aU[3]*dl) << 16);
      *(uint2*)(ubufP + (size_t)ch*4096 + (mt*4 + nt)*256 + ln*4) = up;
      float m0 = (aG[0] + (i0r+0 == col ? 1.f : 0.f)) * dl;
      float m1 = (aG[1] + (i0r+1 == col ? 1.f : 0.f)) * dl;
      float m2 = (aG[2] + (i0r+2 == col ? 1.f : 0.f)) * dl;
      float m3 = (aG[3] + (i0r+3 == col ? 1.f : 0.f)) * dl;
      uint2 mp;
      mp.x = (unsigned int)bfbits(m0) | ((unsigned int)bfbits(m1) << 16);
      mp.y = (unsigned int)bfbits(m2) | ((unsigned int)bfbits(m3) << 16);
      const int laned = (((mt*2) + (kg >> 1)) & 3) * 16 + lm;
      *(uint2*)(mbufT + (size_t)ch*4096 + (nt*2 + (mt >> 1))*512
                + laned*8 + (kg & 1)*4) = mp;
    }
  }
}

// Phase B: serial over chunks; 32 blocks (one per bh) x 4 waves, no barriers.
__global__ __launch_bounds__(256) void rwkv_chunk_state(
    const bf16* __restrict__ mbufT, const bf16* __restrict__ ubufP,
    bf16* __restrict__ s0bufb)
{
  __shared__ bf16 Sst[4][16][72];
  const int bh = blockIdx.x;
  const int tid = threadIdx.x, wv = tid >> 6, ln = tid & 63;
  const int lm = ln & 15, kg = ln >> 4;

#pragma unroll
  for (int r = 0; r < 16; ++r) {
    Sst[wv][r][ln] = tobf(0.f);
    if (ln < 8) Sst[wv][r][64 + ln] = tobf(0.f);
  }

  bf16x8 BfA[4][2], BfB[4][2];
  uint2 UpA[4], UpB[4];
  auto prefetch = [&](bf16x8 (&Bf)[4][2], uint2 (&Up)[4], int c) {
    const size_t chp = (size_t)(bh*NCH + c) * 4096;
#pragma unroll
    for (int nt = 0; nt < 4; ++nt) {
      Bf[nt][0] = *(const bf16x8*)(mbufT + chp + (nt*2 + 0)*512 + ln*8);
      Bf[nt][1] = *(const bf16x8*)(mbufT + chp + (nt*2 + 1)*512 + ln*8);
      Up[nt]    = *(const uint2*) (ubufP + chp + (wv*4 + nt)*256 + ln*4);
    }
  };
  prefetch(BfA, UpA, 0);
  prefetch(BfB, UpB, 1);

  auto body = [&](bf16x8 (&Bf)[4][2], uint2 (&Up)[4], int c) {
    const size_t ch4 = (size_t)(bh*NCH + c) * 4096;
    const int sr = ln >> 2, sc = (ln & 3) * 16;
    uint4 v0 = *(const uint4*)&Sst[wv][sr][sc];
    uint4 v1 = *(const uint4*)&Sst[wv][sr][sc + 8];
    *(uint4*)(s0bufb + ch4 + (size_t)(wv*16 + sr)*64 + sc) = v0;
    *(uint4*)(s0bufb + ch4 + (size_t)(wv*16 + sr)*64 + sc + 8) = v1;
    bf16x8 A0 = *(const bf16x8*)&Sst[wv][lm][kg*8];
    bf16x8 A1 = *(const bf16x8*)&Sst[wv][lm][32 + kg*8];
    f32x4 acc[4];
#pragma unroll
    for (int nt = 0; nt < 4; ++nt) {
      acc[nt][0] = bf2f((unsigned short)(Up[nt].x & 0xffff));
      acc[nt][1] = bf2f((unsigned short)(Up[nt].x >> 16));
      acc[nt][2] = bf2f((unsigned short)(Up[nt].y & 0xffff));
      acc[nt][3] = bf2f((unsigned short)(Up[nt].y >> 16));
      acc[nt] = mfma16x16x32(A0, Bf[nt][0], acc[nt]);
      acc[nt] = mfma16x16x32(A1, Bf[nt][1], acc[nt]);
    }
    int cp = c + 2; if (cp > NCH - 1) cp = NCH - 1;
    prefetch(Bf, Up, cp);
#pragma unroll
    for (int nt = 0; nt < 4; ++nt)
#pragma unroll
      for (int q = 0; q < 4; ++q)
        Sst[wv][kg*4 + q][nt*16 + lm] = tobf(acc[nt][q]);
  };

  for (int cc = 0; cc < NCH; cc += 2) {
    body(BfA, UpA, cc);
    body(BfB, UpB, cc + 1);
  }
}

// Phase C: per chunk-head: SA = W*S0^T + SAll; y = Rt*S0^T + ABl*SAo + CKl*V;
// then FUSED groupnorm (group == head, size 64) + bonus + gate -> zb (bf16).
__global__ __launch_bounds__(256, 4) void rwkv_chunk_out(
    const bf16* __restrict__ rr, const bf16* __restrict__ lw,
    const bf16* __restrict__ vv, const bf16* __restrict__ kks,
    const bf16* __restrict__ gg, const bf16* __restrict__ s0bufb,
    const bf16* __restrict__ wbufb, const bf16* __restrict__ sabufb,
    const bf16* __restrict__ abybufb, const bf16* __restrict__ ckybufb,
    const float* __restrict__ faaaa, const float* __restrict__ lnw,
    const float* __restrict__ lnb, bf16* __restrict__ zb)
{
  __shared__ bf16 S0b[64][72];                    // B^T layout: [i][j]
  __shared__ bf16 ABl[LCH][40], CKl[LCH][40];     // A layouts: [s][u]
  __shared__ bf16 SAot[64][40], VlT[64][40];      // B^T layouts: [i][u]
  __shared__ float wtot[4][64];
  __shared__ float bonus[LCH];
  __shared__ float uni2f[2304];  // {Wb,Rlb}[32][72] bf16 | Yl[32][68] f32
  bf16 (*Wb)[72]  = (bf16(*)[72])uni2f;
  bf16 (*Rlb)[72] = (bf16(*)[72])((bf16*)uni2f + 2304);
  float (*Yl)[68] = (float(*)[68])uni2f;

  const int ch = blockIdx.x;
  const int c = ch & (NCH - 1), bh = ch >> 6, b = bh >> 4, h = bh & 15;
  const int tid = threadIdx.x, wv = tid >> 6, ln = tid & 63;
  const int lm = ln & 15, kg = ln >> 4;
  const size_t base = ((size_t)(b*T_ + c*LCH) * C_) + h*N_ + ln;

  float lwr[8], lcE[8];
  {
    float run = 0.f;
#pragma unroll
    for (int q = 0; q < 8; ++q) {
      lwr[q] = frombf(lw[base + (size_t)(wv*8 + q) * C_]);
      lcE[q] = run; run += lwr[q];
    }
    wtot[wv][ln] = run;
  }
  __syncthreads();
  {
    float pre = 0.f;
    for (int w2 = 0; w2 < wv; ++w2) pre += wtot[w2][ln];
#pragma unroll
    for (int q = 0; q < 8; ++q) lcE[q] += pre;
  }
  const float fa = faaaa[h*N_ + ln];
#pragma unroll
  for (int q = 0; q < 8; ++q) {
    const int s = wv*8 + q;
    const size_t off = base + (size_t)s * C_;
    float rf = frombf(rr[off]);
    Rlb[s][ln] = tobf(rf * __expf(lcE[q] + lwr[q]));
    VlT[ln][s] = vv[off];
    float rk = allred64(rf * frombf(kks[off]) * fa);   // bonus dot
    if (ln == 0) bonus[s] = rk;
  }
#pragma unroll
  for (int t = 0; t < 2; ++t) {
    int cc2 = tid*2 + t; int ri = cc2 >> 3, co = (cc2 & 7) * 8;
    *(uint4*)&S0b[ri][co] = *(const uint4*)(s0bufb + (size_t)ch*4096 + ri*64 + co);
  }
  { int ri = tid >> 3, co = (tid & 7) * 8;
    *(uint4*)&Wb[ri][co] = *(const uint4*)(wbufb + (size_t)ch*2048 + ri*64 + co); }
  if (tid < 128) {
    int ri = tid >> 2, co = (tid & 3) * 8;
    *(uint4*)&ABl[ri][co] = *(const uint4*)(abybufb + (size_t)ch*1024 + ri*32 + co);
  } else {
    int t2 = tid - 128; int ri = t2 >> 2, co = (t2 & 3) * 8;
    *(uint4*)&CKl[ri][co] = *(const uint4*)(ckybufb + (size_t)ch*1024 + ri*32 + co);
  }
  __syncthreads();

  const int mt = wv >> 1, ntb = (wv & 1) * 2;
#pragma unroll
  for (int t = 0; t < 2; ++t) {
    const int nt = ntb + t;
    const int row0 = mt*16 + kg*4, col = nt*16 + lm;
    f32x4 acc;
#pragma unroll
    for (int q = 0; q < 4; ++q)
      acc[q] = frombf(sabufb[(size_t)ch*2048 + (row0+q)*64 + col]);
#pragma unroll
    for (int ks = 0; ks < 2; ++ks) {
      bf16x8 af = *(const bf16x8*)&Wb[mt*16 + lm][ks*32 + kg*8];
      bf16x8 bq = *(const bf16x8*)&S0b[nt*16 + lm][ks*32 + kg*8];
      acc = mfma16x16x32(af, bq, acc);
    }
#pragma unroll
    for (int q = 0; q < 4; ++q) SAot[col][row0+q] = tobf(acc[q]);
  }
  __syncthreads();

  f32x4 yacc[2];
#pragma unroll
  for (int t = 0; t < 2; ++t) {
    const int nt = ntb + t;
    f32x4 acc = {};
#pragma unroll
    for (int ks = 0; ks < 2; ++ks) {
      bf16x8 af = *(const bf16x8*)&Rlb[mt*16 + lm][ks*32 + kg*8];
      bf16x8 bq = *(const bf16x8*)&S0b[nt*16 + lm][ks*32 + kg*8];
      acc = mfma16x16x32(af, bq, acc);
    }
    {
      bf16x8 af = *(const bf16x8*)&ABl[mt*16 + lm][kg*8];
      bf16x8 bq = *(const bf16x8*)&SAot[nt*16 + lm][kg*8];
      acc = mfma16x16x32(af, bq, acc);
    }
    {
      bf16x8 af = *(const bf16x8*)&CKl[mt*16 + lm][kg*8];
      bf16x8 bq = *(const bf16x8*)&VlT[nt*16 + lm][kg*8];
      acc = mfma16x16x32(af, bq, acc);
    }
    yacc[t] = acc;
  }
  __syncthreads();   // all Rlb reads done before Yl overwrites the alias

#pragma unroll
  for (int t = 0; t < 2; ++t) {
    const int nt = ntb + t;
    const int row0 = mt*16 + kg*4, col = nt*16 + lm;
#pragma unroll
    for (int q = 0; q < 4; ++q) Yl[row0 + q][col] = yacc[t][q];
  }
  __syncthreads();

  // fused groupnorm + bonus + gate: thread = (row s2, 8 cols)
  {
    const int s2 = tid >> 3, c0 = (tid & 7) * 8;
    float yv[8]; float sum = 0.f;
#pragma unroll
    for (int i = 0; i < 8; ++i) { yv[i] = Yl[s2][c0 + i]; sum += yv[i]; }
#pragma unroll
    for (int m = 1; m < 8; m <<= 1) sum += __shfl_xor(sum, m, 64);
    const float mean = sum * (1.f/64.f);
    float ss = 0.f;
#pragma unroll
    for (int i = 0; i < 8; ++i) { float d = yv[i] - mean; ss += d * d; }
#pragma unroll
    for (int m = 1; m < 8; m <<= 1) ss += __shfl_xor(ss, m, 64);
    const float inv = rsqrtf(ss * (1.f/64.f) + 6.4e-4f);
    const float bn = bonus[s2];
    const size_t trow = (size_t)(b*T_ + c*LCH + s2) * C_ + h*N_ + c0;
    bf16 zout[8];
#pragma unroll
    for (int i = 0; i < 8; ++i) {
      float gn = (yv[i] - mean) * inv * lnw[h*N_ + c0 + i] + lnb[h*N_ + c0 + i];
      float z = (gn + bn * frombf(VlT[c0 + i][s2])) * frombf(gg[trow + i]);
      zout[i] = tobf(z);
    }
    *(uint4*)(zb + trow) = *(const uint4*)&zout[0];
  }
}

// ---------------- driver ----------------------------------------------------
extern "C" void kernel_launch(void* const* d_in, const int* in_sizes, int n_in,
                              void* d_out, int out_size, void* d_ws, size_t ws_size,
                              hipStream_t stream)
{
  const float* x     = (const float*)d_in[0];
  const float* maa_x = (const float*)d_in[1];
  const float* maa_r = (const float*)d_in[2];
  const float* maa_w = (const float*)d_in[3];
  const float* maa_k = (const float*)d_in[4];
  const float* maa_v = (const float*)d_in[5];
  const float* maa_a = (const float*)d_in[6];
  const float* maa_g = (const float*)d_in[7];
  const float* tdec  = (const float*)d_in[8];
  const float* faaaa = (const float*)d_in[9];
  const float* aaaaa = (const float*)d_in[10];
  const float* maa_w1= (const float*)d_in[11];
  const float* maa_w2= (const float*)d_in[12];
  const float* dec_w1= (const float*)d_in[13];
  const float* dec_w2= (const float*)d_in[14];
  const float* aaa_w1= (const float*)d_in[15];
  const float* aaa_w2= (const float*)d_in[16];
  const float* kkk_w1= (const float*)d_in[17];
  const float* kkk_w2= (const float*)d_in[18];
  const float* gate_w1=(const float*)d_in[19];
  const float* gate_w2=(const float*)d_in[20];
  const float* W_r   = (const float*)d_in[21];
  const float* W_k   = (const float*)d_in[22];
  const float* W_v   = (const float*)d_in[23];
  const float* W_o   = (const float*)d_in[24];
  const float* lnw   = (const float*)d_in[25];
  const float* lnb   = (const float*)d_in[26];

  char* ws = (char*)d_ws;
  size_t cur = 0;
  auto alloc = [&](size_t bytes) -> void* {
    void* p = ws + cur; cur += (bytes + 255) & ~(size_t)255; return p;
  };
  const size_t HBT = (size_t)BT_ * C_ * 2;  // bf16 activation buffer

  // ---- persistent (activations bf16) ----
  bf16* rb   = (bf16*)alloc(HBT);
  bf16* kb   = (bf16*)alloc(HBT);   // UNscaled k (for kk_normalize)
  bf16* ksb  = (bf16*)alloc(HBT);   // scaled k (for scan + bonus)
  bf16* vb   = (bf16*)alloc(HBT);
  bf16* gbb  = (bf16*)alloc(HBT);
  bf16* WtR  = (bf16*)alloc((size_t)C_*C_*2);
  bf16* WtK  = (bf16*)alloc((size_t)C_*C_*2);
  bf16* WtV  = (bf16*)alloc((size_t)C_*C_*2);
  bf16* WtO  = (bf16*)alloc((size_t)C_*C_*2);
  bf16* w1t  = (bf16*)alloc((size_t)192*C_*2);
  bf16* w2t  = (bf16*)alloc((size_t)6*C_*32*2);
  bf16* d1t  = (bf16*)alloc((size_t)64*C_*2);
  bf16* d2t  = (bf16*)alloc((size_t)C_*64*2);
  bf16* a1t  = (bf16*)alloc((size_t)64*C_*2);
  bf16* a2t  = (bf16*)alloc((size_t)C_*64*2);
  bf16* k1t  = (bf16*)alloc((size_t)64*C_*2);
  bf16* k2t  = (bf16*)alloc((size_t)C_*64*2);
  bf16* g1t  = (bf16*)alloc((size_t)128*C_*2);
  bf16* g2t  = (bf16*)alloc((size_t)C_*128*2);
  bf16* lwb  = (bf16*)alloc(HBT);
  bf16* kkb  = (bf16*)alloc(HBT);
  bf16* aamt = (bf16*)alloc(HBT);
  bf16* s0bufb = kkb;                 // overlay: kkb+aamt dead after chunk_pre

  // ---- union region ----
  const size_t ubase = cur;
  bf16* mtmpb = (bf16*)alloc(HBT);
  bf16* xinb = (bf16*)alloc(HBT);
  bf16* xb   = (bf16*)alloc(HBT);
  bf16* mixb = (bf16*)alloc((size_t)BT_*192*2);
  bf16* xbr[6];
  for (int s = 0; s < 6; ++s) xbr[s] = (bf16*)alloc(HBT);
  bf16* h64k = (bf16*)alloc((size_t)BT_*64*2);
  bf16* h64d = (bf16*)alloc((size_t)BT_*64*2);
  bf16* h64a = (bf16*)alloc((size_t)BT_*64*2);
  bf16* h128b= (bf16*)alloc((size_t)BT_*128*2);
  const size_t tmp_end = cur;
  cur = ubase;  // overlay
  bf16*  wbufb   = (bf16*)alloc((size_t)CHD*2048*2);
  bf16*  sabufb  = (bf16*)alloc((size_t)CHD*2048*2);
  bf16*  abybufb = (bf16*)alloc((size_t)CHD*1024*2);
  bf16*  ckybufb = (bf16*)alloc((size_t)CHD*1024*2);
  bf16*  ubufP   = (bf16*)alloc((size_t)CHD*4096*2);
  bf16*  mbufT   = (bf16*)alloc((size_t)CHD*4096*2);
  bf16*  zb      = (bf16*)ubufP;   // alias: ubufP dead after chunk_state
  if (tmp_end > cur) cur = tmp_end;
  const size_t need = cur;
  (void)in_sizes; (void)n_in; (void)out_size;

  if (ws_size < need) {
    ws_diag<<<1, 1, 0, stream>>>((float)ws_size, (float)need, (float*)d_out);
    return;
  }

  PrepArgs pa;
  pa.src[0] = W_r;  pa.dst[0] = WtR;
  pa.src[1] = W_k;  pa.dst[1] = WtK;
  pa.src[2] = W_v;  pa.dst[2] = WtV;
  pa.src[3] = W_o;  pa.dst[3] = WtO;
  pa.src[4] = maa_w1; pa.dst[4] = w1t;
  for (int s = 0; s < 6; ++s) { pa.src[5+s] = maa_w2 + (size_t)s*32*C_; pa.dst[5+s] = w2t + (size_t)s*C_*32; }
  pa.src[11] = dec_w1; pa.dst[11] = d1t;
  pa.src[12] = dec_w2; pa.dst[12] = d2t;
  pa.src[13] = aaa_w1; pa.dst[13] = a1t;
  pa.src[14] = aaa_w2; pa.dst[14] = a2t;
  pa.src[15] = kkk_w1; pa.dst[15] = k1t;
  pa.src[16] = kkk_w2; pa.dst[16] = k2t;
  pa.src[17] = gate_w1; pa.dst[17] = g1t;
  pa.src[18] = gate_w2; pa.dst[18] = g2t;
  prep_weights<<<dim3(1024, 19), 256, 0, stream>>>(pa);

  const int EW_GRID = (BT_ * C_) / 256;  // 16384
  xin_k<<<EW_GRID, 256, 0, stream>>>(x, maa_x, xinb, xb);

  gemm_bt<1><<<dim3(64, 3), 256, 0, stream>>>(xinb, C_, w1t, C_, mixb, 192, C_);

  Mix6Args ma;
  ma.maa[0] = maa_r; ma.maa[1] = maa_w; ma.maa[2] = maa_k;
  ma.maa[3] = maa_v; ma.maa[4] = maa_a; ma.maa[5] = maa_g;
  for (int s = 0; s < 6; ++s) ma.out[s] = xbr[s];
  mix_combine<<<dim3(64, 16, 6), 256, 0, stream>>>(mixb, w2t, xb, ma);

  // r, k, v batched (one launch, bf16 out)
  RkvArgs ra;
  ra.A[0] = xbr[0]; ra.Bt[0] = WtR; ra.Cq[0] = rb;
  ra.A[1] = xbr[2]; ra.Bt[1] = WtK; ra.Cq[1] = kb;
  ra.A[2] = xbr[3]; ra.Bt[2] = WtV; ra.Cq[2] = vb;
  gemm128_rkv<<<dim3(32, 8, 3), 256, 0, stream>>>(ra);

  // batched small projections: k1 (tanh), d1 (tanh), a1 (raw), g1 (tanh)
  Proj4Args p4;
  p4.A[0] = xbr[2]; p4.Bt[0] = k1t; p4.out[0] = h64k; p4.N[0] = 64;  p4.tnh[0] = 1;
  p4.A[1] = xbr[1]; p4.Bt[1] = d1t; p4.out[1] = h64d; p4.N[1] = 64;  p4.tnh[1] = 1;
  p4.A[2] = xbr[4]; p4.Bt[2] = a1t; p4.out[2] = h64a; p4.N[2] = 64;  p4.tnh[2] = 0;
  p4.A[3] = xbr[5]; p4.Bt[3] = g1t; p4.out[3] = h128b; p4.N[3] = 128; p4.tnh[3] = 1;
  proj4<<<dim3(64, 2, 4), 256, 0, stream>>>(p4);

  // batched epilogue GEMMs: z0 kk-add, z1 w-finalize (kb->ksb), z2 a, z3 g
  Ep4Args ea;
  ea.A[0] = h64k;  ea.Bt[0] = k2t; ea.Cout[0] = mtmpb; ea.K[0] = 64;  ea.epi[0] = 2; ea.aux[0] = nullptr;
  ea.A[1] = h64d;  ea.Bt[1] = d2t; ea.Cout[1] = lwb;   ea.K[1] = 64;  ea.epi[1] = 5; ea.aux[1] = tdec;
  ea.A[2] = h64a;  ea.Bt[2] = a2t; ea.Cout[2] = aamt;  ea.K[2] = 64;  ea.epi[2] = 4; ea.aux[2] = aaaaa;
  ea.A[3] = h128b; ea.Bt[3] = g2t; ea.Cout[3] = gbb;   ea.K[3] = 128; ea.epi[3] = 2; ea.aux[3] = nullptr;
  ea.kin = kb; ea.ksout = ksb;
  gemm128_ep4<<<dim3(32, 8, 4), 256, 0, stream>>>(ea);

  kk_normalize<<<BT_, 256, 0, stream>>>(kb, mtmpb, kkb);

  // ---- chunked scan (scaled k = ksb) ----
  rwkv_chunk_pre<<<CHD, 256, 0, stream>>>(rb, lwb, ksb, kkb, aamt, vb,
      wbufb, sabufb, abybufb, ckybufb, ubufP, mbufT);
  rwkv_chunk_state<<<32, 256, 0, stream>>>(mbufT, ubufP, s0bufb);
  rwkv_chunk_out<<<CHD, 256, 0, stream>>>(rb, lwb, vb, ksb, gbb, s0bufb,
      wbufb, sabufb, abybufb, ckybufb, faaaa, lnw, lnb, zb);

  gemm128<0><<<dim3(32, 8), 256, 0, stream>>>(zb, C_, WtO, C_, d_out, C_, C_);
}